// Round 1
// 665.337 us; speedup vs baseline: 1.1225x; 1.1225x over previous
//
#include <hip/hip_runtime.h>
#include <hip/hip_bf16.h>
#include <math.h>

#define BB 8
#define NN 2048
#define FF 64
#define DD 6
#define NSAMP 64
#define TOPK 16
#define NHEAD 8
#define HD 8
#define NLAYER 2
#define EPSF 1e-5f
#define R2 0.09f

typedef short short8 __attribute__((ext_vector_type(8)));
typedef float f32x4 __attribute__((ext_vector_type(4)));

// split-pack: u32 = (bf16_hi << 16) | bf16_lo, both RNE. x ≈ hi + lo, err ~2^-16 rel.
__device__ inline unsigned pk2(float x) {
  unsigned b = __float_as_uint(x);
  unsigned hi = (b + 0x7fffu + ((b >> 16) & 1u)) >> 16;
  float r = x - __uint_as_float(hi << 16);
  unsigned c = __float_as_uint(r);
  unsigned lo = (c + 0x7fffu + ((c >> 16) & 1u)) >> 16;
  return (hi << 16) | lo;
}

__device__ inline void unpk(const unsigned* p, short8& hi, short8& lo) {
  #pragma unroll
  for (int i = 0; i < 8; ++i) {
    hi[i] = (short)(p[i] >> 16);
    lo[i] = (short)(p[i] & 0xffffu);
  }
}

// ---------------- transpose sortvec (B,1,F,N) -> x (B,N,F) ----------------
__global__ void k_transpose(const float* __restrict__ sv, float* __restrict__ x) {
  int i = blockIdx.x * 256 + threadIdx.x;
  if (i >= BB * NN * FF) return;
  int f = i % FF;
  int n = (i / FF) % NN;
  int b = i / (FF * NN);
  x[i] = sv[(b * FF + f) * NN + n];
}

// ---------------- pack fp32 weights -> split-bf16 u32 ----------------
__global__ void k_wpack(const float* __restrict__ w, unsigned* __restrict__ o, int n) {
  int i = blockIdx.x * 256 + threadIdx.x;
  if (i < n) o[i] = pk2(w[i]);
}

// ---------------- tiled GEMM: qkv[row][192] = x[row][64] @ win^T + bin ----------
__global__ void k_qkv2(const float* __restrict__ x, const float* __restrict__ win,
                       const float* __restrict__ bin, float* __restrict__ qkv) {
  __shared__ float xs[64 * 68];
  __shared__ float ws[64 * 68];
  int row0 = blockIdx.x * 64, col0 = blockIdx.y * 64;
  int t = threadIdx.x;
  #pragma unroll
  for (int i = 0; i < 4; ++i) {
    int q = t + i * 256, r = q >> 4, c = (q & 15) * 4;
    *(float4*)(xs + r * 68 + c) = *(const float4*)(x + (size_t)(row0 + r) * 64 + c);
    *(float4*)(ws + r * 68 + c) = *(const float4*)(win + (size_t)(col0 + r) * 64 + c);
  }
  __syncthreads();
  int tx = t & 15, ty = t >> 4;
  float acc[4][4] = {};
  for (int f = 0; f < 64; f += 4) {
    float4 xv[4], wv[4];
    #pragma unroll
    for (int ri = 0; ri < 4; ++ri) xv[ri] = *(const float4*)(xs + (ty * 4 + ri) * 68 + f);
    #pragma unroll
    for (int ci = 0; ci < 4; ++ci) wv[ci] = *(const float4*)(ws + (tx + 16 * ci) * 68 + f);
    #pragma unroll
    for (int ri = 0; ri < 4; ++ri)
      #pragma unroll
      for (int ci = 0; ci < 4; ++ci)
        acc[ri][ci] += xv[ri].x * wv[ci].x + xv[ri].y * wv[ci].y +
                       xv[ri].z * wv[ci].z + xv[ri].w * wv[ci].w;
  }
  #pragma unroll
  for (int ri = 0; ri < 4; ++ri)
    #pragma unroll
    for (int ci = 0; ci < 4; ++ci) {
      int r = row0 + ty * 4 + ri, c = col0 + tx + 16 * ci;
      qkv[(size_t)r * 192 + c] = acc[ri][ci] + bin[c];
    }
}

// ---- attention v6: single-plane bf16 MFMA flash. Wave = 16 queries x 2048
// keys. bf16 rounding of K/V/P is statistically safe here (near-uniform
// softmax over 2048 keys averages independent roundings to ~1e-5; ones-row
// makes num/denom use the same p-tilde). K staged in 40-u16 rows zero-padded
// to k=32 so the B-frag needs no masking. 1 mfma per QK half, 1 per PV.
__global__ void __launch_bounds__(256, 5)
k_attn6(const float* __restrict__ qkv, float* __restrict__ a) {
  __shared__ __attribute__((aligned(16))) unsigned short kb16[256 * 40];  // 20 KB
  __shared__ __attribute__((aligned(16))) unsigned short vb16[9 * 264];   // 4.6 KB
  __shared__ __attribute__((aligned(16))) unsigned short pb16[4 * 16 * 40]; // 5 KB
  int t = threadIdx.x;
  int lane = t & 63, w = t >> 6;
  int nIdx = lane & 15, lq = lane >> 4;
  int h = blockIdx.y, b = blockIdx.z;
  int qwb = blockIdx.x * 64 + w * 16;
  const float kf = 0.35355339059327373f * 1.4426950408889634f;  // scale*log2e
  // zero K pad (d=8..31 stays zero; staging writes only d<8)
  {
    unsigned* kz = (unsigned*)kb16;
    #pragma unroll
    for (int i = 0; i < 20; ++i) kz[t + i * 256] = 0u;
  }
  // Q A-fragment: quad0 lanes hold k=0..7 (RNE bf16), others zero
  short8 qF = {0, 0, 0, 0, 0, 0, 0, 0};
  if (lq == 0) {
    const float* qr = qkv + ((size_t)(b * NN + qwb + nIdx)) * 192 + h * HD;
    #pragma unroll
    for (int j = 0; j < 8; ++j) {
      float v = qr[j] * kf;
      unsigned bb = __float_as_uint(v);
      qF[j] = (short)((bb + 0x7fffu + ((bb >> 16) & 1u)) >> 16);
    }
  }
  f32x4 acc = {0.f, 0.f, 0.f, 0.f};
  unsigned short* mypb = pb16 + w * 640;
  for (int kc = 0; kc < NN; kc += 256) {
    __syncthreads();
    // stage K chunk: pairs (d0,d0+1) -> one u32 (trunc bf16)
    #pragma unroll
    for (int i = 0; i < 4; ++i) {
      int p = t + i * 256;               // 0..1023
      int key = p >> 2, d0 = (p & 3) * 2;
      const float* src = qkv + ((size_t)(b * NN + kc + key)) * 192 + 64 + h * HD + d0;
      float2 f = *(const float2*)(src);
      unsigned u = (__float_as_uint(f.x) >> 16) | (__float_as_uint(f.y) & 0xffff0000u);
      *(unsigned*)(kb16 + key * 40 + d0) = u;
    }
    // stage V^T chunk: pairs of keys -> one u32
    #pragma unroll
    for (int i = 0; i < 4; ++i) {
      int p = t + i * 256;
      int d = p >> 7, kp = p & 127;
      int key0 = 2 * kp;
      float f0 = qkv[((size_t)(b * NN + kc + key0)) * 192 + 128 + h * HD + d];
      float f1 = qkv[((size_t)(b * NN + kc + key0 + 1)) * 192 + 128 + h * HD + d];
      unsigned u = (__float_as_uint(f0) >> 16) | (__float_as_uint(f1) & 0xffff0000u);
      *(unsigned*)(vb16 + d * 264 + key0) = u;
    }
    if (t < 132) ((unsigned*)(vb16 + 8 * 264))[t] = 0x3f803f80u;  // ones row
    __syncthreads();
    for (int s = 0; s < 8; ++s) {
      int kb = s * 32;
      #pragma unroll
      for (int half = 0; half < 2; ++half) {
        int key = kb + half * 16 + nIdx;
        short8 bF = *(const short8*)(kb16 + key * 40 + lq * 8);  // zeros for k>=8
        f32x4 c = {0.f, 0.f, 0.f, 0.f};
        c = __builtin_amdgcn_mfma_f32_16x16x32_bf16(qF, bF, c, 0, 0, 0);
        #pragma unroll
        for (int r = 0; r < 4; ++r) {
          float p = __builtin_amdgcn_exp2f(c[r]);
          int row = lq * 4 + r;
          mypb[row * 40 + half * 16 + nIdx] = (unsigned short)(__float_as_uint(p) >> 16);
        }
      }
      // C->A readback (same-wave LDS)
      short8 pa = *(const short8*)(mypb + nIdx * 40 + lq * 8);
      int vn = nIdx < 9 ? nIdx : 8;
      short8 vb = *(const short8*)(vb16 + vn * 264 + kb + lq * 8);
      acc = __builtin_amdgcn_mfma_f32_16x16x32_bf16(pa, vb, acc, 0, 0, 0);
    }
  }
  // epilogue: col 8 holds l = sum(p); divide, scatter cols 0..7
  #pragma unroll
  for (int r = 0; r < 4; ++r) {
    float lr = __shfl(acc[r], (lane & 48) | 8);
    if (nIdx < 8) {
      int row = qwb + lq * 4 + r;
      a[((size_t)(b * NN + row)) * 64 + h * HD + nIdx] = acc[r] / lr;
    }
  }
}

// ------- proj + residual + LN, tiled GEMM ---------
__global__ void k_proj2(const float* __restrict__ a, const float* __restrict__ wout,
                        const float* __restrict__ bout, const float* __restrict__ g,
                        const float* __restrict__ be, float* __restrict__ x) {
  __shared__ float xs[64 * 68];
  __shared__ float ws[64 * 68];
  int row0 = blockIdx.x * 64;
  int t = threadIdx.x;
  #pragma unroll
  for (int i = 0; i < 4; ++i) {
    int q = t + i * 256, r = q >> 4, c = (q & 15) * 4;
    *(float4*)(xs + r * 68 + c) = *(const float4*)(a + (size_t)(row0 + r) * 64 + c);
    *(float4*)(ws + r * 68 + c) = *(const float4*)(wout + r * 64 + c);
  }
  __syncthreads();
  int tx = t & 15, ty = t >> 4;
  float acc[4][4] = {};
  for (int f = 0; f < 64; f += 4) {
    float4 xv[4], wv[4];
    #pragma unroll
    for (int ri = 0; ri < 4; ++ri) xv[ri] = *(const float4*)(xs + (ty * 4 + ri) * 68 + f);
    #pragma unroll
    for (int ci = 0; ci < 4; ++ci) wv[ci] = *(const float4*)(ws + (tx + 16 * ci) * 68 + f);
    #pragma unroll
    for (int ri = 0; ri < 4; ++ri)
      #pragma unroll
      for (int ci = 0; ci < 4; ++ci)
        acc[ri][ci] += xv[ri].x * wv[ci].x + xv[ri].y * wv[ci].y +
                       xv[ri].z * wv[ci].z + xv[ri].w * wv[ci].w;
  }
  #pragma unroll
  for (int ri = 0; ri < 4; ++ri) {
    int rl = ty * 4 + ri;
    float val[4], s = 0.f, sq = 0.f;
    #pragma unroll
    for (int ci = 0; ci < 4; ++ci) {
      int c = tx + 16 * ci;
      val[ci] = x[(size_t)(row0 + rl) * 64 + c] + bout[c] + acc[ri][ci];
      s += val[ci]; sq += val[ci] * val[ci];
    }
    #pragma unroll
    for (int off = 1; off < 16; off <<= 1) { s += __shfl_xor(s, off); sq += __shfl_xor(sq, off); }
    float mean = s * (1.f / 64.f);
    float var = sq * (1.f / 64.f) - mean * mean;
    float rstd = rsqrtf(var + EPSF);
    #pragma unroll
    for (int ci = 0; ci < 4; ++ci) {
      int c = tx + 16 * ci;
      x[(size_t)(row0 + rl) * 64 + c] = (val[ci] - mean) * rstd * g[c] + be[c];
    }
  }
}

// ------- FFN v4: MFMA split-bf16 (hi*hi + hi*lo + lo*hi), split-K grid (256,4) ----
__global__ void __launch_bounds__(256, 4)
k_ffn4(const float* __restrict__ x, const unsigned* __restrict__ w1p,
       const float* __restrict__ b1, const unsigned* __restrict__ w2p,
       float* __restrict__ part) {
  __shared__ unsigned xs[64 * 68];
  __shared__ unsigned ws[64 * 68];
  __shared__ unsigned hs[64 * 68];
  __shared__ float b1s[64];
  int row0 = blockIdx.x * 64;
  int ks = blockIdx.y;
  int t = threadIdx.x;
  int lane = t & 63, wv = t >> 6;
  int lm = lane & 15, lq = lane >> 4;
  #pragma unroll
  for (int i = 0; i < 4; ++i) {
    int q = t + i * 256, r = q >> 4, c = (q & 15) * 4;
    float4 v = *(const float4*)(x + (size_t)(row0 + r) * 64 + c);
    xs[r * 68 + c]     = pk2(v.x);
    xs[r * 68 + c + 1] = pk2(v.y);
    xs[r * 68 + c + 2] = pk2(v.z);
    xs[r * 68 + c + 3] = pk2(v.w);
  }
  f32x4 acc[4];
  #pragma unroll
  for (int tn = 0; tn < 4; ++tn) acc[tn] = (f32x4){0.f, 0.f, 0.f, 0.f};

  for (int ch = 0; ch < 8; ++ch) {
    int kc = (ks * 8 + ch) * 64;
    uint4 rw[4];
    #pragma unroll
    for (int i = 0; i < 4; ++i) {
      int q = t + i * 256, r = q >> 4, c = (q & 15) * 4;
      rw[i] = *(const uint4*)(w1p + (size_t)(kc + r) * 64 + c);
    }
    float rbv = 0.f;
    if (t < 64) rbv = b1[kc + t];
    __syncthreads();  // (A)
    #pragma unroll
    for (int i = 0; i < 4; ++i) {
      int q = t + i * 256, r = q >> 4, c = (q & 15) * 4;
      *(uint4*)(ws + r * 68 + c) = rw[i];
    }
    if (t < 64) b1s[t] = rbv;
    __syncthreads();  // (B)
    f32x4 h4[4];
    #pragma unroll
    for (int tn = 0; tn < 4; ++tn) h4[tn] = (f32x4){0.f, 0.f, 0.f, 0.f};
    #pragma unroll
    for (int kb = 0; kb < 64; kb += 32) {
      unsigned ap[8];
      const unsigned* abase = xs + (wv * 16 + lm) * 68 + kb + lq * 8;
      *(uint4*)(ap)     = *(const uint4*)(abase);
      *(uint4*)(ap + 4) = *(const uint4*)(abase + 4);
      short8 ahi, alo; unpk(ap, ahi, alo);
      #pragma unroll
      for (int tn = 0; tn < 4; ++tn) {
        unsigned bp[8];
        const unsigned* bbase = ws + (tn * 16 + lm) * 68 + kb + lq * 8;
        *(uint4*)(bp)     = *(const uint4*)(bbase);
        *(uint4*)(bp + 4) = *(const uint4*)(bbase + 4);
        short8 bhi, blo; unpk(bp, bhi, blo);
        h4[tn] = __builtin_amdgcn_mfma_f32_16x16x32_bf16(ahi, bhi, h4[tn], 0, 0, 0);
        h4[tn] = __builtin_amdgcn_mfma_f32_16x16x32_bf16(ahi, blo, h4[tn], 0, 0, 0);
        h4[tn] = __builtin_amdgcn_mfma_f32_16x16x32_bf16(alo, bhi, h4[tn], 0, 0, 0);
      }
    }
    #pragma unroll
    for (int tn = 0; tn < 4; ++tn)
      #pragma unroll
      for (int r = 0; r < 4; ++r) {
        float hv = fmaxf(h4[tn][r] + b1s[tn * 16 + lm], 0.f);
        hs[(wv * 16 + lq * 4 + r) * 68 + tn * 16 + lm] = pk2(hv);
      }
    #pragma unroll
    for (int i = 0; i < 4; ++i) {
      int q = t + i * 256, j = q >> 4, c = (q & 15) * 4;
      rw[i] = *(const uint4*)(w2p + (size_t)j * 2048 + kc + c);
    }
    __syncthreads();  // (C)
    #pragma unroll
    for (int i = 0; i < 4; ++i) {
      int q = t + i * 256, j = q >> 4, c = (q & 15) * 4;
      *(uint4*)(ws + j * 68 + c) = rw[i];
    }
    __syncthreads();  // (D)
    #pragma unroll
    for (int kb = 0; kb < 64; kb += 32) {
      unsigned ap[8];
      const unsigned* abase = hs + (wv * 16 + lm) * 68 + kb + lq * 8;
      *(uint4*)(ap)     = *(const uint4*)(abase);
      *(uint4*)(ap + 4) = *(const uint4*)(abase + 4);
      short8 ahi, alo; unpk(ap, ahi, alo);
      #pragma unroll
      for (int tn = 0; tn < 4; ++tn) {
        unsigned bp[8];
        const unsigned* bbase = ws + (tn * 16 + lm) * 68 + kb + lq * 8;
        *(uint4*)(bp)     = *(const uint4*)(bbase);
        *(uint4*)(bp + 4) = *(const uint4*)(bbase + 4);
        short8 bhi, blo; unpk(bp, bhi, blo);
        acc[tn] = __builtin_amdgcn_mfma_f32_16x16x32_bf16(ahi, bhi, acc[tn], 0, 0, 0);
        acc[tn] = __builtin_amdgcn_mfma_f32_16x16x32_bf16(ahi, blo, acc[tn], 0, 0, 0);
        acc[tn] = __builtin_amdgcn_mfma_f32_16x16x32_bf16(alo, bhi, acc[tn], 0, 0, 0);
      }
    }
  }
  float* pb = part + (size_t)ks * (BB * NN * 64);
  #pragma unroll
  for (int tn = 0; tn < 4; ++tn)
    #pragma unroll
    for (int r = 0; r < 4; ++r)
      pb[(size_t)(row0 + wv * 16 + lq * 4 + r) * 64 + tn * 16 + lm] = acc[tn][r];
}

// ------- combine 4 partials + residual + b2 + LN; one wave per row ---------
__global__ void k_ffn_ln(const float* __restrict__ part, const float* __restrict__ b2,
                         const float* __restrict__ g, const float* __restrict__ be,
                         float* __restrict__ x) {
  int row = blockIdx.x * 4 + (threadIdx.x >> 6);
  int j = threadIdx.x & 63;
  size_t o = (size_t)row * 64 + j;
  const size_t S = (size_t)BB * NN * 64;
  float val = x[o] + b2[j] + ((part[o] + part[o + S]) + (part[o + 2 * S] + part[o + 3 * S]));
  float s = val;
  for (int off = 32; off; off >>= 1) s += __shfl_xor(s, off);
  s *= (1.f / 64.f);
  float d = val - s;
  float v = d * d;
  for (int off = 32; off; off >>= 1) v += __shfl_xor(v, off);
  v *= (1.f / 64.f);
  x[o] = d * rsqrtf(v + EPSF) * g[j] + be[j];
}

// ------- score head tiled ----------
__global__ void k_fg2(const float* __restrict__ x,
                      const float* __restrict__ w0, const float* __restrict__ b0, const float* __restrict__ bn0,
                      const float* __restrict__ w1, const float* __restrict__ b1, const float* __restrict__ bn1,
                      const float* __restrict__ w2, const float* __restrict__ b2, const float* __restrict__ bn2,
                      float* __restrict__ scores) {
  __shared__ float xs[64 * 68];
  __shared__ float ws[64 * 68];
  __shared__ float s0s[64 * 68];
  __shared__ float s1s[64 * 20];
  int row0 = blockIdx.x * 64;
  int t = threadIdx.x;
  #pragma unroll
  for (int i = 0; i < 4; ++i) {
    int q = t + i * 256, r = q >> 4, c = (q & 15) * 4;
    *(float4*)(xs + r * 68 + c) = *(const float4*)(x + (size_t)(row0 + r) * 64 + c);
    *(float4*)(ws + r * 68 + c) = *(const float4*)(w0 + r * 64 + c);
  }
  __syncthreads();
  int tx = t & 15, ty = t >> 4;
  float acc[4][4] = {};
  for (int f = 0; f < 64; f += 4) {
    float4 xv[4], wv[4];
    #pragma unroll
    for (int ri = 0; ri < 4; ++ri) xv[ri] = *(const float4*)(xs + (ty * 4 + ri) * 68 + f);
    #pragma unroll
    for (int ci = 0; ci < 4; ++ci) wv[ci] = *(const float4*)(ws + (tx + 16 * ci) * 68 + f);
    #pragma unroll
    for (int ri = 0; ri < 4; ++ri)
      #pragma unroll
      for (int ci = 0; ci < 4; ++ci)
        acc[ri][ci] += xv[ri].x * wv[ci].x + xv[ri].y * wv[ci].y +
                       xv[ri].z * wv[ci].z + xv[ri].w * wv[ci].w;
  }
  #pragma unroll
  for (int ri = 0; ri < 4; ++ri)
    #pragma unroll
    for (int ci = 0; ci < 4; ++ci) {
      int c = tx + 16 * ci;
      float sc = bn0[c] * rsqrtf(bn0[192 + c] + EPSF);
      float v = (acc[ri][ci] + b0[c] - bn0[128 + c]) * sc + bn0[64 + c];
      s0s[(ty * 4 + ri) * 68 + c] = fmaxf(v, 0.f);
    }
  __syncthreads();
  {
    int rl = t & 63, j0 = t >> 6;
    #pragma unroll
    for (int i = 0; i < 4; ++i) {
      int j = j0 + 4 * i;
      float s = b1[j];
      const float* wr = w1 + j * 64;
      #pragma unroll 16
      for (int c = 0; c < 64; ++c) s += s0s[rl * 68 + c] * wr[c];
      float sc = bn1[j] * rsqrtf(bn1[48 + j] + EPSF);
      s = (s - bn1[32 + j]) * sc + bn1[16 + j];
      s1s[rl * 20 + j] = fmaxf(s, 0.f);
    }
  }
  __syncthreads();
  if (t < 64) {
    float s = b2[0];
    #pragma unroll
    for (int o = 0; o < 16; ++o) s += s1s[t * 20 + o] * w2[o];
    float sc = bn2[0] * rsqrtf(bn2[3] + EPSF);
    s = (s - bn2[2]) * sc + bn2[1];
    scores[row0 + t] = fmaxf(s, 0.f);
  }
}

// ---- top-k (k=16) ----
__global__ void k_topk2(const float* __restrict__ scores, int* __restrict__ idx,
                        float* __restrict__ out_idx) {
  int b = blockIdx.x, t = threadIdx.x;
  float v[8];
  int base = b * NN;
  #pragma unroll
  for (int u = 0; u < 8; ++u) v[u] = scores[base + t + 256 * u];
  __shared__ float wvs[4];
  __shared__ int wis[4];
  __shared__ int winner;
  unsigned taken = 0;
  for (int r = 0; r < TOPK; ++r) {
    float best = -1e30f; int bi = 1 << 30;
    #pragma unroll
    for (int u = 0; u < 8; ++u) {
      if (!((taken >> u) & 1)) {
        float vv = v[u]; int ii = t + 256 * u;
        if (vv > best || (vv == best && ii < bi)) { best = vv; bi = ii; }
      }
    }
    for (int off = 32; off; off >>= 1) {
      float ov = __shfl_xor(best, off);
      int oi = __shfl_xor(bi, off);
      if (ov > best || (ov == best && oi < bi)) { best = ov; bi = oi; }
    }
    if ((t & 63) == 0) { wvs[t >> 6] = best; wis[t >> 6] = bi; }
    __syncthreads();
    if (t == 0) {
      float B = wvs[0]; int I = wis[0];
      #pragma unroll
      for (int q = 1; q < 4; ++q)
        if (wvs[q] > B || (wvs[q] == B && wis[q] < I)) { B = wvs[q]; I = wis[q]; }
      winner = I;
      idx[b * TOPK + r] = I;
      out_idx[b * TOPK + r] = (float)I;
    }
    __syncthreads();
    int w = winner;
    if ((w & 255) == t) taken |= 1u << (w >> 8);
  }
}

// ---------------- ball query + 3 conv stages, v2: 512 threads (8 waves) per (b,k).
// Ball query parallelized 8-way (chunked ballot compaction, per-chunk cap 64 is
// exact: any dropped element has >=64 lower-index elements in its own chunk).
// conv0: 4 lanes/ch (float2), conv1: 2 lanes/ch (float4), conv2: 1 lane/ch with
// 4 accumulators (float4). Kills the 3300-deep serial FMA chain of v1.
__global__ void __launch_bounds__(512)
k_group(const float* __restrict__ inp, const int* __restrict__ idx,
        const float* __restrict__ w0, const float* __restrict__ b0, const float* __restrict__ bn0,
        const float* __restrict__ w1, const float* __restrict__ b1, const float* __restrict__ bn1,
        const float* __restrict__ w2, const float* __restrict__ b2, const float* __restrict__ bn2,
        float* __restrict__ r2g) {
  __shared__ int swave[8 * 64];
  __shared__ int scnt[8];
  __shared__ int gidx[NSAMP];
  __shared__ __attribute__((aligned(16))) float gsh[65 * DD];  // 390
  __shared__ __attribute__((aligned(16))) float r0[128];
  __shared__ __attribute__((aligned(16))) float r1[256];
  int k = blockIdx.x, b = blockIdx.y;
  int t = threadIdx.x;
  int lane = t & 63, w = t >> 6;
  int qn = idx[b * TOPK + k];
  const float* px = inp + (size_t)b * DD * NN;
  float qx = px[qn], qy = px[NN + qn], qz = px[2 * NN + qn];
  // --- ball query: wave w scans points [w*256, w*256+256), ascending ---
  {
    int cnt = 0;
    #pragma unroll
    for (int i = 0; i < 4; ++i) {
      int n = w * 256 + i * 64 + lane;
      float dx = px[n] - qx, dy = px[NN + n] - qy, dz = px[2 * NN + n] - qz;
      bool flag = (dx * dx + dy * dy + dz * dz <= R2);
      unsigned long long m = __ballot(flag);
      int pos = cnt + __popcll(m & ((1ull << lane) - 1ull));
      if (flag && pos < NSAMP) swave[w * 64 + pos] = n;
      cnt += (int)__popcll(m);
    }
    if (lane == 0) scnt[w] = cnt < NSAMP ? cnt : NSAMP;
  }
  __syncthreads();
  // --- merge the 8 ascending per-chunk lists (first 64 overall) ---
  if (t < NSAMP) {
    int run = 0, val = -1;
    #pragma unroll
    for (int ww = 0; ww < 8; ++ww) {
      int c = scnt[ww];
      int loc = t - run;
      if (loc >= 0 && loc < c) val = swave[ww * 64 + loc];
      run += c;
    }
    gidx[t] = val;  // -1 if t >= total
  }
  __syncthreads();
  if (t < NSAMP) {
    int g0 = gidx[0];  // always valid: query point itself qualifies (d2 = 0)
    int gt = gidx[t];
    gidx[t] = (gt < 0) ? g0 : gt;
  }
  __syncthreads();
  // --- gather grouped points: 65 x 6 ---
  if (t < 65 * DD) {
    int p = t / DD, d = t - p * DD;
    int n = (p == 0) ? qn : gidx[p - 1];
    gsh[t] = px[d * NN + n];
  }
  __syncthreads();
  // --- conv0: 128 ch, K=390; 4 lanes per channel (98/98/98/96) ---
  {
    int c = t >> 2, part = t & 3;
    const float2* wr = (const float2*)(w0 + c * 390 + part * 98);
    const float2* gr = (const float2*)(gsh + part * 98);
    int n2 = (part == 3) ? 48 : 49;
    float s = 0.f;
    #pragma unroll 7
    for (int i = 0; i < n2; ++i) {
      float2 a = gr[i], ww = wr[i];
      s += a.x * ww.x + a.y * ww.y;
    }
    s += __shfl_xor(s, 1);
    s += __shfl_xor(s, 2);
    if (part == 0) {
      s += b0[c];
      float sc = bn0[c] * rsqrtf(bn0[384 + c] + EPSF);
      s = (s - bn0[256 + c]) * sc + bn0[128 + c];
      r0[c] = fmaxf(s, 0.f);
    }
  }
  __syncthreads();
  // --- conv1: 256 ch, K=128; 2 lanes per channel ---
  {
    int c = t >> 1, part = t & 1;
    const float4* wr = (const float4*)(w1 + c * 128 + part * 64);
    const float4* rr = (const float4*)(r0 + part * 64);
    float s0 = 0.f, s1 = 0.f, s2 = 0.f, s3 = 0.f;
    #pragma unroll 8
    for (int o = 0; o < 16; ++o) {
      float4 a = rr[o], ww = wr[o];
      s0 += a.x * ww.x; s1 += a.y * ww.y; s2 += a.z * ww.z; s3 += a.w * ww.w;
    }
    float s = (s0 + s1) + (s2 + s3);
    s += __shfl_xor(s, 1);
    if (part == 0) {
      s += b1[c];
      float sc = bn1[c] * rsqrtf(bn1[768 + c] + EPSF);
      s = (s - bn1[512 + c]) * sc + bn1[256 + c];
      r1[c] = fmaxf(s, 0.f);
    }
  }
  __syncthreads();
  // --- conv2: 512 ch, K=256; 1 lane per channel, 4 accumulators ---
  {
    int c = t;
    const float4* wr = (const float4*)(w2 + c * 256);
    const float4* rr = (const float4*)r1;
    float s0 = 0.f, s1 = 0.f, s2 = 0.f, s3 = 0.f;
    #pragma unroll 8
    for (int o = 0; o < 64; ++o) {
      float4 a = rr[o], ww = wr[o];
      s0 += a.x * ww.x; s1 += a.y * ww.y; s2 += a.z * ww.z; s3 += a.w * ww.w;
    }
    float s = (s0 + s1) + (s2 + s3) + b2[c];
    float sc = bn2[c] * rsqrtf(bn2[1536 + c] + EPSF);
    s = (s - bn2[1024 + c]) * sc + bn2[512 + c];
    r2g[b * 8192 + c * TOPK + k] = fmaxf(s, 0.f);
  }
}

// ---------------- FC + BN + ReLU (wave-reduced dot), block=64 ----------------
__global__ void k_fl(const float* __restrict__ hin, const float* __restrict__ w,
                     const float* __restrict__ bias, const float* __restrict__ bn,
                     float* __restrict__ hout, int IN, int OUT) {
  int blk = blockIdx.x;
  int b = blk / OUT, j = blk % OUT;
  int lane = threadIdx.x;
  const float* hr = hin + (size_t)b * IN;
  const float* wr = w + (size_t)j * IN;
  float s = 0.f;
  for (int i = lane; i < IN; i += 64) s += hr[i] * wr[i];
  for (int o = 32; o; o >>= 1) s += __shfl_xor(s, o);
  if (lane == 0) {
    s += bias[j];
    float sc = bn[j] * rsqrtf(bn[3 * OUT + j] + EPSF);
    s = (s - bn[2 * OUT + j]) * sc + bn[OUT + j];
    hout[b * OUT + j] = fmaxf(s, 0.f);
  }
}

extern "C" void kernel_launch(void* const* d_in, const int* in_sizes, int n_in,
                              void* d_out, int out_size, void* d_ws, size_t ws_size,
                              hipStream_t stream) {
  const float* sv      = (const float*)d_in[0];
  const float* inp     = (const float*)d_in[1];
  const float* tl_win  = (const float*)d_in[2];
  const float* tl_bin  = (const float*)d_in[3];
  const float* tl_wout = (const float*)d_in[4];
  const float* tl_bout = (const float*)d_in[5];
  const float* tl_w1   = (const float*)d_in[6];
  const float* tl_b1   = (const float*)d_in[7];
  const float* tl_w2   = (const float*)d_in[8];
  const float* tl_b2   = (const float*)d_in[9];
  const float* tl_ln1g = (const float*)d_in[10];
  const float* tl_ln1b = (const float*)d_in[11];
  const float* tl_ln2g = (const float*)d_in[12];
  const float* tl_ln2b = (const float*)d_in[13];
  const float* fg_w0   = (const float*)d_in[14];
  const float* fg_b0   = (const float*)d_in[15];
  const float* fg_w1   = (const float*)d_in[16];
  const float* fg_b1   = (const float*)d_in[17];
  const float* fg_w2   = (const float*)d_in[18];
  const float* fg_b2   = (const float*)d_in[19];
  const float* fbn0    = (const float*)d_in[20];
  const float* fbn1    = (const float*)d_in[21];
  const float* fbn2    = (const float*)d_in[22];
  const float* rc_w0   = (const float*)d_in[23];
  const float* rc_b0   = (const float*)d_in[24];
  const float* rc_w1   = (const float*)d_in[25];
  const float* rc_b1   = (const float*)d_in[26];
  const float* rc_w2   = (const float*)d_in[27];
  const float* rc_b2   = (const float*)d_in[28];
  const float* rbn0    = (const float*)d_in[29];
  const float* rbn1    = (const float*)d_in[30];
  const float* rbn2    = (const float*)d_in[31];
  const float* fl_w0   = (const float*)d_in[32];
  const float* fl_b0   = (const float*)d_in[33];
  const float* fl_w1   = (const float*)d_in[34];
  const float* fl_b1   = (const float*)d_in[35];
  const float* lbn0    = (const float*)d_in[36];
  const float* lbn1    = (const float*)d_in[37];
  (void)in_sizes; (void)n_in; (void)out_size; (void)ws_size;

  float* wsp = (float*)d_ws;
  float* x      = wsp;                        // B*N*F      = 1048576
  float* qkv    = x + BB * NN * FF;           // B*N*192    = 3145728
  float* a      = qkv + BB * NN * 192;        // B*N*F      = 1048576
  float* scores = a + BB * NN * FF;           // B*N        = 16384
  int*   idxb   = (int*)(scores + BB * NN);   // B*TOPK     = 128
  float* r2g    = (float*)(idxb + BB * TOPK); // B*8192     = 65536
  float* h1g    = r2g + BB * 8192;            // B*1024     = 8192
  unsigned* wpk1 = (unsigned*)(h1g + BB * 1024);   // 2*2048*64 = 262144
  unsigned* wpk2 = wpk1 + NLAYER * 2048 * 64;      // 2*64*2048 = 262144
  float* part   = qkv;  // FFN split-K partials reuse qkv+a (4*16384*64 floats)

  float* out = (float*)d_out;  // fp32: h at [0,4096), idx-as-float at [4096,4224)

  k_transpose<<<(BB * NN * FF) / 256, 256, 0, stream>>>(sv, x);
  k_wpack<<<(NLAYER * 2048 * 64) / 256, 256, 0, stream>>>(tl_w1, wpk1, NLAYER * 2048 * 64);
  k_wpack<<<(NLAYER * 2048 * 64) / 256, 256, 0, stream>>>(tl_w2, wpk2, NLAYER * 2048 * 64);

  for (int l = 0; l < NLAYER; ++l) {
    k_qkv2<<<dim3(BB * NN / 64, 3), 256, 0, stream>>>(x, tl_win + l * 192 * FF,
                                                      tl_bin + l * 192, qkv);
    k_attn6<<<dim3(NN / 64, NHEAD, BB), 256, 0, stream>>>(qkv, a);
    k_proj2<<<BB * NN / 64, 256, 0, stream>>>(a, tl_wout + l * FF * FF, tl_bout + l * FF,
                                              tl_ln1g + l * FF, tl_ln1b + l * FF, x);
    k_ffn4<<<dim3(BB * NN / 64, 4), 256, 0, stream>>>(x, wpk1 + l * 2048 * 64,
                                                      tl_b1 + l * 2048,
                                                      wpk2 + l * 2048 * 64, part);
    k_ffn_ln<<<BB * NN / 4, 256, 0, stream>>>(part, tl_b2 + l * FF,
                                              tl_ln2g + l * FF, tl_ln2b + l * FF, x);
  }

  k_fg2<<<BB * NN / 64, 256, 0, stream>>>(x, fg_w0, fg_b0, fbn0, fg_w1, fg_b1, fbn1,
                                          fg_w2, fg_b2, fbn2, scores);
  k_topk2<<<BB, 256, 0, stream>>>(scores, idxb, out + BB * 512);
  k_group<<<dim3(TOPK, BB), 512, 0, stream>>>(inp, idxb, rc_w0, rc_b0, rbn0,
                                              rc_w1, rc_b1, rbn1, rc_w2, rc_b2, rbn2, r2g);
  k_fl<<<BB * 1024, 64, 0, stream>>>(r2g, fl_w0, fl_b0, lbn0, h1g, 8192, 1024);
  k_fl<<<BB * 512, 64, 0, stream>>>(h1g, fl_w1, fl_b1, lbn1, out, 1024, 512);
}

// Round 2
// 652.993 us; speedup vs baseline: 1.1437x; 1.0189x over previous
//
#include <hip/hip_runtime.h>
#include <hip/hip_bf16.h>
#include <math.h>

#define BB 8
#define NN 2048
#define FF 64
#define DD 6
#define NSAMP 64
#define TOPK 16
#define NHEAD 8
#define HD 8
#define NLAYER 2
#define EPSF 1e-5f
#define R2 0.09f

typedef short short8 __attribute__((ext_vector_type(8)));
typedef float f32x4 __attribute__((ext_vector_type(4)));

// split-pack: u32 = (bf16_hi << 16) | bf16_lo, both RNE. x ≈ hi + lo, err ~2^-16 rel.
__device__ inline unsigned pk2(float x) {
  unsigned b = __float_as_uint(x);
  unsigned hi = (b + 0x7fffu + ((b >> 16) & 1u)) >> 16;
  float r = x - __uint_as_float(hi << 16);
  unsigned c = __float_as_uint(r);
  unsigned lo = (c + 0x7fffu + ((c >> 16) & 1u)) >> 16;
  return (hi << 16) | lo;
}

// ---------------- transpose sortvec (B,1,F,N) -> x (B,N,F) ----------------
__global__ void k_transpose(const float* __restrict__ sv, float* __restrict__ x) {
  int i = blockIdx.x * 256 + threadIdx.x;
  if (i >= BB * NN * FF) return;
  int f = i % FF;
  int n = (i / FF) % NN;
  int b = i / (FF * NN);
  x[i] = sv[(b * FF + f) * NN + n];
}

// ---------------- pack fp32 weights -> separate bf16 hi/lo planes ----------------
__global__ void k_wpack16(const float* __restrict__ w, unsigned short* __restrict__ hi,
                          unsigned short* __restrict__ lo, int n) {
  int i = blockIdx.x * 256 + threadIdx.x;
  if (i < n) {
    unsigned p = pk2(w[i]);
    hi[i] = (unsigned short)(p >> 16);
    lo[i] = (unsigned short)(p & 0xffffu);
  }
}

// ---------------- tiled GEMM: qkv[row][192] = x[row][64] @ win^T + bin ----------
__global__ void k_qkv2(const float* __restrict__ x, const float* __restrict__ win,
                       const float* __restrict__ bin, float* __restrict__ qkv) {
  __shared__ float xs[64 * 68];
  __shared__ float ws[64 * 68];
  int row0 = blockIdx.x * 64, col0 = blockIdx.y * 64;
  int t = threadIdx.x;
  #pragma unroll
  for (int i = 0; i < 4; ++i) {
    int q = t + i * 256, r = q >> 4, c = (q & 15) * 4;
    *(float4*)(xs + r * 68 + c) = *(const float4*)(x + (size_t)(row0 + r) * 64 + c);
    *(float4*)(ws + r * 68 + c) = *(const float4*)(win + (size_t)(col0 + r) * 64 + c);
  }
  __syncthreads();
  int tx = t & 15, ty = t >> 4;
  float acc[4][4] = {};
  for (int f = 0; f < 64; f += 4) {
    float4 xv[4], wv[4];
    #pragma unroll
    for (int ri = 0; ri < 4; ++ri) xv[ri] = *(const float4*)(xs + (ty * 4 + ri) * 68 + f);
    #pragma unroll
    for (int ci = 0; ci < 4; ++ci) wv[ci] = *(const float4*)(ws + (tx + 16 * ci) * 68 + f);
    #pragma unroll
    for (int ri = 0; ri < 4; ++ri)
      #pragma unroll
      for (int ci = 0; ci < 4; ++ci)
        acc[ri][ci] += xv[ri].x * wv[ci].x + xv[ri].y * wv[ci].y +
                       xv[ri].z * wv[ci].z + xv[ri].w * wv[ci].w;
  }
  #pragma unroll
  for (int ri = 0; ri < 4; ++ri)
    #pragma unroll
    for (int ci = 0; ci < 4; ++ci) {
      int r = row0 + ty * 4 + ri, c = col0 + tx + 16 * ci;
      qkv[(size_t)r * 192 + c] = acc[ri][ci] + bin[c];
    }
}

// ---- attention v6: single-plane bf16 MFMA flash. Wave = 16 queries x 2048
// keys. bf16 rounding of K/V/P is statistically safe here (near-uniform
// softmax over 2048 keys averages independent roundings to ~1e-5; ones-row
// makes num/denom use the same p-tilde). K staged in 40-u16 rows zero-padded
// to k=32 so the B-frag needs no masking. 1 mfma per QK half, 1 per PV.
__global__ void __launch_bounds__(256, 5)
k_attn6(const float* __restrict__ qkv, float* __restrict__ a) {
  __shared__ __attribute__((aligned(16))) unsigned short kb16[256 * 40];  // 20 KB
  __shared__ __attribute__((aligned(16))) unsigned short vb16[9 * 264];   // 4.6 KB
  __shared__ __attribute__((aligned(16))) unsigned short pb16[4 * 16 * 40]; // 5 KB
  int t = threadIdx.x;
  int lane = t & 63, w = t >> 6;
  int nIdx = lane & 15, lq = lane >> 4;
  int h = blockIdx.y, b = blockIdx.z;
  int qwb = blockIdx.x * 64 + w * 16;
  const float kf = 0.35355339059327373f * 1.4426950408889634f;  // scale*log2e
  // zero K pad (d=8..31 stays zero; staging writes only d<8)
  {
    unsigned* kz = (unsigned*)kb16;
    #pragma unroll
    for (int i = 0; i < 20; ++i) kz[t + i * 256] = 0u;
  }
  // Q A-fragment: quad0 lanes hold k=0..7 (RNE bf16), others zero
  short8 qF = {0, 0, 0, 0, 0, 0, 0, 0};
  if (lq == 0) {
    const float* qr = qkv + ((size_t)(b * NN + qwb + nIdx)) * 192 + h * HD;
    #pragma unroll
    for (int j = 0; j < 8; ++j) {
      float v = qr[j] * kf;
      unsigned bb = __float_as_uint(v);
      qF[j] = (short)((bb + 0x7fffu + ((bb >> 16) & 1u)) >> 16);
    }
  }
  f32x4 acc = {0.f, 0.f, 0.f, 0.f};
  unsigned short* mypb = pb16 + w * 640;
  for (int kc = 0; kc < NN; kc += 256) {
    __syncthreads();
    // stage K chunk: pairs (d0,d0+1) -> one u32 (trunc bf16)
    #pragma unroll
    for (int i = 0; i < 4; ++i) {
      int p = t + i * 256;               // 0..1023
      int key = p >> 2, d0 = (p & 3) * 2;
      const float* src = qkv + ((size_t)(b * NN + kc + key)) * 192 + 64 + h * HD + d0;
      float2 f = *(const float2*)(src);
      unsigned u = (__float_as_uint(f.x) >> 16) | (__float_as_uint(f.y) & 0xffff0000u);
      *(unsigned*)(kb16 + key * 40 + d0) = u;
    }
    // stage V^T chunk: pairs of keys -> one u32
    #pragma unroll
    for (int i = 0; i < 4; ++i) {
      int p = t + i * 256;
      int d = p >> 7, kp = p & 127;
      int key0 = 2 * kp;
      float f0 = qkv[((size_t)(b * NN + kc + key0)) * 192 + 128 + h * HD + d];
      float f1 = qkv[((size_t)(b * NN + kc + key0 + 1)) * 192 + 128 + h * HD + d];
      unsigned u = (__float_as_uint(f0) >> 16) | (__float_as_uint(f1) & 0xffff0000u);
      *(unsigned*)(vb16 + d * 264 + key0) = u;
    }
    if (t < 132) ((unsigned*)(vb16 + 8 * 264))[t] = 0x3f803f80u;  // ones row
    __syncthreads();
    for (int s = 0; s < 8; ++s) {
      int kb = s * 32;
      #pragma unroll
      for (int half = 0; half < 2; ++half) {
        int key = kb + half * 16 + nIdx;
        short8 bF = *(const short8*)(kb16 + key * 40 + lq * 8);  // zeros for k>=8
        f32x4 c = {0.f, 0.f, 0.f, 0.f};
        c = __builtin_amdgcn_mfma_f32_16x16x32_bf16(qF, bF, c, 0, 0, 0);
        #pragma unroll
        for (int r = 0; r < 4; ++r) {
          float p = __builtin_amdgcn_exp2f(c[r]);
          int row = lq * 4 + r;
          mypb[row * 40 + half * 16 + nIdx] = (unsigned short)(__float_as_uint(p) >> 16);
        }
      }
      // C->A readback (same-wave LDS)
      short8 pa = *(const short8*)(mypb + nIdx * 40 + lq * 8);
      int vn = nIdx < 9 ? nIdx : 8;
      short8 vb = *(const short8*)(vb16 + vn * 264 + kb + lq * 8);
      acc = __builtin_amdgcn_mfma_f32_16x16x32_bf16(pa, vb, acc, 0, 0, 0);
    }
  }
  // epilogue: col 8 holds l = sum(p); divide, scatter cols 0..7
  #pragma unroll
  for (int r = 0; r < 4; ++r) {
    float lr = __shfl(acc[r], (lane & 48) | 8);
    if (nIdx < 8) {
      int row = qwb + lq * 4 + r;
      a[((size_t)(b * NN + row)) * 64 + h * HD + nIdx] = acc[r] / lr;
    }
  }
}

// ------- proj + residual + LN, tiled GEMM ---------
__global__ void k_proj2(const float* __restrict__ a, const float* __restrict__ wout,
                        const float* __restrict__ bout, const float* __restrict__ g,
                        const float* __restrict__ be, float* __restrict__ x) {
  __shared__ float xs[64 * 68];
  __shared__ float ws[64 * 68];
  int row0 = blockIdx.x * 64;
  int t = threadIdx.x;
  #pragma unroll
  for (int i = 0; i < 4; ++i) {
    int q = t + i * 256, r = q >> 4, c = (q & 15) * 4;
    *(float4*)(xs + r * 68 + c) = *(const float4*)(a + (size_t)(row0 + r) * 64 + c);
    *(float4*)(ws + r * 68 + c) = *(const float4*)(wout + r * 64 + c);
  }
  __syncthreads();
  int tx = t & 15, ty = t >> 4;
  float acc[4][4] = {};
  for (int f = 0; f < 64; f += 4) {
    float4 xv[4], wv[4];
    #pragma unroll
    for (int ri = 0; ri < 4; ++ri) xv[ri] = *(const float4*)(xs + (ty * 4 + ri) * 68 + f);
    #pragma unroll
    for (int ci = 0; ci < 4; ++ci) wv[ci] = *(const float4*)(ws + (tx + 16 * ci) * 68 + f);
    #pragma unroll
    for (int ri = 0; ri < 4; ++ri)
      #pragma unroll
      for (int ci = 0; ci < 4; ++ci)
        acc[ri][ci] += xv[ri].x * wv[ci].x + xv[ri].y * wv[ci].y +
                       xv[ri].z * wv[ci].z + xv[ri].w * wv[ci].w;
  }
  #pragma unroll
  for (int ri = 0; ri < 4; ++ri) {
    int rl = ty * 4 + ri;
    float val[4], s = 0.f, sq = 0.f;
    #pragma unroll
    for (int ci = 0; ci < 4; ++ci) {
      int c = tx + 16 * ci;
      val[ci] = x[(size_t)(row0 + rl) * 64 + c] + bout[c] + acc[ri][ci];
      s += val[ci]; sq += val[ci] * val[ci];
    }
    #pragma unroll
    for (int off = 1; off < 16; off <<= 1) { s += __shfl_xor(s, off); sq += __shfl_xor(sq, off); }
    float mean = s * (1.f / 64.f);
    float var = sq * (1.f / 64.f) - mean * mean;
    float rstd = rsqrtf(var + EPSF);
    #pragma unroll
    for (int ci = 0; ci < 4; ++ci) {
      int c = tx + 16 * ci;
      x[(size_t)(row0 + rl) * 64 + c] = (val[ci] - mean) * rstd * g[c] + be[c];
    }
  }
}

// ------- FFN v5: split-bf16 via SEPARATE hi/lo planes (no inner-loop unpack).
// LDS planes are unpadded 64x64 bf16 with XOR swizzle (16B slot ^= row&7):
// every b128 read/write lands uniformly on all 32 banks (8 accesses each,
// the wave64 minimum). 48.3 KB LDS -> 3 blocks/CU. w2 regs load before GEMM1,
// next w1 during GEMM2 (global latency hidden under MFMA). 3 MFMAs per
// logical MFMA keep the proven 2^-17 precision (hi*hi + hi*lo + lo*hi).
__global__ void __launch_bounds__(256, 3)
k_ffn5(const float* __restrict__ x, const unsigned short* __restrict__ w1h,
       const unsigned short* __restrict__ w1l, const float* __restrict__ b1,
       const unsigned short* __restrict__ w2h, const unsigned short* __restrict__ w2l,
       float* __restrict__ part) {
  __shared__ __attribute__((aligned(16))) unsigned short xhi[64 * 64], xlo[64 * 64];
  __shared__ __attribute__((aligned(16))) unsigned short wshi[64 * 64], wslo[64 * 64];
  __shared__ __attribute__((aligned(16))) unsigned short hhi[64 * 64], hlo[64 * 64];
  __shared__ float b1s[64];
  int row0 = blockIdx.x * 64;
  int ks = blockIdx.y;
  int t = threadIdx.x;
  int lane = t & 63, wv = t >> 6;
  int lm = lane & 15, lq = lane >> 4;

  int kc = ks * 512;
  // reg-load w1 chunk 0 (hi/lo)
  uint4 rwh[2], rwl[2];
  #pragma unroll
  for (int i = 0; i < 2; ++i) {
    int q = t + i * 256;
    rwh[i] = *(const uint4*)(w1h + (size_t)(kc + (q >> 3)) * 64 + (q & 7) * 8);
    rwl[i] = *(const uint4*)(w1l + (size_t)(kc + (q >> 3)) * 64 + (q & 7) * 8);
  }
  float rbv = (t < 64) ? b1[kc + t] : 0.f;

  // stage x -> xhi/xlo (swizzled). 16 values/thread.
  #pragma unroll
  for (int i = 0; i < 4; ++i) {
    int q = t + i * 256, r = q >> 4, c = (q & 15) * 4;
    float4 v = *(const float4*)(x + (size_t)(row0 + r) * 64 + c);
    unsigned p0 = pk2(v.x), p1 = pk2(v.y), p2 = pk2(v.z), p3 = pk2(v.w);
    int off = r * 128 + (((c >> 3) ^ (r & 7)) << 4) + ((c & 7) << 1);
    *(uint2*)((char*)xhi + off) = (uint2){(p0 >> 16) | (p1 & 0xffff0000u),
                                          (p2 >> 16) | (p3 & 0xffff0000u)};
    *(uint2*)((char*)xlo + off) = (uint2){(p0 & 0xffffu) | (p1 << 16),
                                          (p2 & 0xffffu) | (p3 << 16)};
  }

  f32x4 acc[4];
  #pragma unroll
  for (int tn = 0; tn < 4; ++tn) acc[tn] = (f32x4){0.f, 0.f, 0.f, 0.f};

  for (int ch = 0; ch < 8; ++ch) {
    int kcc = kc + ch * 64;
    __syncthreads();  // (A) prior reads of ws / next-x ready
    #pragma unroll
    for (int i = 0; i < 2; ++i) {
      int q = t + i * 256, r = q >> 3, s = q & 7;
      int off = r * 128 + ((s ^ (r & 7)) << 4);
      *(uint4*)((char*)wshi + off) = rwh[i];
      *(uint4*)((char*)wslo + off) = rwl[i];
    }
    if (t < 64) b1s[t] = rbv;
    __syncthreads();  // (B)
    // issue w2 chunk loads (land during GEMM1)
    #pragma unroll
    for (int i = 0; i < 2; ++i) {
      int q = t + i * 256;
      rwh[i] = *(const uint4*)(w2h + (size_t)(q >> 3) * 2048 + kcc + (q & 7) * 8);
      rwl[i] = *(const uint4*)(w2l + (size_t)(q >> 3) * 2048 + kcc + (q & 7) * 8);
    }
    // GEMM1: h = x @ w1chunk^T
    f32x4 h4[4];
    #pragma unroll
    for (int tn = 0; tn < 4; ++tn) h4[tn] = (f32x4){0.f, 0.f, 0.f, 0.f};
    #pragma unroll
    for (int kb = 0; kb < 64; kb += 32) {
      int sw = ((((kb >> 3) + lq) ^ (lm & 7)) << 4);
      int arow = wv * 16 + lm;
      short8 ahi = *(const short8*)((const char*)xhi + arow * 128 + sw);
      short8 alo = *(const short8*)((const char*)xlo + arow * 128 + sw);
      #pragma unroll
      for (int tn = 0; tn < 4; ++tn) {
        int brow = tn * 16 + lm;
        short8 bhi = *(const short8*)((const char*)wshi + brow * 128 + sw);
        short8 blo = *(const short8*)((const char*)wslo + brow * 128 + sw);
        h4[tn] = __builtin_amdgcn_mfma_f32_16x16x32_bf16(ahi, bhi, h4[tn], 0, 0, 0);
        h4[tn] = __builtin_amdgcn_mfma_f32_16x16x32_bf16(ahi, blo, h4[tn], 0, 0, 0);
        h4[tn] = __builtin_amdgcn_mfma_f32_16x16x32_bf16(alo, bhi, h4[tn], 0, 0, 0);
      }
    }
    // h = relu(h + b1); split (trunc hi + RNE residual, err <= 2^-17) -> hhi/hlo
    #pragma unroll
    for (int tn = 0; tn < 4; ++tn)
      #pragma unroll
      for (int r = 0; r < 4; ++r) {
        float hv = fmaxf(h4[tn][r] + b1s[tn * 16 + lm], 0.f);
        unsigned u = __float_as_uint(hv);
        float resid = hv - __uint_as_float(u & 0xffff0000u);
        unsigned c2 = __float_as_uint(resid);
        int hrow = wv * 16 + lq * 4 + r, hcol = tn * 16 + lm;
        int off = hrow * 128 + (((hcol >> 3) ^ (hrow & 7)) << 4) + ((hcol & 7) << 1);
        *(unsigned short*)((char*)hhi + off) = (unsigned short)(u >> 16);
        *(unsigned short*)((char*)hlo + off) =
            (unsigned short)((c2 + 0x7fffu + ((c2 >> 16) & 1u)) >> 16);
      }
    __syncthreads();  // (C) all waves done reading w1 from ws; hs drained
    #pragma unroll
    for (int i = 0; i < 2; ++i) {
      int q = t + i * 256, r = q >> 3, s = q & 7;
      int off = r * 128 + ((s ^ (r & 7)) << 4);
      *(uint4*)((char*)wshi + off) = rwh[i];
      *(uint4*)((char*)wslo + off) = rwl[i];
    }
    __syncthreads();  // (D)
    // prefetch next chunk's w1 + b1 (land during GEMM2)
    if (ch < 7) {
      int kcn = kcc + 64;
      #pragma unroll
      for (int i = 0; i < 2; ++i) {
        int q = t + i * 256;
        rwh[i] = *(const uint4*)(w1h + (size_t)(kcn + (q >> 3)) * 64 + (q & 7) * 8);
        rwl[i] = *(const uint4*)(w1l + (size_t)(kcn + (q >> 3)) * 64 + (q & 7) * 8);
      }
      if (t < 64) rbv = b1[kcn + t];
    }
    // GEMM2: acc += h @ w2chunk
    #pragma unroll
    for (int kb = 0; kb < 64; kb += 32) {
      int sw = ((((kb >> 3) + lq) ^ (lm & 7)) << 4);
      int arow = wv * 16 + lm;
      short8 ahi = *(const short8*)((const char*)hhi + arow * 128 + sw);
      short8 alo = *(const short8*)((const char*)hlo + arow * 128 + sw);
      #pragma unroll
      for (int tn = 0; tn < 4; ++tn) {
        int brow = tn * 16 + lm;
        short8 bhi = *(const short8*)((const char*)wshi + brow * 128 + sw);
        short8 blo = *(const short8*)((const char*)wslo + brow * 128 + sw);
        acc[tn] = __builtin_amdgcn_mfma_f32_16x16x32_bf16(ahi, bhi, acc[tn], 0, 0, 0);
        acc[tn] = __builtin_amdgcn_mfma_f32_16x16x32_bf16(ahi, blo, acc[tn], 0, 0, 0);
        acc[tn] = __builtin_amdgcn_mfma_f32_16x16x32_bf16(alo, bhi, acc[tn], 0, 0, 0);
      }
    }
  }
  float* pb = part + (size_t)ks * (BB * NN * 64);
  #pragma unroll
  for (int tn = 0; tn < 4; ++tn)
    #pragma unroll
    for (int r = 0; r < 4; ++r)
      pb[(size_t)(row0 + wv * 16 + lq * 4 + r) * 64 + tn * 16 + lm] = acc[tn][r];
}

// ------- combine 4 partials + residual + b2 + LN; one wave per row ---------
__global__ void k_ffn_ln(const float* __restrict__ part, const float* __restrict__ b2,
                         const float* __restrict__ g, const float* __restrict__ be,
                         float* __restrict__ x) {
  int row = blockIdx.x * 4 + (threadIdx.x >> 6);
  int j = threadIdx.x & 63;
  size_t o = (size_t)row * 64 + j;
  const size_t S = (size_t)BB * NN * 64;
  float val = x[o] + b2[j] + ((part[o] + part[o + S]) + (part[o + 2 * S] + part[o + 3 * S]));
  float s = val;
  for (int off = 32; off; off >>= 1) s += __shfl_xor(s, off);
  s *= (1.f / 64.f);
  float d = val - s;
  float v = d * d;
  for (int off = 32; off; off >>= 1) v += __shfl_xor(v, off);
  v *= (1.f / 64.f);
  x[o] = d * rsqrtf(v + EPSF) * g[j] + be[j];
}

// ------- score head tiled ----------
__global__ void k_fg2(const float* __restrict__ x,
                      const float* __restrict__ w0, const float* __restrict__ b0, const float* __restrict__ bn0,
                      const float* __restrict__ w1, const float* __restrict__ b1, const float* __restrict__ bn1,
                      const float* __restrict__ w2, const float* __restrict__ b2, const float* __restrict__ bn2,
                      float* __restrict__ scores) {
  __shared__ float xs[64 * 68];
  __shared__ float ws[64 * 68];
  __shared__ float s0s[64 * 68];
  __shared__ float s1s[64 * 20];
  int row0 = blockIdx.x * 64;
  int t = threadIdx.x;
  #pragma unroll
  for (int i = 0; i < 4; ++i) {
    int q = t + i * 256, r = q >> 4, c = (q & 15) * 4;
    *(float4*)(xs + r * 68 + c) = *(const float4*)(x + (size_t)(row0 + r) * 64 + c);
    *(float4*)(ws + r * 68 + c) = *(const float4*)(w0 + r * 64 + c);
  }
  __syncthreads();
  int tx = t & 15, ty = t >> 4;
  float acc[4][4] = {};
  for (int f = 0; f < 64; f += 4) {
    float4 xv[4], wv[4];
    #pragma unroll
    for (int ri = 0; ri < 4; ++ri) xv[ri] = *(const float4*)(xs + (ty * 4 + ri) * 68 + f);
    #pragma unroll
    for (int ci = 0; ci < 4; ++ci) wv[ci] = *(const float4*)(ws + (tx + 16 * ci) * 68 + f);
    #pragma unroll
    for (int ri = 0; ri < 4; ++ri)
      #pragma unroll
      for (int ci = 0; ci < 4; ++ci)
        acc[ri][ci] += xv[ri].x * wv[ci].x + xv[ri].y * wv[ci].y +
                       xv[ri].z * wv[ci].z + xv[ri].w * wv[ci].w;
  }
  #pragma unroll
  for (int ri = 0; ri < 4; ++ri)
    #pragma unroll
    for (int ci = 0; ci < 4; ++ci) {
      int c = tx + 16 * ci;
      float sc = bn0[c] * rsqrtf(bn0[192 + c] + EPSF);
      float v = (acc[ri][ci] + b0[c] - bn0[128 + c]) * sc + bn0[64 + c];
      s0s[(ty * 4 + ri) * 68 + c] = fmaxf(v, 0.f);
    }
  __syncthreads();
  {
    int rl = t & 63, j0 = t >> 6;
    #pragma unroll
    for (int i = 0; i < 4; ++i) {
      int j = j0 + 4 * i;
      float s = b1[j];
      const float* wr = w1 + j * 64;
      #pragma unroll 16
      for (int c = 0; c < 64; ++c) s += s0s[rl * 68 + c] * wr[c];
      float sc = bn1[j] * rsqrtf(bn1[48 + j] + EPSF);
      s = (s - bn1[32 + j]) * sc + bn1[16 + j];
      s1s[rl * 20 + j] = fmaxf(s, 0.f);
    }
  }
  __syncthreads();
  if (t < 64) {
    float s = b2[0];
    #pragma unroll
    for (int o = 0; o < 16; ++o) s += s1s[t * 20 + o] * w2[o];
    float sc = bn2[0] * rsqrtf(bn2[3] + EPSF);
    s = (s - bn2[2]) * sc + bn2[1];
    scores[row0 + t] = fmaxf(s, 0.f);
  }
}

// ---- top-k (k=16) ----
__global__ void k_topk2(const float* __restrict__ scores, int* __restrict__ idx,
                        float* __restrict__ out_idx) {
  int b = blockIdx.x, t = threadIdx.x;
  float v[8];
  int base = b * NN;
  #pragma unroll
  for (int u = 0; u < 8; ++u) v[u] = scores[base + t + 256 * u];
  __shared__ float wvs[4];
  __shared__ int wis[4];
  __shared__ int winner;
  unsigned taken = 0;
  for (int r = 0; r < TOPK; ++r) {
    float best = -1e30f; int bi = 1 << 30;
    #pragma unroll
    for (int u = 0; u < 8; ++u) {
      if (!((taken >> u) & 1)) {
        float vv = v[u]; int ii = t + 256 * u;
        if (vv > best || (vv == best && ii < bi)) { best = vv; bi = ii; }
      }
    }
    for (int off = 32; off; off >>= 1) {
      float ov = __shfl_xor(best, off);
      int oi = __shfl_xor(bi, off);
      if (ov > best || (ov == best && oi < bi)) { best = ov; bi = oi; }
    }
    if ((t & 63) == 0) { wvs[t >> 6] = best; wis[t >> 6] = bi; }
    __syncthreads();
    if (t == 0) {
      float B = wvs[0]; int I = wis[0];
      #pragma unroll
      for (int q = 1; q < 4; ++q)
        if (wvs[q] > B || (wvs[q] == B && wis[q] < I)) { B = wvs[q]; I = wis[q]; }
      winner = I;
      idx[b * TOPK + r] = I;
      out_idx[b * TOPK + r] = (float)I;
    }
    __syncthreads();
    int w = winner;
    if ((w & 255) == t) taken |= 1u << (w >> 8);
  }
}

// ---------------- ball query + 3 conv stages, v2: 512 threads (8 waves) per (b,k).
__global__ void __launch_bounds__(512)
k_group(const float* __restrict__ inp, const int* __restrict__ idx,
        const float* __restrict__ w0, const float* __restrict__ b0, const float* __restrict__ bn0,
        const float* __restrict__ w1, const float* __restrict__ b1, const float* __restrict__ bn1,
        const float* __restrict__ w2, const float* __restrict__ b2, const float* __restrict__ bn2,
        float* __restrict__ r2g) {
  __shared__ int swave[8 * 64];
  __shared__ int scnt[8];
  __shared__ int gidx[NSAMP];
  __shared__ __attribute__((aligned(16))) float gsh[65 * DD];  // 390
  __shared__ __attribute__((aligned(16))) float r0[128];
  __shared__ __attribute__((aligned(16))) float r1[256];
  int k = blockIdx.x, b = blockIdx.y;
  int t = threadIdx.x;
  int lane = t & 63, w = t >> 6;
  int qn = idx[b * TOPK + k];
  const float* px = inp + (size_t)b * DD * NN;
  float qx = px[qn], qy = px[NN + qn], qz = px[2 * NN + qn];
  // --- ball query: wave w scans points [w*256, w*256+256), ascending ---
  {
    int cnt = 0;
    #pragma unroll
    for (int i = 0; i < 4; ++i) {
      int n = w * 256 + i * 64 + lane;
      float dx = px[n] - qx, dy = px[NN + n] - qy, dz = px[2 * NN + n] - qz;
      bool flag = (dx * dx + dy * dy + dz * dz <= R2);
      unsigned long long m = __ballot(flag);
      int pos = cnt + __popcll(m & ((1ull << lane) - 1ull));
      if (flag && pos < NSAMP) swave[w * 64 + pos] = n;
      cnt += (int)__popcll(m);
    }
    if (lane == 0) scnt[w] = cnt < NSAMP ? cnt : NSAMP;
  }
  __syncthreads();
  // --- merge the 8 ascending per-chunk lists (first 64 overall) ---
  if (t < NSAMP) {
    int run = 0, val = -1;
    #pragma unroll
    for (int ww = 0; ww < 8; ++ww) {
      int c = scnt[ww];
      int loc = t - run;
      if (loc >= 0 && loc < c) val = swave[ww * 64 + loc];
      run += c;
    }
    gidx[t] = val;  // -1 if t >= total
  }
  __syncthreads();
  if (t < NSAMP) {
    int g0 = gidx[0];  // always valid: query point itself qualifies (d2 = 0)
    int gt = gidx[t];
    gidx[t] = (gt < 0) ? g0 : gt;
  }
  __syncthreads();
  // --- gather grouped points: 65 x 6 ---
  if (t < 65 * DD) {
    int p = t / DD, d = t - p * DD;
    int n = (p == 0) ? qn : gidx[p - 1];
    gsh[t] = px[d * NN + n];
  }
  __syncthreads();
  // --- conv0: 128 ch, K=390; 4 lanes per channel (98/98/98/96) ---
  {
    int c = t >> 2, part = t & 3;
    const float2* wr = (const float2*)(w0 + c * 390 + part * 98);
    const float2* gr = (const float2*)(gsh + part * 98);
    int n2 = (part == 3) ? 48 : 49;
    float s = 0.f;
    #pragma unroll 7
    for (int i = 0; i < n2; ++i) {
      float2 a = gr[i], ww = wr[i];
      s += a.x * ww.x + a.y * ww.y;
    }
    s += __shfl_xor(s, 1);
    s += __shfl_xor(s, 2);
    if (part == 0) {
      s += b0[c];
      float sc = bn0[c] * rsqrtf(bn0[384 + c] + EPSF);
      s = (s - bn0[256 + c]) * sc + bn0[128 + c];
      r0[c] = fmaxf(s, 0.f);
    }
  }
  __syncthreads();
  // --- conv1: 256 ch, K=128; 2 lanes per channel ---
  {
    int c = t >> 1, part = t & 1;
    const float4* wr = (const float4*)(w1 + c * 128 + part * 64);
    const float4* rr = (const float4*)(r0 + part * 64);
    float s0 = 0.f, s1 = 0.f, s2 = 0.f, s3 = 0.f;
    #pragma unroll 8
    for (int o = 0; o < 16; ++o) {
      float4 a = rr[o], ww = wr[o];
      s0 += a.x * ww.x; s1 += a.y * ww.y; s2 += a.z * ww.z; s3 += a.w * ww.w;
    }
    float s = (s0 + s1) + (s2 + s3);
    s += __shfl_xor(s, 1);
    if (part == 0) {
      s += b1[c];
      float sc = bn1[c] * rsqrtf(bn1[768 + c] + EPSF);
      s = (s - bn1[512 + c]) * sc + bn1[256 + c];
      r1[c] = fmaxf(s, 0.f);
    }
  }
  __syncthreads();
  // --- conv2: 512 ch, K=256; 1 lane per channel, 4 accumulators ---
  {
    int c = t;
    const float4* wr = (const float4*)(w2 + c * 256);
    const float4* rr = (const float4*)r1;
    float s0 = 0.f, s1 = 0.f, s2 = 0.f, s3 = 0.f;
    #pragma unroll 8
    for (int o = 0; o < 64; ++o) {
      float4 a = rr[o], ww = wr[o];
      s0 += a.x * ww.x; s1 += a.y * ww.y; s2 += a.z * ww.z; s3 += a.w * ww.w;
    }
    float s = (s0 + s1) + (s2 + s3) + b2[c];
    float sc = bn2[c] * rsqrtf(bn2[1536 + c] + EPSF);
    s = (s - bn2[1024 + c]) * sc + bn2[512 + c];
    r2g[b * 8192 + c * TOPK + k] = fmaxf(s, 0.f);
  }
}

// ---------------- FC + BN + ReLU (wave-reduced dot), block=64 ----------------
__global__ void k_fl(const float* __restrict__ hin, const float* __restrict__ w,
                     const float* __restrict__ bias, const float* __restrict__ bn,
                     float* __restrict__ hout, int IN, int OUT) {
  int blk = blockIdx.x;
  int b = blk / OUT, j = blk % OUT;
  int lane = threadIdx.x;
  const float* hr = hin + (size_t)b * IN;
  const float* wr = w + (size_t)j * IN;
  float s = 0.f;
  for (int i = lane; i < IN; i += 64) s += hr[i] * wr[i];
  for (int o = 32; o; o >>= 1) s += __shfl_xor(s, o);
  if (lane == 0) {
    s += bias[j];
    float sc = bn[j] * rsqrtf(bn[3 * OUT + j] + EPSF);
    s = (s - bn[2 * OUT + j]) * sc + bn[OUT + j];
    hout[b * OUT + j] = fmaxf(s, 0.f);
  }
}

extern "C" void kernel_launch(void* const* d_in, const int* in_sizes, int n_in,
                              void* d_out, int out_size, void* d_ws, size_t ws_size,
                              hipStream_t stream) {
  const float* sv      = (const float*)d_in[0];
  const float* inp     = (const float*)d_in[1];
  const float* tl_win  = (const float*)d_in[2];
  const float* tl_bin  = (const float*)d_in[3];
  const float* tl_wout = (const float*)d_in[4];
  const float* tl_bout = (const float*)d_in[5];
  const float* tl_w1   = (const float*)d_in[6];
  const float* tl_b1   = (const float*)d_in[7];
  const float* tl_w2   = (const float*)d_in[8];
  const float* tl_b2   = (const float*)d_in[9];
  const float* tl_ln1g = (const float*)d_in[10];
  const float* tl_ln1b = (const float*)d_in[11];
  const float* tl_ln2g = (const float*)d_in[12];
  const float* tl_ln2b = (const float*)d_in[13];
  const float* fg_w0   = (const float*)d_in[14];
  const float* fg_b0   = (const float*)d_in[15];
  const float* fg_w1   = (const float*)d_in[16];
  const float* fg_b1   = (const float*)d_in[17];
  const float* fg_w2   = (const float*)d_in[18];
  const float* fg_b2   = (const float*)d_in[19];
  const float* fbn0    = (const float*)d_in[20];
  const float* fbn1    = (const float*)d_in[21];
  const float* fbn2    = (const float*)d_in[22];
  const float* rc_w0   = (const float*)d_in[23];
  const float* rc_b0   = (const float*)d_in[24];
  const float* rc_w1   = (const float*)d_in[25];
  const float* rc_b1   = (const float*)d_in[26];
  const float* rc_w2   = (const float*)d_in[27];
  const float* rc_b2   = (const float*)d_in[28];
  const float* rbn0    = (const float*)d_in[29];
  const float* rbn1    = (const float*)d_in[30];
  const float* rbn2    = (const float*)d_in[31];
  const float* fl_w0   = (const float*)d_in[32];
  const float* fl_b0   = (const float*)d_in[33];
  const float* fl_w1   = (const float*)d_in[34];
  const float* fl_b1   = (const float*)d_in[35];
  const float* lbn0    = (const float*)d_in[36];
  const float* lbn1    = (const float*)d_in[37];
  (void)in_sizes; (void)n_in; (void)out_size; (void)ws_size;

  float* wsp = (float*)d_ws;
  float* x      = wsp;                        // B*N*F      = 1048576
  float* qkv    = x + BB * NN * FF;           // B*N*192    = 3145728
  float* a      = qkv + BB * NN * 192;        // B*N*F      = 1048576
  float* scores = a + BB * NN * FF;           // B*N        = 16384
  int*   idxb   = (int*)(scores + BB * NN);   // B*TOPK     = 128
  float* r2g    = (float*)(idxb + BB * TOPK); // B*8192     = 65536
  float* h1g    = r2g + BB * 8192;            // B*1024     = 8192
  // bf16 weight planes: 4 arrays x NLAYER*2048*64 ushort = 2 MB total
  unsigned short* w1h = (unsigned short*)(h1g + BB * 1024);
  unsigned short* w1l = w1h + NLAYER * 2048 * 64;
  unsigned short* w2h = w1l + NLAYER * 2048 * 64;
  unsigned short* w2l = w2h + NLAYER * 2048 * 64;
  float* part   = qkv;  // FFN split-K partials reuse qkv+a (4*16384*64 floats)

  float* out = (float*)d_out;  // fp32: h at [0,4096), idx-as-float at [4096,4224)

  k_transpose<<<(BB * NN * FF) / 256, 256, 0, stream>>>(sv, x);
  k_wpack16<<<(NLAYER * 2048 * 64) / 256, 256, 0, stream>>>(tl_w1, w1h, w1l, NLAYER * 2048 * 64);
  k_wpack16<<<(NLAYER * 2048 * 64) / 256, 256, 0, stream>>>(tl_w2, w2h, w2l, NLAYER * 2048 * 64);

  for (int l = 0; l < NLAYER; ++l) {
    k_qkv2<<<dim3(BB * NN / 64, 3), 256, 0, stream>>>(x, tl_win + l * 192 * FF,
                                                      tl_bin + l * 192, qkv);
    k_attn6<<<dim3(NN / 64, NHEAD, BB), 256, 0, stream>>>(qkv, a);
    k_proj2<<<BB * NN / 64, 256, 0, stream>>>(a, tl_wout + l * FF * FF, tl_bout + l * FF,
                                              tl_ln1g + l * FF, tl_ln1b + l * FF, x);
    k_ffn5<<<dim3(BB * NN / 64, 4), 256, 0, stream>>>(x, w1h + l * 2048 * 64,
                                                      w1l + l * 2048 * 64, tl_b1 + l * 2048,
                                                      w2h + l * 2048 * 64, w2l + l * 2048 * 64,
                                                      part);
    k_ffn_ln<<<BB * NN / 4, 256, 0, stream>>>(part, tl_b2 + l * FF,
                                              tl_ln2g + l * FF, tl_ln2b + l * FF, x);
  }

  k_fg2<<<BB * NN / 64, 256, 0, stream>>>(x, fg_w0, fg_b0, fbn0, fg_w1, fg_b1, fbn1,
                                          fg_w2, fg_b2, fbn2, scores);
  k_topk2<<<BB, 256, 0, stream>>>(scores, idxb, out + BB * 512);
  k_group<<<dim3(TOPK, BB), 512, 0, stream>>>(inp, idxb, rc_w0, rc_b0, rbn0,
                                              rc_w1, rc_b1, rbn1, rc_w2, rc_b2, rbn2, r2g);
  k_fl<<<BB * 1024, 64, 0, stream>>>(r2g, fl_w0, fl_b0, lbn0, h1g, 8192, 1024);
  k_fl<<<BB * 512, 64, 0, stream>>>(h1g, fl_w1, fl_b1, lbn1, out, 1024, 512);
}

// Round 3
// 593.511 us; speedup vs baseline: 1.2583x; 1.1002x over previous
//
#include <hip/hip_runtime.h>
#include <hip/hip_bf16.h>
#include <math.h>

#define BB 8
#define NN 2048
#define FF 64
#define DD 6
#define NSAMP 64
#define TOPK 16
#define NHEAD 8
#define HD 8
#define NLAYER 2
#define EPSF 1e-5f
#define R2 0.09f

typedef short short8 __attribute__((ext_vector_type(8)));
typedef float f32x4 __attribute__((ext_vector_type(4)));

// split-pack: u32 = (bf16_hi << 16) | bf16_lo, both RNE. x ≈ hi + lo, err ~2^-16 rel.
__device__ inline unsigned pk2(float x) {
  unsigned b = __float_as_uint(x);
  unsigned hi = (b + 0x7fffu + ((b >> 16) & 1u)) >> 16;
  float r = x - __uint_as_float(hi << 16);
  unsigned c = __float_as_uint(r);
  unsigned lo = (c + 0x7fffu + ((c >> 16) & 1u)) >> 16;
  return (hi << 16) | lo;
}

__device__ inline unsigned short bf16r(float x) {  // RNE bf16
  unsigned b = __float_as_uint(x);
  return (unsigned short)((b + 0x7fffu + ((b >> 16) & 1u)) >> 16);
}

// ---------------- transpose sortvec (B,1,F,N) -> x (B,N,F) ----------------
__global__ void k_transpose(const float* __restrict__ sv, float* __restrict__ x) {
  int i = blockIdx.x * 256 + threadIdx.x;
  if (i >= BB * NN * FF) return;
  int f = i % FF;
  int n = (i / FF) % NN;
  int b = i / (FF * NN);
  x[i] = sv[(b * FF + f) * NN + n];
}

// ---------------- pack fp32 weights -> separate bf16 hi/lo planes ----------------
__global__ void k_wpack16(const float* __restrict__ w, unsigned short* __restrict__ hi,
                          unsigned short* __restrict__ lo, int n) {
  int i = blockIdx.x * 256 + threadIdx.x;
  if (i < n) {
    unsigned p = pk2(w[i]);
    hi[i] = (unsigned short)(p >> 16);
    lo[i] = (unsigned short)(p & 0xffffu);
  }
}

// ---- qkv v3: tiled GEMM; epilogue routes per blockIdx.y:
//   y=0: Q fp32 -> qbuf[b*N+n][64]
//   y=1: K bf16 -> kp[b][h][n][8]  (16B per key, attn-stage-friendly)
//   y=2: V bf16 -> vp[b][h][d][n]  (transposed, contiguous keys)
// K/V go through an LDS u16 tile (reusing xs) for coalesced uint4 stores.
__global__ void k_qkv3(const float* __restrict__ x, const float* __restrict__ win,
                       const float* __restrict__ bin, float* __restrict__ qbuf,
                       uint4* __restrict__ kp4, uint4* __restrict__ vp4) {
  __shared__ float xs[64 * 68];
  __shared__ float ws[64 * 68];
  int row0 = blockIdx.x * 64, y = blockIdx.y, col0 = y * 64;
  int t = threadIdx.x;
  #pragma unroll
  for (int i = 0; i < 4; ++i) {
    int q = t + i * 256, r = q >> 4, c = (q & 15) * 4;
    *(float4*)(xs + r * 68 + c) = *(const float4*)(x + (size_t)(row0 + r) * 64 + c);
    *(float4*)(ws + r * 68 + c) = *(const float4*)(win + (size_t)(col0 + r) * 64 + c);
  }
  __syncthreads();
  int tx = t & 15, ty = t >> 4;
  float acc[4][4] = {};
  for (int f = 0; f < 64; f += 4) {
    float4 xv[4], wv[4];
    #pragma unroll
    for (int ri = 0; ri < 4; ++ri) xv[ri] = *(const float4*)(xs + (ty * 4 + ri) * 68 + f);
    #pragma unroll
    for (int ci = 0; ci < 4; ++ci) wv[ci] = *(const float4*)(ws + (tx + 16 * ci) * 68 + f);
    #pragma unroll
    for (int ri = 0; ri < 4; ++ri)
      #pragma unroll
      for (int ci = 0; ci < 4; ++ci)
        acc[ri][ci] += xv[ri].x * wv[ci].x + xv[ri].y * wv[ci].y +
                       xv[ri].z * wv[ci].z + xv[ri].w * wv[ci].w;
  }
  int b = row0 >> 11, n0 = row0 & (NN - 1);
  if (y == 0) {
    #pragma unroll
    for (int ri = 0; ri < 4; ++ri)
      #pragma unroll
      for (int ci = 0; ci < 4; ++ci) {
        int r = row0 + ty * 4 + ri, c = tx + 16 * ci;
        qbuf[(size_t)r * 64 + c] = acc[ri][ci] + bin[c];
      }
    return;
  }
  __syncthreads();  // all GEMM reads of xs done before reuse
  unsigned short* l16 = (unsigned short*)xs;  // 64x72 u16 tile (9.2 KB)
  if (y == 1) {
    #pragma unroll
    for (int ri = 0; ri < 4; ++ri)
      #pragma unroll
      for (int ci = 0; ci < 4; ++ci) {
        int r = ty * 4 + ri, c = tx + 16 * ci;
        l16[r * 72 + c] = bf16r(acc[ri][ci] + bin[64 + c]);
      }
    __syncthreads();
    #pragma unroll
    for (int i = 0; i < 2; ++i) {
      int idx = t + i * 256;           // 0..511
      int h = idx >> 6, tok = idx & 63;
      uint4 v = *(const uint4*)(l16 + tok * 72 + h * 8);
      kp4[(size_t)(b * NHEAD + h) * NN + n0 + tok] = v;
    }
  } else {
    #pragma unroll
    for (int ri = 0; ri < 4; ++ri)
      #pragma unroll
      for (int ci = 0; ci < 4; ++ci) {
        int r = ty * 4 + ri, c = tx + 16 * ci;
        l16[c * 72 + r] = bf16r(acc[ri][ci] + bin[128 + c]);  // transposed
      }
    __syncthreads();
    #pragma unroll
    for (int i = 0; i < 2; ++i) {
      int idx = t + i * 256;
      int c = idx >> 3, seg = idx & 7;   // c = h*8+d
      uint4 v = *(const uint4*)(l16 + c * 72 + seg * 8);
      vp4[(size_t)(b * 64 + c) * (NN / 8) + (n0 >> 3) + seg] = v;
    }
  }
}

// ---- attention v7: bf16 MFMA flash with pre-packed K/V.
// K staged from kp (1 uint4/thread, coalesced) into 16B rows; B-frag load is
// exec-masked to quad 0 (replaces the 20KB zero-pad plane). V staged from vp
// (coalesced u32). Next chunk register-prefetched during compute (T14).
// LDS 13.8 KB -> 8 blocks/CU.
__global__ void __launch_bounds__(256, 8)
k_attn7(const float* __restrict__ q, const uint4* __restrict__ kp4,
        const unsigned* __restrict__ vp32, float* __restrict__ a) {
  __shared__ uint4 kb4[256];                                            // 4 KB
  __shared__ __attribute__((aligned(16))) unsigned short vb16[9 * 264]; // 4.6 KB
  __shared__ __attribute__((aligned(16))) unsigned short pb16[4 * 16 * 40]; // 5 KB
  int t = threadIdx.x;
  int lane = t & 63, w = t >> 6;
  int nIdx = lane & 15, lq = lane >> 4;
  int h = blockIdx.y, b = blockIdx.z;
  int qwb = blockIdx.x * 64 + w * 16;
  int bh = b * NHEAD + h;
  const float kf = 0.35355339059327373f * 1.4426950408889634f;  // scale*log2e
  // Q A-fragment: quad0 lanes hold k=0..7 (RNE bf16), others zero
  short8 qF = {0, 0, 0, 0, 0, 0, 0, 0};
  if (lq == 0) {
    const float* qr = q + ((size_t)(b * NN + qwb + nIdx)) * 64 + h * HD;
    #pragma unroll
    for (int j = 0; j < 8; ++j) qF[j] = (short)bf16r(qr[j] * kf);
  }
  f32x4 acc = {0.f, 0.f, 0.f, 0.f};
  unsigned short* mypb = pb16 + w * 640;
  const uint4* kbase = kp4 + (size_t)bh * NN;
  const unsigned* vbase = vp32 + (size_t)bh * HD * (NN / 2);
  // prefetch chunk 0
  uint4 kreg = kbase[t];
  unsigned vreg[4];
  #pragma unroll
  for (int i = 0; i < 4; ++i) {
    int g = t + i * 256;
    vreg[i] = vbase[(g >> 7) * (NN / 2) + (g & 127)];
  }
  for (int kc = 0; kc < NN; kc += 256) {
    __syncthreads();  // previous compute done with LDS
    kb4[t] = kreg;
    #pragma unroll
    for (int i = 0; i < 4; ++i) {
      int g = t + i * 256;
      ((unsigned*)vb16)[(g >> 7) * 132 + (g & 127)] = vreg[i];
    }
    if (t < 132) ((unsigned*)(vb16 + 8 * 264))[t] = 0x3f803f80u;  // ones row
    __syncthreads();
    if (kc + 256 < NN) {  // issue next-chunk loads; land during compute
      kreg = kbase[kc + 256 + t];
      #pragma unroll
      for (int i = 0; i < 4; ++i) {
        int g = t + i * 256;
        vreg[i] = vbase[(g >> 7) * (NN / 2) + ((kc + 256) >> 1) + (g & 127)];
      }
    }
    for (int s = 0; s < 8; ++s) {
      int kb = s * 32;
      #pragma unroll
      for (int half = 0; half < 2; ++half) {
        int key = kb + half * 16 + nIdx;
        short8 bF = {0, 0, 0, 0, 0, 0, 0, 0};
        if (lq == 0) bF = *(const short8*)(kb4 + key);  // 16 lanes, 256B contig
        f32x4 c = {0.f, 0.f, 0.f, 0.f};
        c = __builtin_amdgcn_mfma_f32_16x16x32_bf16(qF, bF, c, 0, 0, 0);
        #pragma unroll
        for (int r = 0; r < 4; ++r) {
          float p = __builtin_amdgcn_exp2f(c[r]);
          mypb[(lq * 4 + r) * 40 + half * 16 + nIdx] =
              (unsigned short)(__float_as_uint(p) >> 16);
        }
      }
      // C->A readback (same-wave LDS)
      short8 pa = *(const short8*)(mypb + nIdx * 40 + lq * 8);
      int vn = nIdx < 9 ? nIdx : 8;
      short8 vb = *(const short8*)(vb16 + vn * 264 + kb + lq * 8);
      acc = __builtin_amdgcn_mfma_f32_16x16x32_bf16(pa, vb, acc, 0, 0, 0);
    }
  }
  // epilogue: col 8 holds l = sum(p); divide, scatter cols 0..7
  #pragma unroll
  for (int r = 0; r < 4; ++r) {
    float lr = __shfl(acc[r], (lane & 48) | 8);
    if (nIdx < 8) {
      int row = qwb + lq * 4 + r;
      a[((size_t)(b * NN + row)) * 64 + h * HD + nIdx] = acc[r] / lr;
    }
  }
}

// ------- proj + residual + LN, tiled GEMM ---------
__global__ void k_proj2(const float* __restrict__ a, const float* __restrict__ wout,
                        const float* __restrict__ bout, const float* __restrict__ g,
                        const float* __restrict__ be, float* __restrict__ x) {
  __shared__ float xs[64 * 68];
  __shared__ float ws[64 * 68];
  int row0 = blockIdx.x * 64;
  int t = threadIdx.x;
  #pragma unroll
  for (int i = 0; i < 4; ++i) {
    int q = t + i * 256, r = q >> 4, c = (q & 15) * 4;
    *(float4*)(xs + r * 68 + c) = *(const float4*)(a + (size_t)(row0 + r) * 64 + c);
    *(float4*)(ws + r * 68 + c) = *(const float4*)(wout + r * 64 + c);
  }
  __syncthreads();
  int tx = t & 15, ty = t >> 4;
  float acc[4][4] = {};
  for (int f = 0; f < 64; f += 4) {
    float4 xv[4], wv[4];
    #pragma unroll
    for (int ri = 0; ri < 4; ++ri) xv[ri] = *(const float4*)(xs + (ty * 4 + ri) * 68 + f);
    #pragma unroll
    for (int ci = 0; ci < 4; ++ci) wv[ci] = *(const float4*)(ws + (tx + 16 * ci) * 68 + f);
    #pragma unroll
    for (int ri = 0; ri < 4; ++ri)
      #pragma unroll
      for (int ci = 0; ci < 4; ++ci)
        acc[ri][ci] += xv[ri].x * wv[ci].x + xv[ri].y * wv[ci].y +
                       xv[ri].z * wv[ci].z + xv[ri].w * wv[ci].w;
  }
  #pragma unroll
  for (int ri = 0; ri < 4; ++ri) {
    int rl = ty * 4 + ri;
    float val[4], s = 0.f, sq = 0.f;
    #pragma unroll
    for (int ci = 0; ci < 4; ++ci) {
      int c = tx + 16 * ci;
      val[ci] = x[(size_t)(row0 + rl) * 64 + c] + bout[c] + acc[ri][ci];
      s += val[ci]; sq += val[ci] * val[ci];
    }
    #pragma unroll
    for (int off = 1; off < 16; off <<= 1) { s += __shfl_xor(s, off); sq += __shfl_xor(sq, off); }
    float mean = s * (1.f / 64.f);
    float var = sq * (1.f / 64.f) - mean * mean;
    float rstd = rsqrtf(var + EPSF);
    #pragma unroll
    for (int ci = 0; ci < 4; ++ci) {
      int c = tx + 16 * ci;
      x[(size_t)(row0 + rl) * 64 + c] = (val[ci] - mean) * rstd * g[c] + be[c];
    }
  }
}

// ------- FFN v5: split-bf16 via SEPARATE hi/lo planes (no inner-loop unpack).
__global__ void __launch_bounds__(256, 3)
k_ffn5(const float* __restrict__ x, const unsigned short* __restrict__ w1h,
       const unsigned short* __restrict__ w1l, const float* __restrict__ b1,
       const unsigned short* __restrict__ w2h, const unsigned short* __restrict__ w2l,
       float* __restrict__ part) {
  __shared__ __attribute__((aligned(16))) unsigned short xhi[64 * 64], xlo[64 * 64];
  __shared__ __attribute__((aligned(16))) unsigned short wshi[64 * 64], wslo[64 * 64];
  __shared__ __attribute__((aligned(16))) unsigned short hhi[64 * 64], hlo[64 * 64];
  __shared__ float b1s[64];
  int row0 = blockIdx.x * 64;
  int ks = blockIdx.y;
  int t = threadIdx.x;
  int lane = t & 63, wv = t >> 6;
  int lm = lane & 15, lq = lane >> 4;

  int kc = ks * 512;
  uint4 rwh[2], rwl[2];
  #pragma unroll
  for (int i = 0; i < 2; ++i) {
    int q = t + i * 256;
    rwh[i] = *(const uint4*)(w1h + (size_t)(kc + (q >> 3)) * 64 + (q & 7) * 8);
    rwl[i] = *(const uint4*)(w1l + (size_t)(kc + (q >> 3)) * 64 + (q & 7) * 8);
  }
  float rbv = (t < 64) ? b1[kc + t] : 0.f;

  #pragma unroll
  for (int i = 0; i < 4; ++i) {
    int q = t + i * 256, r = q >> 4, c = (q & 15) * 4;
    float4 v = *(const float4*)(x + (size_t)(row0 + r) * 64 + c);
    unsigned p0 = pk2(v.x), p1 = pk2(v.y), p2 = pk2(v.z), p3 = pk2(v.w);
    int off = r * 128 + (((c >> 3) ^ (r & 7)) << 4) + ((c & 7) << 1);
    *(uint2*)((char*)xhi + off) = (uint2){(p0 >> 16) | (p1 & 0xffff0000u),
                                          (p2 >> 16) | (p3 & 0xffff0000u)};
    *(uint2*)((char*)xlo + off) = (uint2){(p0 & 0xffffu) | (p1 << 16),
                                          (p2 & 0xffffu) | (p3 << 16)};
  }

  f32x4 acc[4];
  #pragma unroll
  for (int tn = 0; tn < 4; ++tn) acc[tn] = (f32x4){0.f, 0.f, 0.f, 0.f};

  for (int ch = 0; ch < 8; ++ch) {
    int kcc = kc + ch * 64;
    __syncthreads();  // (A)
    #pragma unroll
    for (int i = 0; i < 2; ++i) {
      int q = t + i * 256, r = q >> 3, s = q & 7;
      int off = r * 128 + ((s ^ (r & 7)) << 4);
      *(uint4*)((char*)wshi + off) = rwh[i];
      *(uint4*)((char*)wslo + off) = rwl[i];
    }
    if (t < 64) b1s[t] = rbv;
    __syncthreads();  // (B)
    #pragma unroll
    for (int i = 0; i < 2; ++i) {
      int q = t + i * 256;
      rwh[i] = *(const uint4*)(w2h + (size_t)(q >> 3) * 2048 + kcc + (q & 7) * 8);
      rwl[i] = *(const uint4*)(w2l + (size_t)(q >> 3) * 2048 + kcc + (q & 7) * 8);
    }
    f32x4 h4[4];
    #pragma unroll
    for (int tn = 0; tn < 4; ++tn) h4[tn] = (f32x4){0.f, 0.f, 0.f, 0.f};
    #pragma unroll
    for (int kb = 0; kb < 64; kb += 32) {
      int sw = ((((kb >> 3) + lq) ^ (lm & 7)) << 4);
      int arow = wv * 16 + lm;
      short8 ahi = *(const short8*)((const char*)xhi + arow * 128 + sw);
      short8 alo = *(const short8*)((const char*)xlo + arow * 128 + sw);
      #pragma unroll
      for (int tn = 0; tn < 4; ++tn) {
        int brow = tn * 16 + lm;
        short8 bhi = *(const short8*)((const char*)wshi + brow * 128 + sw);
        short8 blo = *(const short8*)((const char*)wslo + brow * 128 + sw);
        h4[tn] = __builtin_amdgcn_mfma_f32_16x16x32_bf16(ahi, bhi, h4[tn], 0, 0, 0);
        h4[tn] = __builtin_amdgcn_mfma_f32_16x16x32_bf16(ahi, blo, h4[tn], 0, 0, 0);
        h4[tn] = __builtin_amdgcn_mfma_f32_16x16x32_bf16(alo, bhi, h4[tn], 0, 0, 0);
      }
    }
    #pragma unroll
    for (int tn = 0; tn < 4; ++tn)
      #pragma unroll
      for (int r = 0; r < 4; ++r) {
        float hv = fmaxf(h4[tn][r] + b1s[tn * 16 + lm], 0.f);
        unsigned u = __float_as_uint(hv);
        float resid = hv - __uint_as_float(u & 0xffff0000u);
        unsigned c2 = __float_as_uint(resid);
        int hrow = wv * 16 + lq * 4 + r, hcol = tn * 16 + lm;
        int off = hrow * 128 + (((hcol >> 3) ^ (hrow & 7)) << 4) + ((hcol & 7) << 1);
        *(unsigned short*)((char*)hhi + off) = (unsigned short)(u >> 16);
        *(unsigned short*)((char*)hlo + off) =
            (unsigned short)((c2 + 0x7fffu + ((c2 >> 16) & 1u)) >> 16);
      }
    __syncthreads();  // (C)
    #pragma unroll
    for (int i = 0; i < 2; ++i) {
      int q = t + i * 256, r = q >> 3, s = q & 7;
      int off = r * 128 + ((s ^ (r & 7)) << 4);
      *(uint4*)((char*)wshi + off) = rwh[i];
      *(uint4*)((char*)wslo + off) = rwl[i];
    }
    __syncthreads();  // (D)
    if (ch < 7) {
      int kcn = kcc + 64;
      #pragma unroll
      for (int i = 0; i < 2; ++i) {
        int q = t + i * 256;
        rwh[i] = *(const uint4*)(w1h + (size_t)(kcn + (q >> 3)) * 64 + (q & 7) * 8);
        rwl[i] = *(const uint4*)(w1l + (size_t)(kcn + (q >> 3)) * 64 + (q & 7) * 8);
      }
      if (t < 64) rbv = b1[kcn + t];
    }
    #pragma unroll
    for (int kb = 0; kb < 64; kb += 32) {
      int sw = ((((kb >> 3) + lq) ^ (lm & 7)) << 4);
      int arow = wv * 16 + lm;
      short8 ahi = *(const short8*)((const char*)hhi + arow * 128 + sw);
      short8 alo = *(const short8*)((const char*)hlo + arow * 128 + sw);
      #pragma unroll
      for (int tn = 0; tn < 4; ++tn) {
        int brow = tn * 16 + lm;
        short8 bhi = *(const short8*)((const char*)wshi + brow * 128 + sw);
        short8 blo = *(const short8*)((const char*)wslo + brow * 128 + sw);
        acc[tn] = __builtin_amdgcn_mfma_f32_16x16x32_bf16(ahi, bhi, acc[tn], 0, 0, 0);
        acc[tn] = __builtin_amdgcn_mfma_f32_16x16x32_bf16(ahi, blo, acc[tn], 0, 0, 0);
        acc[tn] = __builtin_amdgcn_mfma_f32_16x16x32_bf16(alo, bhi, acc[tn], 0, 0, 0);
      }
    }
  }
  float* pb = part + (size_t)ks * (BB * NN * 64);
  #pragma unroll
  for (int tn = 0; tn < 4; ++tn)
    #pragma unroll
    for (int r = 0; r < 4; ++r)
      pb[(size_t)(row0 + wv * 16 + lq * 4 + r) * 64 + tn * 16 + lm] = acc[tn][r];
}

// ------- combine 4 partials + residual + b2 + LN; one wave per row ---------
__global__ void k_ffn_ln(const float* __restrict__ part, const float* __restrict__ b2,
                         const float* __restrict__ g, const float* __restrict__ be,
                         float* __restrict__ x) {
  int row = blockIdx.x * 4 + (threadIdx.x >> 6);
  int j = threadIdx.x & 63;
  size_t o = (size_t)row * 64 + j;
  const size_t S = (size_t)BB * NN * 64;
  float val = x[o] + b2[j] + ((part[o] + part[o + S]) + (part[o + 2 * S] + part[o + 3 * S]));
  float s = val;
  for (int off = 32; off; off >>= 1) s += __shfl_xor(s, off);
  s *= (1.f / 64.f);
  float d = val - s;
  float v = d * d;
  for (int off = 32; off; off >>= 1) v += __shfl_xor(v, off);
  v *= (1.f / 64.f);
  x[o] = d * rsqrtf(v + EPSF) * g[j] + be[j];
}

// ------- score head tiled ----------
__global__ void k_fg2(const float* __restrict__ x,
                      const float* __restrict__ w0, const float* __restrict__ b0, const float* __restrict__ bn0,
                      const float* __restrict__ w1, const float* __restrict__ b1, const float* __restrict__ bn1,
                      const float* __restrict__ w2, const float* __restrict__ b2, const float* __restrict__ bn2,
                      float* __restrict__ scores) {
  __shared__ float xs[64 * 68];
  __shared__ float ws[64 * 68];
  __shared__ float s0s[64 * 68];
  __shared__ float s1s[64 * 20];
  int row0 = blockIdx.x * 64;
  int t = threadIdx.x;
  #pragma unroll
  for (int i = 0; i < 4; ++i) {
    int q = t + i * 256, r = q >> 4, c = (q & 15) * 4;
    *(float4*)(xs + r * 68 + c) = *(const float4*)(x + (size_t)(row0 + r) * 64 + c);
    *(float4*)(ws + r * 68 + c) = *(const float4*)(w0 + r * 64 + c);
  }
  __syncthreads();
  int tx = t & 15, ty = t >> 4;
  float acc[4][4] = {};
  for (int f = 0; f < 64; f += 4) {
    float4 xv[4], wv[4];
    #pragma unroll
    for (int ri = 0; ri < 4; ++ri) xv[ri] = *(const float4*)(xs + (ty * 4 + ri) * 68 + f);
    #pragma unroll
    for (int ci = 0; ci < 4; ++ci) wv[ci] = *(const float4*)(ws + (tx + 16 * ci) * 68 + f);
    #pragma unroll
    for (int ri = 0; ri < 4; ++ri)
      #pragma unroll
      for (int ci = 0; ci < 4; ++ci)
        acc[ri][ci] += xv[ri].x * wv[ci].x + xv[ri].y * wv[ci].y +
                       xv[ri].z * wv[ci].z + xv[ri].w * wv[ci].w;
  }
  #pragma unroll
  for (int ri = 0; ri < 4; ++ri)
    #pragma unroll
    for (int ci = 0; ci < 4; ++ci) {
      int c = tx + 16 * ci;
      float sc = bn0[c] * rsqrtf(bn0[192 + c] + EPSF);
      float v = (acc[ri][ci] + b0[c] - bn0[128 + c]) * sc + bn0[64 + c];
      s0s[(ty * 4 + ri) * 68 + c] = fmaxf(v, 0.f);
    }
  __syncthreads();
  {
    int rl = t & 63, j0 = t >> 6;
    #pragma unroll
    for (int i = 0; i < 4; ++i) {
      int j = j0 + 4 * i;
      float s = b1[j];
      const float* wr = w1 + j * 64;
      #pragma unroll 16
      for (int c = 0; c < 64; ++c) s += s0s[rl * 68 + c] * wr[c];
      float sc = bn1[j] * rsqrtf(bn1[48 + j] + EPSF);
      s = (s - bn1[32 + j]) * sc + bn1[16 + j];
      s1s[rl * 20 + j] = fmaxf(s, 0.f);
    }
  }
  __syncthreads();
  if (t < 64) {
    float s = b2[0];
    #pragma unroll
    for (int o = 0; o < 16; ++o) s += s1s[t * 20 + o] * w2[o];
    float sc = bn2[0] * rsqrtf(bn2[3] + EPSF);
    s = (s - bn2[2]) * sc + bn2[1];
    scores[row0 + t] = fmaxf(s, 0.f);
  }
}

// ---- top-k (k=16) ----
__global__ void k_topk2(const float* __restrict__ scores, int* __restrict__ idx,
                        float* __restrict__ out_idx) {
  int b = blockIdx.x, t = threadIdx.x;
  float v[8];
  int base = b * NN;
  #pragma unroll
  for (int u = 0; u < 8; ++u) v[u] = scores[base + t + 256 * u];
  __shared__ float wvs[4];
  __shared__ int wis[4];
  __shared__ int winner;
  unsigned taken = 0;
  for (int r = 0; r < TOPK; ++r) {
    float best = -1e30f; int bi = 1 << 30;
    #pragma unroll
    for (int u = 0; u < 8; ++u) {
      if (!((taken >> u) & 1)) {
        float vv = v[u]; int ii = t + 256 * u;
        if (vv > best || (vv == best && ii < bi)) { best = vv; bi = ii; }
      }
    }
    for (int off = 32; off; off >>= 1) {
      float ov = __shfl_xor(best, off);
      int oi = __shfl_xor(bi, off);
      if (ov > best || (ov == best && oi < bi)) { best = ov; bi = oi; }
    }
    if ((t & 63) == 0) { wvs[t >> 6] = best; wis[t >> 6] = bi; }
    __syncthreads();
    if (t == 0) {
      float B = wvs[0]; int I = wis[0];
      #pragma unroll
      for (int q = 1; q < 4; ++q)
        if (wvs[q] > B || (wvs[q] == B && wis[q] < I)) { B = wvs[q]; I = wis[q]; }
      winner = I;
      idx[b * TOPK + r] = I;
      out_idx[b * TOPK + r] = (float)I;
    }
    __syncthreads();
    int w = winner;
    if ((w & 255) == t) taken |= 1u << (w >> 8);
  }
}

// ---------------- ball query + 3 conv stages, v2: 512 threads (8 waves) per (b,k).
__global__ void __launch_bounds__(512)
k_group(const float* __restrict__ inp, const int* __restrict__ idx,
        const float* __restrict__ w0, const float* __restrict__ b0, const float* __restrict__ bn0,
        const float* __restrict__ w1, const float* __restrict__ b1, const float* __restrict__ bn1,
        const float* __restrict__ w2, const float* __restrict__ b2, const float* __restrict__ bn2,
        float* __restrict__ r2g) {
  __shared__ int swave[8 * 64];
  __shared__ int scnt[8];
  __shared__ int gidx[NSAMP];
  __shared__ __attribute__((aligned(16))) float gsh[65 * DD];  // 390
  __shared__ __attribute__((aligned(16))) float r0[128];
  __shared__ __attribute__((aligned(16))) float r1[256];
  int k = blockIdx.x, b = blockIdx.y;
  int t = threadIdx.x;
  int lane = t & 63, w = t >> 6;
  int qn = idx[b * TOPK + k];
  const float* px = inp + (size_t)b * DD * NN;
  float qx = px[qn], qy = px[NN + qn], qz = px[2 * NN + qn];
  {
    int cnt = 0;
    #pragma unroll
    for (int i = 0; i < 4; ++i) {
      int n = w * 256 + i * 64 + lane;
      float dx = px[n] - qx, dy = px[NN + n] - qy, dz = px[2 * NN + n] - qz;
      bool flag = (dx * dx + dy * dy + dz * dz <= R2);
      unsigned long long m = __ballot(flag);
      int pos = cnt + __popcll(m & ((1ull << lane) - 1ull));
      if (flag && pos < NSAMP) swave[w * 64 + pos] = n;
      cnt += (int)__popcll(m);
    }
    if (lane == 0) scnt[w] = cnt < NSAMP ? cnt : NSAMP;
  }
  __syncthreads();
  if (t < NSAMP) {
    int run = 0, val = -1;
    #pragma unroll
    for (int ww = 0; ww < 8; ++ww) {
      int c = scnt[ww];
      int loc = t - run;
      if (loc >= 0 && loc < c) val = swave[ww * 64 + loc];
      run += c;
    }
    gidx[t] = val;
  }
  __syncthreads();
  if (t < NSAMP) {
    int g0 = gidx[0];
    int gt = gidx[t];
    gidx[t] = (gt < 0) ? g0 : gt;
  }
  __syncthreads();
  if (t < 65 * DD) {
    int p = t / DD, d = t - p * DD;
    int n = (p == 0) ? qn : gidx[p - 1];
    gsh[t] = px[d * NN + n];
  }
  __syncthreads();
  {
    int c = t >> 2, part = t & 3;
    const float2* wr = (const float2*)(w0 + c * 390 + part * 98);
    const float2* gr = (const float2*)(gsh + part * 98);
    int n2 = (part == 3) ? 48 : 49;
    float s = 0.f;
    #pragma unroll 7
    for (int i = 0; i < n2; ++i) {
      float2 a = gr[i], ww = wr[i];
      s += a.x * ww.x + a.y * ww.y;
    }
    s += __shfl_xor(s, 1);
    s += __shfl_xor(s, 2);
    if (part == 0) {
      s += b0[c];
      float sc = bn0[c] * rsqrtf(bn0[384 + c] + EPSF);
      s = (s - bn0[256 + c]) * sc + bn0[128 + c];
      r0[c] = fmaxf(s, 0.f);
    }
  }
  __syncthreads();
  {
    int c = t >> 1, part = t & 1;
    const float4* wr = (const float4*)(w1 + c * 128 + part * 64);
    const float4* rr = (const float4*)(r0 + part * 64);
    float s0 = 0.f, s1 = 0.f, s2 = 0.f, s3 = 0.f;
    #pragma unroll 8
    for (int o = 0; o < 16; ++o) {
      float4 a = rr[o], ww = wr[o];
      s0 += a.x * ww.x; s1 += a.y * ww.y; s2 += a.z * ww.z; s3 += a.w * ww.w;
    }
    float s = (s0 + s1) + (s2 + s3);
    s += __shfl_xor(s, 1);
    if (part == 0) {
      s += b1[c];
      float sc = bn1[c] * rsqrtf(bn1[768 + c] + EPSF);
      s = (s - bn1[512 + c]) * sc + bn1[256 + c];
      r1[c] = fmaxf(s, 0.f);
    }
  }
  __syncthreads();
  {
    int c = t;
    const float4* wr = (const float4*)(w2 + c * 256);
    const float4* rr = (const float4*)r1;
    float s0 = 0.f, s1 = 0.f, s2 = 0.f, s3 = 0.f;
    #pragma unroll 8
    for (int o = 0; o < 64; ++o) {
      float4 a = rr[o], ww = wr[o];
      s0 += a.x * ww.x; s1 += a.y * ww.y; s2 += a.z * ww.z; s3 += a.w * ww.w;
    }
    float s = (s0 + s1) + (s2 + s3) + b2[c];
    float sc = bn2[c] * rsqrtf(bn2[1536 + c] + EPSF);
    s = (s - bn2[1024 + c]) * sc + bn2[512 + c];
    r2g[b * 8192 + c * TOPK + k] = fmaxf(s, 0.f);
  }
}

// ---------------- FC + BN + ReLU (wave-reduced dot), block=64 ----------------
__global__ void k_fl(const float* __restrict__ hin, const float* __restrict__ w,
                     const float* __restrict__ bias, const float* __restrict__ bn,
                     float* __restrict__ hout, int IN, int OUT) {
  int blk = blockIdx.x;
  int b = blk / OUT, j = blk % OUT;
  int lane = threadIdx.x;
  const float* hr = hin + (size_t)b * IN;
  const float* wr = w + (size_t)j * IN;
  float s = 0.f;
  for (int i = lane; i < IN; i += 64) s += hr[i] * wr[i];
  for (int o = 32; o; o >>= 1) s += __shfl_xor(s, o);
  if (lane == 0) {
    s += bias[j];
    float sc = bn[j] * rsqrtf(bn[3 * OUT + j] + EPSF);
    s = (s - bn[2 * OUT + j]) * sc + bn[OUT + j];
    hout[b * OUT + j] = fmaxf(s, 0.f);
  }
}

extern "C" void kernel_launch(void* const* d_in, const int* in_sizes, int n_in,
                              void* d_out, int out_size, void* d_ws, size_t ws_size,
                              hipStream_t stream) {
  const float* sv      = (const float*)d_in[0];
  const float* inp     = (const float*)d_in[1];
  const float* tl_win  = (const float*)d_in[2];
  const float* tl_bin  = (const float*)d_in[3];
  const float* tl_wout = (const float*)d_in[4];
  const float* tl_bout = (const float*)d_in[5];
  const float* tl_w1   = (const float*)d_in[6];
  const float* tl_b1   = (const float*)d_in[7];
  const float* tl_w2   = (const float*)d_in[8];
  const float* tl_b2   = (const float*)d_in[9];
  const float* tl_ln1g = (const float*)d_in[10];
  const float* tl_ln1b = (const float*)d_in[11];
  const float* tl_ln2g = (const float*)d_in[12];
  const float* tl_ln2b = (const float*)d_in[13];
  const float* fg_w0   = (const float*)d_in[14];
  const float* fg_b0   = (const float*)d_in[15];
  const float* fg_w1   = (const float*)d_in[16];
  const float* fg_b1   = (const float*)d_in[17];
  const float* fg_w2   = (const float*)d_in[18];
  const float* fg_b2   = (const float*)d_in[19];
  const float* fbn0    = (const float*)d_in[20];
  const float* fbn1    = (const float*)d_in[21];
  const float* fbn2    = (const float*)d_in[22];
  const float* rc_w0   = (const float*)d_in[23];
  const float* rc_b0   = (const float*)d_in[24];
  const float* rc_w1   = (const float*)d_in[25];
  const float* rc_b1   = (const float*)d_in[26];
  const float* rc_w2   = (const float*)d_in[27];
  const float* rc_b2   = (const float*)d_in[28];
  const float* rbn0    = (const float*)d_in[29];
  const float* rbn1    = (const float*)d_in[30];
  const float* rbn2    = (const float*)d_in[31];
  const float* fl_w0   = (const float*)d_in[32];
  const float* fl_b0   = (const float*)d_in[33];
  const float* fl_w1   = (const float*)d_in[34];
  const float* fl_b1   = (const float*)d_in[35];
  const float* lbn0    = (const float*)d_in[36];
  const float* lbn1    = (const float*)d_in[37];
  (void)in_sizes; (void)n_in; (void)out_size; (void)ws_size;

  float* wsp = (float*)d_ws;
  float* x      = wsp;                        // B*N*F      = 1048576
  float* qkv    = x + BB * NN * FF;           // 3145728-float region
  float* a      = qkv + BB * NN * 192;        // B*N*F      = 1048576
  float* scores = a + BB * NN * FF;           // B*N        = 16384
  int*   idxb   = (int*)(scores + BB * NN);   // B*TOPK     = 128
  float* r2g    = (float*)(idxb + BB * TOPK); // B*8192     = 65536
  float* h1g    = r2g + BB * 8192;            // B*1024     = 8192
  unsigned short* w1h = (unsigned short*)(h1g + BB * 1024);
  unsigned short* w1l = w1h + NLAYER * 2048 * 64;
  unsigned short* w2h = w1l + NLAYER * 2048 * 64;
  unsigned short* w2l = w2h + NLAYER * 2048 * 64;
  // qkv region carve-out: Q fp32 (1M floats) | kp bf16 (1M u16) | vp bf16 (1M u16)
  float* qbuf = qkv;
  unsigned short* kp = (unsigned short*)(qkv + BB * NN * FF);
  unsigned short* vp = kp + (size_t)BB * NHEAD * NN * HD;
  float* part = qkv;  // FFN split-K partials reuse qkv+a (dead by then)

  float* out = (float*)d_out;  // fp32: h at [0,4096), idx-as-float at [4096,4224)

  k_transpose<<<(BB * NN * FF) / 256, 256, 0, stream>>>(sv, x);
  k_wpack16<<<(NLAYER * 2048 * 64) / 256, 256, 0, stream>>>(tl_w1, w1h, w1l, NLAYER * 2048 * 64);
  k_wpack16<<<(NLAYER * 2048 * 64) / 256, 256, 0, stream>>>(tl_w2, w2h, w2l, NLAYER * 2048 * 64);

  for (int l = 0; l < NLAYER; ++l) {
    k_qkv3<<<dim3(BB * NN / 64, 3), 256, 0, stream>>>(x, tl_win + l * 192 * FF,
                                                      tl_bin + l * 192, qbuf,
                                                      (uint4*)kp, (uint4*)vp);
    k_attn7<<<dim3(NN / 64, NHEAD, BB), 256, 0, stream>>>(qbuf, (const uint4*)kp,
                                                          (const unsigned*)vp, a);
    k_proj2<<<BB * NN / 64, 256, 0, stream>>>(a, tl_wout + l * FF * FF, tl_bout + l * FF,
                                              tl_ln1g + l * FF, tl_ln1b + l * FF, x);
    k_ffn5<<<dim3(BB * NN / 64, 4), 256, 0, stream>>>(x, w1h + l * 2048 * 64,
                                                      w1l + l * 2048 * 64, tl_b1 + l * 2048,
                                                      w2h + l * 2048 * 64, w2l + l * 2048 * 64,
                                                      part);
    k_ffn_ln<<<BB * NN / 4, 256, 0, stream>>>(part, tl_b2 + l * FF,
                                              tl_ln2g + l * FF, tl_ln2b + l * FF, x);
  }

  k_fg2<<<BB * NN / 64, 256, 0, stream>>>(x, fg_w0, fg_b0, fbn0, fg_w1, fg_b1, fbn1,
                                          fg_w2, fg_b2, fbn2, scores);
  k_topk2<<<BB, 256, 0, stream>>>(scores, idxb, out + BB * 512);
  k_group<<<dim3(TOPK, BB), 512, 0, stream>>>(inp, idxb, rc_w0, rc_b0, rbn0,
                                              rc_w1, rc_b1, rbn1, rc_w2, rc_b2, rbn2, r2g);
  k_fl<<<BB * 1024, 64, 0, stream>>>(r2g, fl_w0, fl_b0, lbn0, h1g, 8192, 1024);
  k_fl<<<BB * 512, 64, 0, stream>>>(h1g, fl_w1, fl_b1, lbn1, out, 1024, 512);
}

// Round 4
// 577.055 us; speedup vs baseline: 1.2942x; 1.0285x over previous
//
#include <hip/hip_runtime.h>
#include <hip/hip_bf16.h>
#include <math.h>

#define BB 8
#define NN 2048
#define FF 64
#define DD 6
#define NSAMP 64
#define TOPK 16
#define NHEAD 8
#define HD 8
#define NLAYER 2
#define EPSF 1e-5f
#define R2 0.09f

typedef short short8 __attribute__((ext_vector_type(8)));
typedef float f32x4 __attribute__((ext_vector_type(4)));

// split-pack: u32 = (bf16_hi << 16) | bf16_lo, both RNE. x ≈ hi + lo, err ~2^-16 rel.
__device__ inline unsigned pk2(float x) {
  unsigned b = __float_as_uint(x);
  unsigned hi = (b + 0x7fffu + ((b >> 16) & 1u)) >> 16;
  float r = x - __uint_as_float(hi << 16);
  unsigned c = __float_as_uint(r);
  unsigned lo = (c + 0x7fffu + ((c >> 16) & 1u)) >> 16;
  return (hi << 16) | lo;
}

__device__ inline unsigned short bf16r(float x) {  // RNE bf16
  unsigned b = __float_as_uint(x);
  return (unsigned short)((b + 0x7fffu + ((b >> 16) & 1u)) >> 16);
}

// ---------------- transpose sortvec (B,1,F,N) -> x (B,N,F) ----------------
__global__ void k_transpose(const float* __restrict__ sv, float* __restrict__ x) {
  int i = blockIdx.x * 256 + threadIdx.x;
  if (i >= BB * NN * FF) return;
  int f = i % FF;
  int n = (i / FF) % NN;
  int b = i / (FF * NN);
  x[i] = sv[(b * FF + f) * NN + n];
}

// ---------------- pack fp32 weights -> separate bf16 hi/lo planes ----------------
__global__ void k_wpack16(const float* __restrict__ w, unsigned short* __restrict__ hi,
                          unsigned short* __restrict__ lo, int n) {
  int i = blockIdx.x * 256 + threadIdx.x;
  if (i < n) {
    unsigned p = pk2(w[i]);
    hi[i] = (unsigned short)(p >> 16);
    lo[i] = (unsigned short)(p & 0xffffu);
  }
}

// ---- qkv v3: tiled GEMM; epilogue routes per blockIdx.y:
//   y=0: Q fp32 -> qbuf[b*N+n][64]
//   y=1: K bf16 -> kp[b][h][n][8]  (16B per key, attn-stage-friendly)
//   y=2: V bf16 -> vp[b][h][d][n]  (transposed, contiguous keys)
__global__ void k_qkv3(const float* __restrict__ x, const float* __restrict__ win,
                       const float* __restrict__ bin, float* __restrict__ qbuf,
                       uint4* __restrict__ kp4, uint4* __restrict__ vp4) {
  __shared__ float xs[64 * 68];
  __shared__ float ws[64 * 68];
  int row0 = blockIdx.x * 64, y = blockIdx.y, col0 = y * 64;
  int t = threadIdx.x;
  #pragma unroll
  for (int i = 0; i < 4; ++i) {
    int q = t + i * 256, r = q >> 4, c = (q & 15) * 4;
    *(float4*)(xs + r * 68 + c) = *(const float4*)(x + (size_t)(row0 + r) * 64 + c);
    *(float4*)(ws + r * 68 + c) = *(const float4*)(win + (size_t)(col0 + r) * 64 + c);
  }
  __syncthreads();
  int tx = t & 15, ty = t >> 4;
  float acc[4][4] = {};
  for (int f = 0; f < 64; f += 4) {
    float4 xv[4], wv[4];
    #pragma unroll
    for (int ri = 0; ri < 4; ++ri) xv[ri] = *(const float4*)(xs + (ty * 4 + ri) * 68 + f);
    #pragma unroll
    for (int ci = 0; ci < 4; ++ci) wv[ci] = *(const float4*)(ws + (tx + 16 * ci) * 68 + f);
    #pragma unroll
    for (int ri = 0; ri < 4; ++ri)
      #pragma unroll
      for (int ci = 0; ci < 4; ++ci)
        acc[ri][ci] += xv[ri].x * wv[ci].x + xv[ri].y * wv[ci].y +
                       xv[ri].z * wv[ci].z + xv[ri].w * wv[ci].w;
  }
  int b = row0 >> 11, n0 = row0 & (NN - 1);
  if (y == 0) {
    #pragma unroll
    for (int ri = 0; ri < 4; ++ri)
      #pragma unroll
      for (int ci = 0; ci < 4; ++ci) {
        int r = row0 + ty * 4 + ri, c = tx + 16 * ci;
        qbuf[(size_t)r * 64 + c] = acc[ri][ci] + bin[c];
      }
    return;
  }
  __syncthreads();  // all GEMM reads of xs done before reuse
  unsigned short* l16 = (unsigned short*)xs;  // 64x72 u16 tile (9.2 KB)
  if (y == 1) {
    #pragma unroll
    for (int ri = 0; ri < 4; ++ri)
      #pragma unroll
      for (int ci = 0; ci < 4; ++ci) {
        int r = ty * 4 + ri, c = tx + 16 * ci;
        l16[r * 72 + c] = bf16r(acc[ri][ci] + bin[64 + c]);
      }
    __syncthreads();
    #pragma unroll
    for (int i = 0; i < 2; ++i) {
      int idx = t + i * 256;           // 0..511
      int h = idx >> 6, tok = idx & 63;
      uint4 v = *(const uint4*)(l16 + tok * 72 + h * 8);
      kp4[(size_t)(b * NHEAD + h) * NN + n0 + tok] = v;
    }
  } else {
    #pragma unroll
    for (int ri = 0; ri < 4; ++ri)
      #pragma unroll
      for (int ci = 0; ci < 4; ++ci) {
        int r = ty * 4 + ri, c = tx + 16 * ci;
        l16[c * 72 + r] = bf16r(acc[ri][ci] + bin[128 + c]);  // transposed
      }
    __syncthreads();
    #pragma unroll
    for (int i = 0; i < 2; ++i) {
      int idx = t + i * 256;
      int c = idx >> 3, seg = idx & 7;   // c = h*8+d
      uint4 v = *(const uint4*)(l16 + c * 72 + seg * 8);
      vp4[(size_t)(b * 64 + c) * (NN / 8) + (n0 >> 3) + seg] = v;
    }
  }
}

// ---- attention v7: bf16 MFMA flash with pre-packed K/V. ----
__global__ void __launch_bounds__(256, 8)
k_attn7(const float* __restrict__ q, const uint4* __restrict__ kp4,
        const unsigned* __restrict__ vp32, float* __restrict__ a) {
  __shared__ uint4 kb4[256];                                            // 4 KB
  __shared__ __attribute__((aligned(16))) unsigned short vb16[9 * 264]; // 4.6 KB
  __shared__ __attribute__((aligned(16))) unsigned short pb16[4 * 16 * 40]; // 5 KB
  int t = threadIdx.x;
  int lane = t & 63, w = t >> 6;
  int nIdx = lane & 15, lq = lane >> 4;
  int h = blockIdx.y, b = blockIdx.z;
  int qwb = blockIdx.x * 64 + w * 16;
  int bh = b * NHEAD + h;
  const float kf = 0.35355339059327373f * 1.4426950408889634f;  // scale*log2e
  short8 qF = {0, 0, 0, 0, 0, 0, 0, 0};
  if (lq == 0) {
    const float* qr = q + ((size_t)(b * NN + qwb + nIdx)) * 64 + h * HD;
    #pragma unroll
    for (int j = 0; j < 8; ++j) qF[j] = (short)bf16r(qr[j] * kf);
  }
  f32x4 acc = {0.f, 0.f, 0.f, 0.f};
  unsigned short* mypb = pb16 + w * 640;
  const uint4* kbase = kp4 + (size_t)bh * NN;
  const unsigned* vbase = vp32 + (size_t)bh * HD * (NN / 2);
  uint4 kreg = kbase[t];
  unsigned vreg[4];
  #pragma unroll
  for (int i = 0; i < 4; ++i) {
    int g = t + i * 256;
    vreg[i] = vbase[(g >> 7) * (NN / 2) + (g & 127)];
  }
  for (int kc = 0; kc < NN; kc += 256) {
    __syncthreads();
    kb4[t] = kreg;
    #pragma unroll
    for (int i = 0; i < 4; ++i) {
      int g = t + i * 256;
      ((unsigned*)vb16)[(g >> 7) * 132 + (g & 127)] = vreg[i];
    }
    if (t < 132) ((unsigned*)(vb16 + 8 * 264))[t] = 0x3f803f80u;  // ones row
    __syncthreads();
    if (kc + 256 < NN) {
      kreg = kbase[kc + 256 + t];
      #pragma unroll
      for (int i = 0; i < 4; ++i) {
        int g = t + i * 256;
        vreg[i] = vbase[(g >> 7) * (NN / 2) + ((kc + 256) >> 1) + (g & 127)];
      }
    }
    for (int s = 0; s < 8; ++s) {
      int kb = s * 32;
      #pragma unroll
      for (int half = 0; half < 2; ++half) {
        int key = kb + half * 16 + nIdx;
        short8 bF = {0, 0, 0, 0, 0, 0, 0, 0};
        if (lq == 0) bF = *(const short8*)(kb4 + key);
        f32x4 c = {0.f, 0.f, 0.f, 0.f};
        c = __builtin_amdgcn_mfma_f32_16x16x32_bf16(qF, bF, c, 0, 0, 0);
        #pragma unroll
        for (int r = 0; r < 4; ++r) {
          float p = __builtin_amdgcn_exp2f(c[r]);
          mypb[(lq * 4 + r) * 40 + half * 16 + nIdx] =
              (unsigned short)(__float_as_uint(p) >> 16);
        }
      }
      short8 pa = *(const short8*)(mypb + nIdx * 40 + lq * 8);
      int vn = nIdx < 9 ? nIdx : 8;
      short8 vb = *(const short8*)(vb16 + vn * 264 + kb + lq * 8);
      acc = __builtin_amdgcn_mfma_f32_16x16x32_bf16(pa, vb, acc, 0, 0, 0);
    }
  }
  #pragma unroll
  for (int r = 0; r < 4; ++r) {
    float lr = __shfl(acc[r], (lane & 48) | 8);
    if (nIdx < 8) {
      int row = qwb + lq * 4 + r;
      a[((size_t)(b * NN + row)) * 64 + h * HD + nIdx] = acc[r] / lr;
    }
  }
}

// ------- proj + residual + LN, tiled GEMM ---------
__global__ void k_proj2(const float* __restrict__ a, const float* __restrict__ wout,
                        const float* __restrict__ bout, const float* __restrict__ g,
                        const float* __restrict__ be, float* __restrict__ x) {
  __shared__ float xs[64 * 68];
  __shared__ float ws[64 * 68];
  int row0 = blockIdx.x * 64;
  int t = threadIdx.x;
  #pragma unroll
  for (int i = 0; i < 4; ++i) {
    int q = t + i * 256, r = q >> 4, c = (q & 15) * 4;
    *(float4*)(xs + r * 68 + c) = *(const float4*)(a + (size_t)(row0 + r) * 64 + c);
    *(float4*)(ws + r * 68 + c) = *(const float4*)(wout + r * 64 + c);
  }
  __syncthreads();
  int tx = t & 15, ty = t >> 4;
  float acc[4][4] = {};
  for (int f = 0; f < 64; f += 4) {
    float4 xv[4], wv[4];
    #pragma unroll
    for (int ri = 0; ri < 4; ++ri) xv[ri] = *(const float4*)(xs + (ty * 4 + ri) * 68 + f);
    #pragma unroll
    for (int ci = 0; ci < 4; ++ci) wv[ci] = *(const float4*)(ws + (tx + 16 * ci) * 68 + f);
    #pragma unroll
    for (int ri = 0; ri < 4; ++ri)
      #pragma unroll
      for (int ci = 0; ci < 4; ++ci)
        acc[ri][ci] += xv[ri].x * wv[ci].x + xv[ri].y * wv[ci].y +
                       xv[ri].z * wv[ci].z + xv[ri].w * wv[ci].w;
  }
  #pragma unroll
  for (int ri = 0; ri < 4; ++ri) {
    int rl = ty * 4 + ri;
    float val[4], s = 0.f, sq = 0.f;
    #pragma unroll
    for (int ci = 0; ci < 4; ++ci) {
      int c = tx + 16 * ci;
      val[ci] = x[(size_t)(row0 + rl) * 64 + c] + bout[c] + acc[ri][ci];
      s += val[ci]; sq += val[ci] * val[ci];
    }
    #pragma unroll
    for (int off = 1; off < 16; off <<= 1) { s += __shfl_xor(s, off); sq += __shfl_xor(sq, off); }
    float mean = s * (1.f / 64.f);
    float var = sq * (1.f / 64.f) - mean * mean;
    float rstd = rsqrtf(var + EPSF);
    #pragma unroll
    for (int ci = 0; ci < 4; ++ci) {
      int c = tx + 16 * ci;
      x[(size_t)(row0 + rl) * 64 + c] = (val[ci] - mean) * rstd * g[c] + be[c];
    }
  }
}

// ------- FFN v6: 128-row tiles, x-in-regs, double-buffered weight planes (P0=w1,
// P1=w2) -> 2 barriers/chunk; LDS writes overlap MFMA; coalesced partial stores
// via LDS f32 bounce. Split-bf16 3-MFMA numerics unchanged. LDS 64KB -> 2 blk/CU
// (= grid residency). ----
__global__ void __launch_bounds__(256, 2)
k_ffn6(const float* __restrict__ x, const unsigned short* __restrict__ w1h,
       const unsigned short* __restrict__ w1l, const float* __restrict__ b1,
       const unsigned short* __restrict__ w2h, const unsigned short* __restrict__ w2l,
       float* __restrict__ part) {
  __shared__ __attribute__((aligned(16))) unsigned short P0h[64 * 64], P0l[64 * 64];
  __shared__ __attribute__((aligned(16))) unsigned short P1h[64 * 64], P1l[64 * 64];
  __shared__ __attribute__((aligned(16))) unsigned short hpl[2][128 * 64];
  int row0 = blockIdx.x * 128;
  int ks = blockIdx.y, kc = ks * 512;
  int t = threadIdx.x, lane = t & 63, wv = t >> 6;
  int lm = lane & 15, lq = lane >> 4;

  // x A-fragments in registers: rows (m*64 + wv*16 + lm), cols kbi*32 + lq*8 .. +7
  short8 axh[2][2], axl[2][2];
  #pragma unroll
  for (int m = 0; m < 2; ++m)
    #pragma unroll
    for (int kbi = 0; kbi < 2; ++kbi) {
      const float* xr = x + (size_t)(row0 + m * 64 + wv * 16 + lm) * 64 + kbi * 32 + lq * 8;
      #pragma unroll
      for (int j = 0; j < 8; ++j) {
        unsigned p = pk2(xr[j]);
        axh[m][kbi][j] = (short)(p >> 16);
        axl[m][kbi][j] = (short)(p & 0xffffu);
      }
    }

  uint4 r1h[2], r1l[2], r2h[2], r2l[2];
  // w1[0] -> regs -> P0
  #pragma unroll
  for (int i = 0; i < 2; ++i) {
    int qq = t + i * 256;
    r1h[i] = *(const uint4*)(w1h + (size_t)(kc + (qq >> 3)) * 64 + (qq & 7) * 8);
    r1l[i] = *(const uint4*)(w1l + (size_t)(kc + (qq >> 3)) * 64 + (qq & 7) * 8);
  }
  #pragma unroll
  for (int i = 0; i < 2; ++i) {
    int qq = t + i * 256, r = qq >> 3, s = qq & 7;
    int off = r * 128 + ((s ^ (r & 7)) << 4);
    *(uint4*)((char*)P0h + off) = r1h[i];
    *(uint4*)((char*)P0l + off) = r1l[i];
  }
  // issue w2[0]
  #pragma unroll
  for (int i = 0; i < 2; ++i) {
    int qq = t + i * 256;
    r2h[i] = *(const uint4*)(w2h + (size_t)(qq >> 3) * 2048 + kc + (qq & 7) * 8);
    r2l[i] = *(const uint4*)(w2l + (size_t)(qq >> 3) * 2048 + kc + (qq & 7) * 8);
  }
  __syncthreads();  // P0 visible

  f32x4 acc[2][4];
  #pragma unroll
  for (int m = 0; m < 2; ++m)
    #pragma unroll
    for (int tn = 0; tn < 4; ++tn) acc[m][tn] = (f32x4){0.f, 0.f, 0.f, 0.f};

  for (int ch = 0; ch < 8; ++ch) {
    int kcc = kc + ch * 64;
    // write w2[ch] -> P1 (prev GEMM2 readers drained by loop-end barrier)
    #pragma unroll
    for (int i = 0; i < 2; ++i) {
      int qq = t + i * 256, r = qq >> 3, s = qq & 7;
      int off = r * 128 + ((s ^ (r & 7)) << 4);
      *(uint4*)((char*)P1h + off) = r2h[i];
      *(uint4*)((char*)P1l + off) = r2l[i];
    }
    // issue w1[ch+1] (lands during GEMM1)
    if (ch < 7) {
      #pragma unroll
      for (int i = 0; i < 2; ++i) {
        int qq = t + i * 256;
        r1h[i] = *(const uint4*)(w1h + (size_t)(kcc + 64 + (qq >> 3)) * 64 + (qq & 7) * 8);
        r1l[i] = *(const uint4*)(w1l + (size_t)(kcc + 64 + (qq >> 3)) * 64 + (qq & 7) * 8);
      }
    }
    float bv[4];
    #pragma unroll
    for (int tn = 0; tn < 4; ++tn) bv[tn] = b1[kcc + tn * 16 + lm];
    // GEMM1: h = x @ w1[ch]^T   (reads P0)
    f32x4 h4[2][4];
    #pragma unroll
    for (int m = 0; m < 2; ++m)
      #pragma unroll
      for (int tn = 0; tn < 4; ++tn) h4[m][tn] = (f32x4){0.f, 0.f, 0.f, 0.f};
    #pragma unroll
    for (int kbi = 0; kbi < 2; ++kbi) {
      int sw = (((kbi * 4 + lq) ^ (lm & 7)) << 4);
      #pragma unroll
      for (int tn = 0; tn < 4; ++tn) {
        int brow = tn * 16 + lm;
        short8 bhi = *(const short8*)((const char*)P0h + brow * 128 + sw);
        short8 blo = *(const short8*)((const char*)P0l + brow * 128 + sw);
        #pragma unroll
        for (int m = 0; m < 2; ++m) {
          h4[m][tn] = __builtin_amdgcn_mfma_f32_16x16x32_bf16(axh[m][kbi], bhi, h4[m][tn], 0, 0, 0);
          h4[m][tn] = __builtin_amdgcn_mfma_f32_16x16x32_bf16(axh[m][kbi], blo, h4[m][tn], 0, 0, 0);
          h4[m][tn] = __builtin_amdgcn_mfma_f32_16x16x32_bf16(axl[m][kbi], bhi, h4[m][tn], 0, 0, 0);
        }
      }
    }
    // h = relu(h+b1); split (trunc hi + RNE residual) -> hpl (wave-private rows)
    #pragma unroll
    for (int m = 0; m < 2; ++m)
      #pragma unroll
      for (int tn = 0; tn < 4; ++tn)
        #pragma unroll
        for (int r = 0; r < 4; ++r) {
          float hv = fmaxf(h4[m][tn][r] + bv[tn], 0.f);
          unsigned u = __float_as_uint(hv);
          float resid = hv - __uint_as_float(u & 0xffff0000u);
          unsigned c2 = __float_as_uint(resid);
          int hrow = m * 64 + wv * 16 + lq * 4 + r, hcol = tn * 16 + lm;
          int off = hrow * 128 + (((hcol >> 3) ^ (hrow & 7)) << 4) + ((hcol & 7) << 1);
          *(unsigned short*)((char*)hpl[0] + off) = (unsigned short)(u >> 16);
          *(unsigned short*)((char*)hpl[1] + off) =
              (unsigned short)((c2 + 0x7fffu + ((c2 >> 16) & 1u)) >> 16);
        }
    __syncthreads();  // (A): all GEMM1 reads of P0 done; P1 writes visible
    if (ch < 7) {
      #pragma unroll
      for (int i = 0; i < 2; ++i) {
        int qq = t + i * 256, r = qq >> 3, s = qq & 7;
        int off = r * 128 + ((s ^ (r & 7)) << 4);
        *(uint4*)((char*)P0h + off) = r1h[i];
        *(uint4*)((char*)P0l + off) = r1l[i];
      }
      // issue w2[ch+1] (lands during GEMM2)
      #pragma unroll
      for (int i = 0; i < 2; ++i) {
        int qq = t + i * 256;
        r2h[i] = *(const uint4*)(w2h + (size_t)(qq >> 3) * 2048 + kcc + 64 + (qq & 7) * 8);
        r2l[i] = *(const uint4*)(w2l + (size_t)(qq >> 3) * 2048 + kcc + 64 + (qq & 7) * 8);
      }
    }
    // GEMM2: acc += h @ w2[ch]   (reads P1 + own h rows)
    #pragma unroll
    for (int kbi = 0; kbi < 2; ++kbi) {
      short8 a2h[2], a2l[2];
      #pragma unroll
      for (int m = 0; m < 2; ++m) {
        int arow = m * 64 + wv * 16 + lm;
        int swa = (((kbi * 4 + lq) ^ (arow & 7)) << 4);
        a2h[m] = *(const short8*)((const char*)hpl[0] + arow * 128 + swa);
        a2l[m] = *(const short8*)((const char*)hpl[1] + arow * 128 + swa);
      }
      int swb = (((kbi * 4 + lq) ^ (lm & 7)) << 4);
      #pragma unroll
      for (int tn = 0; tn < 4; ++tn) {
        int brow = tn * 16 + lm;
        short8 bhi = *(const short8*)((const char*)P1h + brow * 128 + swb);
        short8 blo = *(const short8*)((const char*)P1l + brow * 128 + swb);
        #pragma unroll
        for (int m = 0; m < 2; ++m) {
          acc[m][tn] = __builtin_amdgcn_mfma_f32_16x16x32_bf16(a2h[m], bhi, acc[m][tn], 0, 0, 0);
          acc[m][tn] = __builtin_amdgcn_mfma_f32_16x16x32_bf16(a2h[m], blo, acc[m][tn], 0, 0, 0);
          acc[m][tn] = __builtin_amdgcn_mfma_f32_16x16x32_bf16(a2l[m], bhi, acc[m][tn], 0, 0, 0);
        }
      }
    }
    __syncthreads();  // (B): all GEMM2 reads of P1 done (next chunk overwrites P1)
  }
  // epilogue: stage acc to LDS f32 (XOR-swizzled), then coalesced dwordx4 stores
  float* fb = (float*)hpl;
  #pragma unroll
  for (int m = 0; m < 2; ++m)
    #pragma unroll
    for (int tn = 0; tn < 4; ++tn)
      #pragma unroll
      for (int r = 0; r < 4; ++r) {
        int row = m * 64 + wv * 16 + lq * 4 + r;
        int col = (tn * 16 + lm) ^ ((row & 7) << 2);
        fb[row * 64 + col] = acc[m][tn][r];
      }
  __syncthreads();
  float* pb = part + (size_t)ks * (BB * NN * 64);
  #pragma unroll
  for (int i = 0; i < 8; ++i) {
    int idx = t * 4 + i * 1024;
    int row = idx >> 6, c0 = idx & 63;
    int c0s = c0 ^ ((row & 7) << 2);
    float4 v = *(const float4*)(fb + row * 64 + c0s);
    *(float4*)(pb + (size_t)(row0 + row) * 64 + c0) = v;
  }
}

// ------- combine 4 partials + residual + b2 + LN; one wave per row ---------
__global__ void k_ffn_ln(const float* __restrict__ part, const float* __restrict__ b2,
                         const float* __restrict__ g, const float* __restrict__ be,
                         float* __restrict__ x) {
  int row = blockIdx.x * 4 + (threadIdx.x >> 6);
  int j = threadIdx.x & 63;
  size_t o = (size_t)row * 64 + j;
  const size_t S = (size_t)BB * NN * 64;
  float val = x[o] + b2[j] + ((part[o] + part[o + S]) + (part[o + 2 * S] + part[o + 3 * S]));
  float s = val;
  for (int off = 32; off; off >>= 1) s += __shfl_xor(s, off);
  s *= (1.f / 64.f);
  float d = val - s;
  float v = d * d;
  for (int off = 32; off; off >>= 1) v += __shfl_xor(v, off);
  v *= (1.f / 64.f);
  x[o] = d * rsqrtf(v + EPSF) * g[j] + be[j];
}

// ------- score head tiled ----------
__global__ void k_fg2(const float* __restrict__ x,
                      const float* __restrict__ w0, const float* __restrict__ b0, const float* __restrict__ bn0,
                      const float* __restrict__ w1, const float* __restrict__ b1, const float* __restrict__ bn1,
                      const float* __restrict__ w2, const float* __restrict__ b2, const float* __restrict__ bn2,
                      float* __restrict__ scores) {
  __shared__ float xs[64 * 68];
  __shared__ float ws[64 * 68];
  __shared__ float s0s[64 * 68];
  __shared__ float s1s[64 * 20];
  int row0 = blockIdx.x * 64;
  int t = threadIdx.x;
  #pragma unroll
  for (int i = 0; i < 4; ++i) {
    int q = t + i * 256, r = q >> 4, c = (q & 15) * 4;
    *(float4*)(xs + r * 68 + c) = *(const float4*)(x + (size_t)(row0 + r) * 64 + c);
    *(float4*)(ws + r * 68 + c) = *(const float4*)(w0 + r * 64 + c);
  }
  __syncthreads();
  int tx = t & 15, ty = t >> 4;
  float acc[4][4] = {};
  for (int f = 0; f < 64; f += 4) {
    float4 xv[4], wv[4];
    #pragma unroll
    for (int ri = 0; ri < 4; ++ri) xv[ri] = *(const float4*)(xs + (ty * 4 + ri) * 68 + f);
    #pragma unroll
    for (int ci = 0; ci < 4; ++ci) wv[ci] = *(const float4*)(ws + (tx + 16 * ci) * 68 + f);
    #pragma unroll
    for (int ri = 0; ri < 4; ++ri)
      #pragma unroll
      for (int ci = 0; ci < 4; ++ci)
        acc[ri][ci] += xv[ri].x * wv[ci].x + xv[ri].y * wv[ci].y +
                       xv[ri].z * wv[ci].z + xv[ri].w * wv[ci].w;
  }
  #pragma unroll
  for (int ri = 0; ri < 4; ++ri)
    #pragma unroll
    for (int ci = 0; ci < 4; ++ci) {
      int c = tx + 16 * ci;
      float sc = bn0[c] * rsqrtf(bn0[192 + c] + EPSF);
      float v = (acc[ri][ci] + b0[c] - bn0[128 + c]) * sc + bn0[64 + c];
      s0s[(ty * 4 + ri) * 68 + c] = fmaxf(v, 0.f);
    }
  __syncthreads();
  {
    int rl = t & 63, j0 = t >> 6;
    #pragma unroll
    for (int i = 0; i < 4; ++i) {
      int j = j0 + 4 * i;
      float s = b1[j];
      const float* wr = w1 + j * 64;
      #pragma unroll 16
      for (int c = 0; c < 64; ++c) s += s0s[rl * 68 + c] * wr[c];
      float sc = bn1[j] * rsqrtf(bn1[48 + j] + EPSF);
      s = (s - bn1[32 + j]) * sc + bn1[16 + j];
      s1s[rl * 20 + j] = fmaxf(s, 0.f);
    }
  }
  __syncthreads();
  if (t < 64) {
    float s = b2[0];
    #pragma unroll
    for (int o = 0; o < 16; ++o) s += s1s[t * 20 + o] * w2[o];
    float sc = bn2[0] * rsqrtf(bn2[3] + EPSF);
    s = (s - bn2[2]) * sc + bn2[1];
    scores[row0 + t] = fmaxf(s, 0.f);
  }
}

// ---- top-k (k=16) ----
__global__ void k_topk2(const float* __restrict__ scores, int* __restrict__ idx,
                        float* __restrict__ out_idx) {
  int b = blockIdx.x, t = threadIdx.x;
  float v[8];
  int base = b * NN;
  #pragma unroll
  for (int u = 0; u < 8; ++u) v[u] = scores[base + t + 256 * u];
  __shared__ float wvs[4];
  __shared__ int wis[4];
  __shared__ int winner;
  unsigned taken = 0;
  for (int r = 0; r < TOPK; ++r) {
    float best = -1e30f; int bi = 1 << 30;
    #pragma unroll
    for (int u = 0; u < 8; ++u) {
      if (!((taken >> u) & 1)) {
        float vv = v[u]; int ii = t + 256 * u;
        if (vv > best || (vv == best && ii < bi)) { best = vv; bi = ii; }
      }
    }
    for (int off = 32; off; off >>= 1) {
      float ov = __shfl_xor(best, off);
      int oi = __shfl_xor(bi, off);
      if (ov > best || (ov == best && oi < bi)) { best = ov; bi = oi; }
    }
    if ((t & 63) == 0) { wvs[t >> 6] = best; wis[t >> 6] = bi; }
    __syncthreads();
    if (t == 0) {
      float B = wvs[0]; int I = wis[0];
      #pragma unroll
      for (int q = 1; q < 4; ++q)
        if (wvs[q] > B || (wvs[q] == B && wis[q] < I)) { B = wvs[q]; I = wis[q]; }
      winner = I;
      idx[b * TOPK + r] = I;
      out_idx[b * TOPK + r] = (float)I;
    }
    __syncthreads();
    int w = winner;
    if ((w & 255) == t) taken |= 1u << (w >> 8);
  }
}

// ---------------- ball query + 3 conv stages, 512 threads (8 waves) per (b,k). ----
__global__ void __launch_bounds__(512)
k_group(const float* __restrict__ inp, const int* __restrict__ idx,
        const float* __restrict__ w0, const float* __restrict__ b0, const float* __restrict__ bn0,
        const float* __restrict__ w1, const float* __restrict__ b1, const float* __restrict__ bn1,
        const float* __restrict__ w2, const float* __restrict__ b2, const float* __restrict__ bn2,
        float* __restrict__ r2g) {
  __shared__ int swave[8 * 64];
  __shared__ int scnt[8];
  __shared__ int gidx[NSAMP];
  __shared__ __attribute__((aligned(16))) float gsh[65 * DD];  // 390
  __shared__ __attribute__((aligned(16))) float r0[128];
  __shared__ __attribute__((aligned(16))) float r1[256];
  int k = blockIdx.x, b = blockIdx.y;
  int t = threadIdx.x;
  int lane = t & 63, w = t >> 6;
  int qn = idx[b * TOPK + k];
  const float* px = inp + (size_t)b * DD * NN;
  float qx = px[qn], qy = px[NN + qn], qz = px[2 * NN + qn];
  {
    int cnt = 0;
    #pragma unroll
    for (int i = 0; i < 4; ++i) {
      int n = w * 256 + i * 64 + lane;
      float dx = px[n] - qx, dy = px[NN + n] - qy, dz = px[2 * NN + n] - qz;
      bool flag = (dx * dx + dy * dy + dz * dz <= R2);
      unsigned long long m = __ballot(flag);
      int pos = cnt + __popcll(m & ((1ull << lane) - 1ull));
      if (flag && pos < NSAMP) swave[w * 64 + pos] = n;
      cnt += (int)__popcll(m);
    }
    if (lane == 0) scnt[w] = cnt < NSAMP ? cnt : NSAMP;
  }
  __syncthreads();
  if (t < NSAMP) {
    int run = 0, val = -1;
    #pragma unroll
    for (int ww = 0; ww < 8; ++ww) {
      int c = scnt[ww];
      int loc = t - run;
      if (loc >= 0 && loc < c) val = swave[ww * 64 + loc];
      run += c;
    }
    gidx[t] = val;
  }
  __syncthreads();
  if (t < NSAMP) {
    int g0 = gidx[0];
    int gt = gidx[t];
    gidx[t] = (gt < 0) ? g0 : gt;
  }
  __syncthreads();
  if (t < 65 * DD) {
    int p = t / DD, d = t - p * DD;
    int n = (p == 0) ? qn : gidx[p - 1];
    gsh[t] = px[d * NN + n];
  }
  __syncthreads();
  {
    int c = t >> 2, part = t & 3;
    const float2* wr = (const float2*)(w0 + c * 390 + part * 98);
    const float2* gr = (const float2*)(gsh + part * 98);
    int n2 = (part == 3) ? 48 : 49;
    float s = 0.f;
    #pragma unroll 7
    for (int i = 0; i < n2; ++i) {
      float2 a = gr[i], ww = wr[i];
      s += a.x * ww.x + a.y * ww.y;
    }
    s += __shfl_xor(s, 1);
    s += __shfl_xor(s, 2);
    if (part == 0) {
      s += b0[c];
      float sc = bn0[c] * rsqrtf(bn0[384 + c] + EPSF);
      s = (s - bn0[256 + c]) * sc + bn0[128 + c];
      r0[c] = fmaxf(s, 0.f);
    }
  }
  __syncthreads();
  {
    int c = t >> 1, part = t & 1;
    const float4* wr = (const float4*)(w1 + c * 128 + part * 64);
    const float4* rr = (const float4*)(r0 + part * 64);
    float s0 = 0.f, s1 = 0.f, s2 = 0.f, s3 = 0.f;
    #pragma unroll 8
    for (int o = 0; o < 16; ++o) {
      float4 a = rr[o], ww = wr[o];
      s0 += a.x * ww.x; s1 += a.y * ww.y; s2 += a.z * ww.z; s3 += a.w * ww.w;
    }
    float s = (s0 + s1) + (s2 + s3);
    s += __shfl_xor(s, 1);
    if (part == 0) {
      s += b1[c];
      float sc = bn1[c] * rsqrtf(bn1[768 + c] + EPSF);
      s = (s - bn1[512 + c]) * sc + bn1[256 + c];
      r1[c] = fmaxf(s, 0.f);
    }
  }
  __syncthreads();
  {
    int c = t;
    const float4* wr = (const float4*)(w2 + c * 256);
    const float4* rr = (const float4*)r1;
    float s0 = 0.f, s1 = 0.f, s2 = 0.f, s3 = 0.f;
    #pragma unroll 8
    for (int o = 0; o < 64; ++o) {
      float4 a = rr[o], ww = wr[o];
      s0 += a.x * ww.x; s1 += a.y * ww.y; s2 += a.z * ww.z; s3 += a.w * ww.w;
    }
    float s = (s0 + s1) + (s2 + s3) + b2[c];
    float sc = bn2[c] * rsqrtf(bn2[1536 + c] + EPSF);
    s = (s - bn2[1024 + c]) * sc + bn2[512 + c];
    r2g[b * 8192 + c * TOPK + k] = fmaxf(s, 0.f);
  }
}

// ---------------- FC + BN + ReLU (wave-reduced dot), block=64 ----------------
__global__ void k_fl(const float* __restrict__ hin, const float* __restrict__ w,
                     const float* __restrict__ bias, const float* __restrict__ bn,
                     float* __restrict__ hout, int IN, int OUT) {
  int blk = blockIdx.x;
  int b = blk / OUT, j = blk % OUT;
  int lane = threadIdx.x;
  const float* hr = hin + (size_t)b * IN;
  const float* wr = w + (size_t)j * IN;
  float s = 0.f;
  for (int i = lane; i < IN; i += 64) s += hr[i] * wr[i];
  for (int o = 32; o; o >>= 1) s += __shfl_xor(s, o);
  if (lane == 0) {
    s += bias[j];
    float sc = bn[j] * rsqrtf(bn[3 * OUT + j] + EPSF);
    s = (s - bn[2 * OUT + j]) * sc + bn[OUT + j];
    hout[b * OUT + j] = fmaxf(s, 0.f);
  }
}

extern "C" void kernel_launch(void* const* d_in, const int* in_sizes, int n_in,
                              void* d_out, int out_size, void* d_ws, size_t ws_size,
                              hipStream_t stream) {
  const float* sv      = (const float*)d_in[0];
  const float* inp     = (const float*)d_in[1];
  const float* tl_win  = (const float*)d_in[2];
  const float* tl_bin  = (const float*)d_in[3];
  const float* tl_wout = (const float*)d_in[4];
  const float* tl_bout = (const float*)d_in[5];
  const float* tl_w1   = (const float*)d_in[6];
  const float* tl_b1   = (const float*)d_in[7];
  const float* tl_w2   = (const float*)d_in[8];
  const float* tl_b2   = (const float*)d_in[9];
  const float* tl_ln1g = (const float*)d_in[10];
  const float* tl_ln1b = (const float*)d_in[11];
  const float* tl_ln2g = (const float*)d_in[12];
  const float* tl_ln2b = (const float*)d_in[13];
  const float* fg_w0   = (const float*)d_in[14];
  const float* fg_b0   = (const float*)d_in[15];
  const float* fg_w1   = (const float*)d_in[16];
  const float* fg_b1   = (const float*)d_in[17];
  const float* fg_w2   = (const float*)d_in[18];
  const float* fg_b2   = (const float*)d_in[19];
  const float* fbn0    = (const float*)d_in[20];
  const float* fbn1    = (const float*)d_in[21];
  const float* fbn2    = (const float*)d_in[22];
  const float* rc_w0   = (const float*)d_in[23];
  const float* rc_b0   = (const float*)d_in[24];
  const float* rc_w1   = (const float*)d_in[25];
  const float* rc_b1   = (const float*)d_in[26];
  const float* rc_w2   = (const float*)d_in[27];
  const float* rc_b2   = (const float*)d_in[28];
  const float* rbn0    = (const float*)d_in[29];
  const float* rbn1    = (const float*)d_in[30];
  const float* rbn2    = (const float*)d_in[31];
  const float* fl_w0   = (const float*)d_in[32];
  const float* fl_b0   = (const float*)d_in[33];
  const float* fl_w1   = (const float*)d_in[34];
  const float* fl_b1   = (const float*)d_in[35];
  const float* lbn0    = (const float*)d_in[36];
  const float* lbn1    = (const float*)d_in[37];
  (void)in_sizes; (void)n_in; (void)out_size; (void)ws_size;

  float* wsp = (float*)d_ws;
  float* x      = wsp;                        // B*N*F      = 1048576
  float* qkv    = x + BB * NN * FF;           // 3145728-float region
  float* a      = qkv + BB * NN * 192;        // B*N*F      = 1048576
  float* scores = a + BB * NN * FF;           // B*N        = 16384
  int*   idxb   = (int*)(scores + BB * NN);   // B*TOPK     = 128
  float* r2g    = (float*)(idxb + BB * TOPK); // B*8192     = 65536
  float* h1g    = r2g + BB * 8192;            // B*1024     = 8192
  unsigned short* w1h = (unsigned short*)(h1g + BB * 1024);
  unsigned short* w1l = w1h + NLAYER * 2048 * 64;
  unsigned short* w2h = w1l + NLAYER * 2048 * 64;
  unsigned short* w2l = w2h + NLAYER * 2048 * 64;
  // qkv region carve-out: Q fp32 (1M floats) | kp bf16 (1M u16) | vp bf16 (1M u16)
  float* qbuf = qkv;
  unsigned short* kp = (unsigned short*)(qkv + BB * NN * FF);
  unsigned short* vp = kp + (size_t)BB * NHEAD * NN * HD;
  float* part = qkv;  // FFN split-K partials reuse qkv+a (dead by then)

  float* out = (float*)d_out;  // fp32: h at [0,4096), idx-as-float at [4096,4224)

  k_transpose<<<(BB * NN * FF) / 256, 256, 0, stream>>>(sv, x);
  k_wpack16<<<(NLAYER * 2048 * 64) / 256, 256, 0, stream>>>(tl_w1, w1h, w1l, NLAYER * 2048 * 64);
  k_wpack16<<<(NLAYER * 2048 * 64) / 256, 256, 0, stream>>>(tl_w2, w2h, w2l, NLAYER * 2048 * 64);

  for (int l = 0; l < NLAYER; ++l) {
    k_qkv3<<<dim3(BB * NN / 64, 3), 256, 0, stream>>>(x, tl_win + l * 192 * FF,
                                                      tl_bin + l * 192, qbuf,
                                                      (uint4*)kp, (uint4*)vp);
    k_attn7<<<dim3(NN / 64, NHEAD, BB), 256, 0, stream>>>(qbuf, (const uint4*)kp,
                                                          (const unsigned*)vp, a);
    k_proj2<<<BB * NN / 64, 256, 0, stream>>>(a, tl_wout + l * FF * FF, tl_bout + l * FF,
                                              tl_ln1g + l * FF, tl_ln1b + l * FF, x);
    k_ffn6<<<dim3(BB * NN / 128, 4), 256, 0, stream>>>(x, w1h + l * 2048 * 64,
                                                       w1l + l * 2048 * 64, tl_b1 + l * 2048,
                                                       w2h + l * 2048 * 64, w2l + l * 2048 * 64,
                                                       part);
    k_ffn_ln<<<BB * NN / 4, 256, 0, stream>>>(part, tl_b2 + l * FF,
                                              tl_ln2g + l * FF, tl_ln2b + l * FF, x);
  }

  k_fg2<<<BB * NN / 64, 256, 0, stream>>>(x, fg_w0, fg_b0, fbn0, fg_w1, fg_b1, fbn1,
                                          fg_w2, fg_b2, fbn2, scores);
  k_topk2<<<BB, 256, 0, stream>>>(scores, idxb, out + BB * 512);
  k_group<<<dim3(TOPK, BB), 512, 0, stream>>>(inp, idxb, rc_w0, rc_b0, rbn0,
                                              rc_w1, rc_b1, rbn1, rc_w2, rc_b2, rbn2, r2g);
  k_fl<<<BB * 1024, 64, 0, stream>>>(r2g, fl_w0, fl_b0, lbn0, h1g, 8192, 1024);
  k_fl<<<BB * 512, 64, 0, stream>>>(h1g, fl_w1, fl_b1, lbn1, out, 1024, 512);
}

// Round 5
// 506.396 us; speedup vs baseline: 1.4748x; 1.1395x over previous
//
#include <hip/hip_runtime.h>
#include <hip/hip_bf16.h>
#include <math.h>

#define BB 8
#define NN 2048
#define FF 64
#define DD 6
#define NSAMP 64
#define TOPK 16
#define NHEAD 8
#define HD 8
#define NLAYER 2
#define EPSF 1e-5f
#define R2 0.09f

typedef short short8 __attribute__((ext_vector_type(8)));
typedef float f32x4 __attribute__((ext_vector_type(4)));
typedef unsigned int u32;

// split-pack: u32 = (bf16_hi << 16) | bf16_lo, both RNE. x ≈ hi + lo, err ~2^-16 rel.
__device__ inline unsigned pk2(float x) {
  unsigned b = __float_as_uint(x);
  unsigned hi = (b + 0x7fffu + ((b >> 16) & 1u)) >> 16;
  float r = x - __uint_as_float(hi << 16);
  unsigned c = __float_as_uint(r);
  unsigned lo = (c + 0x7fffu + ((c >> 16) & 1u)) >> 16;
  return (hi << 16) | lo;
}

__device__ inline unsigned short bf16r(float x) {  // RNE bf16
  unsigned b = __float_as_uint(x);
  return (unsigned short)((b + 0x7fffu + ((b >> 16) & 1u)) >> 16);
}

// async global->LDS, 16B per lane (dest = wave-uniform base + lane*16)
__device__ __forceinline__ void gl16(const void* g, void* l) {
  __builtin_amdgcn_global_load_lds((const __attribute__((address_space(1))) u32*)g,
                                   (__attribute__((address_space(3))) u32*)l, 16, 0, 0);
}

// ---------------- transpose sortvec (B,1,F,N) -> x (B,N,F) ----------------
__global__ void k_transpose(const float* __restrict__ sv, float* __restrict__ x) {
  int i = blockIdx.x * 256 + threadIdx.x;
  if (i >= BB * NN * FF) return;
  int f = i % FF;
  int n = (i / FF) % NN;
  int b = i / (FF * NN);
  x[i] = sv[(b * FF + f) * NN + n];
}

// ---- pack FFN weights into the exact per-chunk LDS byte image (pre-swizzled).
// img u16 layout: [l][chg(0..31)][plane(0..3: w1hi,w1lo,w2hi,w2lo)][4096]
// plane byte beta = r*128 + sh*16 + inner*2, stored elem uses s = sh ^ (r&7).
__global__ void k_wimg(const float* __restrict__ w1, const float* __restrict__ w2,
                       unsigned short* __restrict__ img) {
  int i = blockIdx.x * 256 + threadIdx.x;     // u16 index, total 2*32*4*4096
  int e = i & 4095;
  int plane = (i >> 12) & 3;
  int chg = (i >> 14) & 31;
  int l = i >> 19;
  int r = e >> 6, sh = (e >> 3) & 7, inner = e & 7;
  int s = sh ^ (r & 7);
  float v;
  if (plane < 2) v = w1[((size_t)(l * 2048 + chg * 64 + r)) * 64 + s * 8 + inner];
  else           v = w2[((size_t)(l * 64 + r)) * 2048 + chg * 64 + s * 8 + inner];
  unsigned p = pk2(v);
  img[i] = (unsigned short)((plane & 1) ? (p & 0xffffu) : (p >> 16));
}

// ---- qkv v3: tiled GEMM; epilogue routes per blockIdx.y:
//   y=0: Q fp32 -> qbuf[b*N+n][64]
//   y=1: K bf16 -> kp[b][h][n][8]  (16B per key)
//   y=2: V bf16 -> vp[b][h][d][n]  (transposed)
__global__ void k_qkv3(const float* __restrict__ x, const float* __restrict__ win,
                       const float* __restrict__ bin, float* __restrict__ qbuf,
                       uint4* __restrict__ kp4, uint4* __restrict__ vp4) {
  __shared__ float xs[64 * 68];
  __shared__ float ws[64 * 68];
  int row0 = blockIdx.x * 64, y = blockIdx.y, col0 = y * 64;
  int t = threadIdx.x;
  #pragma unroll
  for (int i = 0; i < 4; ++i) {
    int q = t + i * 256, r = q >> 4, c = (q & 15) * 4;
    *(float4*)(xs + r * 68 + c) = *(const float4*)(x + (size_t)(row0 + r) * 64 + c);
    *(float4*)(ws + r * 68 + c) = *(const float4*)(win + (size_t)(col0 + r) * 64 + c);
  }
  __syncthreads();
  int tx = t & 15, ty = t >> 4;
  float acc[4][4] = {};
  for (int f = 0; f < 64; f += 4) {
    float4 xv[4], wv[4];
    #pragma unroll
    for (int ri = 0; ri < 4; ++ri) xv[ri] = *(const float4*)(xs + (ty * 4 + ri) * 68 + f);
    #pragma unroll
    for (int ci = 0; ci < 4; ++ci) wv[ci] = *(const float4*)(ws + (tx + 16 * ci) * 68 + f);
    #pragma unroll
    for (int ri = 0; ri < 4; ++ri)
      #pragma unroll
      for (int ci = 0; ci < 4; ++ci)
        acc[ri][ci] += xv[ri].x * wv[ci].x + xv[ri].y * wv[ci].y +
                       xv[ri].z * wv[ci].z + xv[ri].w * wv[ci].w;
  }
  int b = row0 >> 11, n0 = row0 & (NN - 1);
  if (y == 0) {
    #pragma unroll
    for (int ri = 0; ri < 4; ++ri)
      #pragma unroll
      for (int ci = 0; ci < 4; ++ci) {
        int r = row0 + ty * 4 + ri, c = tx + 16 * ci;
        qbuf[(size_t)r * 64 + c] = acc[ri][ci] + bin[c];
      }
    return;
  }
  __syncthreads();  // all GEMM reads of xs done before reuse
  unsigned short* l16 = (unsigned short*)xs;  // 64x72 u16 tile
  if (y == 1) {
    #pragma unroll
    for (int ri = 0; ri < 4; ++ri)
      #pragma unroll
      for (int ci = 0; ci < 4; ++ci) {
        int r = ty * 4 + ri, c = tx + 16 * ci;
        l16[r * 72 + c] = bf16r(acc[ri][ci] + bin[64 + c]);
      }
    __syncthreads();
    #pragma unroll
    for (int i = 0; i < 2; ++i) {
      int idx = t + i * 256;
      int h = idx >> 6, tok = idx & 63;
      uint4 v = *(const uint4*)(l16 + tok * 72 + h * 8);
      kp4[(size_t)(b * NHEAD + h) * NN + n0 + tok] = v;
    }
  } else {
    #pragma unroll
    for (int ri = 0; ri < 4; ++ri)
      #pragma unroll
      for (int ci = 0; ci < 4; ++ci) {
        int r = ty * 4 + ri, c = tx + 16 * ci;
        l16[c * 72 + r] = bf16r(acc[ri][ci] + bin[128 + c]);  // transposed
      }
    __syncthreads();
    #pragma unroll
    for (int i = 0; i < 2; ++i) {
      int idx = t + i * 256;
      int c = idx >> 3, seg = idx & 7;
      uint4 v = *(const uint4*)(l16 + c * 72 + seg * 8);
      vp4[(size_t)(b * 64 + c) * (NN / 8) + (n0 >> 3) + seg] = v;
    }
  }
}

// ---- attention v7: bf16 MFMA flash with pre-packed K/V. ----
__global__ void __launch_bounds__(256, 8)
k_attn7(const float* __restrict__ q, const uint4* __restrict__ kp4,
        const unsigned* __restrict__ vp32, float* __restrict__ a) {
  __shared__ uint4 kb4[256];
  __shared__ __attribute__((aligned(16))) unsigned short vb16[9 * 264];
  __shared__ __attribute__((aligned(16))) unsigned short pb16[4 * 16 * 40];
  int t = threadIdx.x;
  int lane = t & 63, w = t >> 6;
  int nIdx = lane & 15, lq = lane >> 4;
  int h = blockIdx.y, b = blockIdx.z;
  int qwb = blockIdx.x * 64 + w * 16;
  int bh = b * NHEAD + h;
  const float kf = 0.35355339059327373f * 1.4426950408889634f;  // scale*log2e
  short8 qF = {0, 0, 0, 0, 0, 0, 0, 0};
  if (lq == 0) {
    const float* qr = q + ((size_t)(b * NN + qwb + nIdx)) * 64 + h * HD;
    #pragma unroll
    for (int j = 0; j < 8; ++j) qF[j] = (short)bf16r(qr[j] * kf);
  }
  f32x4 acc = {0.f, 0.f, 0.f, 0.f};
  unsigned short* mypb = pb16 + w * 640;
  const uint4* kbase = kp4 + (size_t)bh * NN;
  const unsigned* vbase = vp32 + (size_t)bh * HD * (NN / 2);
  uint4 kreg = kbase[t];
  unsigned vreg[4];
  #pragma unroll
  for (int i = 0; i < 4; ++i) {
    int g = t + i * 256;
    vreg[i] = vbase[(g >> 7) * (NN / 2) + (g & 127)];
  }
  for (int kc = 0; kc < NN; kc += 256) {
    __syncthreads();
    kb4[t] = kreg;
    #pragma unroll
    for (int i = 0; i < 4; ++i) {
      int g = t + i * 256;
      ((unsigned*)vb16)[(g >> 7) * 132 + (g & 127)] = vreg[i];
    }
    if (t < 132) ((unsigned*)(vb16 + 8 * 264))[t] = 0x3f803f80u;  // ones row
    __syncthreads();
    if (kc + 256 < NN) {
      kreg = kbase[kc + 256 + t];
      #pragma unroll
      for (int i = 0; i < 4; ++i) {
        int g = t + i * 256;
        vreg[i] = vbase[(g >> 7) * (NN / 2) + ((kc + 256) >> 1) + (g & 127)];
      }
    }
    for (int s = 0; s < 8; ++s) {
      int kb = s * 32;
      #pragma unroll
      for (int half = 0; half < 2; ++half) {
        int key = kb + half * 16 + nIdx;
        short8 bF = {0, 0, 0, 0, 0, 0, 0, 0};
        if (lq == 0) bF = *(const short8*)(kb4 + key);
        f32x4 c = {0.f, 0.f, 0.f, 0.f};
        c = __builtin_amdgcn_mfma_f32_16x16x32_bf16(qF, bF, c, 0, 0, 0);
        #pragma unroll
        for (int r = 0; r < 4; ++r) {
          float p = __builtin_amdgcn_exp2f(c[r]);
          mypb[(lq * 4 + r) * 40 + half * 16 + nIdx] =
              (unsigned short)(__float_as_uint(p) >> 16);
        }
      }
      short8 pa = *(const short8*)(mypb + nIdx * 40 + lq * 8);
      int vn = nIdx < 9 ? nIdx : 8;
      short8 vb = *(const short8*)(vb16 + vn * 264 + kb + lq * 8);
      acc = __builtin_amdgcn_mfma_f32_16x16x32_bf16(pa, vb, acc, 0, 0, 0);
    }
  }
  #pragma unroll
  for (int r = 0; r < 4; ++r) {
    float lr = __shfl(acc[r], (lane & 48) | 8);
    if (nIdx < 8) {
      int row = qwb + lq * 4 + r;
      a[((size_t)(b * NN + row)) * 64 + h * HD + nIdx] = acc[r] / lr;
    }
  }
}

// ------- proj + residual + LN, tiled GEMM ---------
__global__ void k_proj2(const float* __restrict__ a, const float* __restrict__ wout,
                        const float* __restrict__ bout, const float* __restrict__ g,
                        const float* __restrict__ be, float* __restrict__ x) {
  __shared__ float xs[64 * 68];
  __shared__ float ws[64 * 68];
  int row0 = blockIdx.x * 64;
  int t = threadIdx.x;
  #pragma unroll
  for (int i = 0; i < 4; ++i) {
    int q = t + i * 256, r = q >> 4, c = (q & 15) * 4;
    *(float4*)(xs + r * 68 + c) = *(const float4*)(a + (size_t)(row0 + r) * 64 + c);
    *(float4*)(ws + r * 68 + c) = *(const float4*)(wout + r * 64 + c);
  }
  __syncthreads();
  int tx = t & 15, ty = t >> 4;
  float acc[4][4] = {};
  for (int f = 0; f < 64; f += 4) {
    float4 xv[4], wv[4];
    #pragma unroll
    for (int ri = 0; ri < 4; ++ri) xv[ri] = *(const float4*)(xs + (ty * 4 + ri) * 68 + f);
    #pragma unroll
    for (int ci = 0; ci < 4; ++ci) wv[ci] = *(const float4*)(ws + (tx + 16 * ci) * 68 + f);
    #pragma unroll
    for (int ri = 0; ri < 4; ++ri)
      #pragma unroll
      for (int ci = 0; ci < 4; ++ci)
        acc[ri][ci] += xv[ri].x * wv[ci].x + xv[ri].y * wv[ci].y +
                       xv[ri].z * wv[ci].z + xv[ri].w * wv[ci].w;
  }
  #pragma unroll
  for (int ri = 0; ri < 4; ++ri) {
    int rl = ty * 4 + ri;
    float val[4], s = 0.f, sq = 0.f;
    #pragma unroll
    for (int ci = 0; ci < 4; ++ci) {
      int c = tx + 16 * ci;
      val[ci] = x[(size_t)(row0 + rl) * 64 + c] + bout[c] + acc[ri][ci];
      s += val[ci]; sq += val[ci] * val[ci];
    }
    #pragma unroll
    for (int off = 1; off < 16; off <<= 1) { s += __shfl_xor(s, off); sq += __shfl_xor(sq, off); }
    float mean = s * (1.f / 64.f);
    float var = sq * (1.f / 64.f) - mean * mean;
    float rstd = rsqrtf(var + EPSF);
    #pragma unroll
    for (int ci = 0; ci < 4; ++ci) {
      int c = tx + 16 * ci;
      x[(size_t)(row0 + rl) * 64 + c] = (val[ci] - mean) * rstd * g[c] + be[c];
    }
  }
}

// ------- FFN v7: global_load_lds staging from pre-swizzled image, counted vmcnt,
// raw s_barriers (no full drains in the loop). W1 double-buffered (1 chunk ahead,
// vmcnt(8)); W2 single-buffered (intra-chunk slack, vmcnt(4)). hpl wave-private.
// MFMA order bitwise identical to ffn6. LDS 80KB -> 2 blocks/CU. ----
__global__ void __launch_bounds__(256, 2)
k_ffn7(const float* __restrict__ x, const char* __restrict__ img,
       const float* __restrict__ b1, float* __restrict__ part) {
  __shared__ __attribute__((aligned(16))) char W1b[2][16384];
  __shared__ __attribute__((aligned(16))) char W2b[16384];
  __shared__ __attribute__((aligned(16))) unsigned short hpl[2][128 * 64];
  int row0 = blockIdx.x * 128;
  int ks = blockIdx.y, kc = ks * 512;
  int t = threadIdx.x, lane = t & 63, wv = t >> 6;
  int lm = lane & 15, lq = lane >> 4;
  const char* ibase = img + (size_t)ks * 8 * 32768;

  // x A-fragments in registers
  short8 axh[2][2], axl[2][2];
  #pragma unroll
  for (int m = 0; m < 2; ++m)
    #pragma unroll
    for (int kbi = 0; kbi < 2; ++kbi) {
      const float* xr = x + (size_t)(row0 + m * 64 + wv * 16 + lm) * 64 + kbi * 32 + lq * 8;
      #pragma unroll
      for (int j = 0; j < 8; ++j) {
        unsigned p = pk2(xr[j]);
        axh[m][kbi][j] = (short)(p >> 16);
        axl[m][kbi][j] = (short)(p & 0xffffu);
      }
    }
  // b1 preload (static-indexed register file; keeps loop free of tracked VMEM)
  float bv[8][4];
  #pragma unroll
  for (int ch = 0; ch < 8; ++ch)
    #pragma unroll
    for (int tn = 0; tn < 4; ++tn)
      bv[ch][tn] = b1[kc + ch * 64 + tn * 16 + lm];
  asm volatile("s_waitcnt vmcnt(0)" ::: "memory");  // clean vmcnt before pipeline
  __builtin_amdgcn_sched_barrier(0);
  // prologue: stage W1[0]
  #pragma unroll
  for (int i = 0; i < 4; ++i)
    gl16(ibase + i * 4096 + t * 16, &W1b[0][i * 4096 + t * 16]);

  f32x4 acc[2][4];
  #pragma unroll
  for (int m = 0; m < 2; ++m)
    #pragma unroll
    for (int tn = 0; tn < 4; ++tn) acc[m][tn] = (f32x4){0.f, 0.f, 0.f, 0.f};

  #pragma unroll
  for (int ch = 0; ch < 8; ++ch) {
    const int p = ch & 1;
    const char* cbase = ibase + ch * 32768;
    // issue W2[ch] (consumed this chunk at G2)
    #pragma unroll
    for (int i = 0; i < 4; ++i)
      gl16(cbase + 16384 + i * 4096 + t * 16, &W2b[i * 4096 + t * 16]);
    // issue W1[ch+1] (consumed next chunk at G1)
    if (ch < 7) {
      #pragma unroll
      for (int i = 0; i < 4; ++i)
        gl16(cbase + 32768 + i * 4096 + t * 16, &W1b[p ^ 1][i * 4096 + t * 16]);
    }
    // wait W1[ch] landed (oldest 4); newer 8 (or 4) stay in flight
    if (ch < 7) { asm volatile("s_waitcnt vmcnt(8)" ::: "memory"); }
    else        { asm volatile("s_waitcnt vmcnt(4)" ::: "memory"); }
    __builtin_amdgcn_sched_barrier(0);
    __builtin_amdgcn_s_barrier();
    __builtin_amdgcn_sched_barrier(0);
    // GEMM1: h = x @ w1[ch]^T  (reads W1b[p])
    const char* P0h = W1b[p];
    const char* P0l = W1b[p] + 8192;
    f32x4 h4[2][4];
    #pragma unroll
    for (int m = 0; m < 2; ++m)
      #pragma unroll
      for (int tn = 0; tn < 4; ++tn) h4[m][tn] = (f32x4){0.f, 0.f, 0.f, 0.f};
    #pragma unroll
    for (int kbi = 0; kbi < 2; ++kbi) {
      int sw = (((kbi * 4 + lq) ^ (lm & 7)) << 4);
      #pragma unroll
      for (int tn = 0; tn < 4; ++tn) {
        int brow = tn * 16 + lm;
        short8 bhi = *(const short8*)(P0h + brow * 128 + sw);
        short8 blo = *(const short8*)(P0l + brow * 128 + sw);
        #pragma unroll
        for (int m = 0; m < 2; ++m) {
          h4[m][tn] = __builtin_amdgcn_mfma_f32_16x16x32_bf16(axh[m][kbi], bhi, h4[m][tn], 0, 0, 0);
          h4[m][tn] = __builtin_amdgcn_mfma_f32_16x16x32_bf16(axh[m][kbi], blo, h4[m][tn], 0, 0, 0);
          h4[m][tn] = __builtin_amdgcn_mfma_f32_16x16x32_bf16(axl[m][kbi], bhi, h4[m][tn], 0, 0, 0);
        }
      }
    }
    // h = relu(h+b1); split (trunc hi + RNE residual) -> hpl (wave-private rows)
    #pragma unroll
    for (int m = 0; m < 2; ++m)
      #pragma unroll
      for (int tn = 0; tn < 4; ++tn)
        #pragma unroll
        for (int r = 0; r < 4; ++r) {
          float hv = fmaxf(h4[m][tn][r] + bv[ch][tn], 0.f);
          unsigned u = __float_as_uint(hv);
          float resid = hv - __uint_as_float(u & 0xffff0000u);
          unsigned c2 = __float_as_uint(resid);
          int hrow = m * 64 + wv * 16 + lq * 4 + r, hcol = tn * 16 + lm;
          int off = hrow * 128 + (((hcol >> 3) ^ (hrow & 7)) << 4) + ((hcol & 7) << 1);
          *(unsigned short*)((char*)hpl[0] + off) = (unsigned short)(u >> 16);
          *(unsigned short*)((char*)hpl[1] + off) =
              (unsigned short)((c2 + 0x7fffu + ((c2 >> 16) & 1u)) >> 16);
        }
    // wait W2[ch] landed (next-oldest 4); W1[ch+1] stays in flight
    if (ch < 7) { asm volatile("s_waitcnt vmcnt(4)" ::: "memory"); }
    else        { asm volatile("s_waitcnt vmcnt(0)" ::: "memory"); }
    __builtin_amdgcn_sched_barrier(0);
    __builtin_amdgcn_s_barrier();
    __builtin_amdgcn_sched_barrier(0);
    // GEMM2: acc += h @ w2[ch]  (reads W2b + own hpl rows)
    const char* P1h = W2b;
    const char* P1l = W2b + 8192;
    #pragma unroll
    for (int kbi = 0; kbi < 2; ++kbi) {
      short8 a2h[2], a2l[2];
      #pragma unroll
      for (int m = 0; m < 2; ++m) {
        int arow = m * 64 + wv * 16 + lm;
        int swa = (((kbi * 4 + lq) ^ (arow & 7)) << 4);
        a2h[m] = *(const short8*)((const char*)hpl[0] + arow * 128 + swa);
        a2l[m] = *(const short8*)((const char*)hpl[1] + arow * 128 + swa);
      }
      int swb = (((kbi * 4 + lq) ^ (lm & 7)) << 4);
      #pragma unroll
      for (int tn = 0; tn < 4; ++tn) {
        int brow = tn * 16 + lm;
        short8 bhi = *(const short8*)(P1h + brow * 128 + swb);
        short8 blo = *(const short8*)(P1l + brow * 128 + swb);
        #pragma unroll
        for (int m = 0; m < 2; ++m) {
          acc[m][tn] = __builtin_amdgcn_mfma_f32_16x16x32_bf16(a2h[m], bhi, acc[m][tn], 0, 0, 0);
          acc[m][tn] = __builtin_amdgcn_mfma_f32_16x16x32_bf16(a2h[m], blo, acc[m][tn], 0, 0, 0);
          acc[m][tn] = __builtin_amdgcn_mfma_f32_16x16x32_bf16(a2l[m], bhi, acc[m][tn], 0, 0, 0);
        }
      }
    }
    // all waves done reading W2b before next chunk's issue overwrites it
    __builtin_amdgcn_s_barrier();
    __builtin_amdgcn_sched_barrier(0);
  }
  // epilogue: stage acc to LDS f32 (XOR-swizzled), then coalesced dwordx4 stores
  float* fb = (float*)hpl;
  #pragma unroll
  for (int m = 0; m < 2; ++m)
    #pragma unroll
    for (int tn = 0; tn < 4; ++tn)
      #pragma unroll
      for (int r = 0; r < 4; ++r) {
        int row = m * 64 + wv * 16 + lq * 4 + r;
        int col = (tn * 16 + lm) ^ ((row & 7) << 2);
        fb[row * 64 + col] = acc[m][tn][r];
      }
  __syncthreads();
  float* pb = part + (size_t)ks * (BB * NN * 64);
  #pragma unroll
  for (int i = 0; i < 8; ++i) {
    int idx = t * 4 + i * 1024;
    int row = idx >> 6, c0 = idx & 63;
    int c0s = c0 ^ ((row & 7) << 2);
    float4 v = *(const float4*)(fb + row * 64 + c0s);
    *(float4*)(pb + (size_t)(row0 + row) * 64 + c0) = v;
  }
}

// ------- combine 4 partials + residual + b2 + LN; one wave per row ---------
__global__ void k_ffn_ln(const float* __restrict__ part, const float* __restrict__ b2,
                         const float* __restrict__ g, const float* __restrict__ be,
                         float* __restrict__ x) {
  int row = blockIdx.x * 4 + (threadIdx.x >> 6);
  int j = threadIdx.x & 63;
  size_t o = (size_t)row * 64 + j;
  const size_t S = (size_t)BB * NN * 64;
  float val = x[o] + b2[j] + ((part[o] + part[o + S]) + (part[o + 2 * S] + part[o + 3 * S]));
  float s = val;
  for (int off = 32; off; off >>= 1) s += __shfl_xor(s, off);
  s *= (1.f / 64.f);
  float d = val - s;
  float v = d * d;
  for (int off = 32; off; off >>= 1) v += __shfl_xor(v, off);
  v *= (1.f / 64.f);
  x[o] = d * rsqrtf(v + EPSF) * g[j] + be[j];
}

// ------- score head tiled ----------
__global__ void k_fg2(const float* __restrict__ x,
                      const float* __restrict__ w0, const float* __restrict__ b0, const float* __restrict__ bn0,
                      const float* __restrict__ w1, const float* __restrict__ b1, const float* __restrict__ bn1,
                      const float* __restrict__ w2, const float* __restrict__ b2, const float* __restrict__ bn2,
                      float* __restrict__ scores) {
  __shared__ float xs[64 * 68];
  __shared__ float ws[64 * 68];
  __shared__ float s0s[64 * 68];
  __shared__ float s1s[64 * 20];
  int row0 = blockIdx.x * 64;
  int t = threadIdx.x;
  #pragma unroll
  for (int i = 0; i < 4; ++i) {
    int q = t + i * 256, r = q >> 4, c = (q & 15) * 4;
    *(float4*)(xs + r * 68 + c) = *(const float4*)(x + (size_t)(row0 + r) * 64 + c);
    *(float4*)(ws + r * 68 + c) = *(const float4*)(w0 + r * 64 + c);
  }
  __syncthreads();
  int tx = t & 15, ty = t >> 4;
  float acc[4][4] = {};
  for (int f = 0; f < 64; f += 4) {
    float4 xv[4], wv[4];
    #pragma unroll
    for (int ri = 0; ri < 4; ++ri) xv[ri] = *(const float4*)(xs + (ty * 4 + ri) * 68 + f);
    #pragma unroll
    for (int ci = 0; ci < 4; ++ci) wv[ci] = *(const float4*)(ws + (tx + 16 * ci) * 68 + f);
    #pragma unroll
    for (int ri = 0; ri < 4; ++ri)
      #pragma unroll
      for (int ci = 0; ci < 4; ++ci)
        acc[ri][ci] += xv[ri].x * wv[ci].x + xv[ri].y * wv[ci].y +
                       xv[ri].z * wv[ci].z + xv[ri].w * wv[ci].w;
  }
  #pragma unroll
  for (int ri = 0; ri < 4; ++ri)
    #pragma unroll
    for (int ci = 0; ci < 4; ++ci) {
      int c = tx + 16 * ci;
      float sc = bn0[c] * rsqrtf(bn0[192 + c] + EPSF);
      float v = (acc[ri][ci] + b0[c] - bn0[128 + c]) * sc + bn0[64 + c];
      s0s[(ty * 4 + ri) * 68 + c] = fmaxf(v, 0.f);
    }
  __syncthreads();
  {
    int rl = t & 63, j0 = t >> 6;
    #pragma unroll
    for (int i = 0; i < 4; ++i) {
      int j = j0 + 4 * i;
      float s = b1[j];
      const float* wr = w1 + j * 64;
      #pragma unroll 16
      for (int c = 0; c < 64; ++c) s += s0s[rl * 68 + c] * wr[c];
      float sc = bn1[j] * rsqrtf(bn1[48 + j] + EPSF);
      s = (s - bn1[32 + j]) * sc + bn1[16 + j];
      s1s[rl * 20 + j] = fmaxf(s, 0.f);
    }
  }
  __syncthreads();
  if (t < 64) {
    float s = b2[0];
    #pragma unroll
    for (int o = 0; o < 16; ++o) s += s1s[t * 20 + o] * w2[o];
    float sc = bn2[0] * rsqrtf(bn2[3] + EPSF);
    s = (s - bn2[2]) * sc + bn2[1];
    scores[row0 + t] = fmaxf(s, 0.f);
  }
}

// ---- top-k (k=16) ----
__global__ void k_topk2(const float* __restrict__ scores, int* __restrict__ idx,
                        float* __restrict__ out_idx) {
  int b = blockIdx.x, t = threadIdx.x;
  float v[8];
  int base = b * NN;
  #pragma unroll
  for (int u = 0; u < 8; ++u) v[u] = scores[base + t + 256 * u];
  __shared__ float wvs[4];
  __shared__ int wis[4];
  __shared__ int winner;
  unsigned taken = 0;
  for (int r = 0; r < TOPK; ++r) {
    float best = -1e30f; int bi = 1 << 30;
    #pragma unroll
    for (int u = 0; u < 8; ++u) {
      if (!((taken >> u) & 1)) {
        float vv = v[u]; int ii = t + 256 * u;
        if (vv > best || (vv == best && ii < bi)) { best = vv; bi = ii; }
      }
    }
    for (int off = 32; off; off >>= 1) {
      float ov = __shfl_xor(best, off);
      int oi = __shfl_xor(bi, off);
      if (ov > best || (ov == best && oi < bi)) { best = ov; bi = oi; }
    }
    if ((t & 63) == 0) { wvs[t >> 6] = best; wis[t >> 6] = bi; }
    __syncthreads();
    if (t == 0) {
      float B = wvs[0]; int I = wis[0];
      #pragma unroll
      for (int q = 1; q < 4; ++q)
        if (wvs[q] > B || (wvs[q] == B && wis[q] < I)) { B = wvs[q]; I = wis[q]; }
      winner = I;
      idx[b * TOPK + r] = I;
      out_idx[b * TOPK + r] = (float)I;
    }
    __syncthreads();
    int w = winner;
    if ((w & 255) == t) taken |= 1u << (w >> 8);
  }
}

// ---------------- ball query + 3 conv stages, 512 threads (8 waves) per (b,k). ----
__global__ void __launch_bounds__(512)
k_group(const float* __restrict__ inp, const int* __restrict__ idx,
        const float* __restrict__ w0, const float* __restrict__ b0, const float* __restrict__ bn0,
        const float* __restrict__ w1, const float* __restrict__ b1, const float* __restrict__ bn1,
        const float* __restrict__ w2, const float* __restrict__ b2, const float* __restrict__ bn2,
        float* __restrict__ r2g) {
  __shared__ int swave[8 * 64];
  __shared__ int scnt[8];
  __shared__ int gidx[NSAMP];
  __shared__ __attribute__((aligned(16))) float gsh[65 * DD];
  __shared__ __attribute__((aligned(16))) float r0[128];
  __shared__ __attribute__((aligned(16))) float r1[256];
  int k = blockIdx.x, b = blockIdx.y;
  int t = threadIdx.x;
  int lane = t & 63, w = t >> 6;
  int qn = idx[b * TOPK + k];
  const float* px = inp + (size_t)b * DD * NN;
  float qx = px[qn], qy = px[NN + qn], qz = px[2 * NN + qn];
  {
    int cnt = 0;
    #pragma unroll
    for (int i = 0; i < 4; ++i) {
      int n = w * 256 + i * 64 + lane;
      float dx = px[n] - qx, dy = px[NN + n] - qy, dz = px[2 * NN + n] - qz;
      bool flag = (dx * dx + dy * dy + dz * dz <= R2);
      unsigned long long m = __ballot(flag);
      int pos = cnt + __popcll(m & ((1ull << lane) - 1ull));
      if (flag && pos < NSAMP) swave[w * 64 + pos] = n;
      cnt += (int)__popcll(m);
    }
    if (lane == 0) scnt[w] = cnt < NSAMP ? cnt : NSAMP;
  }
  __syncthreads();
  if (t < NSAMP) {
    int run = 0, val = -1;
    #pragma unroll
    for (int ww = 0; ww < 8; ++ww) {
      int c = scnt[ww];
      int loc = t - run;
      if (loc >= 0 && loc < c) val = swave[ww * 64 + loc];
      run += c;
    }
    gidx[t] = val;
  }
  __syncthreads();
  if (t < NSAMP) {
    int g0 = gidx[0];
    int gt = gidx[t];
    gidx[t] = (gt < 0) ? g0 : gt;
  }
  __syncthreads();
  if (t < 65 * DD) {
    int p = t / DD, d = t - p * DD;
    int n = (p == 0) ? qn : gidx[p - 1];
    gsh[t] = px[d * NN + n];
  }
  __syncthreads();
  {
    int c = t >> 2, part = t & 3;
    const float2* wr = (const float2*)(w0 + c * 390 + part * 98);
    const float2* gr = (const float2*)(gsh + part * 98);
    int n2 = (part == 3) ? 48 : 49;
    float s = 0.f;
    #pragma unroll 7
    for (int i = 0; i < n2; ++i) {
      float2 a = gr[i], ww = wr[i];
      s += a.x * ww.x + a.y * ww.y;
    }
    s += __shfl_xor(s, 1);
    s += __shfl_xor(s, 2);
    if (part == 0) {
      s += b0[c];
      float sc = bn0[c] * rsqrtf(bn0[384 + c] + EPSF);
      s = (s - bn0[256 + c]) * sc + bn0[128 + c];
      r0[c] = fmaxf(s, 0.f);
    }
  }
  __syncthreads();
  {
    int c = t >> 1, part = t & 1;
    const float4* wr = (const float4*)(w1 + c * 128 + part * 64);
    const float4* rr = (const float4*)(r0 + part * 64);
    float s0 = 0.f, s1 = 0.f, s2 = 0.f, s3 = 0.f;
    #pragma unroll 8
    for (int o = 0; o < 16; ++o) {
      float4 a = rr[o], ww = wr[o];
      s0 += a.x * ww.x; s1 += a.y * ww.y; s2 += a.z * ww.z; s3 += a.w * ww.w;
    }
    float s = (s0 + s1) + (s2 + s3);
    s += __shfl_xor(s, 1);
    if (part == 0) {
      s += b1[c];
      float sc = bn1[c] * rsqrtf(bn1[768 + c] + EPSF);
      s = (s - bn1[512 + c]) * sc + bn1[256 + c];
      r1[c] = fmaxf(s, 0.f);
    }
  }
  __syncthreads();
  {
    int c = t;
    const float4* wr = (const float4*)(w2 + c * 256);
    const float4* rr = (const float4*)r1;
    float s0 = 0.f, s1 = 0.f, s2 = 0.f, s3 = 0.f;
    #pragma unroll 8
    for (int o = 0; o < 64; ++o) {
      float4 a = rr[o], ww = wr[o];
      s0 += a.x * ww.x; s1 += a.y * ww.y; s2 += a.z * ww.z; s3 += a.w * ww.w;
    }
    float s = (s0 + s1) + (s2 + s3) + b2[c];
    float sc = bn2[c] * rsqrtf(bn2[1536 + c] + EPSF);
    s = (s - bn2[1024 + c]) * sc + bn2[512 + c];
    r2g[b * 8192 + c * TOPK + k] = fmaxf(s, 0.f);
  }
}

// ---------------- FC + BN + ReLU (wave-reduced dot), block=64 ----------------
__global__ void k_fl(const float* __restrict__ hin, const float* __restrict__ w,
                     const float* __restrict__ bias, const float* __restrict__ bn,
                     float* __restrict__ hout, int IN, int OUT) {
  int blk = blockIdx.x;
  int b = blk / OUT, j = blk % OUT;
  int lane = threadIdx.x;
  const float* hr = hin + (size_t)b * IN;
  const float* wr = w + (size_t)j * IN;
  float s = 0.f;
  for (int i = lane; i < IN; i += 64) s += hr[i] * wr[i];
  for (int o = 32; o; o >>= 1) s += __shfl_xor(s, o);
  if (lane == 0) {
    s += bias[j];
    float sc = bn[j] * rsqrtf(bn[3 * OUT + j] + EPSF);
    s = (s - bn[2 * OUT + j]) * sc + bn[OUT + j];
    hout[b * OUT + j] = fmaxf(s, 0.f);
  }
}

extern "C" void kernel_launch(void* const* d_in, const int* in_sizes, int n_in,
                              void* d_out, int out_size, void* d_ws, size_t ws_size,
                              hipStream_t stream) {
  const float* sv      = (const float*)d_in[0];
  const float* inp     = (const float*)d_in[1];
  const float* tl_win  = (const float*)d_in[2];
  const float* tl_bin  = (const float*)d_in[3];
  const float* tl_wout = (const float*)d_in[4];
  const float* tl_bout = (const float*)d_in[5];
  const float* tl_w1   = (const float*)d_in[6];
  const float* tl_b1   = (const float*)d_in[7];
  const float* tl_w2   = (const float*)d_in[8];
  const float* tl_b2   = (const float*)d_in[9];
  const float* tl_ln1g = (const float*)d_in[10];
  const float* tl_ln1b = (const float*)d_in[11];
  const float* tl_ln2g = (const float*)d_in[12];
  const float* tl_ln2b = (const float*)d_in[13];
  const float* fg_w0   = (const float*)d_in[14];
  const float* fg_b0   = (const float*)d_in[15];
  const float* fg_w1   = (const float*)d_in[16];
  const float* fg_b1   = (const float*)d_in[17];
  const float* fg_w2   = (const float*)d_in[18];
  const float* fg_b2   = (const float*)d_in[19];
  const float* fbn0    = (const float*)d_in[20];
  const float* fbn1    = (const float*)d_in[21];
  const float* fbn2    = (const float*)d_in[22];
  const float* rc_w0   = (const float*)d_in[23];
  const float* rc_b0   = (const float*)d_in[24];
  const float* rc_w1   = (const float*)d_in[25];
  const float* rc_b1   = (const float*)d_in[26];
  const float* rc_w2   = (const float*)d_in[27];
  const float* rc_b2   = (const float*)d_in[28];
  const float* rbn0    = (const float*)d_in[29];
  const float* rbn1    = (const float*)d_in[30];
  const float* rbn2    = (const float*)d_in[31];
  const float* fl_w0   = (const float*)d_in[32];
  const float* fl_b0   = (const float*)d_in[33];
  const float* fl_w1   = (const float*)d_in[34];
  const float* fl_b1   = (const float*)d_in[35];
  const float* lbn0    = (const float*)d_in[36];
  const float* lbn1    = (const float*)d_in[37];
  (void)in_sizes; (void)n_in; (void)out_size; (void)ws_size;

  float* wsp = (float*)d_ws;
  float* x      = wsp;                        // B*N*F      = 1048576
  float* qkv    = x + BB * NN * FF;           // 3145728-float region
  float* a      = qkv + BB * NN * 192;        // B*N*F      = 1048576
  float* scores = a + BB * NN * FF;           // B*N        = 16384
  int*   idxb   = (int*)(scores + BB * NN);   // B*TOPK     = 128
  float* r2g    = (float*)(idxb + BB * TOPK); // B*8192     = 65536
  float* h1g    = r2g + BB * 8192;            // B*1024     = 8192
  // FFN weight image: [l][chg][4 planes][4096 u16] = 1M u16 = 2MB
  unsigned short* img = (unsigned short*)(h1g + BB * 1024);
  // qkv region carve-out: Q fp32 (1M floats) | kp bf16 (1M u16) | vp bf16 (1M u16)
  float* qbuf = qkv;
  unsigned short* kp = (unsigned short*)(qkv + BB * NN * FF);
  unsigned short* vp = kp + (size_t)BB * NHEAD * NN * HD;
  float* part = qkv;  // FFN split-K partials reuse qkv+a (dead by then)

  float* out = (float*)d_out;  // fp32: h at [0,4096), idx-as-float at [4096,4224)

  k_transpose<<<(BB * NN * FF) / 256, 256, 0, stream>>>(sv, x);
  k_wimg<<<(NLAYER * 32 * 4 * 4096) / 256, 256, 0, stream>>>(tl_w1, tl_w2, img);

  for (int l = 0; l < NLAYER; ++l) {
    k_qkv3<<<dim3(BB * NN / 64, 3), 256, 0, stream>>>(x, tl_win + l * 192 * FF,
                                                      tl_bin + l * 192, qbuf,
                                                      (uint4*)kp, (uint4*)vp);
    k_attn7<<<dim3(NN / 64, NHEAD, BB), 256, 0, stream>>>(qbuf, (const uint4*)kp,
                                                          (const unsigned*)vp, a);
    k_proj2<<<BB * NN / 64, 256, 0, stream>>>(a, tl_wout + l * FF * FF, tl_bout + l * FF,
                                              tl_ln1g + l * FF, tl_ln1b + l * FF, x);
    k_ffn7<<<dim3(BB * NN / 128, 4), 256, 0, stream>>>(x, (const char*)(img + (size_t)l * 524288),
                                                       tl_b1 + l * 2048, part);
    k_ffn_ln<<<BB * NN / 4, 256, 0, stream>>>(part, tl_b2 + l * FF,
                                              tl_ln2g + l * FF, tl_ln2b + l * FF, x);
  }

  k_fg2<<<BB * NN / 64, 256, 0, stream>>>(x, fg_w0, fg_b0, fbn0, fg_w1, fg_b1, fbn1,
                                          fg_w2, fg_b2, fbn2, scores);
  k_topk2<<<BB, 256, 0, stream>>>(scores, idxb, out + BB * 512);
  k_group<<<dim3(TOPK, BB), 512, 0, stream>>>(inp, idxb, rc_w0, rc_b0, rbn0,
                                              rc_w1, rc_b1, rbn1, rc_w2, rc_b2, rbn2, r2g);
  k_fl<<<BB * 1024, 64, 0, stream>>>(r2g, fl_w0, fl_b0, lbn0, h1g, 8192, 1024);
  k_fl<<<BB * 512, 64, 0, stream>>>(h1g, fl_w1, fl_b1, lbn1, out, 1024, 512);
}

// Round 6
// 469.315 us; speedup vs baseline: 1.5913x; 1.0790x over previous
//
#include <hip/hip_runtime.h>
#include <hip/hip_bf16.h>
#include <math.h>

#define BB 8
#define NN 2048
#define FF 64
#define DD 6
#define NSAMP 64
#define TOPK 16
#define NHEAD 8
#define HD 8
#define NLAYER 2
#define EPSF 1e-5f
#define R2 0.09f

typedef short short8 __attribute__((ext_vector_type(8)));
typedef float f32x4 __attribute__((ext_vector_type(4)));
typedef unsigned uint4v __attribute__((ext_vector_type(4)));
typedef unsigned int u32;

// split-pack: u32 = (bf16_hi << 16) | bf16_lo, both RNE. x ≈ hi + lo, err ~2^-16 rel.
__device__ inline unsigned pk2(float x) {
  unsigned b = __float_as_uint(x);
  unsigned hi = (b + 0x7fffu + ((b >> 16) & 1u)) >> 16;
  float r = x - __uint_as_float(hi << 16);
  unsigned c = __float_as_uint(r);
  unsigned lo = (c + 0x7fffu + ((c >> 16) & 1u)) >> 16;
  return (hi << 16) | lo;
}

__device__ inline unsigned short bf16r(float x) {  // RNE bf16
  unsigned b = __float_as_uint(x);
  return (unsigned short)((b + 0x7fffu + ((b >> 16) & 1u)) >> 16);
}

// async global->LDS, 16B per lane (dest = wave-uniform base + lane*16)
__device__ __forceinline__ void gl16(const void* g, void* l) {
  __builtin_amdgcn_global_load_lds((const __attribute__((address_space(1))) u32*)g,
                                   (__attribute__((address_space(3))) u32*)l, 16, 0, 0);
}

// ---------------- transpose sortvec (B,1,F,N) -> x (B,N,F) ----------------
__global__ void k_transpose(const float* __restrict__ sv, float* __restrict__ x) {
  int i = blockIdx.x * 256 + threadIdx.x;
  if (i >= BB * NN * FF) return;
  int f = i % FF;
  int n = (i / FF) % NN;
  int b = i / (FF * NN);
  x[i] = sv[(b * FF + f) * NN + n];
}

// ---- pack FFN weights into the exact per-chunk LDS byte image (pre-swizzled).
__global__ void k_wimg(const float* __restrict__ w1, const float* __restrict__ w2,
                       unsigned short* __restrict__ img) {
  int i = blockIdx.x * 256 + threadIdx.x;     // u16 index, total 2*32*4*4096
  int e = i & 4095;
  int plane = (i >> 12) & 3;
  int chg = (i >> 14) & 31;
  int l = i >> 19;
  int r = e >> 6, sh = (e >> 3) & 7, inner = e & 7;
  int s = sh ^ (r & 7);
  float v;
  if (plane < 2) v = w1[((size_t)(l * 2048 + chg * 64 + r)) * 64 + s * 8 + inner];
  else           v = w2[((size_t)(l * 64 + r)) * 2048 + chg * 64 + s * 8 + inner];
  unsigned p = pk2(v);
  img[i] = (unsigned short)((plane & 1) ? (p & 0xffffu) : (p >> 16));
}

// ---- qkv v3: tiled GEMM; epilogue routes per blockIdx.y ----
__global__ void k_qkv3(const float* __restrict__ x, const float* __restrict__ win,
                       const float* __restrict__ bin, float* __restrict__ qbuf,
                       uint4* __restrict__ kp4, uint4* __restrict__ vp4) {
  __shared__ float xs[64 * 68];
  __shared__ float ws[64 * 68];
  int row0 = blockIdx.x * 64, y = blockIdx.y, col0 = y * 64;
  int t = threadIdx.x;
  #pragma unroll
  for (int i = 0; i < 4; ++i) {
    int q = t + i * 256, r = q >> 4, c = (q & 15) * 4;
    *(float4*)(xs + r * 68 + c) = *(const float4*)(x + (size_t)(row0 + r) * 64 + c);
    *(float4*)(ws + r * 68 + c) = *(const float4*)(win + (size_t)(col0 + r) * 64 + c);
  }
  __syncthreads();
  int tx = t & 15, ty = t >> 4;
  float acc[4][4] = {};
  for (int f = 0; f < 64; f += 4) {
    float4 xv[4], wv[4];
    #pragma unroll
    for (int ri = 0; ri < 4; ++ri) xv[ri] = *(const float4*)(xs + (ty * 4 + ri) * 68 + f);
    #pragma unroll
    for (int ci = 0; ci < 4; ++ci) wv[ci] = *(const float4*)(ws + (tx + 16 * ci) * 68 + f);
    #pragma unroll
    for (int ri = 0; ri < 4; ++ri)
      #pragma unroll
      for (int ci = 0; ci < 4; ++ci)
        acc[ri][ci] += xv[ri].x * wv[ci].x + xv[ri].y * wv[ci].y +
                       xv[ri].z * wv[ci].z + xv[ri].w * wv[ci].w;
  }
  int b = row0 >> 11, n0 = row0 & (NN - 1);
  if (y == 0) {
    #pragma unroll
    for (int ri = 0; ri < 4; ++ri)
      #pragma unroll
      for (int ci = 0; ci < 4; ++ci) {
        int r = row0 + ty * 4 + ri, c = tx + 16 * ci;
        qbuf[(size_t)r * 64 + c] = acc[ri][ci] + bin[c];
      }
    return;
  }
  __syncthreads();  // all GEMM reads of xs done before reuse
  unsigned short* l16 = (unsigned short*)xs;  // 64x72 u16 tile
  if (y == 1) {
    #pragma unroll
    for (int ri = 0; ri < 4; ++ri)
      #pragma unroll
      for (int ci = 0; ci < 4; ++ci) {
        int r = ty * 4 + ri, c = tx + 16 * ci;
        l16[r * 72 + c] = bf16r(acc[ri][ci] + bin[64 + c]);
      }
    __syncthreads();
    #pragma unroll
    for (int i = 0; i < 2; ++i) {
      int idx = t + i * 256;
      int h = idx >> 6, tok = idx & 63;
      uint4 v = *(const uint4*)(l16 + tok * 72 + h * 8);
      kp4[(size_t)(b * NHEAD + h) * NN + n0 + tok] = v;
    }
  } else {
    #pragma unroll
    for (int ri = 0; ri < 4; ++ri)
      #pragma unroll
      for (int ci = 0; ci < 4; ++ci) {
        int r = ty * 4 + ri, c = tx + 16 * ci;
        l16[c * 72 + r] = bf16r(acc[ri][ci] + bin[128 + c]);  // transposed
      }
    __syncthreads();
    #pragma unroll
    for (int i = 0; i < 2; ++i) {
      int idx = t + i * 256;
      int c = idx >> 3, seg = idx & 7;
      uint4 v = *(const uint4*)(l16 + c * 72 + seg * 8);
      vp4[(size_t)(b * 64 + c) * (NN / 8) + (n0 >> 3) + seg] = v;
    }
  }
}

// ---- attention v8: swapped-operand flash (T12 analog). QK computed as
// mfma(K,Q) -> C rows=keys, cols=queries, so each lane owns 8 P-values for its
// query. P -> bf16 pairs (same truncation as v7) -> one shfl_xor(16) exchange
// -> direct PV B-operand. PV computes O^T = mfma(V^T, P) with the key
// permutation [0..7,16..23,8..15,24..31] baked into the V read offset.
// No P LDS round-trip, no pb16 (LDS 8.7 KB), float4 output stores.
__global__ void __launch_bounds__(256, 8)
k_attn8(const float* __restrict__ q, const uint4* __restrict__ kp4,
        const unsigned* __restrict__ vp32, float* __restrict__ a) {
  __shared__ uint4 kb4[256];                                            // 4 KB
  __shared__ __attribute__((aligned(16))) unsigned short vb16[9 * 264]; // 4.6 KB
  int t = threadIdx.x;
  int lane = t & 63, w = t >> 6;
  int nIdx = lane & 15, lq = lane >> 4;
  int h = blockIdx.y, b = blockIdx.z;
  int qwb = blockIdx.x * 64 + w * 16;
  int bh = b * NHEAD + h;
  const float kf = 0.35355339059327373f * 1.4426950408889634f;  // scale*log2e
  // Q B-fragment: quad0 lanes hold d=0..7 (RNE bf16), others zero
  short8 qF = {0, 0, 0, 0, 0, 0, 0, 0};
  if (lq == 0) {
    const float* qr = q + ((size_t)(b * NN + qwb + nIdx)) * 64 + h * HD;
    #pragma unroll
    for (int j = 0; j < 8; ++j) qF[j] = (short)bf16r(qr[j] * kf);
  }
  f32x4 acc = {0.f, 0.f, 0.f, 0.f};
  const uint4* kbase = kp4 + (size_t)bh * NN;
  const unsigned* vbase = vp32 + (size_t)bh * HD * (NN / 2);
  int vn = nIdx < 9 ? nIdx : 8;
  int voff = ((lq & 1) << 4) + ((lq >> 1) << 3);  // key perm per quad
  // ones row (l-sum) written once; first barrier in loop makes it visible
  if (t < 132) ((unsigned*)(vb16 + 8 * 264))[t] = 0x3f803f80u;
  // prefetch chunk 0
  uint4 kreg = kbase[t];
  unsigned vreg[4];
  #pragma unroll
  for (int i = 0; i < 4; ++i) {
    int g = t + i * 256;
    vreg[i] = vbase[(g >> 7) * (NN / 2) + (g & 127)];
  }
  for (int kc = 0; kc < NN; kc += 256) {
    __syncthreads();  // previous compute done with LDS
    kb4[t] = kreg;
    #pragma unroll
    for (int i = 0; i < 4; ++i) {
      int g = t + i * 256;
      ((unsigned*)vb16)[(g >> 7) * 132 + (g & 127)] = vreg[i];
    }
    __syncthreads();
    if (kc + 256 < NN) {  // issue next-chunk loads; land during compute
      kreg = kbase[kc + 256 + t];
      #pragma unroll
      for (int i = 0; i < 4; ++i) {
        int g = t + i * 256;
        vreg[i] = vbase[(g >> 7) * (NN / 2) + ((kc + 256) >> 1) + (g & 127)];
      }
    }
    for (int s = 0; s < 8; ++s) {
      int kb = s * 32;
      unsigned pk_[4];
      #pragma unroll
      for (int half = 0; half < 2; ++half) {
        int key = kb + half * 16 + nIdx;
        short8 aK = {0, 0, 0, 0, 0, 0, 0, 0};
        if (lq == 0) aK = *(const short8*)(kb4 + key);
        f32x4 c = {0.f, 0.f, 0.f, 0.f};
        c = __builtin_amdgcn_mfma_f32_16x16x32_bf16(aK, qF, c, 0, 0, 0);
        unsigned u0 = __float_as_uint(__builtin_amdgcn_exp2f(c[0]));
        unsigned u1 = __float_as_uint(__builtin_amdgcn_exp2f(c[1]));
        unsigned u2 = __float_as_uint(__builtin_amdgcn_exp2f(c[2]));
        unsigned u3 = __float_as_uint(__builtin_amdgcn_exp2f(c[3]));
        pk_[half * 2]     = (u0 >> 16) | (u1 & 0xffff0000u);  // trunc bf16 pair
        pk_[half * 2 + 1] = (u2 >> 16) | (u3 & 0xffff0000u);
      }
      unsigned e0 = (unsigned)__shfl_xor((int)pk_[0], 16);
      unsigned e1 = (unsigned)__shfl_xor((int)pk_[1], 16);
      unsigned e2 = (unsigned)__shfl_xor((int)pk_[2], 16);
      unsigned e3 = (unsigned)__shfl_xor((int)pk_[3], 16);
      bool odd = (lq & 1);
      uint4v bw;
      bw[0] = odd ? e2 : pk_[0];
      bw[1] = odd ? e3 : pk_[1];
      bw[2] = odd ? pk_[2] : e0;
      bw[3] = odd ? pk_[3] : e1;
      short8 bP = *(short8*)&bw;
      short8 aV = *(const short8*)(vb16 + vn * 264 + kb + voff);
      acc = __builtin_amdgcn_mfma_f32_16x16x32_bf16(aV, bP, acc, 0, 0, 0);
    }
  }
  // epilogue: O^T rows d=lq*4+r, col q=nIdx; row 8 (lane lq=2, r=0) holds l.
  float lr = __shfl(acc[0], 32 + nIdx);
  if (lq < 2) {
    int row = qwb + nIdx;
    float4 o;
    o.x = acc[0] / lr; o.y = acc[1] / lr; o.z = acc[2] / lr; o.w = acc[3] / lr;
    *(float4*)(a + ((size_t)(b * NN + row)) * 64 + h * HD + lq * 4) = o;
  }
}

// ------- proj + residual + LN, tiled GEMM ---------
__global__ void k_proj2(const float* __restrict__ a, const float* __restrict__ wout,
                        const float* __restrict__ bout, const float* __restrict__ g,
                        const float* __restrict__ be, float* __restrict__ x) {
  __shared__ float xs[64 * 68];
  __shared__ float ws[64 * 68];
  int row0 = blockIdx.x * 64;
  int t = threadIdx.x;
  #pragma unroll
  for (int i = 0; i < 4; ++i) {
    int q = t + i * 256, r = q >> 4, c = (q & 15) * 4;
    *(float4*)(xs + r * 68 + c) = *(const float4*)(a + (size_t)(row0 + r) * 64 + c);
    *(float4*)(ws + r * 68 + c) = *(const float4*)(wout + r * 64 + c);
  }
  __syncthreads();
  int tx = t & 15, ty = t >> 4;
  float acc[4][4] = {};
  for (int f = 0; f < 64; f += 4) {
    float4 xv[4], wv[4];
    #pragma unroll
    for (int ri = 0; ri < 4; ++ri) xv[ri] = *(const float4*)(xs + (ty * 4 + ri) * 68 + f);
    #pragma unroll
    for (int ci = 0; ci < 4; ++ci) wv[ci] = *(const float4*)(ws + (tx + 16 * ci) * 68 + f);
    #pragma unroll
    for (int ri = 0; ri < 4; ++ri)
      #pragma unroll
      for (int ci = 0; ci < 4; ++ci)
        acc[ri][ci] += xv[ri].x * wv[ci].x + xv[ri].y * wv[ci].y +
                       xv[ri].z * wv[ci].z + xv[ri].w * wv[ci].w;
  }
  #pragma unroll
  for (int ri = 0; ri < 4; ++ri) {
    int rl = ty * 4 + ri;
    float val[4], s = 0.f, sq = 0.f;
    #pragma unroll
    for (int ci = 0; ci < 4; ++ci) {
      int c = tx + 16 * ci;
      val[ci] = x[(size_t)(row0 + rl) * 64 + c] + bout[c] + acc[ri][ci];
      s += val[ci]; sq += val[ci] * val[ci];
    }
    #pragma unroll
    for (int off = 1; off < 16; off <<= 1) { s += __shfl_xor(s, off); sq += __shfl_xor(sq, off); }
    float mean = s * (1.f / 64.f);
    float var = sq * (1.f / 64.f) - mean * mean;
    float rstd = rsqrtf(var + EPSF);
    #pragma unroll
    for (int ci = 0; ci < 4; ++ci) {
      int c = tx + 16 * ci;
      x[(size_t)(row0 + rl) * 64 + c] = (val[ci] - mean) * rstd * g[c] + be[c];
    }
  }
}

// ------- FFN v7: global_load_lds staging, counted vmcnt, raw s_barriers ----
__global__ void __launch_bounds__(256, 2)
k_ffn7(const float* __restrict__ x, const char* __restrict__ img,
       const float* __restrict__ b1, float* __restrict__ part) {
  __shared__ __attribute__((aligned(16))) char W1b[2][16384];
  __shared__ __attribute__((aligned(16))) char W2b[16384];
  __shared__ __attribute__((aligned(16))) unsigned short hpl[2][128 * 64];
  int row0 = blockIdx.x * 128;
  int ks = blockIdx.y, kc = ks * 512;
  int t = threadIdx.x, lane = t & 63, wv = t >> 6;
  int lm = lane & 15, lq = lane >> 4;
  const char* ibase = img + (size_t)ks * 8 * 32768;

  short8 axh[2][2], axl[2][2];
  #pragma unroll
  for (int m = 0; m < 2; ++m)
    #pragma unroll
    for (int kbi = 0; kbi < 2; ++kbi) {
      const float* xr = x + (size_t)(row0 + m * 64 + wv * 16 + lm) * 64 + kbi * 32 + lq * 8;
      #pragma unroll
      for (int j = 0; j < 8; ++j) {
        unsigned p = pk2(xr[j]);
        axh[m][kbi][j] = (short)(p >> 16);
        axl[m][kbi][j] = (short)(p & 0xffffu);
      }
    }
  float bv[8][4];
  #pragma unroll
  for (int ch = 0; ch < 8; ++ch)
    #pragma unroll
    for (int tn = 0; tn < 4; ++tn)
      bv[ch][tn] = b1[kc + ch * 64 + tn * 16 + lm];
  asm volatile("s_waitcnt vmcnt(0)" ::: "memory");
  __builtin_amdgcn_sched_barrier(0);
  #pragma unroll
  for (int i = 0; i < 4; ++i)
    gl16(ibase + i * 4096 + t * 16, &W1b[0][i * 4096 + t * 16]);

  f32x4 acc[2][4];
  #pragma unroll
  for (int m = 0; m < 2; ++m)
    #pragma unroll
    for (int tn = 0; tn < 4; ++tn) acc[m][tn] = (f32x4){0.f, 0.f, 0.f, 0.f};

  #pragma unroll
  for (int ch = 0; ch < 8; ++ch) {
    const int p = ch & 1;
    const char* cbase = ibase + ch * 32768;
    #pragma unroll
    for (int i = 0; i < 4; ++i)
      gl16(cbase + 16384 + i * 4096 + t * 16, &W2b[i * 4096 + t * 16]);
    if (ch < 7) {
      #pragma unroll
      for (int i = 0; i < 4; ++i)
        gl16(cbase + 32768 + i * 4096 + t * 16, &W1b[p ^ 1][i * 4096 + t * 16]);
    }
    if (ch < 7) { asm volatile("s_waitcnt vmcnt(8)" ::: "memory"); }
    else        { asm volatile("s_waitcnt vmcnt(4)" ::: "memory"); }
    __builtin_amdgcn_sched_barrier(0);
    __builtin_amdgcn_s_barrier();
    __builtin_amdgcn_sched_barrier(0);
    const char* P0h = W1b[p];
    const char* P0l = W1b[p] + 8192;
    f32x4 h4[2][4];
    #pragma unroll
    for (int m = 0; m < 2; ++m)
      #pragma unroll
      for (int tn = 0; tn < 4; ++tn) h4[m][tn] = (f32x4){0.f, 0.f, 0.f, 0.f};
    #pragma unroll
    for (int kbi = 0; kbi < 2; ++kbi) {
      int sw = (((kbi * 4 + lq) ^ (lm & 7)) << 4);
      #pragma unroll
      for (int tn = 0; tn < 4; ++tn) {
        int brow = tn * 16 + lm;
        short8 bhi = *(const short8*)(P0h + brow * 128 + sw);
        short8 blo = *(const short8*)(P0l + brow * 128 + sw);
        #pragma unroll
        for (int m = 0; m < 2; ++m) {
          h4[m][tn] = __builtin_amdgcn_mfma_f32_16x16x32_bf16(axh[m][kbi], bhi, h4[m][tn], 0, 0, 0);
          h4[m][tn] = __builtin_amdgcn_mfma_f32_16x16x32_bf16(axh[m][kbi], blo, h4[m][tn], 0, 0, 0);
          h4[m][tn] = __builtin_amdgcn_mfma_f32_16x16x32_bf16(axl[m][kbi], bhi, h4[m][tn], 0, 0, 0);
        }
      }
    }
    #pragma unroll
    for (int m = 0; m < 2; ++m)
      #pragma unroll
      for (int tn = 0; tn < 4; ++tn)
        #pragma unroll
        for (int r = 0; r < 4; ++r) {
          float hv = fmaxf(h4[m][tn][r] + bv[ch][tn], 0.f);
          unsigned u = __float_as_uint(hv);
          float resid = hv - __uint_as_float(u & 0xffff0000u);
          unsigned c2 = __float_as_uint(resid);
          int hrow = m * 64 + wv * 16 + lq * 4 + r, hcol = tn * 16 + lm;
          int off = hrow * 128 + (((hcol >> 3) ^ (hrow & 7)) << 4) + ((hcol & 7) << 1);
          *(unsigned short*)((char*)hpl[0] + off) = (unsigned short)(u >> 16);
          *(unsigned short*)((char*)hpl[1] + off) =
              (unsigned short)((c2 + 0x7fffu + ((c2 >> 16) & 1u)) >> 16);
        }
    if (ch < 7) { asm volatile("s_waitcnt vmcnt(4)" ::: "memory"); }
    else        { asm volatile("s_waitcnt vmcnt(0)" ::: "memory"); }
    __builtin_amdgcn_sched_barrier(0);
    __builtin_amdgcn_s_barrier();
    __builtin_amdgcn_sched_barrier(0);
    const char* P1h = W2b;
    const char* P1l = W2b + 8192;
    #pragma unroll
    for (int kbi = 0; kbi < 2; ++kbi) {
      short8 a2h[2], a2l[2];
      #pragma unroll
      for (int m = 0; m < 2; ++m) {
        int arow = m * 64 + wv * 16 + lm;
        int swa = (((kbi * 4 + lq) ^ (arow & 7)) << 4);
        a2h[m] = *(const short8*)((const char*)hpl[0] + arow * 128 + swa);
        a2l[m] = *(const short8*)((const char*)hpl[1] + arow * 128 + swa);
      }
      int swb = (((kbi * 4 + lq) ^ (lm & 7)) << 4);
      #pragma unroll
      for (int tn = 0; tn < 4; ++tn) {
        int brow = tn * 16 + lm;
        short8 bhi = *(const short8*)(P1h + brow * 128 + swb);
        short8 blo = *(const short8*)(P1l + brow * 128 + swb);
        #pragma unroll
        for (int m = 0; m < 2; ++m) {
          acc[m][tn] = __builtin_amdgcn_mfma_f32_16x16x32_bf16(a2h[m], bhi, acc[m][tn], 0, 0, 0);
          acc[m][tn] = __builtin_amdgcn_mfma_f32_16x16x32_bf16(a2h[m], blo, acc[m][tn], 0, 0, 0);
          acc[m][tn] = __builtin_amdgcn_mfma_f32_16x16x32_bf16(a2l[m], bhi, acc[m][tn], 0, 0, 0);
        }
      }
    }
    __builtin_amdgcn_s_barrier();
    __builtin_amdgcn_sched_barrier(0);
  }
  float* fb = (float*)hpl;
  #pragma unroll
  for (int m = 0; m < 2; ++m)
    #pragma unroll
    for (int tn = 0; tn < 4; ++tn)
      #pragma unroll
      for (int r = 0; r < 4; ++r) {
        int row = m * 64 + wv * 16 + lq * 4 + r;
        int col = (tn * 16 + lm) ^ ((row & 7) << 2);
        fb[row * 64 + col] = acc[m][tn][r];
      }
  __syncthreads();
  float* pb = part + (size_t)ks * (BB * NN * 64);
  #pragma unroll
  for (int i = 0; i < 8; ++i) {
    int idx = t * 4 + i * 1024;
    int row = idx >> 6, c0 = idx & 63;
    int c0s = c0 ^ ((row & 7) << 2);
    float4 v = *(const float4*)(fb + row * 64 + c0s);
    *(float4*)(pb + (size_t)(row0 + row) * 64 + c0) = v;
  }
}

// ------- combine 4 partials + residual + b2 + LN; one wave per row ---------
__global__ void k_ffn_ln(const float* __restrict__ part, const float* __restrict__ b2,
                         const float* __restrict__ g, const float* __restrict__ be,
                         float* __restrict__ x) {
  int row = blockIdx.x * 4 + (threadIdx.x >> 6);
  int j = threadIdx.x & 63;
  size_t o = (size_t)row * 64 + j;
  const size_t S = (size_t)BB * NN * 64;
  float val = x[o] + b2[j] + ((part[o] + part[o + S]) + (part[o + 2 * S] + part[o + 3 * S]));
  float s = val;
  for (int off = 32; off; off >>= 1) s += __shfl_xor(s, off);
  s *= (1.f / 64.f);
  float d = val - s;
  float v = d * d;
  for (int off = 32; off; off >>= 1) v += __shfl_xor(v, off);
  v *= (1.f / 64.f);
  x[o] = d * rsqrtf(v + EPSF) * g[j] + be[j];
}

// ------- score head tiled ----------
__global__ void k_fg2(const float* __restrict__ x,
                      const float* __restrict__ w0, const float* __restrict__ b0, const float* __restrict__ bn0,
                      const float* __restrict__ w1, const float* __restrict__ b1, const float* __restrict__ bn1,
                      const float* __restrict__ w2, const float* __restrict__ b2, const float* __restrict__ bn2,
                      float* __restrict__ scores) {
  __shared__ float xs[64 * 68];
  __shared__ float ws[64 * 68];
  __shared__ float s0s[64 * 68];
  __shared__ float s1s[64 * 20];
  int row0 = blockIdx.x * 64;
  int t = threadIdx.x;
  #pragma unroll
  for (int i = 0; i < 4; ++i) {
    int q = t + i * 256, r = q >> 4, c = (q & 15) * 4;
    *(float4*)(xs + r * 68 + c) = *(const float4*)(x + (size_t)(row0 + r) * 64 + c);
    *(float4*)(ws + r * 68 + c) = *(const float4*)(w0 + r * 64 + c);
  }
  __syncthreads();
  int tx = t & 15, ty = t >> 4;
  float acc[4][4] = {};
  for (int f = 0; f < 64; f += 4) {
    float4 xv[4], wv[4];
    #pragma unroll
    for (int ri = 0; ri < 4; ++ri) xv[ri] = *(const float4*)(xs + (ty * 4 + ri) * 68 + f);
    #pragma unroll
    for (int ci = 0; ci < 4; ++ci) wv[ci] = *(const float4*)(ws + (tx + 16 * ci) * 68 + f);
    #pragma unroll
    for (int ri = 0; ri < 4; ++ri)
      #pragma unroll
      for (int ci = 0; ci < 4; ++ci)
        acc[ri][ci] += xv[ri].x * wv[ci].x + xv[ri].y * wv[ci].y +
                       xv[ri].z * wv[ci].z + xv[ri].w * wv[ci].w;
  }
  #pragma unroll
  for (int ri = 0; ri < 4; ++ri)
    #pragma unroll
    for (int ci = 0; ci < 4; ++ci) {
      int c = tx + 16 * ci;
      float sc = bn0[c] * rsqrtf(bn0[192 + c] + EPSF);
      float v = (acc[ri][ci] + b0[c] - bn0[128 + c]) * sc + bn0[64 + c];
      s0s[(ty * 4 + ri) * 68 + c] = fmaxf(v, 0.f);
    }
  __syncthreads();
  {
    int rl = t & 63, j0 = t >> 6;
    #pragma unroll
    for (int i = 0; i < 4; ++i) {
      int j = j0 + 4 * i;
      float s = b1[j];
      const float* wr = w1 + j * 64;
      #pragma unroll 16
      for (int c = 0; c < 64; ++c) s += s0s[rl * 68 + c] * wr[c];
      float sc = bn1[j] * rsqrtf(bn1[48 + j] + EPSF);
      s = (s - bn1[32 + j]) * sc + bn1[16 + j];
      s1s[rl * 20 + j] = fmaxf(s, 0.f);
    }
  }
  __syncthreads();
  if (t < 64) {
    float s = b2[0];
    #pragma unroll
    for (int o = 0; o < 16; ++o) s += s1s[t * 20 + o] * w2[o];
    float sc = bn2[0] * rsqrtf(bn2[3] + EPSF);
    s = (s - bn2[2]) * sc + bn2[1];
    scores[row0 + t] = fmaxf(s, 0.f);
  }
}

// ---- top-k (k=16) ----
__global__ void k_topk2(const float* __restrict__ scores, int* __restrict__ idx,
                        float* __restrict__ out_idx) {
  int b = blockIdx.x, t = threadIdx.x;
  float v[8];
  int base = b * NN;
  #pragma unroll
  for (int u = 0; u < 8; ++u) v[u] = scores[base + t + 256 * u];
  __shared__ float wvs[4];
  __shared__ int wis[4];
  __shared__ int winner;
  unsigned taken = 0;
  for (int r = 0; r < TOPK; ++r) {
    float best = -1e30f; int bi = 1 << 30;
    #pragma unroll
    for (int u = 0; u < 8; ++u) {
      if (!((taken >> u) & 1)) {
        float vv = v[u]; int ii = t + 256 * u;
        if (vv > best || (vv == best && ii < bi)) { best = vv; bi = ii; }
      }
    }
    for (int off = 32; off; off >>= 1) {
      float ov = __shfl_xor(best, off);
      int oi = __shfl_xor(bi, off);
      if (ov > best || (ov == best && oi < bi)) { best = ov; bi = oi; }
    }
    if ((t & 63) == 0) { wvs[t >> 6] = best; wis[t >> 6] = bi; }
    __syncthreads();
    if (t == 0) {
      float B = wvs[0]; int I = wis[0];
      #pragma unroll
      for (int q = 1; q < 4; ++q)
        if (wvs[q] > B || (wvs[q] == B && wis[q] < I)) { B = wvs[q]; I = wis[q]; }
      winner = I;
      idx[b * TOPK + r] = I;
      out_idx[b * TOPK + r] = (float)I;
    }
    __syncthreads();
    int w = winner;
    if ((w & 255) == t) taken |= 1u << (w >> 8);
  }
}

// ---------------- ball query + 3 conv stages, 512 threads (8 waves) per (b,k). ----
__global__ void __launch_bounds__(512)
k_group(const float* __restrict__ inp, const int* __restrict__ idx,
        const float* __restrict__ w0, const float* __restrict__ b0, const float* __restrict__ bn0,
        const float* __restrict__ w1, const float* __restrict__ b1, const float* __restrict__ bn1,
        const float* __restrict__ w2, const float* __restrict__ b2, const float* __restrict__ bn2,
        float* __restrict__ r2g) {
  __shared__ int swave[8 * 64];
  __shared__ int scnt[8];
  __shared__ int gidx[NSAMP];
  __shared__ __attribute__((aligned(16))) float gsh[65 * DD];
  __shared__ __attribute__((aligned(16))) float r0[128];
  __shared__ __attribute__((aligned(16))) float r1[256];
  int k = blockIdx.x, b = blockIdx.y;
  int t = threadIdx.x;
  int lane = t & 63, w = t >> 6;
  int qn = idx[b * TOPK + k];
  const float* px = inp + (size_t)b * DD * NN;
  float qx = px[qn], qy = px[NN + qn], qz = px[2 * NN + qn];
  {
    int cnt = 0;
    #pragma unroll
    for (int i = 0; i < 4; ++i) {
      int n = w * 256 + i * 64 + lane;
      float dx = px[n] - qx, dy = px[NN + n] - qy, dz = px[2 * NN + n] - qz;
      bool flag = (dx * dx + dy * dy + dz * dz <= R2);
      unsigned long long m = __ballot(flag);
      int pos = cnt + __popcll(m & ((1ull << lane) - 1ull));
      if (flag && pos < NSAMP) swave[w * 64 + pos] = n;
      cnt += (int)__popcll(m);
    }
    if (lane == 0) scnt[w] = cnt < NSAMP ? cnt : NSAMP;
  }
  __syncthreads();
  if (t < NSAMP) {
    int run = 0, val = -1;
    #pragma unroll
    for (int ww = 0; ww < 8; ++ww) {
      int c = scnt[ww];
      int loc = t - run;
      if (loc >= 0 && loc < c) val = swave[ww * 64 + loc];
      run += c;
    }
    gidx[t] = val;
  }
  __syncthreads();
  if (t < NSAMP) {
    int g0 = gidx[0];
    int gt = gidx[t];
    gidx[t] = (gt < 0) ? g0 : gt;
  }
  __syncthreads();
  if (t < 65 * DD) {
    int p = t / DD, d = t - p * DD;
    int n = (p == 0) ? qn : gidx[p - 1];
    gsh[t] = px[d * NN + n];
  }
  __syncthreads();
  {
    int c = t >> 2, part = t & 3;
    const float2* wr = (const float2*)(w0 + c * 390 + part * 98);
    const float2* gr = (const float2*)(gsh + part * 98);
    int n2 = (part == 3) ? 48 : 49;
    float s = 0.f;
    #pragma unroll 7
    for (int i = 0; i < n2; ++i) {
      float2 a = gr[i], ww = wr[i];
      s += a.x * ww.x + a.y * ww.y;
    }
    s += __shfl_xor(s, 1);
    s += __shfl_xor(s, 2);
    if (part == 0) {
      s += b0[c];
      float sc = bn0[c] * rsqrtf(bn0[384 + c] + EPSF);
      s = (s - bn0[256 + c]) * sc + bn0[128 + c];
      r0[c] = fmaxf(s, 0.f);
    }
  }
  __syncthreads();
  {
    int c = t >> 1, part = t & 1;
    const float4* wr = (const float4*)(w1 + c * 128 + part * 64);
    const float4* rr = (const float4*)(r0 + part * 64);
    float s0 = 0.f, s1 = 0.f, s2 = 0.f, s3 = 0.f;
    #pragma unroll 8
    for (int o = 0; o < 16; ++o) {
      float4 a = rr[o], ww = wr[o];
      s0 += a.x * ww.x; s1 += a.y * ww.y; s2 += a.z * ww.z; s3 += a.w * ww.w;
    }
    float s = (s0 + s1) + (s2 + s3);
    s += __shfl_xor(s, 1);
    if (part == 0) {
      s += b1[c];
      float sc = bn1[c] * rsqrtf(bn1[768 + c] + EPSF);
      s = (s - bn1[512 + c]) * sc + bn1[256 + c];
      r1[c] = fmaxf(s, 0.f);
    }
  }
  __syncthreads();
  {
    int c = t;
    const float4* wr = (const float4*)(w2 + c * 256);
    const float4* rr = (const float4*)r1;
    float s0 = 0.f, s1 = 0.f, s2 = 0.f, s3 = 0.f;
    #pragma unroll 8
    for (int o = 0; o < 64; ++o) {
      float4 a = rr[o], ww = wr[o];
      s0 += a.x * ww.x; s1 += a.y * ww.y; s2 += a.z * ww.z; s3 += a.w * ww.w;
    }
    float s = (s0 + s1) + (s2 + s3) + b2[c];
    float sc = bn2[c] * rsqrtf(bn2[1536 + c] + EPSF);
    s = (s - bn2[1024 + c]) * sc + bn2[512 + c];
    r2g[b * 8192 + c * TOPK + k] = fmaxf(s, 0.f);
  }
}

// ---------------- FC + BN + ReLU (wave-reduced dot), block=64 ----------------
__global__ void k_fl(const float* __restrict__ hin, const float* __restrict__ w,
                     const float* __restrict__ bias, const float* __restrict__ bn,
                     float* __restrict__ hout, int IN, int OUT) {
  int blk = blockIdx.x;
  int b = blk / OUT, j = blk % OUT;
  int lane = threadIdx.x;
  const float* hr = hin + (size_t)b * IN;
  const float* wr = w + (size_t)j * IN;
  float s = 0.f;
  for (int i = lane; i < IN; i += 64) s += hr[i] * wr[i];
  for (int o = 32; o; o >>= 1) s += __shfl_xor(s, o);
  if (lane == 0) {
    s += bias[j];
    float sc = bn[j] * rsqrtf(bn[3 * OUT + j] + EPSF);
    s = (s - bn[2 * OUT + j]) * sc + bn[OUT + j];
    hout[b * OUT + j] = fmaxf(s, 0.f);
  }
}

extern "C" void kernel_launch(void* const* d_in, const int* in_sizes, int n_in,
                              void* d_out, int out_size, void* d_ws, size_t ws_size,
                              hipStream_t stream) {
  const float* sv      = (const float*)d_in[0];
  const float* inp     = (const float*)d_in[1];
  const float* tl_win  = (const float*)d_in[2];
  const float* tl_bin  = (const float*)d_in[3];
  const float* tl_wout = (const float*)d_in[4];
  const float* tl_bout = (const float*)d_in[5];
  const float* tl_w1   = (const float*)d_in[6];
  const float* tl_b1   = (const float*)d_in[7];
  const float* tl_w2   = (const float*)d_in[8];
  const float* tl_b2   = (const float*)d_in[9];
  const float* tl_ln1g = (const float*)d_in[10];
  const float* tl_ln1b = (const float*)d_in[11];
  const float* tl_ln2g = (const float*)d_in[12];
  const float* tl_ln2b = (const float*)d_in[13];
  const float* fg_w0   = (const float*)d_in[14];
  const float* fg_b0   = (const float*)d_in[15];
  const float* fg_w1   = (const float*)d_in[16];
  const float* fg_b1   = (const float*)d_in[17];
  const float* fg_w2   = (const float*)d_in[18];
  const float* fg_b2   = (const float*)d_in[19];
  const float* fbn0    = (const float*)d_in[20];
  const float* fbn1    = (const float*)d_in[21];
  const float* fbn2    = (const float*)d_in[22];
  const float* rc_w0   = (const float*)d_in[23];
  const float* rc_b0   = (const float*)d_in[24];
  const float* rc_w1   = (const float*)d_in[25];
  const float* rc_b1   = (const float*)d_in[26];
  const float* rc_w2   = (const float*)d_in[27];
  const float* rc_b2   = (const float*)d_in[28];
  const float* rbn0    = (const float*)d_in[29];
  const float* rbn1    = (const float*)d_in[30];
  const float* rbn2    = (const float*)d_in[31];
  const float* fl_w0   = (const float*)d_in[32];
  const float* fl_b0   = (const float*)d_in[33];
  const float* fl_w1   = (const float*)d_in[34];
  const float* fl_b1   = (const float*)d_in[35];
  const float* lbn0    = (const float*)d_in[36];
  const float* lbn1    = (const float*)d_in[37];
  (void)in_sizes; (void)n_in; (void)out_size; (void)ws_size;

  float* wsp = (float*)d_ws;
  float* x      = wsp;                        // B*N*F      = 1048576
  float* qkv    = x + BB * NN * FF;           // 3145728-float region
  float* a      = qkv + BB * NN * 192;        // B*N*F      = 1048576
  float* scores = a + BB * NN * FF;           // B*N        = 16384
  int*   idxb   = (int*)(scores + BB * NN);   // B*TOPK     = 128
  float* r2g    = (float*)(idxb + BB * TOPK); // B*8192     = 65536
  float* h1g    = r2g + BB * 8192;            // B*1024     = 8192
  // FFN weight image: [l][chg][4 planes][4096 u16] = 1M u16 = 2MB
  unsigned short* img = (unsigned short*)(h1g + BB * 1024);
  // qkv region carve-out: Q fp32 (1M floats) | kp bf16 (1M u16) | vp bf16 (1M u16)
  float* qbuf = qkv;
  unsigned short* kp = (unsigned short*)(qkv + BB * NN * FF);
  unsigned short* vp = kp + (size_t)BB * NHEAD * NN * HD;
  float* part = qkv;  // FFN split-K partials reuse qkv+a (dead by then)

  float* out = (float*)d_out;  // fp32: h at [0,4096), idx-as-float at [4096,4224)

  k_transpose<<<(BB * NN * FF) / 256, 256, 0, stream>>>(sv, x);
  k_wimg<<<(NLAYER * 32 * 4 * 4096) / 256, 256, 0, stream>>>(tl_w1, tl_w2, img);

  for (int l = 0; l < NLAYER; ++l) {
    k_qkv3<<<dim3(BB * NN / 64, 3), 256, 0, stream>>>(x, tl_win + l * 192 * FF,
                                                      tl_bin + l * 192, qbuf,
                                                      (uint4*)kp, (uint4*)vp);
    k_attn8<<<dim3(NN / 64, NHEAD, BB), 256, 0, stream>>>(qbuf, (const uint4*)kp,
                                                          (const unsigned*)vp, a);
    k_proj2<<<BB * NN / 64, 256, 0, stream>>>(a, tl_wout + l * FF * FF, tl_bout + l * FF,
                                              tl_ln1g + l * FF, tl_ln1b + l * FF, x);
    k_ffn7<<<dim3(BB * NN / 128, 4), 256, 0, stream>>>(x, (const char*)(img + (size_t)l * 524288),
                                                       tl_b1 + l * 2048, part);
    k_ffn_ln<<<BB * NN / 4, 256, 0, stream>>>(part, tl_b2 + l * FF,
                                              tl_ln2g + l * FF, tl_ln2b + l * FF, x);
  }

  k_fg2<<<BB * NN / 64, 256, 0, stream>>>(x, fg_w0, fg_b0, fbn0, fg_w1, fg_b1, fbn1,
                                          fg_w2, fg_b2, fbn2, scores);
  k_topk2<<<BB, 256, 0, stream>>>(scores, idxb, out + BB * 512);
  k_group<<<dim3(TOPK, BB), 512, 0, stream>>>(inp, idxb, rc_w0, rc_b0, rbn0,
                                              rc_w1, rc_b1, rbn1, rc_w2, rc_b2, rbn2, r2g);
  k_fl<<<BB * 1024, 64, 0, stream>>>(r2g, fl_w0, fl_b0, lbn0, h1g, 8192, 1024);
  k_fl<<<BB * 512, 64, 0, stream>>>(h1g, fl_w1, fl_b1, lbn1, out, 1024, 512);
}

// Round 7
// 447.850 us; speedup vs baseline: 1.6676x; 1.0479x over previous
//
#include <hip/hip_runtime.h>
#include <hip/hip_bf16.h>
#include <math.h>

#define BB 8
#define NN 2048
#define FF 64
#define DD 6
#define NSAMP 64
#define TOPK 16
#define NHEAD 8
#define HD 8
#define NLAYER 2
#define EPSF 1e-5f
#define R2 0.09f

typedef short short8 __attribute__((ext_vector_type(8)));
typedef float f32x4 __attribute__((ext_vector_type(4)));
typedef unsigned uint4v __attribute__((ext_vector_type(4)));
typedef unsigned int u32;

// split-pack: u32 = (bf16_hi << 16) | bf16_lo, both RNE. x ≈ hi + lo, err ~2^-16 rel.
__device__ inline unsigned pk2(float x) {
  unsigned b = __float_as_uint(x);
  unsigned hi = (b + 0x7fffu + ((b >> 16) & 1u)) >> 16;
  float r = x - __uint_as_float(hi << 16);
  unsigned c = __float_as_uint(r);
  unsigned lo = (c + 0x7fffu + ((c >> 16) & 1u)) >> 16;
  return (hi << 16) | lo;
}

__device__ inline unsigned short bf16r(float x) {  // RNE bf16
  unsigned b = __float_as_uint(x);
  return (unsigned short)((b + 0x7fffu + ((b >> 16) & 1u)) >> 16);
}

// async global->LDS, 16B per lane (dest = wave-uniform base + lane*16)
__device__ __forceinline__ void gl16(const void* g, void* l) {
  __builtin_amdgcn_global_load_lds((const __attribute__((address_space(1))) u32*)g,
                                   (__attribute__((address_space(3))) u32*)l, 16, 0, 0);
}

// ---------------- transpose sortvec (B,1,F,N) -> x (B,N,F) ----------------
__global__ void k_transpose(const float* __restrict__ sv, float* __restrict__ x) {
  int i = blockIdx.x * 256 + threadIdx.x;
  if (i >= BB * NN * FF) return;
  int f = i % FF;
  int n = (i / FF) % NN;
  int b = i / (FF * NN);
  x[i] = sv[(b * FF + f) * NN + n];
}

// ---- pack FFN weights into the exact per-chunk LDS byte image (pre-swizzled).
__global__ void k_wimg(const float* __restrict__ w1, const float* __restrict__ w2,
                       unsigned short* __restrict__ img) {
  int i = blockIdx.x * 256 + threadIdx.x;     // u16 index, total 2*32*4*4096
  int e = i & 4095;
  int plane = (i >> 12) & 3;
  int chg = (i >> 14) & 31;
  int l = i >> 19;
  int r = e >> 6, sh = (e >> 3) & 7, inner = e & 7;
  int s = sh ^ (r & 7);
  float v;
  if (plane < 2) v = w1[((size_t)(l * 2048 + chg * 64 + r)) * 64 + s * 8 + inner];
  else           v = w2[((size_t)(l * 64 + r)) * 2048 + chg * 64 + s * 8 + inner];
  unsigned p = pk2(v);
  img[i] = (unsigned short)((plane & 1) ? (p & 0xffffu) : (p >> 16));
}

// ---- qkv v3: tiled GEMM; epilogue routes per blockIdx.y ----
__global__ void k_qkv3(const float* __restrict__ x, const float* __restrict__ win,
                       const float* __restrict__ bin, float* __restrict__ qbuf,
                       uint4* __restrict__ kp4, uint4* __restrict__ vp4) {
  __shared__ float xs[64 * 68];
  __shared__ float ws[64 * 68];
  int row0 = blockIdx.x * 64, y = blockIdx.y, col0 = y * 64;
  int t = threadIdx.x;
  #pragma unroll
  for (int i = 0; i < 4; ++i) {
    int q = t + i * 256, r = q >> 4, c = (q & 15) * 4;
    *(float4*)(xs + r * 68 + c) = *(const float4*)(x + (size_t)(row0 + r) * 64 + c);
    *(float4*)(ws + r * 68 + c) = *(const float4*)(win + (size_t)(col0 + r) * 64 + c);
  }
  __syncthreads();
  int tx = t & 15, ty = t >> 4;
  float acc[4][4] = {};
  for (int f = 0; f < 64; f += 4) {
    float4 xv[4], wv[4];
    #pragma unroll
    for (int ri = 0; ri < 4; ++ri) xv[ri] = *(const float4*)(xs + (ty * 4 + ri) * 68 + f);
    #pragma unroll
    for (int ci = 0; ci < 4; ++ci) wv[ci] = *(const float4*)(ws + (tx + 16 * ci) * 68 + f);
    #pragma unroll
    for (int ri = 0; ri < 4; ++ri)
      #pragma unroll
      for (int ci = 0; ci < 4; ++ci)
        acc[ri][ci] += xv[ri].x * wv[ci].x + xv[ri].y * wv[ci].y +
                       xv[ri].z * wv[ci].z + xv[ri].w * wv[ci].w;
  }
  int b = row0 >> 11, n0 = row0 & (NN - 1);
  if (y == 0) {
    #pragma unroll
    for (int ri = 0; ri < 4; ++ri)
      #pragma unroll
      for (int ci = 0; ci < 4; ++ci) {
        int r = row0 + ty * 4 + ri, c = tx + 16 * ci;
        qbuf[(size_t)r * 64 + c] = acc[ri][ci] + bin[c];
      }
    return;
  }
  __syncthreads();  // all GEMM reads of xs done before reuse
  unsigned short* l16 = (unsigned short*)xs;  // 64x72 u16 tile
  if (y == 1) {
    #pragma unroll
    for (int ri = 0; ri < 4; ++ri)
      #pragma unroll
      for (int ci = 0; ci < 4; ++ci) {
        int r = ty * 4 + ri, c = tx + 16 * ci;
        l16[r * 72 + c] = bf16r(acc[ri][ci] + bin[64 + c]);
      }
    __syncthreads();
    #pragma unroll
    for (int i = 0; i < 2; ++i) {
      int idx = t + i * 256;
      int h = idx >> 6, tok = idx & 63;
      uint4 v = *(const uint4*)(l16 + tok * 72 + h * 8);
      kp4[(size_t)(b * NHEAD + h) * NN + n0 + tok] = v;
    }
  } else {
    #pragma unroll
    for (int ri = 0; ri < 4; ++ri)
      #pragma unroll
      for (int ci = 0; ci < 4; ++ci) {
        int r = ty * 4 + ri, c = tx + 16 * ci;
        l16[c * 72 + r] = bf16r(acc[ri][ci] + bin[128 + c]);  // transposed
      }
    __syncthreads();
    #pragma unroll
    for (int i = 0; i < 2; ++i) {
      int idx = t + i * 256;
      int c = idx >> 3, seg = idx & 7;
      uint4 v = *(const uint4*)(l16 + c * 72 + seg * 8);
      vp4[(size_t)(b * 64 + c) * (NN / 8) + (n0 >> 3) + seg] = v;
    }
  }
}

// ---- attention v8: swapped-operand flash. ----
__global__ void __launch_bounds__(256, 8)
k_attn8(const float* __restrict__ q, const uint4* __restrict__ kp4,
        const unsigned* __restrict__ vp32, float* __restrict__ a) {
  __shared__ uint4 kb4[256];                                            // 4 KB
  __shared__ __attribute__((aligned(16))) unsigned short vb16[9 * 264]; // 4.6 KB
  int t = threadIdx.x;
  int lane = t & 63, w = t >> 6;
  int nIdx = lane & 15, lq = lane >> 4;
  int h = blockIdx.y, b = blockIdx.z;
  int qwb = blockIdx.x * 64 + w * 16;
  int bh = b * NHEAD + h;
  const float kf = 0.35355339059327373f * 1.4426950408889634f;  // scale*log2e
  short8 qF = {0, 0, 0, 0, 0, 0, 0, 0};
  if (lq == 0) {
    const float* qr = q + ((size_t)(b * NN + qwb + nIdx)) * 64 + h * HD;
    #pragma unroll
    for (int j = 0; j < 8; ++j) qF[j] = (short)bf16r(qr[j] * kf);
  }
  f32x4 acc = {0.f, 0.f, 0.f, 0.f};
  const uint4* kbase = kp4 + (size_t)bh * NN;
  const unsigned* vbase = vp32 + (size_t)bh * HD * (NN / 2);
  int vn = nIdx < 9 ? nIdx : 8;
  int voff = ((lq & 1) << 4) + ((lq >> 1) << 3);  // key perm per quad
  if (t < 132) ((unsigned*)(vb16 + 8 * 264))[t] = 0x3f803f80u;
  uint4 kreg = kbase[t];
  unsigned vreg[4];
  #pragma unroll
  for (int i = 0; i < 4; ++i) {
    int g = t + i * 256;
    vreg[i] = vbase[(g >> 7) * (NN / 2) + (g & 127)];
  }
  for (int kc = 0; kc < NN; kc += 256) {
    __syncthreads();
    kb4[t] = kreg;
    #pragma unroll
    for (int i = 0; i < 4; ++i) {
      int g = t + i * 256;
      ((unsigned*)vb16)[(g >> 7) * 132 + (g & 127)] = vreg[i];
    }
    __syncthreads();
    if (kc + 256 < NN) {
      kreg = kbase[kc + 256 + t];
      #pragma unroll
      for (int i = 0; i < 4; ++i) {
        int g = t + i * 256;
        vreg[i] = vbase[(g >> 7) * (NN / 2) + ((kc + 256) >> 1) + (g & 127)];
      }
    }
    for (int s = 0; s < 8; ++s) {
      int kb = s * 32;
      unsigned pk_[4];
      #pragma unroll
      for (int half = 0; half < 2; ++half) {
        int key = kb + half * 16 + nIdx;
        short8 aK = {0, 0, 0, 0, 0, 0, 0, 0};
        if (lq == 0) aK = *(const short8*)(kb4 + key);
        f32x4 c = {0.f, 0.f, 0.f, 0.f};
        c = __builtin_amdgcn_mfma_f32_16x16x32_bf16(aK, qF, c, 0, 0, 0);
        unsigned u0 = __float_as_uint(__builtin_amdgcn_exp2f(c[0]));
        unsigned u1 = __float_as_uint(__builtin_amdgcn_exp2f(c[1]));
        unsigned u2 = __float_as_uint(__builtin_amdgcn_exp2f(c[2]));
        unsigned u3 = __float_as_uint(__builtin_amdgcn_exp2f(c[3]));
        pk_[half * 2]     = (u0 >> 16) | (u1 & 0xffff0000u);  // trunc bf16 pair
        pk_[half * 2 + 1] = (u2 >> 16) | (u3 & 0xffff0000u);
      }
      unsigned e0 = (unsigned)__shfl_xor((int)pk_[0], 16);
      unsigned e1 = (unsigned)__shfl_xor((int)pk_[1], 16);
      unsigned e2 = (unsigned)__shfl_xor((int)pk_[2], 16);
      unsigned e3 = (unsigned)__shfl_xor((int)pk_[3], 16);
      bool odd = (lq & 1);
      uint4v bw;
      bw[0] = odd ? e2 : pk_[0];
      bw[1] = odd ? e3 : pk_[1];
      bw[2] = odd ? pk_[2] : e0;
      bw[3] = odd ? pk_[3] : e1;
      short8 bP = *(short8*)&bw;
      short8 aV = *(const short8*)(vb16 + vn * 264 + kb + voff);
      acc = __builtin_amdgcn_mfma_f32_16x16x32_bf16(aV, bP, acc, 0, 0, 0);
    }
  }
  float lr = __shfl(acc[0], 32 + nIdx);
  if (lq < 2) {
    int row = qwb + nIdx;
    float4 o;
    o.x = acc[0] / lr; o.y = acc[1] / lr; o.z = acc[2] / lr; o.w = acc[3] / lr;
    *(float4*)(a + ((size_t)(b * NN + row)) * 64 + h * HD + lq * 4) = o;
  }
}

// ------- proj + residual + LN, tiled GEMM ---------
__global__ void k_proj2(const float* __restrict__ a, const float* __restrict__ wout,
                        const float* __restrict__ bout, const float* __restrict__ g,
                        const float* __restrict__ be, float* __restrict__ x) {
  __shared__ float xs[64 * 68];
  __shared__ float ws[64 * 68];
  int row0 = blockIdx.x * 64;
  int t = threadIdx.x;
  #pragma unroll
  for (int i = 0; i < 4; ++i) {
    int q = t + i * 256, r = q >> 4, c = (q & 15) * 4;
    *(float4*)(xs + r * 68 + c) = *(const float4*)(a + (size_t)(row0 + r) * 64 + c);
    *(float4*)(ws + r * 68 + c) = *(const float4*)(wout + r * 64 + c);
  }
  __syncthreads();
  int tx = t & 15, ty = t >> 4;
  float acc[4][4] = {};
  for (int f = 0; f < 64; f += 4) {
    float4 xv[4], wv[4];
    #pragma unroll
    for (int ri = 0; ri < 4; ++ri) xv[ri] = *(const float4*)(xs + (ty * 4 + ri) * 68 + f);
    #pragma unroll
    for (int ci = 0; ci < 4; ++ci) wv[ci] = *(const float4*)(ws + (tx + 16 * ci) * 68 + f);
    #pragma unroll
    for (int ri = 0; ri < 4; ++ri)
      #pragma unroll
      for (int ci = 0; ci < 4; ++ci)
        acc[ri][ci] += xv[ri].x * wv[ci].x + xv[ri].y * wv[ci].y +
                       xv[ri].z * wv[ci].z + xv[ri].w * wv[ci].w;
  }
  #pragma unroll
  for (int ri = 0; ri < 4; ++ri) {
    int rl = ty * 4 + ri;
    float val[4], s = 0.f, sq = 0.f;
    #pragma unroll
    for (int ci = 0; ci < 4; ++ci) {
      int c = tx + 16 * ci;
      val[ci] = x[(size_t)(row0 + rl) * 64 + c] + bout[c] + acc[ri][ci];
      s += val[ci]; sq += val[ci] * val[ci];
    }
    #pragma unroll
    for (int off = 1; off < 16; off <<= 1) { s += __shfl_xor(s, off); sq += __shfl_xor(sq, off); }
    float mean = s * (1.f / 64.f);
    float var = sq * (1.f / 64.f) - mean * mean;
    float rstd = rsqrtf(var + EPSF);
    #pragma unroll
    for (int ci = 0; ci < 4; ++ci) {
      int c = tx + 16 * ci;
      x[(size_t)(row0 + rl) * 64 + c] = (val[ci] - mean) * rstd * g[c] + be[c];
    }
  }
}

// ------- FFN v7: global_load_lds staging, counted vmcnt, raw s_barriers ----
__global__ void __launch_bounds__(256, 2)
k_ffn7(const float* __restrict__ x, const char* __restrict__ img,
       const float* __restrict__ b1, float* __restrict__ part) {
  __shared__ __attribute__((aligned(16))) char W1b[2][16384];
  __shared__ __attribute__((aligned(16))) char W2b[16384];
  __shared__ __attribute__((aligned(16))) unsigned short hpl[2][128 * 64];
  int row0 = blockIdx.x * 128;
  int ks = blockIdx.y, kc = ks * 512;
  int t = threadIdx.x, lane = t & 63, wv = t >> 6;
  int lm = lane & 15, lq = lane >> 4;
  const char* ibase = img + (size_t)ks * 8 * 32768;

  short8 axh[2][2], axl[2][2];
  #pragma unroll
  for (int m = 0; m < 2; ++m)
    #pragma unroll
    for (int kbi = 0; kbi < 2; ++kbi) {
      const float* xr = x + (size_t)(row0 + m * 64 + wv * 16 + lm) * 64 + kbi * 32 + lq * 8;
      #pragma unroll
      for (int j = 0; j < 8; ++j) {
        unsigned p = pk2(xr[j]);
        axh[m][kbi][j] = (short)(p >> 16);
        axl[m][kbi][j] = (short)(p & 0xffffu);
      }
    }
  float bv[8][4];
  #pragma unroll
  for (int ch = 0; ch < 8; ++ch)
    #pragma unroll
    for (int tn = 0; tn < 4; ++tn)
      bv[ch][tn] = b1[kc + ch * 64 + tn * 16 + lm];
  asm volatile("s_waitcnt vmcnt(0)" ::: "memory");
  __builtin_amdgcn_sched_barrier(0);
  #pragma unroll
  for (int i = 0; i < 4; ++i)
    gl16(ibase + i * 4096 + t * 16, &W1b[0][i * 4096 + t * 16]);

  f32x4 acc[2][4];
  #pragma unroll
  for (int m = 0; m < 2; ++m)
    #pragma unroll
    for (int tn = 0; tn < 4; ++tn) acc[m][tn] = (f32x4){0.f, 0.f, 0.f, 0.f};

  #pragma unroll
  for (int ch = 0; ch < 8; ++ch) {
    const int p = ch & 1;
    const char* cbase = ibase + ch * 32768;
    #pragma unroll
    for (int i = 0; i < 4; ++i)
      gl16(cbase + 16384 + i * 4096 + t * 16, &W2b[i * 4096 + t * 16]);
    if (ch < 7) {
      #pragma unroll
      for (int i = 0; i < 4; ++i)
        gl16(cbase + 32768 + i * 4096 + t * 16, &W1b[p ^ 1][i * 4096 + t * 16]);
    }
    if (ch < 7) { asm volatile("s_waitcnt vmcnt(8)" ::: "memory"); }
    else        { asm volatile("s_waitcnt vmcnt(4)" ::: "memory"); }
    __builtin_amdgcn_sched_barrier(0);
    __builtin_amdgcn_s_barrier();
    __builtin_amdgcn_sched_barrier(0);
    const char* P0h = W1b[p];
    const char* P0l = W1b[p] + 8192;
    f32x4 h4[2][4];
    #pragma unroll
    for (int m = 0; m < 2; ++m)
      #pragma unroll
      for (int tn = 0; tn < 4; ++tn) h4[m][tn] = (f32x4){0.f, 0.f, 0.f, 0.f};
    #pragma unroll
    for (int kbi = 0; kbi < 2; ++kbi) {
      int sw = (((kbi * 4 + lq) ^ (lm & 7)) << 4);
      #pragma unroll
      for (int tn = 0; tn < 4; ++tn) {
        int brow = tn * 16 + lm;
        short8 bhi = *(const short8*)(P0h + brow * 128 + sw);
        short8 blo = *(const short8*)(P0l + brow * 128 + sw);
        #pragma unroll
        for (int m = 0; m < 2; ++m) {
          h4[m][tn] = __builtin_amdgcn_mfma_f32_16x16x32_bf16(axh[m][kbi], bhi, h4[m][tn], 0, 0, 0);
          h4[m][tn] = __builtin_amdgcn_mfma_f32_16x16x32_bf16(axh[m][kbi], blo, h4[m][tn], 0, 0, 0);
          h4[m][tn] = __builtin_amdgcn_mfma_f32_16x16x32_bf16(axl[m][kbi], bhi, h4[m][tn], 0, 0, 0);
        }
      }
    }
    #pragma unroll
    for (int m = 0; m < 2; ++m)
      #pragma unroll
      for (int tn = 0; tn < 4; ++tn)
        #pragma unroll
        for (int r = 0; r < 4; ++r) {
          float hv = fmaxf(h4[m][tn][r] + bv[ch][tn], 0.f);
          unsigned u = __float_as_uint(hv);
          float resid = hv - __uint_as_float(u & 0xffff0000u);
          unsigned c2 = __float_as_uint(resid);
          int hrow = m * 64 + wv * 16 + lq * 4 + r, hcol = tn * 16 + lm;
          int off = hrow * 128 + (((hcol >> 3) ^ (hrow & 7)) << 4) + ((hcol & 7) << 1);
          *(unsigned short*)((char*)hpl[0] + off) = (unsigned short)(u >> 16);
          *(unsigned short*)((char*)hpl[1] + off) =
              (unsigned short)((c2 + 0x7fffu + ((c2 >> 16) & 1u)) >> 16);
        }
    if (ch < 7) { asm volatile("s_waitcnt vmcnt(4)" ::: "memory"); }
    else        { asm volatile("s_waitcnt vmcnt(0)" ::: "memory"); }
    __builtin_amdgcn_sched_barrier(0);
    __builtin_amdgcn_s_barrier();
    __builtin_amdgcn_sched_barrier(0);
    const char* P1h = W2b;
    const char* P1l = W2b + 8192;
    #pragma unroll
    for (int kbi = 0; kbi < 2; ++kbi) {
      short8 a2h[2], a2l[2];
      #pragma unroll
      for (int m = 0; m < 2; ++m) {
        int arow = m * 64 + wv * 16 + lm;
        int swa = (((kbi * 4 + lq) ^ (arow & 7)) << 4);
        a2h[m] = *(const short8*)((const char*)hpl[0] + arow * 128 + swa);
        a2l[m] = *(const short8*)((const char*)hpl[1] + arow * 128 + swa);
      }
      int swb = (((kbi * 4 + lq) ^ (lm & 7)) << 4);
      #pragma unroll
      for (int tn = 0; tn < 4; ++tn) {
        int brow = tn * 16 + lm;
        short8 bhi = *(const short8*)(P1h + brow * 128 + swb);
        short8 blo = *(const short8*)(P1l + brow * 128 + swb);
        #pragma unroll
        for (int m = 0; m < 2; ++m) {
          acc[m][tn] = __builtin_amdgcn_mfma_f32_16x16x32_bf16(a2h[m], bhi, acc[m][tn], 0, 0, 0);
          acc[m][tn] = __builtin_amdgcn_mfma_f32_16x16x32_bf16(a2h[m], blo, acc[m][tn], 0, 0, 0);
          acc[m][tn] = __builtin_amdgcn_mfma_f32_16x16x32_bf16(a2l[m], bhi, acc[m][tn], 0, 0, 0);
        }
      }
    }
    __builtin_amdgcn_s_barrier();
    __builtin_amdgcn_sched_barrier(0);
  }
  float* fb = (float*)hpl;
  #pragma unroll
  for (int m = 0; m < 2; ++m)
    #pragma unroll
    for (int tn = 0; tn < 4; ++tn)
      #pragma unroll
      for (int r = 0; r < 4; ++r) {
        int row = m * 64 + wv * 16 + lq * 4 + r;
        int col = (tn * 16 + lm) ^ ((row & 7) << 2);
        fb[row * 64 + col] = acc[m][tn][r];
      }
  __syncthreads();
  float* pb = part + (size_t)ks * (BB * NN * 64);
  #pragma unroll
  for (int i = 0; i < 8; ++i) {
    int idx = t * 4 + i * 1024;
    int row = idx >> 6, c0 = idx & 63;
    int c0s = c0 ^ ((row & 7) << 2);
    float4 v = *(const float4*)(fb + row * 64 + c0s);
    *(float4*)(pb + (size_t)(row0 + row) * 64 + c0) = v;
  }
}

// ------- combine 4 partials + residual + b2 + LN; one wave per row ---------
__global__ void k_ffn_ln(const float* __restrict__ part, const float* __restrict__ b2,
                         const float* __restrict__ g, const float* __restrict__ be,
                         float* __restrict__ x) {
  int row = blockIdx.x * 4 + (threadIdx.x >> 6);
  int j = threadIdx.x & 63;
  size_t o = (size_t)row * 64 + j;
  const size_t S = (size_t)BB * NN * 64;
  float val = x[o] + b2[j] + ((part[o] + part[o + S]) + (part[o + 2 * S] + part[o + 3 * S]));
  float s = val;
  for (int off = 32; off; off >>= 1) s += __shfl_xor(s, off);
  s *= (1.f / 64.f);
  float d = val - s;
  float v = d * d;
  for (int off = 32; off; off >>= 1) v += __shfl_xor(v, off);
  v *= (1.f / 64.f);
  x[o] = d * rsqrtf(v + EPSF) * g[j] + be[j];
}

// ------- score head tiled ----------
__global__ void k_fg2(const float* __restrict__ x,
                      const float* __restrict__ w0, const float* __restrict__ b0, const float* __restrict__ bn0,
                      const float* __restrict__ w1, const float* __restrict__ b1, const float* __restrict__ bn1,
                      const float* __restrict__ w2, const float* __restrict__ b2, const float* __restrict__ bn2,
                      float* __restrict__ scores) {
  __shared__ float xs[64 * 68];
  __shared__ float ws[64 * 68];
  __shared__ float s0s[64 * 68];
  __shared__ float s1s[64 * 20];
  int row0 = blockIdx.x * 64;
  int t = threadIdx.x;
  #pragma unroll
  for (int i = 0; i < 4; ++i) {
    int q = t + i * 256, r = q >> 4, c = (q & 15) * 4;
    *(float4*)(xs + r * 68 + c) = *(const float4*)(x + (size_t)(row0 + r) * 64 + c);
    *(float4*)(ws + r * 68 + c) = *(const float4*)(w0 + r * 64 + c);
  }
  __syncthreads();
  int tx = t & 15, ty = t >> 4;
  float acc[4][4] = {};
  for (int f = 0; f < 64; f += 4) {
    float4 xv[4], wv[4];
    #pragma unroll
    for (int ri = 0; ri < 4; ++ri) xv[ri] = *(const float4*)(xs + (ty * 4 + ri) * 68 + f);
    #pragma unroll
    for (int ci = 0; ci < 4; ++ci) wv[ci] = *(const float4*)(ws + (tx + 16 * ci) * 68 + f);
    #pragma unroll
    for (int ri = 0; ri < 4; ++ri)
      #pragma unroll
      for (int ci = 0; ci < 4; ++ci)
        acc[ri][ci] += xv[ri].x * wv[ci].x + xv[ri].y * wv[ci].y +
                       xv[ri].z * wv[ci].z + xv[ri].w * wv[ci].w;
  }
  #pragma unroll
  for (int ri = 0; ri < 4; ++ri)
    #pragma unroll
    for (int ci = 0; ci < 4; ++ci) {
      int c = tx + 16 * ci;
      float sc = bn0[c] * rsqrtf(bn0[192 + c] + EPSF);
      float v = (acc[ri][ci] + b0[c] - bn0[128 + c]) * sc + bn0[64 + c];
      s0s[(ty * 4 + ri) * 68 + c] = fmaxf(v, 0.f);
    }
  __syncthreads();
  {
    int rl = t & 63, j0 = t >> 6;
    #pragma unroll
    for (int i = 0; i < 4; ++i) {
      int j = j0 + 4 * i;
      float s = b1[j];
      const float* wr = w1 + j * 64;
      #pragma unroll 16
      for (int c = 0; c < 64; ++c) s += s0s[rl * 68 + c] * wr[c];
      float sc = bn1[j] * rsqrtf(bn1[48 + j] + EPSF);
      s = (s - bn1[32 + j]) * sc + bn1[16 + j];
      s1s[rl * 20 + j] = fmaxf(s, 0.f);
    }
  }
  __syncthreads();
  if (t < 64) {
    float s = b2[0];
    #pragma unroll
    for (int o = 0; o < 16; ++o) s += s1s[t * 20 + o] * w2[o];
    float sc = bn2[0] * rsqrtf(bn2[3] + EPSF);
    s = (s - bn2[2]) * sc + bn2[1];
    scores[row0 + t] = fmaxf(s, 0.f);
  }
}

// ---- top-k (k=16) ----
__global__ void k_topk2(const float* __restrict__ scores, int* __restrict__ idx,
                        float* __restrict__ out_idx) {
  int b = blockIdx.x, t = threadIdx.x;
  float v[8];
  int base = b * NN;
  #pragma unroll
  for (int u = 0; u < 8; ++u) v[u] = scores[base + t + 256 * u];
  __shared__ float wvs[4];
  __shared__ int wis[4];
  __shared__ int winner;
  unsigned taken = 0;
  for (int r = 0; r < TOPK; ++r) {
    float best = -1e30f; int bi = 1 << 30;
    #pragma unroll
    for (int u = 0; u < 8; ++u) {
      if (!((taken >> u) & 1)) {
        float vv = v[u]; int ii = t + 256 * u;
        if (vv > best || (vv == best && ii < bi)) { best = vv; bi = ii; }
      }
    }
    for (int off = 32; off; off >>= 1) {
      float ov = __shfl_xor(best, off);
      int oi = __shfl_xor(bi, off);
      if (ov > best || (ov == best && oi < bi)) { best = ov; bi = oi; }
    }
    if ((t & 63) == 0) { wvs[t >> 6] = best; wis[t >> 6] = bi; }
    __syncthreads();
    if (t == 0) {
      float B = wvs[0]; int I = wis[0];
      #pragma unroll
      for (int q = 1; q < 4; ++q)
        if (wvs[q] > B || (wvs[q] == B && wis[q] < I)) { B = wvs[q]; I = wis[q]; }
      winner = I;
      idx[b * TOPK + r] = I;
      out_idx[b * TOPK + r] = (float)I;
    }
    __syncthreads();
    int w = winner;
    if ((w & 255) == t) taken |= 1u << (w >> 8);
  }
}

// ---------------- ball query + 3 conv stages, 512 threads (8 waves) per (b,k). ----
__global__ void __launch_bounds__(512)
k_group(const float* __restrict__ inp, const int* __restrict__ idx,
        const float* __restrict__ w0, const float* __restrict__ b0, const float* __restrict__ bn0,
        const float* __restrict__ w1, const float* __restrict__ b1, const float* __restrict__ bn1,
        const float* __restrict__ w2, const float* __restrict__ b2, const float* __restrict__ bn2,
        float* __restrict__ r2g) {
  __shared__ int swave[8 * 64];
  __shared__ int scnt[8];
  __shared__ int gidx[NSAMP];
  __shared__ __attribute__((aligned(16))) float gsh[65 * DD];
  __shared__ __attribute__((aligned(16))) float r0[128];
  __shared__ __attribute__((aligned(16))) float r1[256];
  int k = blockIdx.x, b = blockIdx.y;
  int t = threadIdx.x;
  int lane = t & 63, w = t >> 6;
  int qn = idx[b * TOPK + k];
  const float* px = inp + (size_t)b * DD * NN;
  float qx = px[qn], qy = px[NN + qn], qz = px[2 * NN + qn];
  {
    int cnt = 0;
    #pragma unroll
    for (int i = 0; i < 4; ++i) {
      int n = w * 256 + i * 64 + lane;
      float dx = px[n] - qx, dy = px[NN + n] - qy, dz = px[2 * NN + n] - qz;
      bool flag = (dx * dx + dy * dy + dz * dz <= R2);
      unsigned long long m = __ballot(flag);
      int pos = cnt + __popcll(m & ((1ull << lane) - 1ull));
      if (flag && pos < NSAMP) swave[w * 64 + pos] = n;
      cnt += (int)__popcll(m);
    }
    if (lane == 0) scnt[w] = cnt < NSAMP ? cnt : NSAMP;
  }
  __syncthreads();
  if (t < NSAMP) {
    int run = 0, val = -1;
    #pragma unroll
    for (int ww = 0; ww < 8; ++ww) {
      int c = scnt[ww];
      int loc = t - run;
      if (loc >= 0 && loc < c) val = swave[ww * 64 + loc];
      run += c;
    }
    gidx[t] = val;
  }
  __syncthreads();
  if (t < NSAMP) {
    int g0 = gidx[0];
    int gt = gidx[t];
    gidx[t] = (gt < 0) ? g0 : gt;
  }
  __syncthreads();
  if (t < 65 * DD) {
    int p = t / DD, d = t - p * DD;
    int n = (p == 0) ? qn : gidx[p - 1];
    gsh[t] = px[d * NN + n];
  }
  __syncthreads();
  {
    int c = t >> 2, part = t & 3;
    const float2* wr = (const float2*)(w0 + c * 390 + part * 98);
    const float2* gr = (const float2*)(gsh + part * 98);
    int n2 = (part == 3) ? 48 : 49;
    float s = 0.f;
    #pragma unroll 7
    for (int i = 0; i < n2; ++i) {
      float2 a = gr[i], ww = wr[i];
      s += a.x * ww.x + a.y * ww.y;
    }
    s += __shfl_xor(s, 1);
    s += __shfl_xor(s, 2);
    if (part == 0) {
      s += b0[c];
      float sc = bn0[c] * rsqrtf(bn0[384 + c] + EPSF);
      s = (s - bn0[256 + c]) * sc + bn0[128 + c];
      r0[c] = fmaxf(s, 0.f);
    }
  }
  __syncthreads();
  {
    int c = t >> 1, part = t & 1;
    const float4* wr = (const float4*)(w1 + c * 128 + part * 64);
    const float4* rr = (const float4*)(r0 + part * 64);
    float s0 = 0.f, s1 = 0.f, s2 = 0.f, s3 = 0.f;
    #pragma unroll 8
    for (int o = 0; o < 16; ++o) {
      float4 a = rr[o], ww = wr[o];
      s0 += a.x * ww.x; s1 += a.y * ww.y; s2 += a.z * ww.z; s3 += a.w * ww.w;
    }
    float s = (s0 + s1) + (s2 + s3);
    s += __shfl_xor(s, 1);
    if (part == 0) {
      s += b1[c];
      float sc = bn1[c] * rsqrtf(bn1[768 + c] + EPSF);
      s = (s - bn1[512 + c]) * sc + bn1[256 + c];
      r1[c] = fmaxf(s, 0.f);
    }
  }
  __syncthreads();
  {
    int c = t;
    const float4* wr = (const float4*)(w2 + c * 256);
    const float4* rr = (const float4*)r1;
    float s0 = 0.f, s1 = 0.f, s2 = 0.f, s3 = 0.f;
    #pragma unroll 8
    for (int o = 0; o < 64; ++o) {
      float4 a = rr[o], ww = wr[o];
      s0 += a.x * ww.x; s1 += a.y * ww.y; s2 += a.z * ww.z; s3 += a.w * ww.w;
    }
    float s = (s0 + s1) + (s2 + s3) + b2[c];
    float sc = bn2[c] * rsqrtf(bn2[1536 + c] + EPSF);
    s = (s - bn2[1024 + c]) * sc + bn2[512 + c];
    r2g[b * 8192 + c * TOPK + k] = fmaxf(s, 0.f);
  }
}

// ------- FC layer 1 v2: batched GEMV. Block = 256 thr computes 16 j x 8 b over a
// 1024-wide K chunk (grid 64 x 8 split-K). h chunk staged in LDS (32KB) and reused
// by all 16 output rows -> weights read exactly once (8x traffic cut vs k_fl).
// Per-thread: 16 float4-iters x 8 batch accumulators (deep ILP). ----
__global__ void __launch_bounds__(256)
k_fl2(const float* __restrict__ hin, const float* __restrict__ w,
      float* __restrict__ part) {
  __shared__ float hs[8 * 1032];
  int j0 = blockIdx.x * 16;
  int kc = blockIdx.y * 1024;
  int t = threadIdx.x;
  int jj = t >> 4, l = t & 15;
  #pragma unroll
  for (int i = 0; i < 8; ++i) {
    int idx = t + i * 256;         // 0..2047 float4s of the 8x1024 chunk
    int b = idx >> 8, off = (idx & 255) * 4;
    *(float4*)(hs + b * 1032 + off) = *(const float4*)(hin + (size_t)b * 8192 + kc + off);
  }
  __syncthreads();
  const float* wr = w + (size_t)(j0 + jj) * 8192 + kc;
  float acc[8] = {};
  #pragma unroll
  for (int k = 0; k < 16; ++k) {
    float4 wv = *(const float4*)(wr + l * 4 + k * 64);
    #pragma unroll
    for (int b = 0; b < 8; ++b) {
      float4 hv = *(const float4*)(hs + b * 1032 + l * 4 + k * 64);
      acc[b] += wv.x * hv.x + wv.y * hv.y + wv.z * hv.z + wv.w * hv.w;
    }
  }
  #pragma unroll
  for (int b = 0; b < 8; ++b) {
    #pragma unroll
    for (int off = 1; off < 16; off <<= 1) acc[b] += __shfl_xor(acc[b], off);
  }
  if (l == 0) {
    #pragma unroll
    for (int b = 0; b < 8; ++b)
      part[((size_t)blockIdx.y * 8 + b) * 1024 + j0 + jj] = acc[b];
  }
}

// ------- combine 8 split-K partials + bias + BN + ReLU -> h1g ----
__global__ void k_flc(const float* __restrict__ part, const float* __restrict__ bias,
                      const float* __restrict__ bn, float* __restrict__ hout) {
  int i = blockIdx.x * 256 + threadIdx.x;  // 0..8191
  int b = i >> 10, j = i & 1023;
  float s = bias[j];
  #pragma unroll
  for (int ks = 0; ks < 8; ++ks) s += part[((size_t)ks * 8 + b) * 1024 + j];
  float sc = bn[j] * rsqrtf(bn[3 * 1024 + j] + EPSF);
  s = (s - bn[2 * 1024 + j]) * sc + bn[1024 + j];
  hout[i] = fmaxf(s, 0.f);
}

// ---------------- FC + BN + ReLU (wave-reduced dot), block=64 ----------------
__global__ void k_fl(const float* __restrict__ hin, const float* __restrict__ w,
                     const float* __restrict__ bias, const float* __restrict__ bn,
                     float* __restrict__ hout, int IN, int OUT) {
  int blk = blockIdx.x;
  int b = blk / OUT, j = blk % OUT;
  int lane = threadIdx.x;
  const float* hr = hin + (size_t)b * IN;
  const float* wr = w + (size_t)j * IN;
  float s = 0.f;
  for (int i = lane; i < IN; i += 64) s += hr[i] * wr[i];
  for (int o = 32; o; o >>= 1) s += __shfl_xor(s, o);
  if (lane == 0) {
    s += bias[j];
    float sc = bn[j] * rsqrtf(bn[3 * OUT + j] + EPSF);
    s = (s - bn[2 * OUT + j]) * sc + bn[OUT + j];
    hout[b * OUT + j] = fmaxf(s, 0.f);
  }
}

extern "C" void kernel_launch(void* const* d_in, const int* in_sizes, int n_in,
                              void* d_out, int out_size, void* d_ws, size_t ws_size,
                              hipStream_t stream) {
  const float* sv      = (const float*)d_in[0];
  const float* inp     = (const float*)d_in[1];
  const float* tl_win  = (const float*)d_in[2];
  const float* tl_bin  = (const float*)d_in[3];
  const float* tl_wout = (const float*)d_in[4];
  const float* tl_bout = (const float*)d_in[5];
  const float* tl_w1   = (const float*)d_in[6];
  const float* tl_b1   = (const float*)d_in[7];
  const float* tl_w2   = (const float*)d_in[8];
  const float* tl_b2   = (const float*)d_in[9];
  const float* tl_ln1g = (const float*)d_in[10];
  const float* tl_ln1b = (const float*)d_in[11];
  const float* tl_ln2g = (const float*)d_in[12];
  const float* tl_ln2b = (const float*)d_in[13];
  const float* fg_w0   = (const float*)d_in[14];
  const float* fg_b0   = (const float*)d_in[15];
  const float* fg_w1   = (const float*)d_in[16];
  const float* fg_b1   = (const float*)d_in[17];
  const float* fg_w2   = (const float*)d_in[18];
  const float* fg_b2   = (const float*)d_in[19];
  const float* fbn0    = (const float*)d_in[20];
  const float* fbn1    = (const float*)d_in[21];
  const float* fbn2    = (const float*)d_in[22];
  const float* rc_w0   = (const float*)d_in[23];
  const float* rc_b0   = (const float*)d_in[24];
  const float* rc_w1   = (const float*)d_in[25];
  const float* rc_b1   = (const float*)d_in[26];
  const float* rc_w2   = (const float*)d_in[27];
  const float* rc_b2   = (const float*)d_in[28];
  const float* rbn0    = (const float*)d_in[29];
  const float* rbn1    = (const float*)d_in[30];
  const float* rbn2    = (const float*)d_in[31];
  const float* fl_w0   = (const float*)d_in[32];
  const float* fl_b0   = (const float*)d_in[33];
  const float* fl_w1   = (const float*)d_in[34];
  const float* fl_b1   = (const float*)d_in[35];
  const float* lbn0    = (const float*)d_in[36];
  const float* lbn1    = (const float*)d_in[37];
  (void)in_sizes; (void)n_in; (void)out_size; (void)ws_size;

  float* wsp = (float*)d_ws;
  float* x      = wsp;                        // B*N*F      = 1048576
  float* qkv    = x + BB * NN * FF;           // 3145728-float region
  float* a      = qkv + BB * NN * 192;        // B*N*F      = 1048576
  float* scores = a + BB * NN * FF;           // B*N        = 16384
  int*   idxb   = (int*)(scores + BB * NN);   // B*TOPK     = 128
  float* r2g    = (float*)(idxb + BB * TOPK); // B*8192     = 65536
  float* h1g    = r2g + BB * 8192;            // B*1024     = 8192
  // FFN weight image: [l][chg][4 planes][4096 u16] = 1M u16 = 2MB
  unsigned short* img = (unsigned short*)(h1g + BB * 1024);
  // qkv region carve-out: Q fp32 (1M floats) | kp bf16 (1M u16) | vp bf16 (1M u16)
  float* qbuf = qkv;
  unsigned short* kp = (unsigned short*)(qkv + BB * NN * FF);
  unsigned short* vp = kp + (size_t)BB * NHEAD * NN * HD;
  float* part = qkv;  // FFN & FC split-K partials reuse qkv region (dead by then)

  float* out = (float*)d_out;  // fp32: h at [0,4096), idx-as-float at [4096,4224)

  k_transpose<<<(BB * NN * FF) / 256, 256, 0, stream>>>(sv, x);
  k_wimg<<<(NLAYER * 32 * 4 * 4096) / 256, 256, 0, stream>>>(tl_w1, tl_w2, img);

  for (int l = 0; l < NLAYER; ++l) {
    k_qkv3<<<dim3(BB * NN / 64, 3), 256, 0, stream>>>(x, tl_win + l * 192 * FF,
                                                      tl_bin + l * 192, qbuf,
                                                      (uint4*)kp, (uint4*)vp);
    k_attn8<<<dim3(NN / 64, NHEAD, BB), 256, 0, stream>>>(qbuf, (const uint4*)kp,
                                                          (const unsigned*)vp, a);
    k_proj2<<<BB * NN / 64, 256, 0, stream>>>(a, tl_wout + l * FF * FF, tl_bout + l * FF,
                                              tl_ln1g + l * FF, tl_ln1b + l * FF, x);
    k_ffn7<<<dim3(BB * NN / 128, 4), 256, 0, stream>>>(x, (const char*)(img + (size_t)l * 524288),
                                                       tl_b1 + l * 2048, part);
    k_ffn_ln<<<BB * NN / 4, 256, 0, stream>>>(part, tl_b2 + l * FF,
                                              tl_ln2g + l * FF, tl_ln2b + l * FF, x);
  }

  k_fg2<<<BB * NN / 64, 256, 0, stream>>>(x, fg_w0, fg_b0, fbn0, fg_w1, fg_b1, fbn1,
                                          fg_w2, fg_b2, fbn2, scores);
  k_topk2<<<BB, 256, 0, stream>>>(scores, idxb, out + BB * 512);
  k_group<<<dim3(TOPK, BB), 512, 0, stream>>>(inp, idxb, rc_w0, rc_b0, rbn0,
                                              rc_w1, rc_b1, rbn1, rc_w2, rc_b2, rbn2, r2g);
  k_fl2<<<dim3(64, 8), 256, 0, stream>>>(r2g, fl_w0, part);
  k_flc<<<32, 256, 0, stream>>>(part, fl_b0, lbn0, h1g);
  k_fl<<<BB * 512, 64, 0, stream>>>(h1g, fl_w1, fl_b1, lbn1, out, 1024, 512);
}

// Round 8
// 442.168 us; speedup vs baseline: 1.6890x; 1.0128x over previous
//
#include <hip/hip_runtime.h>
#include <hip/hip_bf16.h>
#include <math.h>

#define BB 8
#define NN 2048
#define FF 64
#define DD 6
#define NSAMP 64
#define TOPK 16
#define NHEAD 8
#define HD 8
#define NLAYER 2
#define EPSF 1e-5f
#define R2 0.09f

typedef short short8 __attribute__((ext_vector_type(8)));
typedef float f32x4 __attribute__((ext_vector_type(4)));
typedef unsigned uint4v __attribute__((ext_vector_type(4)));
typedef unsigned int u32;

// split-pack: u32 = (bf16_hi << 16) | bf16_lo, both RNE. x ≈ hi + lo, err ~2^-16 rel.
__device__ inline unsigned pk2(float x) {
  unsigned b = __float_as_uint(x);
  unsigned hi = (b + 0x7fffu + ((b >> 16) & 1u)) >> 16;
  float r = x - __uint_as_float(hi << 16);
  unsigned c = __float_as_uint(r);
  unsigned lo = (c + 0x7fffu + ((c >> 16) & 1u)) >> 16;
  return (hi << 16) | lo;
}

__device__ inline unsigned short bf16r(float x) {  // RNE bf16
  unsigned b = __float_as_uint(x);
  return (unsigned short)((b + 0x7fffu + ((b >> 16) & 1u)) >> 16);
}

// async global->LDS, 16B per lane (dest = wave-uniform base + lane*16)
__device__ __forceinline__ void gl16(const void* g, void* l) {
  __builtin_amdgcn_global_load_lds((const __attribute__((address_space(1))) u32*)g,
                                   (__attribute__((address_space(3))) u32*)l, 16, 0, 0);
}

// ---------------- transpose sortvec (B,1,F,N) -> x (B,N,F) ----------------
__global__ void k_transpose(const float* __restrict__ sv, float* __restrict__ x) {
  int i = blockIdx.x * 256 + threadIdx.x;
  if (i >= BB * NN * FF) return;
  int f = i % FF;
  int n = (i / FF) % NN;
  int b = i / (FF * NN);
  x[i] = sv[(b * FF + f) * NN + n];
}

// ---- pack FFN weights into the exact per-chunk LDS byte image (pre-swizzled).
__global__ void k_wimg(const float* __restrict__ w1, const float* __restrict__ w2,
                       unsigned short* __restrict__ img) {
  int i = blockIdx.x * 256 + threadIdx.x;     // u16 index, total 2*32*4*4096
  int e = i & 4095;
  int plane = (i >> 12) & 3;
  int chg = (i >> 14) & 31;
  int l = i >> 19;
  int r = e >> 6, sh = (e >> 3) & 7, inner = e & 7;
  int s = sh ^ (r & 7);
  float v;
  if (plane < 2) v = w1[((size_t)(l * 2048 + chg * 64 + r)) * 64 + s * 8 + inner];
  else           v = w2[((size_t)(l * 64 + r)) * 2048 + chg * 64 + s * 8 + inner];
  unsigned p = pk2(v);
  img[i] = (unsigned short)((plane & 1) ? (p & 0xffffu) : (p >> 16));
}

// ---- qkv v3: tiled GEMM; epilogue routes per blockIdx.y ----
__global__ void k_qkv3(const float* __restrict__ x, const float* __restrict__ win,
                       const float* __restrict__ bin, float* __restrict__ qbuf,
                       uint4* __restrict__ kp4, uint4* __restrict__ vp4) {
  __shared__ float xs[64 * 68];
  __shared__ float ws[64 * 68];
  int row0 = blockIdx.x * 64, y = blockIdx.y, col0 = y * 64;
  int t = threadIdx.x;
  #pragma unroll
  for (int i = 0; i < 4; ++i) {
    int q = t + i * 256, r = q >> 4, c = (q & 15) * 4;
    *(float4*)(xs + r * 68 + c) = *(const float4*)(x + (size_t)(row0 + r) * 64 + c);
    *(float4*)(ws + r * 68 + c) = *(const float4*)(win + (size_t)(col0 + r) * 64 + c);
  }
  __syncthreads();
  int tx = t & 15, ty = t >> 4;
  float acc[4][4] = {};
  for (int f = 0; f < 64; f += 4) {
    float4 xv[4], wv[4];
    #pragma unroll
    for (int ri = 0; ri < 4; ++ri) xv[ri] = *(const float4*)(xs + (ty * 4 + ri) * 68 + f);
    #pragma unroll
    for (int ci = 0; ci < 4; ++ci) wv[ci] = *(const float4*)(ws + (tx + 16 * ci) * 68 + f);
    #pragma unroll
    for (int ri = 0; ri < 4; ++ri)
      #pragma unroll
      for (int ci = 0; ci < 4; ++ci)
        acc[ri][ci] += xv[ri].x * wv[ci].x + xv[ri].y * wv[ci].y +
                       xv[ri].z * wv[ci].z + xv[ri].w * wv[ci].w;
  }
  int b = row0 >> 11, n0 = row0 & (NN - 1);
  if (y == 0) {
    #pragma unroll
    for (int ri = 0; ri < 4; ++ri)
      #pragma unroll
      for (int ci = 0; ci < 4; ++ci) {
        int r = row0 + ty * 4 + ri, c = tx + 16 * ci;
        qbuf[(size_t)r * 64 + c] = acc[ri][ci] + bin[c];
      }
    return;
  }
  __syncthreads();  // all GEMM reads of xs done before reuse
  unsigned short* l16 = (unsigned short*)xs;  // 64x72 u16 tile
  if (y == 1) {
    #pragma unroll
    for (int ri = 0; ri < 4; ++ri)
      #pragma unroll
      for (int ci = 0; ci < 4; ++ci) {
        int r = ty * 4 + ri, c = tx + 16 * ci;
        l16[r * 72 + c] = bf16r(acc[ri][ci] + bin[64 + c]);
      }
    __syncthreads();
    #pragma unroll
    for (int i = 0; i < 2; ++i) {
      int idx = t + i * 256;
      int h = idx >> 6, tok = idx & 63;
      uint4 v = *(const uint4*)(l16 + tok * 72 + h * 8);
      kp4[(size_t)(b * NHEAD + h) * NN + n0 + tok] = v;
    }
  } else {
    #pragma unroll
    for (int ri = 0; ri < 4; ++ri)
      #pragma unroll
      for (int ci = 0; ci < 4; ++ci) {
        int r = ty * 4 + ri, c = tx + 16 * ci;
        l16[c * 72 + r] = bf16r(acc[ri][ci] + bin[128 + c]);  // transposed
      }
    __syncthreads();
    #pragma unroll
    for (int i = 0; i < 2; ++i) {
      int idx = t + i * 256;
      int c = idx >> 3, seg = idx & 7;
      uint4 v = *(const uint4*)(l16 + c * 72 + seg * 8);
      vp4[(size_t)(b * 64 + c) * (NN / 8) + (n0 >> 3) + seg] = v;
    }
  }
}

// ---- attention v9: swapped-operand flash + cvt_pk softmax pack (T12) +
// s_setprio around MFMA (T5). RNE pack replaces trunc: num & denom use the
// same p-tilde, so softmax stays self-consistent. ----
__global__ void __launch_bounds__(256, 8)
k_attn9(const float* __restrict__ q, const uint4* __restrict__ kp4,
        const unsigned* __restrict__ vp32, float* __restrict__ a) {
  __shared__ uint4 kb4[256];                                            // 4 KB
  __shared__ __attribute__((aligned(16))) unsigned short vb16[9 * 264]; // 4.6 KB
  int t = threadIdx.x;
  int lane = t & 63, w = t >> 6;
  int nIdx = lane & 15, lq = lane >> 4;
  int h = blockIdx.y, b = blockIdx.z;
  int qwb = blockIdx.x * 64 + w * 16;
  int bh = b * NHEAD + h;
  const float kf = 0.35355339059327373f * 1.4426950408889634f;  // scale*log2e
  short8 qF = {0, 0, 0, 0, 0, 0, 0, 0};
  if (lq == 0) {
    const float* qr = q + ((size_t)(b * NN + qwb + nIdx)) * 64 + h * HD;
    #pragma unroll
    for (int j = 0; j < 8; ++j) qF[j] = (short)bf16r(qr[j] * kf);
  }
  f32x4 acc = {0.f, 0.f, 0.f, 0.f};
  const uint4* kbase = kp4 + (size_t)bh * NN;
  const unsigned* vbase = vp32 + (size_t)bh * HD * (NN / 2);
  int vn = nIdx < 9 ? nIdx : 8;
  int voff = ((lq & 1) << 4) + ((lq >> 1) << 3);  // key perm per quad
  if (t < 132) ((unsigned*)(vb16 + 8 * 264))[t] = 0x3f803f80u;
  uint4 kreg = kbase[t];
  unsigned vreg[4];
  #pragma unroll
  for (int i = 0; i < 4; ++i) {
    int g = t + i * 256;
    vreg[i] = vbase[(g >> 7) * (NN / 2) + (g & 127)];
  }
  for (int kc = 0; kc < NN; kc += 256) {
    __syncthreads();
    kb4[t] = kreg;
    #pragma unroll
    for (int i = 0; i < 4; ++i) {
      int g = t + i * 256;
      ((unsigned*)vb16)[(g >> 7) * 132 + (g & 127)] = vreg[i];
    }
    __syncthreads();
    if (kc + 256 < NN) {
      kreg = kbase[kc + 256 + t];
      #pragma unroll
      for (int i = 0; i < 4; ++i) {
        int g = t + i * 256;
        vreg[i] = vbase[(g >> 7) * (NN / 2) + ((kc + 256) >> 1) + (g & 127)];
      }
    }
    for (int s = 0; s < 8; ++s) {
      int kb = s * 32;
      unsigned pk_[4];
      #pragma unroll
      for (int half = 0; half < 2; ++half) {
        int key = kb + half * 16 + nIdx;
        short8 aK = {0, 0, 0, 0, 0, 0, 0, 0};
        if (lq == 0) aK = *(const short8*)(kb4 + key);
        f32x4 c = {0.f, 0.f, 0.f, 0.f};
        __builtin_amdgcn_s_setprio(1);
        c = __builtin_amdgcn_mfma_f32_16x16x32_bf16(aK, qF, c, 0, 0, 0);
        __builtin_amdgcn_s_setprio(0);
        float p0 = __builtin_amdgcn_exp2f(c[0]);
        float p1 = __builtin_amdgcn_exp2f(c[1]);
        float p2 = __builtin_amdgcn_exp2f(c[2]);
        float p3 = __builtin_amdgcn_exp2f(c[3]);
        unsigned r0, r1;
        asm("v_cvt_pk_bf16_f32 %0, %1, %2" : "=v"(r0) : "v"(p0), "v"(p1));
        asm("v_cvt_pk_bf16_f32 %0, %1, %2" : "=v"(r1) : "v"(p2), "v"(p3));
        pk_[half * 2]     = r0;
        pk_[half * 2 + 1] = r1;
      }
      unsigned e0 = (unsigned)__shfl_xor((int)pk_[0], 16);
      unsigned e1 = (unsigned)__shfl_xor((int)pk_[1], 16);
      unsigned e2 = (unsigned)__shfl_xor((int)pk_[2], 16);
      unsigned e3 = (unsigned)__shfl_xor((int)pk_[3], 16);
      bool odd = (lq & 1);
      uint4v bw;
      bw[0] = odd ? e2 : pk_[0];
      bw[1] = odd ? e3 : pk_[1];
      bw[2] = odd ? pk_[2] : e0;
      bw[3] = odd ? pk_[3] : e1;
      short8 bP = *(short8*)&bw;
      short8 aV = *(const short8*)(vb16 + vn * 264 + kb + voff);
      __builtin_amdgcn_s_setprio(1);
      acc = __builtin_amdgcn_mfma_f32_16x16x32_bf16(aV, bP, acc, 0, 0, 0);
      __builtin_amdgcn_s_setprio(0);
    }
  }
  float lr = __shfl(acc[0], 32 + nIdx);
  if (lq < 2) {
    int row = qwb + nIdx;
    float4 o;
    o.x = acc[0] / lr; o.y = acc[1] / lr; o.z = acc[2] / lr; o.w = acc[3] / lr;
    *(float4*)(a + ((size_t)(b * NN + row)) * 64 + h * HD + lq * 4) = o;
  }
}

// ------- proj + residual + LN, tiled GEMM ---------
__global__ void k_proj2(const float* __restrict__ a, const float* __restrict__ wout,
                        const float* __restrict__ bout, const float* __restrict__ g,
                        const float* __restrict__ be, float* __restrict__ x) {
  __shared__ float xs[64 * 68];
  __shared__ float ws[64 * 68];
  int row0 = blockIdx.x * 64;
  int t = threadIdx.x;
  #pragma unroll
  for (int i = 0; i < 4; ++i) {
    int q = t + i * 256, r = q >> 4, c = (q & 15) * 4;
    *(float4*)(xs + r * 68 + c) = *(const float4*)(a + (size_t)(row0 + r) * 64 + c);
    *(float4*)(ws + r * 68 + c) = *(const float4*)(wout + r * 64 + c);
  }
  __syncthreads();
  int tx = t & 15, ty = t >> 4;
  float acc[4][4] = {};
  for (int f = 0; f < 64; f += 4) {
    float4 xv[4], wv[4];
    #pragma unroll
    for (int ri = 0; ri < 4; ++ri) xv[ri] = *(const float4*)(xs + (ty * 4 + ri) * 68 + f);
    #pragma unroll
    for (int ci = 0; ci < 4; ++ci) wv[ci] = *(const float4*)(ws + (tx + 16 * ci) * 68 + f);
    #pragma unroll
    for (int ri = 0; ri < 4; ++ri)
      #pragma unroll
      for (int ci = 0; ci < 4; ++ci)
        acc[ri][ci] += xv[ri].x * wv[ci].x + xv[ri].y * wv[ci].y +
                       xv[ri].z * wv[ci].z + xv[ri].w * wv[ci].w;
  }
  #pragma unroll
  for (int ri = 0; ri < 4; ++ri) {
    int rl = ty * 4 + ri;
    float val[4], s = 0.f, sq = 0.f;
    #pragma unroll
    for (int ci = 0; ci < 4; ++ci) {
      int c = tx + 16 * ci;
      val[ci] = x[(size_t)(row0 + rl) * 64 + c] + bout[c] + acc[ri][ci];
      s += val[ci]; sq += val[ci] * val[ci];
    }
    #pragma unroll
    for (int off = 1; off < 16; off <<= 1) { s += __shfl_xor(s, off); sq += __shfl_xor(sq, off); }
    float mean = s * (1.f / 64.f);
    float var = sq * (1.f / 64.f) - mean * mean;
    float rstd = rsqrtf(var + EPSF);
    #pragma unroll
    for (int ci = 0; ci < 4; ++ci) {
      int c = tx + 16 * ci;
      x[(size_t)(row0 + rl) * 64 + c] = (val[ci] - mean) * rstd * g[c] + be[c];
    }
  }
}

// ------- FFN v7: global_load_lds staging, counted vmcnt, raw s_barriers ----
__global__ void __launch_bounds__(256, 2)
k_ffn7(const float* __restrict__ x, const char* __restrict__ img,
       const float* __restrict__ b1, float* __restrict__ part) {
  __shared__ __attribute__((aligned(16))) char W1b[2][16384];
  __shared__ __attribute__((aligned(16))) char W2b[16384];
  __shared__ __attribute__((aligned(16))) unsigned short hpl[2][128 * 64];
  int row0 = blockIdx.x * 128;
  int ks = blockIdx.y, kc = ks * 512;
  int t = threadIdx.x, lane = t & 63, wv = t >> 6;
  int lm = lane & 15, lq = lane >> 4;
  const char* ibase = img + (size_t)ks * 8 * 32768;

  short8 axh[2][2], axl[2][2];
  #pragma unroll
  for (int m = 0; m < 2; ++m)
    #pragma unroll
    for (int kbi = 0; kbi < 2; ++kbi) {
      const float* xr = x + (size_t)(row0 + m * 64 + wv * 16 + lm) * 64 + kbi * 32 + lq * 8;
      #pragma unroll
      for (int j = 0; j < 8; ++j) {
        unsigned p = pk2(xr[j]);
        axh[m][kbi][j] = (short)(p >> 16);
        axl[m][kbi][j] = (short)(p & 0xffffu);
      }
    }
  float bv[8][4];
  #pragma unroll
  for (int ch = 0; ch < 8; ++ch)
    #pragma unroll
    for (int tn = 0; tn < 4; ++tn)
      bv[ch][tn] = b1[kc + ch * 64 + tn * 16 + lm];
  asm volatile("s_waitcnt vmcnt(0)" ::: "memory");
  __builtin_amdgcn_sched_barrier(0);
  #pragma unroll
  for (int i = 0; i < 4; ++i)
    gl16(ibase + i * 4096 + t * 16, &W1b[0][i * 4096 + t * 16]);

  f32x4 acc[2][4];
  #pragma unroll
  for (int m = 0; m < 2; ++m)
    #pragma unroll
    for (int tn = 0; tn < 4; ++tn) acc[m][tn] = (f32x4){0.f, 0.f, 0.f, 0.f};

  #pragma unroll
  for (int ch = 0; ch < 8; ++ch) {
    const int p = ch & 1;
    const char* cbase = ibase + ch * 32768;
    #pragma unroll
    for (int i = 0; i < 4; ++i)
      gl16(cbase + 16384 + i * 4096 + t * 16, &W2b[i * 4096 + t * 16]);
    if (ch < 7) {
      #pragma unroll
      for (int i = 0; i < 4; ++i)
        gl16(cbase + 32768 + i * 4096 + t * 16, &W1b[p ^ 1][i * 4096 + t * 16]);
    }
    if (ch < 7) { asm volatile("s_waitcnt vmcnt(8)" ::: "memory"); }
    else        { asm volatile("s_waitcnt vmcnt(4)" ::: "memory"); }
    __builtin_amdgcn_sched_barrier(0);
    __builtin_amdgcn_s_barrier();
    __builtin_amdgcn_sched_barrier(0);
    const char* P0h = W1b[p];
    const char* P0l = W1b[p] + 8192;
    f32x4 h4[2][4];
    #pragma unroll
    for (int m = 0; m < 2; ++m)
      #pragma unroll
      for (int tn = 0; tn < 4; ++tn) h4[m][tn] = (f32x4){0.f, 0.f, 0.f, 0.f};
    #pragma unroll
    for (int kbi = 0; kbi < 2; ++kbi) {
      int sw = (((kbi * 4 + lq) ^ (lm & 7)) << 4);
      #pragma unroll
      for (int tn = 0; tn < 4; ++tn) {
        int brow = tn * 16 + lm;
        short8 bhi = *(const short8*)(P0h + brow * 128 + sw);
        short8 blo = *(const short8*)(P0l + brow * 128 + sw);
        #pragma unroll
        for (int m = 0; m < 2; ++m) {
          h4[m][tn] = __builtin_amdgcn_mfma_f32_16x16x32_bf16(axh[m][kbi], bhi, h4[m][tn], 0, 0, 0);
          h4[m][tn] = __builtin_amdgcn_mfma_f32_16x16x32_bf16(axh[m][kbi], blo, h4[m][tn], 0, 0, 0);
          h4[m][tn] = __builtin_amdgcn_mfma_f32_16x16x32_bf16(axl[m][kbi], bhi, h4[m][tn], 0, 0, 0);
        }
      }
    }
    #pragma unroll
    for (int m = 0; m < 2; ++m)
      #pragma unroll
      for (int tn = 0; tn < 4; ++tn)
        #pragma unroll
        for (int r = 0; r < 4; ++r) {
          float hv = fmaxf(h4[m][tn][r] + bv[ch][tn], 0.f);
          unsigned u = __float_as_uint(hv);
          float resid = hv - __uint_as_float(u & 0xffff0000u);
          unsigned c2 = __float_as_uint(resid);
          int hrow = m * 64 + wv * 16 + lq * 4 + r, hcol = tn * 16 + lm;
          int off = hrow * 128 + (((hcol >> 3) ^ (hrow & 7)) << 4) + ((hcol & 7) << 1);
          *(unsigned short*)((char*)hpl[0] + off) = (unsigned short)(u >> 16);
          *(unsigned short*)((char*)hpl[1] + off) =
              (unsigned short)((c2 + 0x7fffu + ((c2 >> 16) & 1u)) >> 16);
        }
    if (ch < 7) { asm volatile("s_waitcnt vmcnt(4)" ::: "memory"); }
    else        { asm volatile("s_waitcnt vmcnt(0)" ::: "memory"); }
    __builtin_amdgcn_sched_barrier(0);
    __builtin_amdgcn_s_barrier();
    __builtin_amdgcn_sched_barrier(0);
    const char* P1h = W2b;
    const char* P1l = W2b + 8192;
    #pragma unroll
    for (int kbi = 0; kbi < 2; ++kbi) {
      short8 a2h[2], a2l[2];
      #pragma unroll
      for (int m = 0; m < 2; ++m) {
        int arow = m * 64 + wv * 16 + lm;
        int swa = (((kbi * 4 + lq) ^ (arow & 7)) << 4);
        a2h[m] = *(const short8*)((const char*)hpl[0] + arow * 128 + swa);
        a2l[m] = *(const short8*)((const char*)hpl[1] + arow * 128 + swa);
      }
      int swb = (((kbi * 4 + lq) ^ (lm & 7)) << 4);
      #pragma unroll
      for (int tn = 0; tn < 4; ++tn) {
        int brow = tn * 16 + lm;
        short8 bhi = *(const short8*)(P1h + brow * 128 + swb);
        short8 blo = *(const short8*)(P1l + brow * 128 + swb);
        #pragma unroll
        for (int m = 0; m < 2; ++m) {
          acc[m][tn] = __builtin_amdgcn_mfma_f32_16x16x32_bf16(a2h[m], bhi, acc[m][tn], 0, 0, 0);
          acc[m][tn] = __builtin_amdgcn_mfma_f32_16x16x32_bf16(a2h[m], blo, acc[m][tn], 0, 0, 0);
          acc[m][tn] = __builtin_amdgcn_mfma_f32_16x16x32_bf16(a2l[m], bhi, acc[m][tn], 0, 0, 0);
        }
      }
    }
    __builtin_amdgcn_s_barrier();
    __builtin_amdgcn_sched_barrier(0);
  }
  float* fb = (float*)hpl;
  #pragma unroll
  for (int m = 0; m < 2; ++m)
    #pragma unroll
    for (int tn = 0; tn < 4; ++tn)
      #pragma unroll
      for (int r = 0; r < 4; ++r) {
        int row = m * 64 + wv * 16 + lq * 4 + r;
        int col = (tn * 16 + lm) ^ ((row & 7) << 2);
        fb[row * 64 + col] = acc[m][tn][r];
      }
  __syncthreads();
  float* pb = part + (size_t)ks * (BB * NN * 64);
  #pragma unroll
  for (int i = 0; i < 8; ++i) {
    int idx = t * 4 + i * 1024;
    int row = idx >> 6, c0 = idx & 63;
    int c0s = c0 ^ ((row & 7) << 2);
    float4 v = *(const float4*)(fb + row * 64 + c0s);
    *(float4*)(pb + (size_t)(row0 + row) * 64 + c0) = v;
  }
}

// ------- combine 4 partials + residual + b2 + LN; one wave per row ---------
__global__ void k_ffn_ln(const float* __restrict__ part, const float* __restrict__ b2,
                         const float* __restrict__ g, const float* __restrict__ be,
                         float* __restrict__ x) {
  int row = blockIdx.x * 4 + (threadIdx.x >> 6);
  int j = threadIdx.x & 63;
  size_t o = (size_t)row * 64 + j;
  const size_t S = (size_t)BB * NN * 64;
  float val = x[o] + b2[j] + ((part[o] + part[o + S]) + (part[o + 2 * S] + part[o + 3 * S]));
  float s = val;
  for (int off = 32; off; off >>= 1) s += __shfl_xor(s, off);
  s *= (1.f / 64.f);
  float d = val - s;
  float v = d * d;
  for (int off = 32; off; off >>= 1) v += __shfl_xor(v, off);
  v *= (1.f / 64.f);
  x[o] = d * rsqrtf(v + EPSF) * g[j] + be[j];
}

// ------- score head tiled ----------
__global__ void k_fg2(const float* __restrict__ x,
                      const float* __restrict__ w0, const float* __restrict__ b0, const float* __restrict__ bn0,
                      const float* __restrict__ w1, const float* __restrict__ b1, const float* __restrict__ bn1,
                      const float* __restrict__ w2, const float* __restrict__ b2, const float* __restrict__ bn2,
                      float* __restrict__ scores) {
  __shared__ float xs[64 * 68];
  __shared__ float ws[64 * 68];
  __shared__ float s0s[64 * 68];
  __shared__ float s1s[64 * 20];
  int row0 = blockIdx.x * 64;
  int t = threadIdx.x;
  #pragma unroll
  for (int i = 0; i < 4; ++i) {
    int q = t + i * 256, r = q >> 4, c = (q & 15) * 4;
    *(float4*)(xs + r * 68 + c) = *(const float4*)(x + (size_t)(row0 + r) * 64 + c);
    *(float4*)(ws + r * 68 + c) = *(const float4*)(w0 + r * 64 + c);
  }
  __syncthreads();
  int tx = t & 15, ty = t >> 4;
  float acc[4][4] = {};
  for (int f = 0; f < 64; f += 4) {
    float4 xv[4], wv[4];
    #pragma unroll
    for (int ri = 0; ri < 4; ++ri) xv[ri] = *(const float4*)(xs + (ty * 4 + ri) * 68 + f);
    #pragma unroll
    for (int ci = 0; ci < 4; ++ci) wv[ci] = *(const float4*)(ws + (tx + 16 * ci) * 68 + f);
    #pragma unroll
    for (int ri = 0; ri < 4; ++ri)
      #pragma unroll
      for (int ci = 0; ci < 4; ++ci)
        acc[ri][ci] += xv[ri].x * wv[ci].x + xv[ri].y * wv[ci].y +
                       xv[ri].z * wv[ci].z + xv[ri].w * wv[ci].w;
  }
  #pragma unroll
  for (int ri = 0; ri < 4; ++ri)
    #pragma unroll
    for (int ci = 0; ci < 4; ++ci) {
      int c = tx + 16 * ci;
      float sc = bn0[c] * rsqrtf(bn0[192 + c] + EPSF);
      float v = (acc[ri][ci] + b0[c] - bn0[128 + c]) * sc + bn0[64 + c];
      s0s[(ty * 4 + ri) * 68 + c] = fmaxf(v, 0.f);
    }
  __syncthreads();
  {
    int rl = t & 63, j0 = t >> 6;
    #pragma unroll
    for (int i = 0; i < 4; ++i) {
      int j = j0 + 4 * i;
      float s = b1[j];
      const float* wr = w1 + j * 64;
      #pragma unroll 16
      for (int c = 0; c < 64; ++c) s += s0s[rl * 68 + c] * wr[c];
      float sc = bn1[j] * rsqrtf(bn1[48 + j] + EPSF);
      s = (s - bn1[32 + j]) * sc + bn1[16 + j];
      s1s[rl * 20 + j] = fmaxf(s, 0.f);
    }
  }
  __syncthreads();
  if (t < 64) {
    float s = b2[0];
    #pragma unroll
    for (int o = 0; o < 16; ++o) s += s1s[t * 20 + o] * w2[o];
    float sc = bn2[0] * rsqrtf(bn2[3] + EPSF);
    s = (s - bn2[2]) * sc + bn2[1];
    scores[row0 + t] = fmaxf(s, 0.f);
  }
}

// ---- top-k (k=16) ----
__global__ void k_topk2(const float* __restrict__ scores, int* __restrict__ idx,
                        float* __restrict__ out_idx) {
  int b = blockIdx.x, t = threadIdx.x;
  float v[8];
  int base = b * NN;
  #pragma unroll
  for (int u = 0; u < 8; ++u) v[u] = scores[base + t + 256 * u];
  __shared__ float wvs[4];
  __shared__ int wis[4];
  __shared__ int winner;
  unsigned taken = 0;
  for (int r = 0; r < TOPK; ++r) {
    float best = -1e30f; int bi = 1 << 30;
    #pragma unroll
    for (int u = 0; u < 8; ++u) {
      if (!((taken >> u) & 1)) {
        float vv = v[u]; int ii = t + 256 * u;
        if (vv > best || (vv == best && ii < bi)) { best = vv; bi = ii; }
      }
    }
    for (int off = 32; off; off >>= 1) {
      float ov = __shfl_xor(best, off);
      int oi = __shfl_xor(bi, off);
      if (ov > best || (ov == best && oi < bi)) { best = ov; bi = oi; }
    }
    if ((t & 63) == 0) { wvs[t >> 6] = best; wis[t >> 6] = bi; }
    __syncthreads();
    if (t == 0) {
      float B = wvs[0]; int I = wis[0];
      #pragma unroll
      for (int q = 1; q < 4; ++q)
        if (wvs[q] > B || (wvs[q] == B && wis[q] < I)) { B = wvs[q]; I = wis[q]; }
      winner = I;
      idx[b * TOPK + r] = I;
      out_idx[b * TOPK + r] = (float)I;
    }
    __syncthreads();
    int w = winner;
    if ((w & 255) == t) taken |= 1u << (w >> 8);
  }
}

// ---------------- ball query + 3 conv stages, 512 threads (8 waves) per (b,k). ----
__global__ void __launch_bounds__(512)
k_group(const float* __restrict__ inp, const int* __restrict__ idx,
        const float* __restrict__ w0, const float* __restrict__ b0, const float* __restrict__ bn0,
        const float* __restrict__ w1, const float* __restrict__ b1, const float* __restrict__ bn1,
        const float* __restrict__ w2, const float* __restrict__ b2, const float* __restrict__ bn2,
        float* __restrict__ r2g) {
  __shared__ int swave[8 * 64];
  __shared__ int scnt[8];
  __shared__ int gidx[NSAMP];
  __shared__ __attribute__((aligned(16))) float gsh[65 * DD];
  __shared__ __attribute__((aligned(16))) float r0[128];
  __shared__ __attribute__((aligned(16))) float r1[256];
  int k = blockIdx.x, b = blockIdx.y;
  int t = threadIdx.x;
  int lane = t & 63, w = t >> 6;
  int qn = idx[b * TOPK + k];
  const float* px = inp + (size_t)b * DD * NN;
  float qx = px[qn], qy = px[NN + qn], qz = px[2 * NN + qn];
  {
    int cnt = 0;
    #pragma unroll
    for (int i = 0; i < 4; ++i) {
      int n = w * 256 + i * 64 + lane;
      float dx = px[n] - qx, dy = px[NN + n] - qy, dz = px[2 * NN + n] - qz;
      bool flag = (dx * dx + dy * dy + dz * dz <= R2);
      unsigned long long m = __ballot(flag);
      int pos = cnt + __popcll(m & ((1ull << lane) - 1ull));
      if (flag && pos < NSAMP) swave[w * 64 + pos] = n;
      cnt += (int)__popcll(m);
    }
    if (lane == 0) scnt[w] = cnt < NSAMP ? cnt : NSAMP;
  }
  __syncthreads();
  if (t < NSAMP) {
    int run = 0, val = -1;
    #pragma unroll
    for (int ww = 0; ww < 8; ++ww) {
      int c = scnt[ww];
      int loc = t - run;
      if (loc >= 0 && loc < c) val = swave[ww * 64 + loc];
      run += c;
    }
    gidx[t] = val;
  }
  __syncthreads();
  if (t < NSAMP) {
    int g0 = gidx[0];
    int gt = gidx[t];
    gidx[t] = (gt < 0) ? g0 : gt;
  }
  __syncthreads();
  if (t < 65 * DD) {
    int p = t / DD, d = t - p * DD;
    int n = (p == 0) ? qn : gidx[p - 1];
    gsh[t] = px[d * NN + n];
  }
  __syncthreads();
  {
    int c = t >> 2, part = t & 3;
    const float2* wr = (const float2*)(w0 + c * 390 + part * 98);
    const float2* gr = (const float2*)(gsh + part * 98);
    int n2 = (part == 3) ? 48 : 49;
    float s = 0.f;
    #pragma unroll 7
    for (int i = 0; i < n2; ++i) {
      float2 a = gr[i], ww = wr[i];
      s += a.x * ww.x + a.y * ww.y;
    }
    s += __shfl_xor(s, 1);
    s += __shfl_xor(s, 2);
    if (part == 0) {
      s += b0[c];
      float sc = bn0[c] * rsqrtf(bn0[384 + c] + EPSF);
      s = (s - bn0[256 + c]) * sc + bn0[128 + c];
      r0[c] = fmaxf(s, 0.f);
    }
  }
  __syncthreads();
  {
    int c = t >> 1, part = t & 1;
    const float4* wr = (const float4*)(w1 + c * 128 + part * 64);
    const float4* rr = (const float4*)(r0 + part * 64);
    float s0 = 0.f, s1 = 0.f, s2 = 0.f, s3 = 0.f;
    #pragma unroll 8
    for (int o = 0; o < 16; ++o) {
      float4 a = rr[o], ww = wr[o];
      s0 += a.x * ww.x; s1 += a.y * ww.y; s2 += a.z * ww.z; s3 += a.w * ww.w;
    }
    float s = (s0 + s1) + (s2 + s3);
    s += __shfl_xor(s, 1);
    if (part == 0) {
      s += b1[c];
      float sc = bn1[c] * rsqrtf(bn1[768 + c] + EPSF);
      s = (s - bn1[512 + c]) * sc + bn1[256 + c];
      r1[c] = fmaxf(s, 0.f);
    }
  }
  __syncthreads();
  {
    int c = t;
    const float4* wr = (const float4*)(w2 + c * 256);
    const float4* rr = (const float4*)r1;
    float s0 = 0.f, s1 = 0.f, s2 = 0.f, s3 = 0.f;
    #pragma unroll 8
    for (int o = 0; o < 64; ++o) {
      float4 a = rr[o], ww = wr[o];
      s0 += a.x * ww.x; s1 += a.y * ww.y; s2 += a.z * ww.z; s3 += a.w * ww.w;
    }
    float s = (s0 + s1) + (s2 + s3) + b2[c];
    float sc = bn2[c] * rsqrtf(bn2[1536 + c] + EPSF);
    s = (s - bn2[1024 + c]) * sc + bn2[512 + c];
    r2g[b * 8192 + c * TOPK + k] = fmaxf(s, 0.f);
  }
}

// ------- FC layer 1: batched GEMV, split-K 8 ----
__global__ void __launch_bounds__(256)
k_fl2(const float* __restrict__ hin, const float* __restrict__ w,
      float* __restrict__ part) {
  __shared__ float hs[8 * 1032];
  int j0 = blockIdx.x * 16;
  int kc = blockIdx.y * 1024;
  int t = threadIdx.x;
  int jj = t >> 4, l = t & 15;
  #pragma unroll
  for (int i = 0; i < 8; ++i) {
    int idx = t + i * 256;
    int b = idx >> 8, off = (idx & 255) * 4;
    *(float4*)(hs + b * 1032 + off) = *(const float4*)(hin + (size_t)b * 8192 + kc + off);
  }
  __syncthreads();
  const float* wr = w + (size_t)(j0 + jj) * 8192 + kc;
  float acc[8] = {};
  #pragma unroll
  for (int k = 0; k < 16; ++k) {
    float4 wv = *(const float4*)(wr + l * 4 + k * 64);
    #pragma unroll
    for (int b = 0; b < 8; ++b) {
      float4 hv = *(const float4*)(hs + b * 1032 + l * 4 + k * 64);
      acc[b] += wv.x * hv.x + wv.y * hv.y + wv.z * hv.z + wv.w * hv.w;
    }
  }
  #pragma unroll
  for (int b = 0; b < 8; ++b) {
    #pragma unroll
    for (int off = 1; off < 16; off <<= 1) acc[b] += __shfl_xor(acc[b], off);
  }
  if (l == 0) {
    #pragma unroll
    for (int b = 0; b < 8; ++b)
      part[((size_t)blockIdx.y * 8 + b) * 1024 + j0 + jj] = acc[b];
  }
}

// ------- combine 8 split-K partials + bias + BN + ReLU -> h1g ----
__global__ void k_flc(const float* __restrict__ part, const float* __restrict__ bias,
                      const float* __restrict__ bn, float* __restrict__ hout) {
  int i = blockIdx.x * 256 + threadIdx.x;  // 0..8191
  int b = i >> 10, j = i & 1023;
  float s = bias[j];
  #pragma unroll
  for (int ks = 0; ks < 8; ++ks) s += part[((size_t)ks * 8 + b) * 1024 + j];
  float sc = bn[j] * rsqrtf(bn[3 * 1024 + j] + EPSF);
  s = (s - bn[2 * 1024 + j]) * sc + bn[1024 + j];
  hout[i] = fmaxf(s, 0.f);
}

// ------- FC layer 2: batched GEMV, split-K 4. 16 j x 8 b per block; h chunk in
// LDS reused by 16 rows; weights read once. ----
__global__ void __launch_bounds__(256)
k_fl3(const float* __restrict__ hin, const float* __restrict__ w,
      float* __restrict__ part) {
  __shared__ float hs[8 * 264];
  int j0 = blockIdx.x * 16;
  int kc = blockIdx.y * 256;
  int t = threadIdx.x;
  int jj = t >> 4, l = t & 15;
  #pragma unroll
  for (int i = 0; i < 2; ++i) {
    int idx = t + i * 256;          // 0..511 float4s of the 8x256 chunk
    int b = idx >> 6, off = (idx & 63) * 4;
    *(float4*)(hs + b * 264 + off) = *(const float4*)(hin + (size_t)b * 1024 + kc + off);
  }
  __syncthreads();
  const float* wr = w + (size_t)(j0 + jj) * 1024 + kc;
  float acc[8] = {};
  #pragma unroll
  for (int k = 0; k < 4; ++k) {
    float4 wv = *(const float4*)(wr + l * 4 + k * 64);
    #pragma unroll
    for (int b = 0; b < 8; ++b) {
      float4 hv = *(const float4*)(hs + b * 264 + l * 4 + k * 64);
      acc[b] += wv.x * hv.x + wv.y * hv.y + wv.z * hv.z + wv.w * hv.w;
    }
  }
  #pragma unroll
  for (int b = 0; b < 8; ++b) {
    #pragma unroll
    for (int off = 1; off < 16; off <<= 1) acc[b] += __shfl_xor(acc[b], off);
  }
  if (l == 0) {
    #pragma unroll
    for (int b = 0; b < 8; ++b)
      part[((size_t)blockIdx.y * 8 + b) * 512 + j0 + jj] = acc[b];
  }
}

// ------- combine 4 split-K partials + bias + BN + ReLU -> out ----
__global__ void k_flc2(const float* __restrict__ part, const float* __restrict__ bias,
                       const float* __restrict__ bn, float* __restrict__ hout) {
  int i = blockIdx.x * 256 + threadIdx.x;  // 0..4095
  int b = i >> 9, j = i & 511;
  float s = bias[j];
  #pragma unroll
  for (int ks = 0; ks < 4; ++ks) s += part[((size_t)ks * 8 + b) * 512 + j];
  float sc = bn[j] * rsqrtf(bn[3 * 512 + j] + EPSF);
  s = (s - bn[2 * 512 + j]) * sc + bn[512 + j];
  hout[i] = fmaxf(s, 0.f);
}

extern "C" void kernel_launch(void* const* d_in, const int* in_sizes, int n_in,
                              void* d_out, int out_size, void* d_ws, size_t ws_size,
                              hipStream_t stream) {
  const float* sv      = (const float*)d_in[0];
  const float* inp     = (const float*)d_in[1];
  const float* tl_win  = (const float*)d_in[2];
  const float* tl_bin  = (const float*)d_in[3];
  const float* tl_wout = (const float*)d_in[4];
  const float* tl_bout = (const float*)d_in[5];
  const float* tl_w1   = (const float*)d_in[6];
  const float* tl_b1   = (const float*)d_in[7];
  const float* tl_w2   = (const float*)d_in[8];
  const float* tl_b2   = (const float*)d_in[9];
  const float* tl_ln1g = (const float*)d_in[10];
  const float* tl_ln1b = (const float*)d_in[11];
  const float* tl_ln2g = (const float*)d_in[12];
  const float* tl_ln2b = (const float*)d_in[13];
  const float* fg_w0   = (const float*)d_in[14];
  const float* fg_b0   = (const float*)d_in[15];
  const float* fg_w1   = (const float*)d_in[16];
  const float* fg_b1   = (const float*)d_in[17];
  const float* fg_w2   = (const float*)d_in[18];
  const float* fg_b2   = (const float*)d_in[19];
  const float* fbn0    = (const float*)d_in[20];
  const float* fbn1    = (const float*)d_in[21];
  const float* fbn2    = (const float*)d_in[22];
  const float* rc_w0   = (const float*)d_in[23];
  const float* rc_b0   = (const float*)d_in[24];
  const float* rc_w1   = (const float*)d_in[25];
  const float* rc_b1   = (const float*)d_in[26];
  const float* rc_w2   = (const float*)d_in[27];
  const float* rc_b2   = (const float*)d_in[28];
  const float* rbn0    = (const float*)d_in[29];
  const float* rbn1    = (const float*)d_in[30];
  const float* rbn2    = (const float*)d_in[31];
  const float* fl_w0   = (const float*)d_in[32];
  const float* fl_b0   = (const float*)d_in[33];
  const float* fl_w1   = (const float*)d_in[34];
  const float* fl_b1   = (const float*)d_in[35];
  const float* lbn0    = (const float*)d_in[36];
  const float* lbn1    = (const float*)d_in[37];
  (void)in_sizes; (void)n_in; (void)out_size; (void)ws_size;

  float* wsp = (float*)d_ws;
  float* x      = wsp;                        // B*N*F      = 1048576
  float* qkv    = x + BB * NN * FF;           // 3145728-float region
  float* a      = qkv + BB * NN * 192;        // B*N*F      = 1048576
  float* scores = a + BB * NN * FF;           // B*N        = 16384
  int*   idxb   = (int*)(scores + BB * NN);   // B*TOPK     = 128
  float* r2g    = (float*)(idxb + BB * TOPK); // B*8192     = 65536
  float* h1g    = r2g + BB * 8192;            // B*1024     = 8192
  // FFN weight image: [l][chg][4 planes][4096 u16] = 1M u16 = 2MB
  unsigned short* img = (unsigned short*)(h1g + BB * 1024);
  // qkv region carve-out: Q fp32 (1M floats) | kp bf16 (1M u16) | vp bf16 (1M u16)
  float* qbuf = qkv;
  unsigned short* kp = (unsigned short*)(qkv + BB * NN * FF);
  unsigned short* vp = kp + (size_t)BB * NHEAD * NN * HD;
  float* part = qkv;        // FFN & FC-1 split-K partials reuse qkv region
  float* part2 = qkv + 65536;  // FC-2 partials (4*8*512 floats)

  float* out = (float*)d_out;  // fp32: h at [0,4096), idx-as-float at [4096,4224)

  k_transpose<<<(BB * NN * FF) / 256, 256, 0, stream>>>(sv, x);
  k_wimg<<<(NLAYER * 32 * 4 * 4096) / 256, 256, 0, stream>>>(tl_w1, tl_w2, img);

  for (int l = 0; l < NLAYER; ++l) {
    k_qkv3<<<dim3(BB * NN / 64, 3), 256, 0, stream>>>(x, tl_win + l * 192 * FF,
                                                      tl_bin + l * 192, qbuf,
                                                      (uint4*)kp, (uint4*)vp);
    k_attn9<<<dim3(NN / 64, NHEAD, BB), 256, 0, stream>>>(qbuf, (const uint4*)kp,
                                                          (const unsigned*)vp, a);
    k_proj2<<<BB * NN / 64, 256, 0, stream>>>(a, tl_wout + l * FF * FF, tl_bout + l * FF,
                                              tl_ln1g + l * FF, tl_ln1b + l * FF, x);
    k_ffn7<<<dim3(BB * NN / 128, 4), 256, 0, stream>>>(x, (const char*)(img + (size_t)l * 524288),
                                                       tl_b1 + l * 2048, part);
    k_ffn_ln<<<BB * NN / 4, 256, 0, stream>>>(part, tl_b2 + l * FF,
                                              tl_ln2g + l * FF, tl_ln2b + l * FF, x);
  }

  k_fg2<<<BB * NN / 64, 256, 0, stream>>>(x, fg_w0, fg_b0, fbn0, fg_w1, fg_b1, fbn1,
                                          fg_w2, fg_b2, fbn2, scores);
  k_topk2<<<BB, 256, 0, stream>>>(scores, idxb, out + BB * 512);
  k_group<<<dim3(TOPK, BB), 512, 0, stream>>>(inp, idxb, rc_w0, rc_b0, rbn0,
                                              rc_w1, rc_b1, rbn1, rc_w2, rc_b2, rbn2, r2g);
  k_fl2<<<dim3(64, 8), 256, 0, stream>>>(r2g, fl_w0, part);
  k_flc<<<32, 256, 0, stream>>>(part, fl_b0, lbn0, h1g);
  k_fl3<<<dim3(32, 4), 256, 0, stream>>>(h1g, fl_w1, part2);
  k_flc2<<<16, 256, 0, stream>>>(part2, fl_b1, lbn1, out);
}

// Round 9
// 424.438 us; speedup vs baseline: 1.7596x; 1.0418x over previous
//
#include <hip/hip_runtime.h>
#include <hip/hip_bf16.h>
#include <math.h>

#define BB 8
#define NN 2048
#define FF 64
#define DD 6
#define NSAMP 64
#define TOPK 16
#define NHEAD 8
#define HD 8
#define NLAYER 2
#define EPSF 1e-5f
#define R2 0.09f

typedef short short8 __attribute__((ext_vector_type(8)));
typedef float f32x4 __attribute__((ext_vector_type(4)));
typedef unsigned uint4v __attribute__((ext_vector_type(4)));
typedef unsigned int u32;

// split-pack: u32 = (bf16_hi << 16) | bf16_lo, both RNE. x ≈ hi + lo, err ~2^-16 rel.
__device__ inline unsigned pk2(float x) {
  unsigned b = __float_as_uint(x);
  unsigned hi = (b + 0x7fffu + ((b >> 16) & 1u)) >> 16;
  float r = x - __uint_as_float(hi << 16);
  unsigned c = __float_as_uint(r);
  unsigned lo = (c + 0x7fffu + ((c >> 16) & 1u)) >> 16;
  return (hi << 16) | lo;
}

__device__ inline unsigned short bf16r(float x) {  // RNE bf16
  unsigned b = __float_as_uint(x);
  return (unsigned short)((b + 0x7fffu + ((b >> 16) & 1u)) >> 16);
}

// async global->LDS, 16B per lane (dest = wave-uniform base + lane*16)
__device__ __forceinline__ void gl16(const void* g, void* l) {
  __builtin_amdgcn_global_load_lds((const __attribute__((address_space(1))) u32*)g,
                                   (__attribute__((address_space(3))) u32*)l, 16, 0, 0);
}

// ---------------- transpose sortvec (B,1,F,N) -> x (B,N,F) ----------------
__global__ void k_transpose(const float* __restrict__ sv, float* __restrict__ x) {
  int i = blockIdx.x * 256 + threadIdx.x;
  if (i >= BB * NN * FF) return;
  int f = i % FF;
  int n = (i / FF) % NN;
  int b = i / (FF * NN);
  x[i] = sv[(b * FF + f) * NN + n];
}

// ---- pack FFN weights into the exact per-chunk LDS byte image (pre-swizzled).
__global__ void k_wimg(const float* __restrict__ w1, const float* __restrict__ w2,
                       unsigned short* __restrict__ img) {
  int i = blockIdx.x * 256 + threadIdx.x;     // u16 index, total 2*32*4*4096
  int e = i & 4095;
  int plane = (i >> 12) & 3;
  int chg = (i >> 14) & 31;
  int l = i >> 19;
  int r = e >> 6, sh = (e >> 3) & 7, inner = e & 7;
  int s = sh ^ (r & 7);
  float v;
  if (plane < 2) v = w1[((size_t)(l * 2048 + chg * 64 + r)) * 64 + s * 8 + inner];
  else           v = w2[((size_t)(l * 64 + r)) * 2048 + chg * 64 + s * 8 + inner];
  unsigned p = pk2(v);
  img[i] = (unsigned short)((plane & 1) ? (p & 0xffffu) : (p >> 16));
}

// ---- qkv v3: tiled GEMM; epilogue routes per blockIdx.y ----
__global__ void k_qkv3(const float* __restrict__ x, const float* __restrict__ win,
                       const float* __restrict__ bin, float* __restrict__ qbuf,
                       uint4* __restrict__ kp4, uint4* __restrict__ vp4) {
  __shared__ float xs[64 * 68];
  __shared__ float ws[64 * 68];
  int row0 = blockIdx.x * 64, y = blockIdx.y, col0 = y * 64;
  int t = threadIdx.x;
  #pragma unroll
  for (int i = 0; i < 4; ++i) {
    int q = t + i * 256, r = q >> 4, c = (q & 15) * 4;
    *(float4*)(xs + r * 68 + c) = *(const float4*)(x + (size_t)(row0 + r) * 64 + c);
    *(float4*)(ws + r * 68 + c) = *(const float4*)(win + (size_t)(col0 + r) * 64 + c);
  }
  __syncthreads();
  int tx = t & 15, ty = t >> 4;
  float acc[4][4] = {};
  for (int f = 0; f < 64; f += 4) {
    float4 xv[4], wv[4];
    #pragma unroll
    for (int ri = 0; ri < 4; ++ri) xv[ri] = *(const float4*)(xs + (ty * 4 + ri) * 68 + f);
    #pragma unroll
    for (int ci = 0; ci < 4; ++ci) wv[ci] = *(const float4*)(ws + (tx + 16 * ci) * 68 + f);
    #pragma unroll
    for (int ri = 0; ri < 4; ++ri)
      #pragma unroll
      for (int ci = 0; ci < 4; ++ci)
        acc[ri][ci] += xv[ri].x * wv[ci].x + xv[ri].y * wv[ci].y +
                       xv[ri].z * wv[ci].z + xv[ri].w * wv[ci].w;
  }
  int b = row0 >> 11, n0 = row0 & (NN - 1);
  if (y == 0) {
    #pragma unroll
    for (int ri = 0; ri < 4; ++ri)
      #pragma unroll
      for (int ci = 0; ci < 4; ++ci) {
        int r = row0 + ty * 4 + ri, c = tx + 16 * ci;
        qbuf[(size_t)r * 64 + c] = acc[ri][ci] + bin[c];
      }
    return;
  }
  __syncthreads();  // all GEMM reads of xs done before reuse
  unsigned short* l16 = (unsigned short*)xs;  // 64x72 u16 tile
  if (y == 1) {
    #pragma unroll
    for (int ri = 0; ri < 4; ++ri)
      #pragma unroll
      for (int ci = 0; ci < 4; ++ci) {
        int r = ty * 4 + ri, c = tx + 16 * ci;
        l16[r * 72 + c] = bf16r(acc[ri][ci] + bin[64 + c]);
      }
    __syncthreads();
    #pragma unroll
    for (int i = 0; i < 2; ++i) {
      int idx = t + i * 256;
      int h = idx >> 6, tok = idx & 63;
      uint4 v = *(const uint4*)(l16 + tok * 72 + h * 8);
      kp4[(size_t)(b * NHEAD + h) * NN + n0 + tok] = v;
    }
  } else {
    #pragma unroll
    for (int ri = 0; ri < 4; ++ri)
      #pragma unroll
      for (int ci = 0; ci < 4; ++ci) {
        int r = ty * 4 + ri, c = tx + 16 * ci;
        l16[c * 72 + r] = bf16r(acc[ri][ci] + bin[128 + c]);  // transposed
      }
    __syncthreads();
    #pragma unroll
    for (int i = 0; i < 2; ++i) {
      int idx = t + i * 256;
      int c = idx >> 3, seg = idx & 7;
      uint4 v = *(const uint4*)(l16 + c * 72 + seg * 8);
      vp4[(size_t)(b * 64 + c) * (NN / 8) + (n0 >> 3) + seg] = v;
    }
  }
}

// ---- attention v10: swapped-operand flash. vs v9: (a) unconditional K A-frag
// read — qF (B-op) is zero for k>=8, so A's k>=8 lanes are multiplied by zero;
// kb4 holds finite bf16 so no NaN risk. Kills the per-step exec-mask + re-zero.
// (b) dual PV accumulators (even/odd s) break the 64-deep serial MFMA chain.
__global__ void __launch_bounds__(256, 8)
k_attn10(const float* __restrict__ q, const uint4* __restrict__ kp4,
         const unsigned* __restrict__ vp32, float* __restrict__ a) {
  __shared__ uint4 kb4[256];                                            // 4 KB
  __shared__ __attribute__((aligned(16))) unsigned short vb16[9 * 264]; // 4.6 KB
  int t = threadIdx.x;
  int lane = t & 63, w = t >> 6;
  int nIdx = lane & 15, lq = lane >> 4;
  int h = blockIdx.y, b = blockIdx.z;
  int qwb = blockIdx.x * 64 + w * 16;
  int bh = b * NHEAD + h;
  const float kf = 0.35355339059327373f * 1.4426950408889634f;  // scale*log2e
  short8 qF = {0, 0, 0, 0, 0, 0, 0, 0};
  if (lq == 0) {
    const float* qr = q + ((size_t)(b * NN + qwb + nIdx)) * 64 + h * HD;
    #pragma unroll
    for (int j = 0; j < 8; ++j) qF[j] = (short)bf16r(qr[j] * kf);
  }
  f32x4 acc0 = {0.f, 0.f, 0.f, 0.f};
  f32x4 acc1 = {0.f, 0.f, 0.f, 0.f};
  const uint4* kbase = kp4 + (size_t)bh * NN;
  const unsigned* vbase = vp32 + (size_t)bh * HD * (NN / 2);
  int vn = nIdx < 9 ? nIdx : 8;
  int voff = ((lq & 1) << 4) + ((lq >> 1) << 3);  // key perm per quad
  if (t < 132) ((unsigned*)(vb16 + 8 * 264))[t] = 0x3f803f80u;
  uint4 kreg = kbase[t];
  unsigned vreg[4];
  #pragma unroll
  for (int i = 0; i < 4; ++i) {
    int g = t + i * 256;
    vreg[i] = vbase[(g >> 7) * (NN / 2) + (g & 127)];
  }
  for (int kc = 0; kc < NN; kc += 256) {
    __syncthreads();
    kb4[t] = kreg;
    #pragma unroll
    for (int i = 0; i < 4; ++i) {
      int g = t + i * 256;
      ((unsigned*)vb16)[(g >> 7) * 132 + (g & 127)] = vreg[i];
    }
    __syncthreads();
    if (kc + 256 < NN) {
      kreg = kbase[kc + 256 + t];
      #pragma unroll
      for (int i = 0; i < 4; ++i) {
        int g = t + i * 256;
        vreg[i] = vbase[(g >> 7) * (NN / 2) + ((kc + 256) >> 1) + (g & 127)];
      }
    }
    #pragma unroll
    for (int s = 0; s < 8; ++s) {
      int kb = s * 32;
      unsigned pk_[4];
      #pragma unroll
      for (int half = 0; half < 2; ++half) {
        int key = kb + half * 16 + nIdx;
        short8 aK = *(const short8*)(kb4 + key);  // unmasked: k>=8 lanes * 0
        f32x4 c = {0.f, 0.f, 0.f, 0.f};
        __builtin_amdgcn_s_setprio(1);
        c = __builtin_amdgcn_mfma_f32_16x16x32_bf16(aK, qF, c, 0, 0, 0);
        __builtin_amdgcn_s_setprio(0);
        float p0 = __builtin_amdgcn_exp2f(c[0]);
        float p1 = __builtin_amdgcn_exp2f(c[1]);
        float p2 = __builtin_amdgcn_exp2f(c[2]);
        float p3 = __builtin_amdgcn_exp2f(c[3]);
        unsigned r0, r1;
        asm("v_cvt_pk_bf16_f32 %0, %1, %2" : "=v"(r0) : "v"(p0), "v"(p1));
        asm("v_cvt_pk_bf16_f32 %0, %1, %2" : "=v"(r1) : "v"(p2), "v"(p3));
        pk_[half * 2]     = r0;
        pk_[half * 2 + 1] = r1;
      }
      unsigned e0 = (unsigned)__shfl_xor((int)pk_[0], 16);
      unsigned e1 = (unsigned)__shfl_xor((int)pk_[1], 16);
      unsigned e2 = (unsigned)__shfl_xor((int)pk_[2], 16);
      unsigned e3 = (unsigned)__shfl_xor((int)pk_[3], 16);
      bool odd = (lq & 1);
      uint4v bw;
      bw[0] = odd ? e2 : pk_[0];
      bw[1] = odd ? e3 : pk_[1];
      bw[2] = odd ? pk_[2] : e0;
      bw[3] = odd ? pk_[3] : e1;
      short8 bP = *(short8*)&bw;
      short8 aV = *(const short8*)(vb16 + vn * 264 + kb + voff);
      __builtin_amdgcn_s_setprio(1);
      if (s & 1) acc1 = __builtin_amdgcn_mfma_f32_16x16x32_bf16(aV, bP, acc1, 0, 0, 0);
      else       acc0 = __builtin_amdgcn_mfma_f32_16x16x32_bf16(aV, bP, acc0, 0, 0, 0);
      __builtin_amdgcn_s_setprio(0);
    }
  }
  f32x4 acc;
  acc[0] = acc0[0] + acc1[0];
  acc[1] = acc0[1] + acc1[1];
  acc[2] = acc0[2] + acc1[2];
  acc[3] = acc0[3] + acc1[3];
  float lr = __shfl(acc[0], 32 + nIdx);
  if (lq < 2) {
    int row = qwb + nIdx;
    float4 o;
    o.x = acc[0] / lr; o.y = acc[1] / lr; o.z = acc[2] / lr; o.w = acc[3] / lr;
    *(float4*)(a + ((size_t)(b * NN + row)) * 64 + h * HD + lq * 4) = o;
  }
}

// ------- proj + residual + LN, tiled GEMM ---------
__global__ void k_proj2(const float* __restrict__ a, const float* __restrict__ wout,
                        const float* __restrict__ bout, const float* __restrict__ g,
                        const float* __restrict__ be, float* __restrict__ x) {
  __shared__ float xs[64 * 68];
  __shared__ float ws[64 * 68];
  int row0 = blockIdx.x * 64;
  int t = threadIdx.x;
  #pragma unroll
  for (int i = 0; i < 4; ++i) {
    int q = t + i * 256, r = q >> 4, c = (q & 15) * 4;
    *(float4*)(xs + r * 68 + c) = *(const float4*)(a + (size_t)(row0 + r) * 64 + c);
    *(float4*)(ws + r * 68 + c) = *(const float4*)(wout + r * 64 + c);
  }
  __syncthreads();
  int tx = t & 15, ty = t >> 4;
  float acc[4][4] = {};
  for (int f = 0; f < 64; f += 4) {
    float4 xv[4], wv[4];
    #pragma unroll
    for (int ri = 0; ri < 4; ++ri) xv[ri] = *(const float4*)(xs + (ty * 4 + ri) * 68 + f);
    #pragma unroll
    for (int ci = 0; ci < 4; ++ci) wv[ci] = *(const float4*)(ws + (tx + 16 * ci) * 68 + f);
    #pragma unroll
    for (int ri = 0; ri < 4; ++ri)
      #pragma unroll
      for (int ci = 0; ci < 4; ++ci)
        acc[ri][ci] += xv[ri].x * wv[ci].x + xv[ri].y * wv[ci].y +
                       xv[ri].z * wv[ci].z + xv[ri].w * wv[ci].w;
  }
  #pragma unroll
  for (int ri = 0; ri < 4; ++ri) {
    int rl = ty * 4 + ri;
    float val[4], s = 0.f, sq = 0.f;
    #pragma unroll
    for (int ci = 0; ci < 4; ++ci) {
      int c = tx + 16 * ci;
      val[ci] = x[(size_t)(row0 + rl) * 64 + c] + bout[c] + acc[ri][ci];
      s += val[ci]; sq += val[ci] * val[ci];
    }
    #pragma unroll
    for (int off = 1; off < 16; off <<= 1) { s += __shfl_xor(s, off); sq += __shfl_xor(sq, off); }
    float mean = s * (1.f / 64.f);
    float var = sq * (1.f / 64.f) - mean * mean;
    float rstd = rsqrtf(var + EPSF);
    #pragma unroll
    for (int ci = 0; ci < 4; ++ci) {
      int c = tx + 16 * ci;
      x[(size_t)(row0 + rl) * 64 + c] = (val[ci] - mean) * rstd * g[c] + be[c];
    }
  }
}

// ------- FFN v7: global_load_lds staging, counted vmcnt, raw s_barriers ----
__global__ void __launch_bounds__(256, 2)
k_ffn7(const float* __restrict__ x, const char* __restrict__ img,
       const float* __restrict__ b1, float* __restrict__ part) {
  __shared__ __attribute__((aligned(16))) char W1b[2][16384];
  __shared__ __attribute__((aligned(16))) char W2b[16384];
  __shared__ __attribute__((aligned(16))) unsigned short hpl[2][128 * 64];
  int row0 = blockIdx.x * 128;
  int ks = blockIdx.y, kc = ks * 512;
  int t = threadIdx.x, lane = t & 63, wv = t >> 6;
  int lm = lane & 15, lq = lane >> 4;
  const char* ibase = img + (size_t)ks * 8 * 32768;

  short8 axh[2][2], axl[2][2];
  #pragma unroll
  for (int m = 0; m < 2; ++m)
    #pragma unroll
    for (int kbi = 0; kbi < 2; ++kbi) {
      const float* xr = x + (size_t)(row0 + m * 64 + wv * 16 + lm) * 64 + kbi * 32 + lq * 8;
      #pragma unroll
      for (int j = 0; j < 8; ++j) {
        unsigned p = pk2(xr[j]);
        axh[m][kbi][j] = (short)(p >> 16);
        axl[m][kbi][j] = (short)(p & 0xffffu);
      }
    }
  float bv[8][4];
  #pragma unroll
  for (int ch = 0; ch < 8; ++ch)
    #pragma unroll
    for (int tn = 0; tn < 4; ++tn)
      bv[ch][tn] = b1[kc + ch * 64 + tn * 16 + lm];
  asm volatile("s_waitcnt vmcnt(0)" ::: "memory");
  __builtin_amdgcn_sched_barrier(0);
  #pragma unroll
  for (int i = 0; i < 4; ++i)
    gl16(ibase + i * 4096 + t * 16, &W1b[0][i * 4096 + t * 16]);

  f32x4 acc[2][4];
  #pragma unroll
  for (int m = 0; m < 2; ++m)
    #pragma unroll
    for (int tn = 0; tn < 4; ++tn) acc[m][tn] = (f32x4){0.f, 0.f, 0.f, 0.f};

  #pragma unroll
  for (int ch = 0; ch < 8; ++ch) {
    const int p = ch & 1;
    const char* cbase = ibase + ch * 32768;
    #pragma unroll
    for (int i = 0; i < 4; ++i)
      gl16(cbase + 16384 + i * 4096 + t * 16, &W2b[i * 4096 + t * 16]);
    if (ch < 7) {
      #pragma unroll
      for (int i = 0; i < 4; ++i)
        gl16(cbase + 32768 + i * 4096 + t * 16, &W1b[p ^ 1][i * 4096 + t * 16]);
    }
    if (ch < 7) { asm volatile("s_waitcnt vmcnt(8)" ::: "memory"); }
    else        { asm volatile("s_waitcnt vmcnt(4)" ::: "memory"); }
    __builtin_amdgcn_sched_barrier(0);
    __builtin_amdgcn_s_barrier();
    __builtin_amdgcn_sched_barrier(0);
    const char* P0h = W1b[p];
    const char* P0l = W1b[p] + 8192;
    f32x4 h4[2][4];
    #pragma unroll
    for (int m = 0; m < 2; ++m)
      #pragma unroll
      for (int tn = 0; tn < 4; ++tn) h4[m][tn] = (f32x4){0.f, 0.f, 0.f, 0.f};
    #pragma unroll
    for (int kbi = 0; kbi < 2; ++kbi) {
      int sw = (((kbi * 4 + lq) ^ (lm & 7)) << 4);
      #pragma unroll
      for (int tn = 0; tn < 4; ++tn) {
        int brow = tn * 16 + lm;
        short8 bhi = *(const short8*)(P0h + brow * 128 + sw);
        short8 blo = *(const short8*)(P0l + brow * 128 + sw);
        #pragma unroll
        for (int m = 0; m < 2; ++m) {
          h4[m][tn] = __builtin_amdgcn_mfma_f32_16x16x32_bf16(axh[m][kbi], bhi, h4[m][tn], 0, 0, 0);
          h4[m][tn] = __builtin_amdgcn_mfma_f32_16x16x32_bf16(axh[m][kbi], blo, h4[m][tn], 0, 0, 0);
          h4[m][tn] = __builtin_amdgcn_mfma_f32_16x16x32_bf16(axl[m][kbi], bhi, h4[m][tn], 0, 0, 0);
        }
      }
    }
    #pragma unroll
    for (int m = 0; m < 2; ++m)
      #pragma unroll
      for (int tn = 0; tn < 4; ++tn)
        #pragma unroll
        for (int r = 0; r < 4; ++r) {
          float hv = fmaxf(h4[m][tn][r] + bv[ch][tn], 0.f);
          unsigned u = __float_as_uint(hv);
          float resid = hv - __uint_as_float(u & 0xffff0000u);
          unsigned c2 = __float_as_uint(resid);
          int hrow = m * 64 + wv * 16 + lq * 4 + r, hcol = tn * 16 + lm;
          int off = hrow * 128 + (((hcol >> 3) ^ (hrow & 7)) << 4) + ((hcol & 7) << 1);
          *(unsigned short*)((char*)hpl[0] + off) = (unsigned short)(u >> 16);
          *(unsigned short*)((char*)hpl[1] + off) =
              (unsigned short)((c2 + 0x7fffu + ((c2 >> 16) & 1u)) >> 16);
        }
    if (ch < 7) { asm volatile("s_waitcnt vmcnt(4)" ::: "memory"); }
    else        { asm volatile("s_waitcnt vmcnt(0)" ::: "memory"); }
    __builtin_amdgcn_sched_barrier(0);
    __builtin_amdgcn_s_barrier();
    __builtin_amdgcn_sched_barrier(0);
    const char* P1h = W2b;
    const char* P1l = W2b + 8192;
    #pragma unroll
    for (int kbi = 0; kbi < 2; ++kbi) {
      short8 a2h[2], a2l[2];
      #pragma unroll
      for (int m = 0; m < 2; ++m) {
        int arow = m * 64 + wv * 16 + lm;
        int swa = (((kbi * 4 + lq) ^ (arow & 7)) << 4);
        a2h[m] = *(const short8*)((const char*)hpl[0] + arow * 128 + swa);
        a2l[m] = *(const short8*)((const char*)hpl[1] + arow * 128 + swa);
      }
      int swb = (((kbi * 4 + lq) ^ (lm & 7)) << 4);
      #pragma unroll
      for (int tn = 0; tn < 4; ++tn) {
        int brow = tn * 16 + lm;
        short8 bhi = *(const short8*)(P1h + brow * 128 + swb);
        short8 blo = *(const short8*)(P1l + brow * 128 + swb);
        #pragma unroll
        for (int m = 0; m < 2; ++m) {
          acc[m][tn] = __builtin_amdgcn_mfma_f32_16x16x32_bf16(a2h[m], bhi, acc[m][tn], 0, 0, 0);
          acc[m][tn] = __builtin_amdgcn_mfma_f32_16x16x32_bf16(a2h[m], blo, acc[m][tn], 0, 0, 0);
          acc[m][tn] = __builtin_amdgcn_mfma_f32_16x16x32_bf16(a2l[m], bhi, acc[m][tn], 0, 0, 0);
        }
      }
    }
    __builtin_amdgcn_s_barrier();
    __builtin_amdgcn_sched_barrier(0);
  }
  float* fb = (float*)hpl;
  #pragma unroll
  for (int m = 0; m < 2; ++m)
    #pragma unroll
    for (int tn = 0; tn < 4; ++tn)
      #pragma unroll
      for (int r = 0; r < 4; ++r) {
        int row = m * 64 + wv * 16 + lq * 4 + r;
        int col = (tn * 16 + lm) ^ ((row & 7) << 2);
        fb[row * 64 + col] = acc[m][tn][r];
      }
  __syncthreads();
  float* pb = part + (size_t)ks * (BB * NN * 64);
  #pragma unroll
  for (int i = 0; i < 8; ++i) {
    int idx = t * 4 + i * 1024;
    int row = idx >> 6, c0 = idx & 63;
    int c0s = c0 ^ ((row & 7) << 2);
    float4 v = *(const float4*)(fb + row * 64 + c0s);
    *(float4*)(pb + (size_t)(row0 + row) * 64 + c0) = v;
  }
}

// ------- combine 4 partials + residual + b2 + LN; one wave per row ---------
__global__ void k_ffn_ln(const float* __restrict__ part, const float* __restrict__ b2,
                         const float* __restrict__ g, const float* __restrict__ be,
                         float* __restrict__ x) {
  int row = blockIdx.x * 4 + (threadIdx.x >> 6);
  int j = threadIdx.x & 63;
  size_t o = (size_t)row * 64 + j;
  const size_t S = (size_t)BB * NN * 64;
  float val = x[o] + b2[j] + ((part[o] + part[o + S]) + (part[o + 2 * S] + part[o + 3 * S]));
  float s = val;
  for (int off = 32; off; off >>= 1) s += __shfl_xor(s, off);
  s *= (1.f / 64.f);
  float d = val - s;
  float v = d * d;
  for (int off = 32; off; off >>= 1) v += __shfl_xor(v, off);
  v *= (1.f / 64.f);
  x[o] = d * rsqrtf(v + EPSF) * g[j] + be[j];
}

// ------- score head tiled ----------
__global__ void k_fg2(const float* __restrict__ x,
                      const float* __restrict__ w0, const float* __restrict__ b0, const float* __restrict__ bn0,
                      const float* __restrict__ w1, const float* __restrict__ b1, const float* __restrict__ bn1,
                      const float* __restrict__ w2, const float* __restrict__ b2, const float* __restrict__ bn2,
                      float* __restrict__ scores) {
  __shared__ float xs[64 * 68];
  __shared__ float ws[64 * 68];
  __shared__ float s0s[64 * 68];
  __shared__ float s1s[64 * 20];
  int row0 = blockIdx.x * 64;
  int t = threadIdx.x;
  #pragma unroll
  for (int i = 0; i < 4; ++i) {
    int q = t + i * 256, r = q >> 4, c = (q & 15) * 4;
    *(float4*)(xs + r * 68 + c) = *(const float4*)(x + (size_t)(row0 + r) * 64 + c);
    *(float4*)(ws + r * 68 + c) = *(const float4*)(w0 + r * 64 + c);
  }
  __syncthreads();
  int tx = t & 15, ty = t >> 4;
  float acc[4][4] = {};
  for (int f = 0; f < 64; f += 4) {
    float4 xv[4], wv[4];
    #pragma unroll
    for (int ri = 0; ri < 4; ++ri) xv[ri] = *(const float4*)(xs + (ty * 4 + ri) * 68 + f);
    #pragma unroll
    for (int ci = 0; ci < 4; ++ci) wv[ci] = *(const float4*)(ws + (tx + 16 * ci) * 68 + f);
    #pragma unroll
    for (int ri = 0; ri < 4; ++ri)
      #pragma unroll
      for (int ci = 0; ci < 4; ++ci)
        acc[ri][ci] += xv[ri].x * wv[ci].x + xv[ri].y * wv[ci].y +
                       xv[ri].z * wv[ci].z + xv[ri].w * wv[ci].w;
  }
  #pragma unroll
  for (int ri = 0; ri < 4; ++ri)
    #pragma unroll
    for (int ci = 0; ci < 4; ++ci) {
      int c = tx + 16 * ci;
      float sc = bn0[c] * rsqrtf(bn0[192 + c] + EPSF);
      float v = (acc[ri][ci] + b0[c] - bn0[128 + c]) * sc + bn0[64 + c];
      s0s[(ty * 4 + ri) * 68 + c] = fmaxf(v, 0.f);
    }
  __syncthreads();
  {
    int rl = t & 63, j0 = t >> 6;
    #pragma unroll
    for (int i = 0; i < 4; ++i) {
      int j = j0 + 4 * i;
      float s = b1[j];
      const float* wr = w1 + j * 64;
      #pragma unroll 16
      for (int c = 0; c < 64; ++c) s += s0s[rl * 68 + c] * wr[c];
      float sc = bn1[j] * rsqrtf(bn1[48 + j] + EPSF);
      s = (s - bn1[32 + j]) * sc + bn1[16 + j];
      s1s[rl * 20 + j] = fmaxf(s, 0.f);
    }
  }
  __syncthreads();
  if (t < 64) {
    float s = b2[0];
    #pragma unroll
    for (int o = 0; o < 16; ++o) s += s1s[t * 20 + o] * w2[o];
    float sc = bn2[0] * rsqrtf(bn2[3] + EPSF);
    s = (s - bn2[2]) * sc + bn2[1];
    scores[row0 + t] = fmaxf(s, 0.f);
  }
}

// ---- top-k (k=16) ----
__global__ void k_topk2(const float* __restrict__ scores, int* __restrict__ idx,
                        float* __restrict__ out_idx) {
  int b = blockIdx.x, t = threadIdx.x;
  float v[8];
  int base = b * NN;
  #pragma unroll
  for (int u = 0; u < 8; ++u) v[u] = scores[base + t + 256 * u];
  __shared__ float wvs[4];
  __shared__ int wis[4];
  __shared__ int winner;
  unsigned taken = 0;
  for (int r = 0; r < TOPK; ++r) {
    float best = -1e30f; int bi = 1 << 30;
    #pragma unroll
    for (int u = 0; u < 8; ++u) {
      if (!((taken >> u) & 1)) {
        float vv = v[u]; int ii = t + 256 * u;
        if (vv > best || (vv == best && ii < bi)) { best = vv; bi = ii; }
      }
    }
    for (int off = 32; off; off >>= 1) {
      float ov = __shfl_xor(best, off);
      int oi = __shfl_xor(bi, off);
      if (ov > best || (ov == best && oi < bi)) { best = ov; bi = oi; }
    }
    if ((t & 63) == 0) { wvs[t >> 6] = best; wis[t >> 6] = bi; }
    __syncthreads();
    if (t == 0) {
      float B = wvs[0]; int I = wis[0];
      #pragma unroll
      for (int q = 1; q < 4; ++q)
        if (wvs[q] > B || (wvs[q] == B && wis[q] < I)) { B = wvs[q]; I = wis[q]; }
      winner = I;
      idx[b * TOPK + r] = I;
      out_idx[b * TOPK + r] = (float)I;
    }
    __syncthreads();
    int w = winner;
    if ((w & 255) == t) taken |= 1u << (w >> 8);
  }
}

// ---------------- ball query + 3 conv stages. v3: grid z=2 splits conv2's 512
// channels (the dominant 131K MACs); ball query + conv0 + conv1 duplicated
// (cheap). 256 blocks fill all 256 CUs. conv2: 2 lanes/channel + shfl combine.
__global__ void __launch_bounds__(512)
k_group(const float* __restrict__ inp, const int* __restrict__ idx,
        const float* __restrict__ w0, const float* __restrict__ b0, const float* __restrict__ bn0,
        const float* __restrict__ w1, const float* __restrict__ b1, const float* __restrict__ bn1,
        const float* __restrict__ w2, const float* __restrict__ b2, const float* __restrict__ bn2,
        float* __restrict__ r2g) {
  __shared__ int swave[8 * 64];
  __shared__ int scnt[8];
  __shared__ int gidx[NSAMP];
  __shared__ __attribute__((aligned(16))) float gsh[65 * DD];
  __shared__ __attribute__((aligned(16))) float r0[128];
  __shared__ __attribute__((aligned(16))) float r1[256];
  int k = blockIdx.x, b = blockIdx.y, z = blockIdx.z;
  int t = threadIdx.x;
  int lane = t & 63, w = t >> 6;
  int qn = idx[b * TOPK + k];
  const float* px = inp + (size_t)b * DD * NN;
  float qx = px[qn], qy = px[NN + qn], qz = px[2 * NN + qn];
  {
    int cnt = 0;
    #pragma unroll
    for (int i = 0; i < 4; ++i) {
      int n = w * 256 + i * 64 + lane;
      float dx = px[n] - qx, dy = px[NN + n] - qy, dz = px[2 * NN + n] - qz;
      bool flag = (dx * dx + dy * dy + dz * dz <= R2);
      unsigned long long m = __ballot(flag);
      int pos = cnt + __popcll(m & ((1ull << lane) - 1ull));
      if (flag && pos < NSAMP) swave[w * 64 + pos] = n;
      cnt += (int)__popcll(m);
    }
    if (lane == 0) scnt[w] = cnt < NSAMP ? cnt : NSAMP;
  }
  __syncthreads();
  if (t < NSAMP) {
    int run = 0, val = -1;
    #pragma unroll
    for (int ww = 0; ww < 8; ++ww) {
      int c = scnt[ww];
      int loc = t - run;
      if (loc >= 0 && loc < c) val = swave[ww * 64 + loc];
      run += c;
    }
    gidx[t] = val;
  }
  __syncthreads();
  if (t < NSAMP) {
    int g0 = gidx[0];
    int gt = gidx[t];
    gidx[t] = (gt < 0) ? g0 : gt;
  }
  __syncthreads();
  if (t < 65 * DD) {
    int p = t / DD, d = t - p * DD;
    int n = (p == 0) ? qn : gidx[p - 1];
    gsh[t] = px[d * NN + n];
  }
  __syncthreads();
  {
    int c = t >> 2, part = t & 3;
    const float2* wr = (const float2*)(w0 + c * 390 + part * 98);
    const float2* gr = (const float2*)(gsh + part * 98);
    int n2 = (part == 3) ? 48 : 49;
    float s = 0.f;
    #pragma unroll 7
    for (int i = 0; i < n2; ++i) {
      float2 a = gr[i], ww = wr[i];
      s += a.x * ww.x + a.y * ww.y;
    }
    s += __shfl_xor(s, 1);
    s += __shfl_xor(s, 2);
    if (part == 0) {
      s += b0[c];
      float sc = bn0[c] * rsqrtf(bn0[384 + c] + EPSF);
      s = (s - bn0[256 + c]) * sc + bn0[128 + c];
      r0[c] = fmaxf(s, 0.f);
    }
  }
  __syncthreads();
  {
    int c = t >> 1, part = t & 1;
    const float4* wr = (const float4*)(w1 + c * 128 + part * 64);
    const float4* rr = (const float4*)(r0 + part * 64);
    float s0 = 0.f, s1 = 0.f, s2 = 0.f, s3 = 0.f;
    #pragma unroll 8
    for (int o = 0; o < 16; ++o) {
      float4 a = rr[o], ww = wr[o];
      s0 += a.x * ww.x; s1 += a.y * ww.y; s2 += a.z * ww.z; s3 += a.w * ww.w;
    }
    float s = (s0 + s1) + (s2 + s3);
    s += __shfl_xor(s, 1);
    if (part == 0) {
      s += b1[c];
      float sc = bn1[c] * rsqrtf(bn1[768 + c] + EPSF);
      s = (s - bn1[512 + c]) * sc + bn1[256 + c];
      r1[c] = fmaxf(s, 0.f);
    }
  }
  __syncthreads();
  {
    int c = z * 256 + (t >> 1), part = t & 1;
    const float4* wr = (const float4*)(w2 + c * 256 + part * 128);
    const float4* rr = (const float4*)(r1 + part * 128);
    float s0 = 0.f, s1 = 0.f, s2 = 0.f, s3 = 0.f;
    #pragma unroll 8
    for (int o = 0; o < 32; ++o) {
      float4 a = rr[o], ww = wr[o];
      s0 += a.x * ww.x; s1 += a.y * ww.y; s2 += a.z * ww.z; s3 += a.w * ww.w;
    }
    float s = (s0 + s1) + (s2 + s3);
    s += __shfl_xor(s, 1);
    if (part == 0) {
      s += b2[c];
      float sc = bn2[c] * rsqrtf(bn2[1536 + c] + EPSF);
      s = (s - bn2[1024 + c]) * sc + bn2[512 + c];
      r2g[b * 8192 + c * TOPK + k] = fmaxf(s, 0.f);
    }
  }
}

// ------- FC layer 1: batched GEMV, split-K 8 ----
__global__ void __launch_bounds__(256)
k_fl2(const float* __restrict__ hin, const float* __restrict__ w,
      float* __restrict__ part) {
  __shared__ float hs[8 * 1032];
  int j0 = blockIdx.x * 16;
  int kc = blockIdx.y * 1024;
  int t = threadIdx.x;
  int jj = t >> 4, l = t & 15;
  #pragma unroll
  for (int i = 0; i < 8; ++i) {
    int idx = t + i * 256;
    int b = idx >> 8, off = (idx & 255) * 4;
    *(float4*)(hs + b * 1032 + off) = *(const float4*)(hin + (size_t)b * 8192 + kc + off);
  }
  __syncthreads();
  const float* wr = w + (size_t)(j0 + jj) * 8192 + kc;
  float acc[8] = {};
  #pragma unroll
  for (int k = 0; k < 16; ++k) {
    float4 wv = *(const float4*)(wr + l * 4 + k * 64);
    #pragma unroll
    for (int b = 0; b < 8; ++b) {
      float4 hv = *(const float4*)(hs + b * 1032 + l * 4 + k * 64);
      acc[b] += wv.x * hv.x + wv.y * hv.y + wv.z * hv.z + wv.w * hv.w;
    }
  }
  #pragma unroll
  for (int b = 0; b < 8; ++b) {
    #pragma unroll
    for (int off = 1; off < 16; off <<= 1) acc[b] += __shfl_xor(acc[b], off);
  }
  if (l == 0) {
    #pragma unroll
    for (int b = 0; b < 8; ++b)
      part[((size_t)blockIdx.y * 8 + b) * 1024 + j0 + jj] = acc[b];
  }
}

// ------- combine 8 split-K partials + bias + BN + ReLU -> h1g ----
__global__ void k_flc(const float* __restrict__ part, const float* __restrict__ bias,
                      const float* __restrict__ bn, float* __restrict__ hout) {
  int i = blockIdx.x * 256 + threadIdx.x;  // 0..8191
  int b = i >> 10, j = i & 1023;
  float s = bias[j];
  #pragma unroll
  for (int ks = 0; ks < 8; ++ks) s += part[((size_t)ks * 8 + b) * 1024 + j];
  float sc = bn[j] * rsqrtf(bn[3 * 1024 + j] + EPSF);
  s = (s - bn[2 * 1024 + j]) * sc + bn[1024 + j];
  hout[i] = fmaxf(s, 0.f);
}

// ------- FC layer 2: batched GEMV, split-K 4 ----
__global__ void __launch_bounds__(256)
k_fl3(const float* __restrict__ hin, const float* __restrict__ w,
      float* __restrict__ part) {
  __shared__ float hs[8 * 264];
  int j0 = blockIdx.x * 16;
  int kc = blockIdx.y * 256;
  int t = threadIdx.x;
  int jj = t >> 4, l = t & 15;
  #pragma unroll
  for (int i = 0; i < 2; ++i) {
    int idx = t + i * 256;
    int b = idx >> 6, off = (idx & 63) * 4;
    *(float4*)(hs + b * 264 + off) = *(const float4*)(hin + (size_t)b * 1024 + kc + off);
  }
  __syncthreads();
  const float* wr = w + (size_t)(j0 + jj) * 1024 + kc;
  float acc[8] = {};
  #pragma unroll
  for (int k = 0; k < 4; ++k) {
    float4 wv = *(const float4*)(wr + l * 4 + k * 64);
    #pragma unroll
    for (int b = 0; b < 8; ++b) {
      float4 hv = *(const float4*)(hs + b * 264 + l * 4 + k * 64);
      acc[b] += wv.x * hv.x + wv.y * hv.y + wv.z * hv.z + wv.w * hv.w;
    }
  }
  #pragma unroll
  for (int b = 0; b < 8; ++b) {
    #pragma unroll
    for (int off = 1; off < 16; off <<= 1) acc[b] += __shfl_xor(acc[b], off);
  }
  if (l == 0) {
    #pragma unroll
    for (int b = 0; b < 8; ++b)
      part[((size_t)blockIdx.y * 8 + b) * 512 + j0 + jj] = acc[b];
  }
}

// ------- combine 4 split-K partials + bias + BN + ReLU -> out ----
__global__ void k_flc2(const float* __restrict__ part, const float* __restrict__ bias,
                       const float* __restrict__ bn, float* __restrict__ hout) {
  int i = blockIdx.x * 256 + threadIdx.x;  // 0..4095
  int b = i >> 9, j = i & 511;
  float s = bias[j];
  #pragma unroll
  for (int ks = 0; ks < 4; ++ks) s += part[((size_t)ks * 8 + b) * 512 + j];
  float sc = bn[j] * rsqrtf(bn[3 * 512 + j] + EPSF);
  s = (s - bn[2 * 512 + j]) * sc + bn[512 + j];
  hout[i] = fmaxf(s, 0.f);
}

extern "C" void kernel_launch(void* const* d_in, const int* in_sizes, int n_in,
                              void* d_out, int out_size, void* d_ws, size_t ws_size,
                              hipStream_t stream) {
  const float* sv      = (const float*)d_in[0];
  const float* inp     = (const float*)d_in[1];
  const float* tl_win  = (const float*)d_in[2];
  const float* tl_bin  = (const float*)d_in[3];
  const float* tl_wout = (const float*)d_in[4];
  const float* tl_bout = (const float*)d_in[5];
  const float* tl_w1   = (const float*)d_in[6];
  const float* tl_b1   = (const float*)d_in[7];
  const float* tl_w2   = (const float*)d_in[8];
  const float* tl_b2   = (const float*)d_in[9];
  const float* tl_ln1g = (const float*)d_in[10];
  const float* tl_ln1b = (const float*)d_in[11];
  const float* tl_ln2g = (const float*)d_in[12];
  const float* tl_ln2b = (const float*)d_in[13];
  const float* fg_w0   = (const float*)d_in[14];
  const float* fg_b0   = (const float*)d_in[15];
  const float* fg_w1   = (const float*)d_in[16];
  const float* fg_b1   = (const float*)d_in[17];
  const float* fg_w2   = (const float*)d_in[18];
  const float* fg_b2   = (const float*)d_in[19];
  const float* fbn0    = (const float*)d_in[20];
  const float* fbn1    = (const float*)d_in[21];
  const float* fbn2    = (const float*)d_in[22];
  const float* rc_w0   = (const float*)d_in[23];
  const float* rc_b0   = (const float*)d_in[24];
  const float* rc_w1   = (const float*)d_in[25];
  const float* rc_b1   = (const float*)d_in[26];
  const float* rc_w2   = (const float*)d_in[27];
  const float* rc_b2   = (const float*)d_in[28];
  const float* rbn0    = (const float*)d_in[29];
  const float* rbn1    = (const float*)d_in[30];
  const float* rbn2    = (const float*)d_in[31];
  const float* fl_w0   = (const float*)d_in[32];
  const float* fl_b0   = (const float*)d_in[33];
  const float* fl_w1   = (const float*)d_in[34];
  const float* fl_b1   = (const float*)d_in[35];
  const float* lbn0    = (const float*)d_in[36];
  const float* lbn1    = (const float*)d_in[37];
  (void)in_sizes; (void)n_in; (void)out_size; (void)ws_size;

  float* wsp = (float*)d_ws;
  float* x      = wsp;                        // B*N*F      = 1048576
  float* qkv    = x + BB * NN * FF;           // 3145728-float region
  float* a      = qkv + BB * NN * 192;        // B*N*F      = 1048576
  float* scores = a + BB * NN * FF;           // B*N        = 16384
  int*   idxb   = (int*)(scores + BB * NN);   // B*TOPK     = 128
  float* r2g    = (float*)(idxb + BB * TOPK); // B*8192     = 65536
  float* h1g    = r2g + BB * 8192;            // B*1024     = 8192
  // FFN weight image: [l][chg][4 planes][4096 u16] = 1M u16 = 2MB
  unsigned short* img = (unsigned short*)(h1g + BB * 1024);
  // qkv region carve-out: Q fp32 (1M floats) | kp bf16 (1M u16) | vp bf16 (1M u16)
  float* qbuf = qkv;
  unsigned short* kp = (unsigned short*)(qkv + BB * NN * FF);
  unsigned short* vp = kp + (size_t)BB * NHEAD * NN * HD;
  float* part = qkv;        // FFN & FC-1 split-K partials reuse qkv region
  float* part2 = qkv + 65536;  // FC-2 partials (4*8*512 floats)

  float* out = (float*)d_out;  // fp32: h at [0,4096), idx-as-float at [4096,4224)

  k_transpose<<<(BB * NN * FF) / 256, 256, 0, stream>>>(sv, x);
  k_wimg<<<(NLAYER * 32 * 4 * 4096) / 256, 256, 0, stream>>>(tl_w1, tl_w2, img);

  for (int l = 0; l < NLAYER; ++l) {
    k_qkv3<<<dim3(BB * NN / 64, 3), 256, 0, stream>>>(x, tl_win + l * 192 * FF,
                                                      tl_bin + l * 192, qbuf,
                                                      (uint4*)kp, (uint4*)vp);
    k_attn10<<<dim3(NN / 64, NHEAD, BB), 256, 0, stream>>>(qbuf, (const uint4*)kp,
                                                           (const unsigned*)vp, a);
    k_proj2<<<BB * NN / 64, 256, 0, stream>>>(a, tl_wout + l * FF * FF, tl_bout + l * FF,
                                              tl_ln1g + l * FF, tl_ln1b + l * FF, x);
    k_ffn7<<<dim3(BB * NN / 128, 4), 256, 0, stream>>>(x, (const char*)(img + (size_t)l * 524288),
                                                       tl_b1 + l * 2048, part);
    k_ffn_ln<<<BB * NN / 4, 256, 0, stream>>>(part, tl_b2 + l * FF,
                                              tl_ln2g + l * FF, tl_ln2b + l * FF, x);
  }

  k_fg2<<<BB * NN / 64, 256, 0, stream>>>(x, fg_w0, fg_b0, fbn0, fg_w1, fg_b1, fbn1,
                                          fg_w2, fg_b2, fbn2, scores);
  k_topk2<<<BB, 256, 0, stream>>>(scores, idxb, out + BB * 512);
  k_group<<<dim3(TOPK, BB, 2), 512, 0, stream>>>(inp, idxb, rc_w0, rc_b0, rbn0,
                                                 rc_w1, rc_b1, rbn1, rc_w2, rc_b2, rbn2, r2g);
  k_fl2<<<dim3(64, 8), 256, 0, stream>>>(r2g, fl_w0, part);
  k_flc<<<32, 256, 0, stream>>>(part, fl_b0, lbn0, h1g);
  k_fl3<<<dim3(32, 4), 256, 0, stream>>>(h1g, fl_w1, part2);
  k_flc2<<<16, 256, 0, stream>>>(part2, fl_b1, lbn1, out);
}

// Round 10
// 419.238 us; speedup vs baseline: 1.7814x; 1.0124x over previous
//
#include <hip/hip_runtime.h>
#include <hip/hip_bf16.h>
#include <math.h>

#define BB 8
#define NN 2048
#define FF 64
#define DD 6
#define NSAMP 64
#define TOPK 16
#define NHEAD 8
#define HD 8
#define NLAYER 2
#define EPSF 1e-5f
#define R2 0.09f

typedef short short8 __attribute__((ext_vector_type(8)));
typedef float f32x4 __attribute__((ext_vector_type(4)));
typedef unsigned uint4v __attribute__((ext_vector_type(4)));
typedef unsigned int u32;

// split-pack: u32 = (bf16_hi << 16) | bf16_lo, both RNE. x ≈ hi + lo, err ~2^-16 rel.
__device__ inline unsigned pk2(float x) {
  unsigned b = __float_as_uint(x);
  unsigned hi = (b + 0x7fffu + ((b >> 16) & 1u)) >> 16;
  float r = x - __uint_as_float(hi << 16);
  unsigned c = __float_as_uint(r);
  unsigned lo = (c + 0x7fffu + ((c >> 16) & 1u)) >> 16;
  return (hi << 16) | lo;
}

__device__ inline unsigned short bf16r(float x) {  // RNE bf16
  unsigned b = __float_as_uint(x);
  return (unsigned short)((b + 0x7fffu + ((b >> 16) & 1u)) >> 16);
}

// async global->LDS, 16B per lane (dest = wave-uniform base + lane*16)
__device__ __forceinline__ void gl16(const void* g, void* l) {
  __builtin_amdgcn_global_load_lds((const __attribute__((address_space(1))) u32*)g,
                                   (__attribute__((address_space(3))) u32*)l, 16, 0, 0);
}

// ---------------- transpose sortvec (B,1,F,N) -> x (B,N,F) ----------------
__global__ void k_transpose(const float* __restrict__ sv, float* __restrict__ x) {
  int i = blockIdx.x * 256 + threadIdx.x;
  if (i >= BB * NN * FF) return;
  int f = i % FF;
  int n = (i / FF) % NN;
  int b = i / (FF * NN);
  x[i] = sv[(b * FF + f) * NN + n];
}

// ---- pack FFN weights into the exact per-chunk LDS byte image (pre-swizzled).
__global__ void k_wimg(const float* __restrict__ w1, const float* __restrict__ w2,
                       unsigned short* __restrict__ img) {
  int i = blockIdx.x * 256 + threadIdx.x;     // u16 index, total 2*32*4*4096
  int e = i & 4095;
  int plane = (i >> 12) & 3;
  int chg = (i >> 14) & 31;
  int l = i >> 19;
  int r = e >> 6, sh = (e >> 3) & 7, inner = e & 7;
  int s = sh ^ (r & 7);
  float v;
  if (plane < 2) v = w1[((size_t)(l * 2048 + chg * 64 + r)) * 64 + s * 8 + inner];
  else           v = w2[((size_t)(l * 64 + r)) * 2048 + chg * 64 + s * 8 + inner];
  unsigned p = pk2(v);
  img[i] = (unsigned short)((plane & 1) ? (p & 0xffffu) : (p >> 16));
}

// ---- qkv v3: tiled GEMM; epilogue routes per blockIdx.y ----
__global__ void k_qkv3(const float* __restrict__ x, const float* __restrict__ win,
                       const float* __restrict__ bin, float* __restrict__ qbuf,
                       uint4* __restrict__ kp4, uint4* __restrict__ vp4) {
  __shared__ float xs[64 * 68];
  __shared__ float ws[64 * 68];
  int row0 = blockIdx.x * 64, y = blockIdx.y, col0 = y * 64;
  int t = threadIdx.x;
  #pragma unroll
  for (int i = 0; i < 4; ++i) {
    int q = t + i * 256, r = q >> 4, c = (q & 15) * 4;
    *(float4*)(xs + r * 68 + c) = *(const float4*)(x + (size_t)(row0 + r) * 64 + c);
    *(float4*)(ws + r * 68 + c) = *(const float4*)(win + (size_t)(col0 + r) * 64 + c);
  }
  __syncthreads();
  int tx = t & 15, ty = t >> 4;
  float acc[4][4] = {};
  for (int f = 0; f < 64; f += 4) {
    float4 xv[4], wv[4];
    #pragma unroll
    for (int ri = 0; ri < 4; ++ri) xv[ri] = *(const float4*)(xs + (ty * 4 + ri) * 68 + f);
    #pragma unroll
    for (int ci = 0; ci < 4; ++ci) wv[ci] = *(const float4*)(ws + (tx + 16 * ci) * 68 + f);
    #pragma unroll
    for (int ri = 0; ri < 4; ++ri)
      #pragma unroll
      for (int ci = 0; ci < 4; ++ci)
        acc[ri][ci] += xv[ri].x * wv[ci].x + xv[ri].y * wv[ci].y +
                       xv[ri].z * wv[ci].z + xv[ri].w * wv[ci].w;
  }
  int b = row0 >> 11, n0 = row0 & (NN - 1);
  if (y == 0) {
    #pragma unroll
    for (int ri = 0; ri < 4; ++ri)
      #pragma unroll
      for (int ci = 0; ci < 4; ++ci) {
        int r = row0 + ty * 4 + ri, c = tx + 16 * ci;
        qbuf[(size_t)r * 64 + c] = acc[ri][ci] + bin[c];
      }
    return;
  }
  __syncthreads();  // all GEMM reads of xs done before reuse
  unsigned short* l16 = (unsigned short*)xs;  // 64x72 u16 tile
  if (y == 1) {
    #pragma unroll
    for (int ri = 0; ri < 4; ++ri)
      #pragma unroll
      for (int ci = 0; ci < 4; ++ci) {
        int r = ty * 4 + ri, c = tx + 16 * ci;
        l16[r * 72 + c] = bf16r(acc[ri][ci] + bin[64 + c]);
      }
    __syncthreads();
    #pragma unroll
    for (int i = 0; i < 2; ++i) {
      int idx = t + i * 256;
      int h = idx >> 6, tok = idx & 63;
      uint4 v = *(const uint4*)(l16 + tok * 72 + h * 8);
      kp4[(size_t)(b * NHEAD + h) * NN + n0 + tok] = v;
    }
  } else {
    #pragma unroll
    for (int ri = 0; ri < 4; ++ri)
      #pragma unroll
      for (int ci = 0; ci < 4; ++ci) {
        int r = ty * 4 + ri, c = tx + 16 * ci;
        l16[c * 72 + r] = bf16r(acc[ri][ci] + bin[128 + c]);  // transposed
      }
    __syncthreads();
    #pragma unroll
    for (int i = 0; i < 2; ++i) {
      int idx = t + i * 256;
      int c = idx >> 3, seg = idx & 7;
      uint4 v = *(const uint4*)(l16 + c * 72 + seg * 8);
      vp4[(size_t)(b * 64 + c) * (NN / 8) + (n0 >> 3) + seg] = v;
    }
  }
}

// ---- attention v11: swapped-operand flash. vs v10: the P redistribution now
// pairs lane l with l^32 so it runs on v_permlane32_swap_b32 (VALU, 2 cyc)
// instead of 4x ds_swizzle (LDS pipe, ~30cyc lgkmcnt on the critical path).
// swap(pk0,pk2) outputs ARE bw[0]/bw[2] for every lane (no selects):
//   ret0 = {lo: own pk0, hi: partner-lo pk2}; ret1 = {lo: partner-hi pk0, hi: own pk2}
// Key->k-slot map: lq0:{0-3,8-11} lq1:{4-7,12-15} lq2:{16-19,24-27} lq3:{20-23,28-31};
// aV reads the matching V keys via off1=(lq&1)*4+(lq>>1)*16, off2=off1+8.
__global__ void __launch_bounds__(256, 8)
k_attn11(const float* __restrict__ q, const uint4* __restrict__ kp4,
         const unsigned* __restrict__ vp32, float* __restrict__ a) {
  __shared__ uint4 kb4[256];                                            // 4 KB
  __shared__ __attribute__((aligned(16))) unsigned short vb16[9 * 264]; // 4.6 KB
  int t = threadIdx.x;
  int lane = t & 63, w = t >> 6;
  int nIdx = lane & 15, lq = lane >> 4;
  int h = blockIdx.y, b = blockIdx.z;
  int qwb = blockIdx.x * 64 + w * 16;
  int bh = b * NHEAD + h;
  const float kf = 0.35355339059327373f * 1.4426950408889634f;  // scale*log2e
  short8 qF = {0, 0, 0, 0, 0, 0, 0, 0};
  if (lq == 0) {
    const float* qr = q + ((size_t)(b * NN + qwb + nIdx)) * 64 + h * HD;
    #pragma unroll
    for (int j = 0; j < 8; ++j) qF[j] = (short)bf16r(qr[j] * kf);
  }
  f32x4 acc0 = {0.f, 0.f, 0.f, 0.f};
  f32x4 acc1 = {0.f, 0.f, 0.f, 0.f};
  const uint4* kbase = kp4 + (size_t)bh * NN;
  const unsigned* vbase = vp32 + (size_t)bh * HD * (NN / 2);
  int vn = nIdx < 9 ? nIdx : 8;
  int voff = ((lq & 1) << 2) + ((lq >> 1) << 4);  // key-group base per quad
  if (t < 132) ((unsigned*)(vb16 + 8 * 264))[t] = 0x3f803f80u;
  uint4 kreg = kbase[t];
  unsigned vreg[4];
  #pragma unroll
  for (int i = 0; i < 4; ++i) {
    int g = t + i * 256;
    vreg[i] = vbase[(g >> 7) * (NN / 2) + (g & 127)];
  }
  for (int kc = 0; kc < NN; kc += 256) {
    __syncthreads();
    kb4[t] = kreg;
    #pragma unroll
    for (int i = 0; i < 4; ++i) {
      int g = t + i * 256;
      ((unsigned*)vb16)[(g >> 7) * 132 + (g & 127)] = vreg[i];
    }
    __syncthreads();
    if (kc + 256 < NN) {
      kreg = kbase[kc + 256 + t];
      #pragma unroll
      for (int i = 0; i < 4; ++i) {
        int g = t + i * 256;
        vreg[i] = vbase[(g >> 7) * (NN / 2) + ((kc + 256) >> 1) + (g & 127)];
      }
    }
    #pragma unroll
    for (int s = 0; s < 8; ++s) {
      int kb = s * 32;
      unsigned pk_[4];
      #pragma unroll
      for (int half = 0; half < 2; ++half) {
        int key = kb + half * 16 + nIdx;
        short8 aK = *(const short8*)(kb4 + key);  // unmasked: k>=8 lanes * 0
        f32x4 c = {0.f, 0.f, 0.f, 0.f};
        __builtin_amdgcn_s_setprio(1);
        c = __builtin_amdgcn_mfma_f32_16x16x32_bf16(aK, qF, c, 0, 0, 0);
        __builtin_amdgcn_s_setprio(0);
        float p0 = __builtin_amdgcn_exp2f(c[0]);
        float p1 = __builtin_amdgcn_exp2f(c[1]);
        float p2 = __builtin_amdgcn_exp2f(c[2]);
        float p3 = __builtin_amdgcn_exp2f(c[3]);
        unsigned r0, r1;
        asm("v_cvt_pk_bf16_f32 %0, %1, %2" : "=v"(r0) : "v"(p0), "v"(p1));
        asm("v_cvt_pk_bf16_f32 %0, %1, %2" : "=v"(r1) : "v"(p2), "v"(p3));
        pk_[half * 2]     = r0;
        pk_[half * 2 + 1] = r1;
      }
      // cross-half exchange on the VALU: dst upper <-> src lower
      unsigned a02 = pk_[0], b02 = pk_[2];
      unsigned a13 = pk_[1], b13 = pk_[3];
      asm("v_permlane32_swap_b32 %0, %1" : "+v"(a02), "+v"(b02));
      asm("v_permlane32_swap_b32 %0, %1" : "+v"(a13), "+v"(b13));
      uint4v bw;
      bw[0] = a02;  // lo: own pk0     | hi: partner pk2
      bw[1] = a13;  // lo: own pk1     | hi: partner pk3
      bw[2] = b02;  // lo: partner pk0 | hi: own pk2
      bw[3] = b13;  // lo: partner pk1 | hi: own pk3
      short8 bP = *(short8*)&bw;
      int vo = vn * 264 + kb + voff;
      uint2 v0 = *(const uint2*)(vb16 + vo);
      uint2 v1 = *(const uint2*)(vb16 + vo + 8);
      uint4v av;
      av[0] = v0.x; av[1] = v0.y; av[2] = v1.x; av[3] = v1.y;
      short8 aV = *(short8*)&av;
      __builtin_amdgcn_s_setprio(1);
      if (s & 1) acc1 = __builtin_amdgcn_mfma_f32_16x16x32_bf16(aV, bP, acc1, 0, 0, 0);
      else       acc0 = __builtin_amdgcn_mfma_f32_16x16x32_bf16(aV, bP, acc0, 0, 0, 0);
      __builtin_amdgcn_s_setprio(0);
    }
  }
  f32x4 acc;
  acc[0] = acc0[0] + acc1[0];
  acc[1] = acc0[1] + acc1[1];
  acc[2] = acc0[2] + acc1[2];
  acc[3] = acc0[3] + acc1[3];
  float lr = __shfl(acc[0], 32 + nIdx);
  if (lq < 2) {
    int row = qwb + nIdx;
    float4 o;
    o.x = acc[0] / lr; o.y = acc[1] / lr; o.z = acc[2] / lr; o.w = acc[3] / lr;
    *(float4*)(a + ((size_t)(b * NN + row)) * 64 + h * HD + lq * 4) = o;
  }
}

// ------- proj + residual + LN, tiled GEMM ---------
__global__ void k_proj2(const float* __restrict__ a, const float* __restrict__ wout,
                        const float* __restrict__ bout, const float* __restrict__ g,
                        const float* __restrict__ be, float* __restrict__ x) {
  __shared__ float xs[64 * 68];
  __shared__ float ws[64 * 68];
  int row0 = blockIdx.x * 64;
  int t = threadIdx.x;
  #pragma unroll
  for (int i = 0; i < 4; ++i) {
    int q = t + i * 256, r = q >> 4, c = (q & 15) * 4;
    *(float4*)(xs + r * 68 + c) = *(const float4*)(a + (size_t)(row0 + r) * 64 + c);
    *(float4*)(ws + r * 68 + c) = *(const float4*)(wout + r * 64 + c);
  }
  __syncthreads();
  int tx = t & 15, ty = t >> 4;
  float acc[4][4] = {};
  for (int f = 0; f < 64; f += 4) {
    float4 xv[4], wv[4];
    #pragma unroll
    for (int ri = 0; ri < 4; ++ri) xv[ri] = *(const float4*)(xs + (ty * 4 + ri) * 68 + f);
    #pragma unroll
    for (int ci = 0; ci < 4; ++ci) wv[ci] = *(const float4*)(ws + (tx + 16 * ci) * 68 + f);
    #pragma unroll
    for (int ri = 0; ri < 4; ++ri)
      #pragma unroll
      for (int ci = 0; ci < 4; ++ci)
        acc[ri][ci] += xv[ri].x * wv[ci].x + xv[ri].y * wv[ci].y +
                       xv[ri].z * wv[ci].z + xv[ri].w * wv[ci].w;
  }
  #pragma unroll
  for (int ri = 0; ri < 4; ++ri) {
    int rl = ty * 4 + ri;
    float val[4], s = 0.f, sq = 0.f;
    #pragma unroll
    for (int ci = 0; ci < 4; ++ci) {
      int c = tx + 16 * ci;
      val[ci] = x[(size_t)(row0 + rl) * 64 + c] + bout[c] + acc[ri][ci];
      s += val[ci]; sq += val[ci] * val[ci];
    }
    #pragma unroll
    for (int off = 1; off < 16; off <<= 1) { s += __shfl_xor(s, off); sq += __shfl_xor(sq, off); }
    float mean = s * (1.f / 64.f);
    float var = sq * (1.f / 64.f) - mean * mean;
    float rstd = rsqrtf(var + EPSF);
    #pragma unroll
    for (int ci = 0; ci < 4; ++ci) {
      int c = tx + 16 * ci;
      x[(size_t)(row0 + rl) * 64 + c] = (val[ci] - mean) * rstd * g[c] + be[c];
    }
  }
}

// ------- FFN v7: global_load_lds staging, counted vmcnt, raw s_barriers ----
__global__ void __launch_bounds__(256, 2)
k_ffn7(const float* __restrict__ x, const char* __restrict__ img,
       const float* __restrict__ b1, float* __restrict__ part) {
  __shared__ __attribute__((aligned(16))) char W1b[2][16384];
  __shared__ __attribute__((aligned(16))) char W2b[16384];
  __shared__ __attribute__((aligned(16))) unsigned short hpl[2][128 * 64];
  int row0 = blockIdx.x * 128;
  int ks = blockIdx.y, kc = ks * 512;
  int t = threadIdx.x, lane = t & 63, wv = t >> 6;
  int lm = lane & 15, lq = lane >> 4;
  const char* ibase = img + (size_t)ks * 8 * 32768;

  short8 axh[2][2], axl[2][2];
  #pragma unroll
  for (int m = 0; m < 2; ++m)
    #pragma unroll
    for (int kbi = 0; kbi < 2; ++kbi) {
      const float* xr = x + (size_t)(row0 + m * 64 + wv * 16 + lm) * 64 + kbi * 32 + lq * 8;
      #pragma unroll
      for (int j = 0; j < 8; ++j) {
        unsigned p = pk2(xr[j]);
        axh[m][kbi][j] = (short)(p >> 16);
        axl[m][kbi][j] = (short)(p & 0xffffu);
      }
    }
  float bv[8][4];
  #pragma unroll
  for (int ch = 0; ch < 8; ++ch)
    #pragma unroll
    for (int tn = 0; tn < 4; ++tn)
      bv[ch][tn] = b1[kc + ch * 64 + tn * 16 + lm];
  asm volatile("s_waitcnt vmcnt(0)" ::: "memory");
  __builtin_amdgcn_sched_barrier(0);
  #pragma unroll
  for (int i = 0; i < 4; ++i)
    gl16(ibase + i * 4096 + t * 16, &W1b[0][i * 4096 + t * 16]);

  f32x4 acc[2][4];
  #pragma unroll
  for (int m = 0; m < 2; ++m)
    #pragma unroll
    for (int tn = 0; tn < 4; ++tn) acc[m][tn] = (f32x4){0.f, 0.f, 0.f, 0.f};

  #pragma unroll
  for (int ch = 0; ch < 8; ++ch) {
    const int p = ch & 1;
    const char* cbase = ibase + ch * 32768;
    #pragma unroll
    for (int i = 0; i < 4; ++i)
      gl16(cbase + 16384 + i * 4096 + t * 16, &W2b[i * 4096 + t * 16]);
    if (ch < 7) {
      #pragma unroll
      for (int i = 0; i < 4; ++i)
        gl16(cbase + 32768 + i * 4096 + t * 16, &W1b[p ^ 1][i * 4096 + t * 16]);
    }
    if (ch < 7) { asm volatile("s_waitcnt vmcnt(8)" ::: "memory"); }
    else        { asm volatile("s_waitcnt vmcnt(4)" ::: "memory"); }
    __builtin_amdgcn_sched_barrier(0);
    __builtin_amdgcn_s_barrier();
    __builtin_amdgcn_sched_barrier(0);
    const char* P0h = W1b[p];
    const char* P0l = W1b[p] + 8192;
    f32x4 h4[2][4];
    #pragma unroll
    for (int m = 0; m < 2; ++m)
      #pragma unroll
      for (int tn = 0; tn < 4; ++tn) h4[m][tn] = (f32x4){0.f, 0.f, 0.f, 0.f};
    #pragma unroll
    for (int kbi = 0; kbi < 2; ++kbi) {
      int sw = (((kbi * 4 + lq) ^ (lm & 7)) << 4);
      #pragma unroll
      for (int tn = 0; tn < 4; ++tn) {
        int brow = tn * 16 + lm;
        short8 bhi = *(const short8*)(P0h + brow * 128 + sw);
        short8 blo = *(const short8*)(P0l + brow * 128 + sw);
        #pragma unroll
        for (int m = 0; m < 2; ++m) {
          h4[m][tn] = __builtin_amdgcn_mfma_f32_16x16x32_bf16(axh[m][kbi], bhi, h4[m][tn], 0, 0, 0);
          h4[m][tn] = __builtin_amdgcn_mfma_f32_16x16x32_bf16(axh[m][kbi], blo, h4[m][tn], 0, 0, 0);
          h4[m][tn] = __builtin_amdgcn_mfma_f32_16x16x32_bf16(axl[m][kbi], bhi, h4[m][tn], 0, 0, 0);
        }
      }
    }
    #pragma unroll
    for (int m = 0; m < 2; ++m)
      #pragma unroll
      for (int tn = 0; tn < 4; ++tn)
        #pragma unroll
        for (int r = 0; r < 4; ++r) {
          float hv = fmaxf(h4[m][tn][r] + bv[ch][tn], 0.f);
          unsigned u = __float_as_uint(hv);
          float resid = hv - __uint_as_float(u & 0xffff0000u);
          unsigned c2 = __float_as_uint(resid);
          int hrow = m * 64 + wv * 16 + lq * 4 + r, hcol = tn * 16 + lm;
          int off = hrow * 128 + (((hcol >> 3) ^ (hrow & 7)) << 4) + ((hcol & 7) << 1);
          *(unsigned short*)((char*)hpl[0] + off) = (unsigned short)(u >> 16);
          *(unsigned short*)((char*)hpl[1] + off) =
              (unsigned short)((c2 + 0x7fffu + ((c2 >> 16) & 1u)) >> 16);
        }
    if (ch < 7) { asm volatile("s_waitcnt vmcnt(4)" ::: "memory"); }
    else        { asm volatile("s_waitcnt vmcnt(0)" ::: "memory"); }
    __builtin_amdgcn_sched_barrier(0);
    __builtin_amdgcn_s_barrier();
    __builtin_amdgcn_sched_barrier(0);
    const char* P1h = W2b;
    const char* P1l = W2b + 8192;
    #pragma unroll
    for (int kbi = 0; kbi < 2; ++kbi) {
      short8 a2h[2], a2l[2];
      #pragma unroll
      for (int m = 0; m < 2; ++m) {
        int arow = m * 64 + wv * 16 + lm;
        int swa = (((kbi * 4 + lq) ^ (arow & 7)) << 4);
        a2h[m] = *(const short8*)((const char*)hpl[0] + arow * 128 + swa);
        a2l[m] = *(const short8*)((const char*)hpl[1] + arow * 128 + swa);
      }
      int swb = (((kbi * 4 + lq) ^ (lm & 7)) << 4);
      #pragma unroll
      for (int tn = 0; tn < 4; ++tn) {
        int brow = tn * 16 + lm;
        short8 bhi = *(const short8*)(P1h + brow * 128 + swb);
        short8 blo = *(const short8*)(P1l + brow * 128 + swb);
        #pragma unroll
        for (int m = 0; m < 2; ++m) {
          acc[m][tn] = __builtin_amdgcn_mfma_f32_16x16x32_bf16(a2h[m], bhi, acc[m][tn], 0, 0, 0);
          acc[m][tn] = __builtin_amdgcn_mfma_f32_16x16x32_bf16(a2h[m], blo, acc[m][tn], 0, 0, 0);
          acc[m][tn] = __builtin_amdgcn_mfma_f32_16x16x32_bf16(a2l[m], bhi, acc[m][tn], 0, 0, 0);
        }
      }
    }
    __builtin_amdgcn_s_barrier();
    __builtin_amdgcn_sched_barrier(0);
  }
  float* fb = (float*)hpl;
  #pragma unroll
  for (int m = 0; m < 2; ++m)
    #pragma unroll
    for (int tn = 0; tn < 4; ++tn)
      #pragma unroll
      for (int r = 0; r < 4; ++r) {
        int row = m * 64 + wv * 16 + lq * 4 + r;
        int col = (tn * 16 + lm) ^ ((row & 7) << 2);
        fb[row * 64 + col] = acc[m][tn][r];
      }
  __syncthreads();
  float* pb = part + (size_t)ks * (BB * NN * 64);
  #pragma unroll
  for (int i = 0; i < 8; ++i) {
    int idx = t * 4 + i * 1024;
    int row = idx >> 6, c0 = idx & 63;
    int c0s = c0 ^ ((row & 7) << 2);
    float4 v = *(const float4*)(fb + row * 64 + c0s);
    *(float4*)(pb + (size_t)(row0 + row) * 64 + c0) = v;
  }
}

// ------- combine 4 partials + residual + b2 + LN; one wave per row ---------
__global__ void k_ffn_ln(const float* __restrict__ part, const float* __restrict__ b2,
                         const float* __restrict__ g, const float* __restrict__ be,
                         float* __restrict__ x) {
  int row = blockIdx.x * 4 + (threadIdx.x >> 6);
  int j = threadIdx.x & 63;
  size_t o = (size_t)row * 64 + j;
  const size_t S = (size_t)BB * NN * 64;
  float val = x[o] + b2[j] + ((part[o] + part[o + S]) + (part[o + 2 * S] + part[o + 3 * S]));
  float s = val;
  for (int off = 32; off; off >>= 1) s += __shfl_xor(s, off);
  s *= (1.f / 64.f);
  float d = val - s;
  float v = d * d;
  for (int off = 32; off; off >>= 1) v += __shfl_xor(v, off);
  v *= (1.f / 64.f);
  x[o] = d * rsqrtf(v + EPSF) * g[j] + be[j];
}

// ------- score head tiled ----------
__global__ void k_fg2(const float* __restrict__ x,
                      const float* __restrict__ w0, const float* __restrict__ b0, const float* __restrict__ bn0,
                      const float* __restrict__ w1, const float* __restrict__ b1, const float* __restrict__ bn1,
                      const float* __restrict__ w2, const float* __restrict__ b2, const float* __restrict__ bn2,
                      float* __restrict__ scores) {
  __shared__ float xs[64 * 68];
  __shared__ float ws[64 * 68];
  __shared__ float s0s[64 * 68];
  __shared__ float s1s[64 * 20];
  int row0 = blockIdx.x * 64;
  int t = threadIdx.x;
  #pragma unroll
  for (int i = 0; i < 4; ++i) {
    int q = t + i * 256, r = q >> 4, c = (q & 15) * 4;
    *(float4*)(xs + r * 68 + c) = *(const float4*)(x + (size_t)(row0 + r) * 64 + c);
    *(float4*)(ws + r * 68 + c) = *(const float4*)(w0 + r * 64 + c);
  }
  __syncthreads();
  int tx = t & 15, ty = t >> 4;
  float acc[4][4] = {};
  for (int f = 0; f < 64; f += 4) {
    float4 xv[4], wv[4];
    #pragma unroll
    for (int ri = 0; ri < 4; ++ri) xv[ri] = *(const float4*)(xs + (ty * 4 + ri) * 68 + f);
    #pragma unroll
    for (int ci = 0; ci < 4; ++ci) wv[ci] = *(const float4*)(ws + (tx + 16 * ci) * 68 + f);
    #pragma unroll
    for (int ri = 0; ri < 4; ++ri)
      #pragma unroll
      for (int ci = 0; ci < 4; ++ci)
        acc[ri][ci] += xv[ri].x * wv[ci].x + xv[ri].y * wv[ci].y +
                       xv[ri].z * wv[ci].z + xv[ri].w * wv[ci].w;
  }
  #pragma unroll
  for (int ri = 0; ri < 4; ++ri)
    #pragma unroll
    for (int ci = 0; ci < 4; ++ci) {
      int c = tx + 16 * ci;
      float sc = bn0[c] * rsqrtf(bn0[192 + c] + EPSF);
      float v = (acc[ri][ci] + b0[c] - bn0[128 + c]) * sc + bn0[64 + c];
      s0s[(ty * 4 + ri) * 68 + c] = fmaxf(v, 0.f);
    }
  __syncthreads();
  {
    int rl = t & 63, j0 = t >> 6;
    #pragma unroll
    for (int i = 0; i < 4; ++i) {
      int j = j0 + 4 * i;
      float s = b1[j];
      const float* wr = w1 + j * 64;
      #pragma unroll 16
      for (int c = 0; c < 64; ++c) s += s0s[rl * 68 + c] * wr[c];
      float sc = bn1[j] * rsqrtf(bn1[48 + j] + EPSF);
      s = (s - bn1[32 + j]) * sc + bn1[16 + j];
      s1s[rl * 20 + j] = fmaxf(s, 0.f);
    }
  }
  __syncthreads();
  if (t < 64) {
    float s = b2[0];
    #pragma unroll
    for (int o = 0; o < 16; ++o) s += s1s[t * 20 + o] * w2[o];
    float sc = bn2[0] * rsqrtf(bn2[3] + EPSF);
    s = (s - bn2[2]) * sc + bn2[1];
    scores[row0 + t] = fmaxf(s, 0.f);
  }
}

// ---- top-k (k=16) ----
__global__ void k_topk2(const float* __restrict__ scores, int* __restrict__ idx,
                        float* __restrict__ out_idx) {
  int b = blockIdx.x, t = threadIdx.x;
  float v[8];
  int base = b * NN;
  #pragma unroll
  for (int u = 0; u < 8; ++u) v[u] = scores[base + t + 256 * u];
  __shared__ float wvs[4];
  __shared__ int wis[4];
  __shared__ int winner;
  unsigned taken = 0;
  for (int r = 0; r < TOPK; ++r) {
    float best = -1e30f; int bi = 1 << 30;
    #pragma unroll
    for (int u = 0; u < 8; ++u) {
      if (!((taken >> u) & 1)) {
        float vv = v[u]; int ii = t + 256 * u;
        if (vv > best || (vv == best && ii < bi)) { best = vv; bi = ii; }
      }
    }
    for (int off = 32; off; off >>= 1) {
      float ov = __shfl_xor(best, off);
      int oi = __shfl_xor(bi, off);
      if (ov > best || (ov == best && oi < bi)) { best = ov; bi = oi; }
    }
    if ((t & 63) == 0) { wvs[t >> 6] = best; wis[t >> 6] = bi; }
    __syncthreads();
    if (t == 0) {
      float B = wvs[0]; int I = wis[0];
      #pragma unroll
      for (int q = 1; q < 4; ++q)
        if (wvs[q] > B || (wvs[q] == B && wis[q] < I)) { B = wvs[q]; I = wis[q]; }
      winner = I;
      idx[b * TOPK + r] = I;
      out_idx[b * TOPK + r] = (float)I;
    }
    __syncthreads();
    int w = winner;
    if ((w & 255) == t) taken |= 1u << (w >> 8);
  }
}

// ---------------- ball query + 3 conv stages; grid z=2 splits conv2. ----
__global__ void __launch_bounds__(512)
k_group(const float* __restrict__ inp, const int* __restrict__ idx,
        const float* __restrict__ w0, const float* __restrict__ b0, const float* __restrict__ bn0,
        const float* __restrict__ w1, const float* __restrict__ b1, const float* __restrict__ bn1,
        const float* __restrict__ w2, const float* __restrict__ b2, const float* __restrict__ bn2,
        float* __restrict__ r2g) {
  __shared__ int swave[8 * 64];
  __shared__ int scnt[8];
  __shared__ int gidx[NSAMP];
  __shared__ __attribute__((aligned(16))) float gsh[65 * DD];
  __shared__ __attribute__((aligned(16))) float r0[128];
  __shared__ __attribute__((aligned(16))) float r1[256];
  int k = blockIdx.x, b = blockIdx.y, z = blockIdx.z;
  int t = threadIdx.x;
  int lane = t & 63, w = t >> 6;
  int qn = idx[b * TOPK + k];
  const float* px = inp + (size_t)b * DD * NN;
  float qx = px[qn], qy = px[NN + qn], qz = px[2 * NN + qn];
  {
    int cnt = 0;
    #pragma unroll
    for (int i = 0; i < 4; ++i) {
      int n = w * 256 + i * 64 + lane;
      float dx = px[n] - qx, dy = px[NN + n] - qy, dz = px[2 * NN + n] - qz;
      bool flag = (dx * dx + dy * dy + dz * dz <= R2);
      unsigned long long m = __ballot(flag);
      int pos = cnt + __popcll(m & ((1ull << lane) - 1ull));
      if (flag && pos < NSAMP) swave[w * 64 + pos] = n;
      cnt += (int)__popcll(m);
    }
    if (lane == 0) scnt[w] = cnt < NSAMP ? cnt : NSAMP;
  }
  __syncthreads();
  if (t < NSAMP) {
    int run = 0, val = -1;
    #pragma unroll
    for (int ww = 0; ww < 8; ++ww) {
      int c = scnt[ww];
      int loc = t - run;
      if (loc >= 0 && loc < c) val = swave[ww * 64 + loc];
      run += c;
    }
    gidx[t] = val;
  }
  __syncthreads();
  if (t < NSAMP) {
    int g0 = gidx[0];
    int gt = gidx[t];
    gidx[t] = (gt < 0) ? g0 : gt;
  }
  __syncthreads();
  if (t < 65 * DD) {
    int p = t / DD, d = t - p * DD;
    int n = (p == 0) ? qn : gidx[p - 1];
    gsh[t] = px[d * NN + n];
  }
  __syncthreads();
  {
    int c = t >> 2, part = t & 3;
    const float2* wr = (const float2*)(w0 + c * 390 + part * 98);
    const float2* gr = (const float2*)(gsh + part * 98);
    int n2 = (part == 3) ? 48 : 49;
    float s = 0.f;
    #pragma unroll 7
    for (int i = 0; i < n2; ++i) {
      float2 a = gr[i], ww = wr[i];
      s += a.x * ww.x + a.y * ww.y;
    }
    s += __shfl_xor(s, 1);
    s += __shfl_xor(s, 2);
    if (part == 0) {
      s += b0[c];
      float sc = bn0[c] * rsqrtf(bn0[384 + c] + EPSF);
      s = (s - bn0[256 + c]) * sc + bn0[128 + c];
      r0[c] = fmaxf(s, 0.f);
    }
  }
  __syncthreads();
  {
    int c = t >> 1, part = t & 1;
    const float4* wr = (const float4*)(w1 + c * 128 + part * 64);
    const float4* rr = (const float4*)(r0 + part * 64);
    float s0 = 0.f, s1 = 0.f, s2 = 0.f, s3 = 0.f;
    #pragma unroll 8
    for (int o = 0; o < 16; ++o) {
      float4 a = rr[o], ww = wr[o];
      s0 += a.x * ww.x; s1 += a.y * ww.y; s2 += a.z * ww.z; s3 += a.w * ww.w;
    }
    float s = (s0 + s1) + (s2 + s3);
    s += __shfl_xor(s, 1);
    if (part == 0) {
      s += b1[c];
      float sc = bn1[c] * rsqrtf(bn1[768 + c] + EPSF);
      s = (s - bn1[512 + c]) * sc + bn1[256 + c];
      r1[c] = fmaxf(s, 0.f);
    }
  }
  __syncthreads();
  {
    int c = z * 256 + (t >> 1), part = t & 1;
    const float4* wr = (const float4*)(w2 + c * 256 + part * 128);
    const float4* rr = (const float4*)(r1 + part * 128);
    float s0 = 0.f, s1 = 0.f, s2 = 0.f, s3 = 0.f;
    #pragma unroll 8
    for (int o = 0; o < 32; ++o) {
      float4 a = rr[o], ww = wr[o];
      s0 += a.x * ww.x; s1 += a.y * ww.y; s2 += a.z * ww.z; s3 += a.w * ww.w;
    }
    float s = (s0 + s1) + (s2 + s3);
    s += __shfl_xor(s, 1);
    if (part == 0) {
      s += b2[c];
      float sc = bn2[c] * rsqrtf(bn2[1536 + c] + EPSF);
      s = (s - bn2[1024 + c]) * sc + bn2[512 + c];
      r2g[b * 8192 + c * TOPK + k] = fmaxf(s, 0.f);
    }
  }
}

// ------- FC layer 1: batched GEMV, split-K 8 ----
__global__ void __launch_bounds__(256)
k_fl2(const float* __restrict__ hin, const float* __restrict__ w,
      float* __restrict__ part) {
  __shared__ float hs[8 * 1032];
  int j0 = blockIdx.x * 16;
  int kc = blockIdx.y * 1024;
  int t = threadIdx.x;
  int jj = t >> 4, l = t & 15;
  #pragma unroll
  for (int i = 0; i < 8; ++i) {
    int idx = t + i * 256;
    int b = idx >> 8, off = (idx & 255) * 4;
    *(float4*)(hs + b * 1032 + off) = *(const float4*)(hin + (size_t)b * 8192 + kc + off);
  }
  __syncthreads();
  const float* wr = w + (size_t)(j0 + jj) * 8192 + kc;
  float acc[8] = {};
  #pragma unroll
  for (int k = 0; k < 16; ++k) {
    float4 wv = *(const float4*)(wr + l * 4 + k * 64);
    #pragma unroll
    for (int b = 0; b < 8; ++b) {
      float4 hv = *(const float4*)(hs + b * 1032 + l * 4 + k * 64);
      acc[b] += wv.x * hv.x + wv.y * hv.y + wv.z * hv.z + wv.w * hv.w;
    }
  }
  #pragma unroll
  for (int b = 0; b < 8; ++b) {
    #pragma unroll
    for (int off = 1; off < 16; off <<= 1) acc[b] += __shfl_xor(acc[b], off);
  }
  if (l == 0) {
    #pragma unroll
    for (int b = 0; b < 8; ++b)
      part[((size_t)blockIdx.y * 8 + b) * 1024 + j0 + jj] = acc[b];
  }
}

// ------- combine 8 split-K partials + bias + BN + ReLU -> h1g ----
__global__ void k_flc(const float* __restrict__ part, const float* __restrict__ bias,
                      const float* __restrict__ bn, float* __restrict__ hout) {
  int i = blockIdx.x * 256 + threadIdx.x;  // 0..8191
  int b = i >> 10, j = i & 1023;
  float s = bias[j];
  #pragma unroll
  for (int ks = 0; ks < 8; ++ks) s += part[((size_t)ks * 8 + b) * 1024 + j];
  float sc = bn[j] * rsqrtf(bn[3 * 1024 + j] + EPSF);
  s = (s - bn[2 * 1024 + j]) * sc + bn[1024 + j];
  hout[i] = fmaxf(s, 0.f);
}

// ------- FC layer 2: batched GEMV, split-K 4 ----
__global__ void __launch_bounds__(256)
k_fl3(const float* __restrict__ hin, const float* __restrict__ w,
      float* __restrict__ part) {
  __shared__ float hs[8 * 264];
  int j0 = blockIdx.x * 16;
  int kc = blockIdx.y * 256;
  int t = threadIdx.x;
  int jj = t >> 4, l = t & 15;
  #pragma unroll
  for (int i = 0; i < 2; ++i) {
    int idx = t + i * 256;
    int b = idx >> 6, off = (idx & 63) * 4;
    *(float4*)(hs + b * 264 + off) = *(const float4*)(hin + (size_t)b * 1024 + kc + off);
  }
  __syncthreads();
  const float* wr = w + (size_t)(j0 + jj) * 1024 + kc;
  float acc[8] = {};
  #pragma unroll
  for (int k = 0; k < 4; ++k) {
    float4 wv = *(const float4*)(wr + l * 4 + k * 64);
    #pragma unroll
    for (int b = 0; b < 8; ++b) {
      float4 hv = *(const float4*)(hs + b * 264 + l * 4 + k * 64);
      acc[b] += wv.x * hv.x + wv.y * hv.y + wv.z * hv.z + wv.w * hv.w;
    }
  }
  #pragma unroll
  for (int b = 0; b < 8; ++b) {
    #pragma unroll
    for (int off = 1; off < 16; off <<= 1) acc[b] += __shfl_xor(acc[b], off);
  }
  if (l == 0) {
    #pragma unroll
    for (int b = 0; b < 8; ++b)
      part[((size_t)blockIdx.y * 8 + b) * 512 + j0 + jj] = acc[b];
  }
}

// ------- combine 4 split-K partials + bias + BN + ReLU -> out ----
__global__ void k_flc2(const float* __restrict__ part, const float* __restrict__ bias,
                       const float* __restrict__ bn, float* __restrict__ hout) {
  int i = blockIdx.x * 256 + threadIdx.x;  // 0..4095
  int b = i >> 9, j = i & 511;
  float s = bias[j];
  #pragma unroll
  for (int ks = 0; ks < 4; ++ks) s += part[((size_t)ks * 8 + b) * 512 + j];
  float sc = bn[j] * rsqrtf(bn[3 * 512 + j] + EPSF);
  s = (s - bn[2 * 512 + j]) * sc + bn[512 + j];
  hout[i] = fmaxf(s, 0.f);
}

extern "C" void kernel_launch(void* const* d_in, const int* in_sizes, int n_in,
                              void* d_out, int out_size, void* d_ws, size_t ws_size,
                              hipStream_t stream) {
  const float* sv      = (const float*)d_in[0];
  const float* inp     = (const float*)d_in[1];
  const float* tl_win  = (const float*)d_in[2];
  const float* tl_bin  = (const float*)d_in[3];
  const float* tl_wout = (const float*)d_in[4];
  const float* tl_bout = (const float*)d_in[5];
  const float* tl_w1   = (const float*)d_in[6];
  const float* tl_b1   = (const float*)d_in[7];
  const float* tl_w2   = (const float*)d_in[8];
  const float* tl_b2   = (const float*)d_in[9];
  const float* tl_ln1g = (const float*)d_in[10];
  const float* tl_ln1b = (const float*)d_in[11];
  const float* tl_ln2g = (const float*)d_in[12];
  const float* tl_ln2b = (const float*)d_in[13];
  const float* fg_w0   = (const float*)d_in[14];
  const float* fg_b0   = (const float*)d_in[15];
  const float* fg_w1   = (const float*)d_in[16];
  const float* fg_b1   = (const float*)d_in[17];
  const float* fg_w2   = (const float*)d_in[18];
  const float* fg_b2   = (const float*)d_in[19];
  const float* fbn0    = (const float*)d_in[20];
  const float* fbn1    = (const float*)d_in[21];
  const float* fbn2    = (const float*)d_in[22];
  const float* rc_w0   = (const float*)d_in[23];
  const float* rc_b0   = (const float*)d_in[24];
  const float* rc_w1   = (const float*)d_in[25];
  const float* rc_b1   = (const float*)d_in[26];
  const float* rc_w2   = (const float*)d_in[27];
  const float* rc_b2   = (const float*)d_in[28];
  const float* rbn0    = (const float*)d_in[29];
  const float* rbn1    = (const float*)d_in[30];
  const float* rbn2    = (const float*)d_in[31];
  const float* fl_w0   = (const float*)d_in[32];
  const float* fl_b0   = (const float*)d_in[33];
  const float* fl_w1   = (const float*)d_in[34];
  const float* fl_b1   = (const float*)d_in[35];
  const float* lbn0    = (const float*)d_in[36];
  const float* lbn1    = (const float*)d_in[37];
  (void)in_sizes; (void)n_in; (void)out_size; (void)ws_size;

  float* wsp = (float*)d_ws;
  float* x      = wsp;                        // B*N*F      = 1048576
  float* qkv    = x + BB * NN * FF;           // 3145728-float region
  float* a      = qkv + BB * NN * 192;        // B*N*F      = 1048576
  float* scores = a + BB * NN * FF;           // B*N        = 16384
  int*   idxb   = (int*)(scores + BB * NN);   // B*TOPK     = 128
  float* r2g    = (float*)(idxb + BB * TOPK); // B*8192     = 65536
  float* h1g    = r2g + BB * 8192;            // B*1024     = 8192
  // FFN weight image: [l][chg][4 planes][4096 u16] = 1M u16 = 2MB
  unsigned short* img = (unsigned short*)(h1g + BB * 1024);
  // qkv region carve-out: Q fp32 (1M floats) | kp bf16 (1M u16) | vp bf16 (1M u16)
  float* qbuf = qkv;
  unsigned short* kp = (unsigned short*)(qkv + BB * NN * FF);
  unsigned short* vp = kp + (size_t)BB * NHEAD * NN * HD;
  float* part = qkv;        // FFN & FC-1 split-K partials reuse qkv region
  float* part2 = qkv + 65536;  // FC-2 partials (4*8*512 floats)

  float* out = (float*)d_out;  // fp32: h at [0,4096), idx-as-float at [4096,4224)

  k_transpose<<<(BB * NN * FF) / 256, 256, 0, stream>>>(sv, x);
  k_wimg<<<(NLAYER * 32 * 4 * 4096) / 256, 256, 0, stream>>>(tl_w1, tl_w2, img);

  for (int l = 0; l < NLAYER; ++l) {
    k_qkv3<<<dim3(BB * NN / 64, 3), 256, 0, stream>>>(x, tl_win + l * 192 * FF,
                                                      tl_bin + l * 192, qbuf,
                                                      (uint4*)kp, (uint4*)vp);
    k_attn11<<<dim3(NN / 64, NHEAD, BB), 256, 0, stream>>>(qbuf, (const uint4*)kp,
                                                           (const unsigned*)vp, a);
    k_proj2<<<BB * NN / 64, 256, 0, stream>>>(a, tl_wout + l * FF * FF, tl_bout + l * FF,
                                              tl_ln1g + l * FF, tl_ln1b + l * FF, x);
    k_ffn7<<<dim3(BB * NN / 128, 4), 256, 0, stream>>>(x, (const char*)(img + (size_t)l * 524288),
                                                       tl_b1 + l * 2048, part);
    k_ffn_ln<<<BB * NN / 4, 256, 0, stream>>>(part, tl_b2 + l * FF,
                                              tl_ln2g + l * FF, tl_ln2b + l * FF, x);
  }

  k_fg2<<<BB * NN / 64, 256, 0, stream>>>(x, fg_w0, fg_b0, fbn0, fg_w1, fg_b1, fbn1,
                                          fg_w2, fg_b2, fbn2, scores);
  k_topk2<<<BB, 256, 0, stream>>>(scores, idxb, out + BB * 512);
  k_group<<<dim3(TOPK, BB, 2), 512, 0, stream>>>(inp, idxb, rc_w0, rc_b0, rbn0,
                                                 rc_w1, rc_b1, rbn1, rc_w2, rc_b2, rbn2, r2g);
  k_fl2<<<dim3(64, 8), 256, 0, stream>>>(r2g, fl_w0, part);
  k_flc<<<32, 256, 0, stream>>>(part, fl_b0, lbn0, h1g);
  k_fl3<<<dim3(32, 4), 256, 0, stream>>>(h1g, fl_w1, part2);
  k_flc2<<<16, 256, 0, stream>>>(part2, fl_b1, lbn1, out);
}

// Round 11
// 413.434 us; speedup vs baseline: 1.8064x; 1.0140x over previous
//
#include <hip/hip_runtime.h>
#include <hip/hip_bf16.h>
#include <math.h>

#define BB 8
#define NN 2048
#define FF 64
#define DD 6
#define NSAMP 64
#define TOPK 16
#define NHEAD 8
#define HD 8
#define NLAYER 2
#define EPSF 1e-5f
#define R2 0.09f

typedef short short8 __attribute__((ext_vector_type(8)));
typedef float f32x4 __attribute__((ext_vector_type(4)));
typedef unsigned uint4v __attribute__((ext_vector_type(4)));
typedef unsigned int u32;

// split-pack: u32 = (bf16_hi << 16) | bf16_lo, both RNE. x ≈ hi + lo, err ~2^-16 rel.
__device__ inline unsigned pk2(float x) {
  unsigned b = __float_as_uint(x);
  unsigned hi = (b + 0x7fffu + ((b >> 16) & 1u)) >> 16;
  float r = x - __uint_as_float(hi << 16);
  unsigned c = __float_as_uint(r);
  unsigned lo = (c + 0x7fffu + ((c >> 16) & 1u)) >> 16;
  return (hi << 16) | lo;
}

__device__ inline unsigned short bf16r(float x) {  // RNE bf16
  unsigned b = __float_as_uint(x);
  return (unsigned short)((b + 0x7fffu + ((b >> 16) & 1u)) >> 16);
}

// async global->LDS, 16B per lane (dest = wave-uniform base + lane*16)
__device__ __forceinline__ void gl16(const void* g, void* l) {
  __builtin_amdgcn_global_load_lds((const __attribute__((address_space(1))) u32*)g,
                                   (__attribute__((address_space(3))) u32*)l, 16, 0, 0);
}

// ---------------- transpose sortvec (B,1,F,N) -> x (B,N,F) ----------------
__global__ void k_transpose(const float* __restrict__ sv, float* __restrict__ x) {
  int i = blockIdx.x * 256 + threadIdx.x;
  if (i >= BB * NN * FF) return;
  int f = i % FF;
  int n = (i / FF) % NN;
  int b = i / (FF * NN);
  x[i] = sv[(b * FF + f) * NN + n];
}

// ---- pack fp32 weights -> separate bf16 hi/lo planes ----
__global__ void k_wpack16(const float* __restrict__ w, unsigned short* __restrict__ hi,
                          unsigned short* __restrict__ lo, int n) {
  int i = blockIdx.x * 256 + threadIdx.x;
  if (i < n) {
    unsigned p = pk2(w[i]);
    hi[i] = (unsigned short)(p >> 16);
    lo[i] = (unsigned short)(p & 0xffffu);
  }
}

// ---- pack FFN weights into the exact per-chunk LDS byte image (pre-swizzled).
__global__ void k_wimg(const float* __restrict__ w1, const float* __restrict__ w2,
                       unsigned short* __restrict__ img) {
  int i = blockIdx.x * 256 + threadIdx.x;     // u16 index, total 2*32*4*4096
  int e = i & 4095;
  int plane = (i >> 12) & 3;
  int chg = (i >> 14) & 31;
  int l = i >> 19;
  int r = e >> 6, sh = (e >> 3) & 7, inner = e & 7;
  int s = sh ^ (r & 7);
  float v;
  if (plane < 2) v = w1[((size_t)(l * 2048 + chg * 64 + r)) * 64 + s * 8 + inner];
  else           v = w2[((size_t)(l * 64 + r)) * 2048 + chg * 64 + s * 8 + inner];
  unsigned p = pk2(v);
  img[i] = (unsigned short)((plane & 1) ? (p & 0xffffu) : (p >> 16));
}

// ---- qkv v4: split-bf16 MFMA GEMM (ffn7 fragment pattern), no input staging.
// Wave w computes rows row0+w*16..+15, cols col0..col0+63 (y selects Q/K/V).
// Weights read directly from packed hi/lo planes (L2-hot, 24K elems).
// Epilogues keep the v3 l16-gather stages, re-indexed to MFMA C-layout.
__global__ void __launch_bounds__(256)
k_qkv4(const float* __restrict__ x, const unsigned short* __restrict__ wqh,
       const unsigned short* __restrict__ wql, const float* __restrict__ bin,
       float* __restrict__ qbuf, uint4* __restrict__ kp4, uint4* __restrict__ vp4) {
  __shared__ __attribute__((aligned(16))) unsigned short l16[64 * 72];
  int row0 = blockIdx.x * 64, y = blockIdx.y, col0 = y * 64;
  int t = threadIdx.x, lane = t & 63, w = t >> 6;
  int nIdx = lane & 15, lq = lane >> 4;
  // A-frags: row = row0 + w*16 + nIdx, k = kbi*32 + lq*8 + j
  short8 axh[2], axl[2];
  #pragma unroll
  for (int kbi = 0; kbi < 2; ++kbi) {
    const float* xr = x + (size_t)(row0 + w * 16 + nIdx) * 64 + kbi * 32 + lq * 8;
    #pragma unroll
    for (int j = 0; j < 8; ++j) {
      unsigned p = pk2(xr[j]);
      axh[kbi][j] = (short)(p >> 16);
      axl[kbi][j] = (short)(p & 0xffffu);
    }
  }
  f32x4 acc[4];
  #pragma unroll
  for (int tn = 0; tn < 4; ++tn) acc[tn] = (f32x4){0.f, 0.f, 0.f, 0.f};
  #pragma unroll
  for (int kbi = 0; kbi < 2; ++kbi)
    #pragma unroll
    for (int tn = 0; tn < 4; ++tn) {
      size_t wo = (size_t)(col0 + tn * 16 + nIdx) * 64 + kbi * 32 + lq * 8;
      short8 bh = *(const short8*)(wqh + wo);
      short8 bl = *(const short8*)(wql + wo);
      acc[tn] = __builtin_amdgcn_mfma_f32_16x16x32_bf16(axh[kbi], bh, acc[tn], 0, 0, 0);
      acc[tn] = __builtin_amdgcn_mfma_f32_16x16x32_bf16(axh[kbi], bl, acc[tn], 0, 0, 0);
      acc[tn] = __builtin_amdgcn_mfma_f32_16x16x32_bf16(axl[kbi], bh, acc[tn], 0, 0, 0);
    }
  int b = row0 >> 11, n0 = row0 & (NN - 1);
  if (y == 0) {
    #pragma unroll
    for (int tn = 0; tn < 4; ++tn)
      #pragma unroll
      for (int r = 0; r < 4; ++r) {
        int c = tn * 16 + nIdx;
        qbuf[(size_t)(row0 + w * 16 + lq * 4 + r) * 64 + c] = acc[tn][r] + bin[c];
      }
    return;
  }
  if (y == 1) {
    #pragma unroll
    for (int tn = 0; tn < 4; ++tn)
      #pragma unroll
      for (int r = 0; r < 4; ++r) {
        int c = tn * 16 + nIdx;
        l16[(w * 16 + lq * 4 + r) * 72 + c] = bf16r(acc[tn][r] + bin[64 + c]);
      }
    __syncthreads();
    #pragma unroll
    for (int i = 0; i < 2; ++i) {
      int idx = t + i * 256;
      int h = idx >> 6, tok = idx & 63;
      uint4 v = *(const uint4*)(l16 + tok * 72 + h * 8);
      kp4[(size_t)(b * NHEAD + h) * NN + n0 + tok] = v;
    }
  } else {
    #pragma unroll
    for (int tn = 0; tn < 4; ++tn)
      #pragma unroll
      for (int r = 0; r < 4; ++r) {
        int c = tn * 16 + nIdx;
        l16[c * 72 + (w * 16 + lq * 4 + r)] = bf16r(acc[tn][r] + bin[128 + c]);  // transposed
      }
    __syncthreads();
    #pragma unroll
    for (int i = 0; i < 2; ++i) {
      int idx = t + i * 256;
      int c = idx >> 3, seg = idx & 7;
      uint4 v = *(const uint4*)(l16 + c * 72 + seg * 8);
      vp4[(size_t)(b * 64 + c) * (NN / 8) + (n0 >> 3) + seg] = v;
    }
  }
}

// ---- attention v11: swapped-operand flash (permlane32_swap redistribution) ----
__global__ void __launch_bounds__(256, 8)
k_attn11(const float* __restrict__ q, const uint4* __restrict__ kp4,
         const unsigned* __restrict__ vp32, float* __restrict__ a) {
  __shared__ uint4 kb4[256];                                            // 4 KB
  __shared__ __attribute__((aligned(16))) unsigned short vb16[9 * 264]; // 4.6 KB
  int t = threadIdx.x;
  int lane = t & 63, w = t >> 6;
  int nIdx = lane & 15, lq = lane >> 4;
  int h = blockIdx.y, b = blockIdx.z;
  int qwb = blockIdx.x * 64 + w * 16;
  int bh = b * NHEAD + h;
  const float kf = 0.35355339059327373f * 1.4426950408889634f;  // scale*log2e
  short8 qF = {0, 0, 0, 0, 0, 0, 0, 0};
  if (lq == 0) {
    const float* qr = q + ((size_t)(b * NN + qwb + nIdx)) * 64 + h * HD;
    #pragma unroll
    for (int j = 0; j < 8; ++j) qF[j] = (short)bf16r(qr[j] * kf);
  }
  f32x4 acc0 = {0.f, 0.f, 0.f, 0.f};
  f32x4 acc1 = {0.f, 0.f, 0.f, 0.f};
  const uint4* kbase = kp4 + (size_t)bh * NN;
  const unsigned* vbase = vp32 + (size_t)bh * HD * (NN / 2);
  int vn = nIdx < 9 ? nIdx : 8;
  int voff = ((lq & 1) << 2) + ((lq >> 1) << 4);  // key-group base per quad
  if (t < 132) ((unsigned*)(vb16 + 8 * 264))[t] = 0x3f803f80u;
  uint4 kreg = kbase[t];
  unsigned vreg[4];
  #pragma unroll
  for (int i = 0; i < 4; ++i) {
    int g = t + i * 256;
    vreg[i] = vbase[(g >> 7) * (NN / 2) + (g & 127)];
  }
  for (int kc = 0; kc < NN; kc += 256) {
    __syncthreads();
    kb4[t] = kreg;
    #pragma unroll
    for (int i = 0; i < 4; ++i) {
      int g = t + i * 256;
      ((unsigned*)vb16)[(g >> 7) * 132 + (g & 127)] = vreg[i];
    }
    __syncthreads();
    if (kc + 256 < NN) {
      kreg = kbase[kc + 256 + t];
      #pragma unroll
      for (int i = 0; i < 4; ++i) {
        int g = t + i * 256;
        vreg[i] = vbase[(g >> 7) * (NN / 2) + ((kc + 256) >> 1) + (g & 127)];
      }
    }
    #pragma unroll
    for (int s = 0; s < 8; ++s) {
      int kb = s * 32;
      unsigned pk_[4];
      #pragma unroll
      for (int half = 0; half < 2; ++half) {
        int key = kb + half * 16 + nIdx;
        short8 aK = *(const short8*)(kb4 + key);  // unmasked: k>=8 lanes * 0
        f32x4 c = {0.f, 0.f, 0.f, 0.f};
        __builtin_amdgcn_s_setprio(1);
        c = __builtin_amdgcn_mfma_f32_16x16x32_bf16(aK, qF, c, 0, 0, 0);
        __builtin_amdgcn_s_setprio(0);
        float p0 = __builtin_amdgcn_exp2f(c[0]);
        float p1 = __builtin_amdgcn_exp2f(c[1]);
        float p2 = __builtin_amdgcn_exp2f(c[2]);
        float p3 = __builtin_amdgcn_exp2f(c[3]);
        unsigned r0, r1;
        asm("v_cvt_pk_bf16_f32 %0, %1, %2" : "=v"(r0) : "v"(p0), "v"(p1));
        asm("v_cvt_pk_bf16_f32 %0, %1, %2" : "=v"(r1) : "v"(p2), "v"(p3));
        pk_[half * 2]     = r0;
        pk_[half * 2 + 1] = r1;
      }
      unsigned a02 = pk_[0], b02 = pk_[2];
      unsigned a13 = pk_[1], b13 = pk_[3];
      asm("v_permlane32_swap_b32 %0, %1" : "+v"(a02), "+v"(b02));
      asm("v_permlane32_swap_b32 %0, %1" : "+v"(a13), "+v"(b13));
      uint4v bw;
      bw[0] = a02;
      bw[1] = a13;
      bw[2] = b02;
      bw[3] = b13;
      short8 bP = *(short8*)&bw;
      int vo = vn * 264 + kb + voff;
      uint2 v0 = *(const uint2*)(vb16 + vo);
      uint2 v1 = *(const uint2*)(vb16 + vo + 8);
      uint4v av;
      av[0] = v0.x; av[1] = v0.y; av[2] = v1.x; av[3] = v1.y;
      short8 aV = *(short8*)&av;
      __builtin_amdgcn_s_setprio(1);
      if (s & 1) acc1 = __builtin_amdgcn_mfma_f32_16x16x32_bf16(aV, bP, acc1, 0, 0, 0);
      else       acc0 = __builtin_amdgcn_mfma_f32_16x16x32_bf16(aV, bP, acc0, 0, 0, 0);
      __builtin_amdgcn_s_setprio(0);
    }
  }
  f32x4 acc;
  acc[0] = acc0[0] + acc1[0];
  acc[1] = acc0[1] + acc1[1];
  acc[2] = acc0[2] + acc1[2];
  acc[3] = acc0[3] + acc1[3];
  float lr = __shfl(acc[0], 32 + nIdx);
  if (lq < 2) {
    int row = qwb + nIdx;
    float4 o;
    o.x = acc[0] / lr; o.y = acc[1] / lr; o.z = acc[2] / lr; o.w = acc[3] / lr;
    *(float4*)(a + ((size_t)(b * NN + row)) * 64 + h * HD + lq * 4) = o;
  }
}

// ------- proj v3: split-bf16 MFMA + residual + LN in MFMA C-layout. No LDS.
// Row reduce: each row's 64 cols = 4 tn x 16 nIdx lanes -> shfl_xor {1,2,4,8}.
__global__ void __launch_bounds__(256)
k_proj3(const float* __restrict__ a, const unsigned short* __restrict__ woh,
        const unsigned short* __restrict__ wol, const float* __restrict__ bout,
        const float* __restrict__ g, const float* __restrict__ be,
        float* __restrict__ x) {
  int row0 = blockIdx.x * 64;
  int t = threadIdx.x, lane = t & 63, w = t >> 6;
  int nIdx = lane & 15, lq = lane >> 4;
  short8 axh[2], axl[2];
  #pragma unroll
  for (int kbi = 0; kbi < 2; ++kbi) {
    const float* ar = a + (size_t)(row0 + w * 16 + nIdx) * 64 + kbi * 32 + lq * 8;
    #pragma unroll
    for (int j = 0; j < 8; ++j) {
      unsigned p = pk2(ar[j]);
      axh[kbi][j] = (short)(p >> 16);
      axl[kbi][j] = (short)(p & 0xffffu);
    }
  }
  f32x4 acc[4];
  #pragma unroll
  for (int tn = 0; tn < 4; ++tn) acc[tn] = (f32x4){0.f, 0.f, 0.f, 0.f};
  #pragma unroll
  for (int kbi = 0; kbi < 2; ++kbi)
    #pragma unroll
    for (int tn = 0; tn < 4; ++tn) {
      size_t wo = (size_t)(tn * 16 + nIdx) * 64 + kbi * 32 + lq * 8;
      short8 bh = *(const short8*)(woh + wo);
      short8 bl = *(const short8*)(wol + wo);
      acc[tn] = __builtin_amdgcn_mfma_f32_16x16x32_bf16(axh[kbi], bh, acc[tn], 0, 0, 0);
      acc[tn] = __builtin_amdgcn_mfma_f32_16x16x32_bf16(axh[kbi], bl, acc[tn], 0, 0, 0);
      acc[tn] = __builtin_amdgcn_mfma_f32_16x16x32_bf16(axl[kbi], bh, acc[tn], 0, 0, 0);
    }
  #pragma unroll
  for (int r = 0; r < 4; ++r) {
    int row = row0 + w * 16 + lq * 4 + r;
    float val[4], s = 0.f, sq = 0.f;
    #pragma unroll
    for (int tn = 0; tn < 4; ++tn) {
      int c = tn * 16 + nIdx;
      val[tn] = x[(size_t)row * 64 + c] + bout[c] + acc[tn][r];
      s += val[tn]; sq += val[tn] * val[tn];
    }
    #pragma unroll
    for (int off = 1; off < 16; off <<= 1) { s += __shfl_xor(s, off); sq += __shfl_xor(sq, off); }
    float mean = s * (1.f / 64.f);
    float var = sq * (1.f / 64.f) - mean * mean;
    float rstd = rsqrtf(var + EPSF);
    #pragma unroll
    for (int tn = 0; tn < 4; ++tn) {
      int c = tn * 16 + nIdx;
      x[(size_t)row * 64 + c] = (val[tn] - mean) * rstd * g[c] + be[c];
    }
  }
}

// ------- FFN v7: global_load_lds staging, counted vmcnt, raw s_barriers ----
__global__ void __launch_bounds__(256, 2)
k_ffn7(const float* __restrict__ x, const char* __restrict__ img,
       const float* __restrict__ b1, float* __restrict__ part) {
  __shared__ __attribute__((aligned(16))) char W1b[2][16384];
  __shared__ __attribute__((aligned(16))) char W2b[16384];
  __shared__ __attribute__((aligned(16))) unsigned short hpl[2][128 * 64];
  int row0 = blockIdx.x * 128;
  int ks = blockIdx.y, kc = ks * 512;
  int t = threadIdx.x, lane = t & 63, wv = t >> 6;
  int lm = lane & 15, lq = lane >> 4;
  const char* ibase = img + (size_t)ks * 8 * 32768;

  short8 axh[2][2], axl[2][2];
  #pragma unroll
  for (int m = 0; m < 2; ++m)
    #pragma unroll
    for (int kbi = 0; kbi < 2; ++kbi) {
      const float* xr = x + (size_t)(row0 + m * 64 + wv * 16 + lm) * 64 + kbi * 32 + lq * 8;
      #pragma unroll
      for (int j = 0; j < 8; ++j) {
        unsigned p = pk2(xr[j]);
        axh[m][kbi][j] = (short)(p >> 16);
        axl[m][kbi][j] = (short)(p & 0xffffu);
      }
    }
  float bv[8][4];
  #pragma unroll
  for (int ch = 0; ch < 8; ++ch)
    #pragma unroll
    for (int tn = 0; tn < 4; ++tn)
      bv[ch][tn] = b1[kc + ch * 64 + tn * 16 + lm];
  asm volatile("s_waitcnt vmcnt(0)" ::: "memory");
  __builtin_amdgcn_sched_barrier(0);
  #pragma unroll
  for (int i = 0; i < 4; ++i)
    gl16(ibase + i * 4096 + t * 16, &W1b[0][i * 4096 + t * 16]);

  f32x4 acc[2][4];
  #pragma unroll
  for (int m = 0; m < 2; ++m)
    #pragma unroll
    for (int tn = 0; tn < 4; ++tn) acc[m][tn] = (f32x4){0.f, 0.f, 0.f, 0.f};

  #pragma unroll
  for (int ch = 0; ch < 8; ++ch) {
    const int p = ch & 1;
    const char* cbase = ibase + ch * 32768;
    #pragma unroll
    for (int i = 0; i < 4; ++i)
      gl16(cbase + 16384 + i * 4096 + t * 16, &W2b[i * 4096 + t * 16]);
    if (ch < 7) {
      #pragma unroll
      for (int i = 0; i < 4; ++i)
        gl16(cbase + 32768 + i * 4096 + t * 16, &W1b[p ^ 1][i * 4096 + t * 16]);
    }
    if (ch < 7) { asm volatile("s_waitcnt vmcnt(8)" ::: "memory"); }
    else        { asm volatile("s_waitcnt vmcnt(4)" ::: "memory"); }
    __builtin_amdgcn_sched_barrier(0);
    __builtin_amdgcn_s_barrier();
    __builtin_amdgcn_sched_barrier(0);
    const char* P0h = W1b[p];
    const char* P0l = W1b[p] + 8192;
    f32x4 h4[2][4];
    #pragma unroll
    for (int m = 0; m < 2; ++m)
      #pragma unroll
      for (int tn = 0; tn < 4; ++tn) h4[m][tn] = (f32x4){0.f, 0.f, 0.f, 0.f};
    #pragma unroll
    for (int kbi = 0; kbi < 2; ++kbi) {
      int sw = (((kbi * 4 + lq) ^ (lm & 7)) << 4);
      #pragma unroll
      for (int tn = 0; tn < 4; ++tn) {
        int brow = tn * 16 + lm;
        short8 bhi = *(const short8*)(P0h + brow * 128 + sw);
        short8 blo = *(const short8*)(P0l + brow * 128 + sw);
        #pragma unroll
        for (int m = 0; m < 2; ++m) {
          h4[m][tn] = __builtin_amdgcn_mfma_f32_16x16x32_bf16(axh[m][kbi], bhi, h4[m][tn], 0, 0, 0);
          h4[m][tn] = __builtin_amdgcn_mfma_f32_16x16x32_bf16(axh[m][kbi], blo, h4[m][tn], 0, 0, 0);
          h4[m][tn] = __builtin_amdgcn_mfma_f32_16x16x32_bf16(axl[m][kbi], bhi, h4[m][tn], 0, 0, 0);
        }
      }
    }
    #pragma unroll
    for (int m = 0; m < 2; ++m)
      #pragma unroll
      for (int tn = 0; tn < 4; ++tn)
        #pragma unroll
        for (int r = 0; r < 4; ++r) {
          float hv = fmaxf(h4[m][tn][r] + bv[ch][tn], 0.f);
          unsigned u = __float_as_uint(hv);
          float resid = hv - __uint_as_float(u & 0xffff0000u);
          unsigned c2 = __float_as_uint(resid);
          int hrow = m * 64 + wv * 16 + lq * 4 + r, hcol = tn * 16 + lm;
          int off = hrow * 128 + (((hcol >> 3) ^ (hrow & 7)) << 4) + ((hcol & 7) << 1);
          *(unsigned short*)((char*)hpl[0] + off) = (unsigned short)(u >> 16);
          *(unsigned short*)((char*)hpl[1] + off) =
              (unsigned short)((c2 + 0x7fffu + ((c2 >> 16) & 1u)) >> 16);
        }
    if (ch < 7) { asm volatile("s_waitcnt vmcnt(4)" ::: "memory"); }
    else        { asm volatile("s_waitcnt vmcnt(0)" ::: "memory"); }
    __builtin_amdgcn_sched_barrier(0);
    __builtin_amdgcn_s_barrier();
    __builtin_amdgcn_sched_barrier(0);
    const char* P1h = W2b;
    const char* P1l = W2b + 8192;
    #pragma unroll
    for (int kbi = 0; kbi < 2; ++kbi) {
      short8 a2h[2], a2l[2];
      #pragma unroll
      for (int m = 0; m < 2; ++m) {
        int arow = m * 64 + wv * 16 + lm;
        int swa = (((kbi * 4 + lq) ^ (arow & 7)) << 4);
        a2h[m] = *(const short8*)((const char*)hpl[0] + arow * 128 + swa);
        a2l[m] = *(const short8*)((const char*)hpl[1] + arow * 128 + swa);
      }
      int swb = (((kbi * 4 + lq) ^ (lm & 7)) << 4);
      #pragma unroll
      for (int tn = 0; tn < 4; ++tn) {
        int brow = tn * 16 + lm;
        short8 bhi = *(const short8*)(P1h + brow * 128 + swb);
        short8 blo = *(const short8*)(P1l + brow * 128 + swb);
        #pragma unroll
        for (int m = 0; m < 2; ++m) {
          acc[m][tn] = __builtin_amdgcn_mfma_f32_16x16x32_bf16(a2h[m], bhi, acc[m][tn], 0, 0, 0);
          acc[m][tn] = __builtin_amdgcn_mfma_f32_16x16x32_bf16(a2h[m], blo, acc[m][tn], 0, 0, 0);
          acc[m][tn] = __builtin_amdgcn_mfma_f32_16x16x32_bf16(a2l[m], bhi, acc[m][tn], 0, 0, 0);
        }
      }
    }
    __builtin_amdgcn_s_barrier();
    __builtin_amdgcn_sched_barrier(0);
  }
  float* fb = (float*)hpl;
  #pragma unroll
  for (int m = 0; m < 2; ++m)
    #pragma unroll
    for (int tn = 0; tn < 4; ++tn)
      #pragma unroll
      for (int r = 0; r < 4; ++r) {
        int row = m * 64 + wv * 16 + lq * 4 + r;
        int col = (tn * 16 + lm) ^ ((row & 7) << 2);
        fb[row * 64 + col] = acc[m][tn][r];
      }
  __syncthreads();
  float* pb = part + (size_t)ks * (BB * NN * 64);
  #pragma unroll
  for (int i = 0; i < 8; ++i) {
    int idx = t * 4 + i * 1024;
    int row = idx >> 6, c0 = idx & 63;
    int c0s = c0 ^ ((row & 7) << 2);
    float4 v = *(const float4*)(fb + row * 64 + c0s);
    *(float4*)(pb + (size_t)(row0 + row) * 64 + c0) = v;
  }
}

// ------- combine 4 partials + residual + b2 + LN; one wave per row ---------
__global__ void k_ffn_ln(const float* __restrict__ part, const float* __restrict__ b2,
                         const float* __restrict__ g, const float* __restrict__ be,
                         float* __restrict__ x) {
  int row = blockIdx.x * 4 + (threadIdx.x >> 6);
  int j = threadIdx.x & 63;
  size_t o = (size_t)row * 64 + j;
  const size_t S = (size_t)BB * NN * 64;
  float val = x[o] + b2[j] + ((part[o] + part[o + S]) + (part[o + 2 * S] + part[o + 3 * S]));
  float s = val;
  for (int off = 32; off; off >>= 1) s += __shfl_xor(s, off);
  s *= (1.f / 64.f);
  float d = val - s;
  float v = d * d;
  for (int off = 32; off; off >>= 1) v += __shfl_xor(v, off);
  v *= (1.f / 64.f);
  x[o] = d * rsqrtf(v + EPSF) * g[j] + be[j];
}

// ------- score head tiled ----------
__global__ void k_fg2(const float* __restrict__ x,
                      const float* __restrict__ w0, const float* __restrict__ b0, const float* __restrict__ bn0,
                      const float* __restrict__ w1, const float* __restrict__ b1, const float* __restrict__ bn1,
                      const float* __restrict__ w2, const float* __restrict__ b2, const float* __restrict__ bn2,
                      float* __restrict__ scores) {
  __shared__ float xs[64 * 68];
  __shared__ float ws[64 * 68];
  __shared__ float s0s[64 * 68];
  __shared__ float s1s[64 * 20];
  int row0 = blockIdx.x * 64;
  int t = threadIdx.x;
  #pragma unroll
  for (int i = 0; i < 4; ++i) {
    int q = t + i * 256, r = q >> 4, c = (q & 15) * 4;
    *(float4*)(xs + r * 68 + c) = *(const float4*)(x + (size_t)(row0 + r) * 64 + c);
    *(float4*)(ws + r * 68 + c) = *(const float4*)(w0 + r * 64 + c);
  }
  __syncthreads();
  int tx = t & 15, ty = t >> 4;
  float acc[4][4] = {};
  for (int f = 0; f < 64; f += 4) {
    float4 xv[4], wv[4];
    #pragma unroll
    for (int ri = 0; ri < 4; ++ri) xv[ri] = *(const float4*)(xs + (ty * 4 + ri) * 68 + f);
    #pragma unroll
    for (int ci = 0; ci < 4; ++ci) wv[ci] = *(const float4*)(ws + (tx + 16 * ci) * 68 + f);
    #pragma unroll
    for (int ri = 0; ri < 4; ++ri)
      #pragma unroll
      for (int ci = 0; ci < 4; ++ci)
        acc[ri][ci] += xv[ri].x * wv[ci].x + xv[ri].y * wv[ci].y +
                       xv[ri].z * wv[ci].z + xv[ri].w * wv[ci].w;
  }
  #pragma unroll
  for (int ri = 0; ri < 4; ++ri)
    #pragma unroll
    for (int ci = 0; ci < 4; ++ci) {
      int c = tx + 16 * ci;
      float sc = bn0[c] * rsqrtf(bn0[192 + c] + EPSF);
      float v = (acc[ri][ci] + b0[c] - bn0[128 + c]) * sc + bn0[64 + c];
      s0s[(ty * 4 + ri) * 68 + c] = fmaxf(v, 0.f);
    }
  __syncthreads();
  {
    int rl = t & 63, j0 = t >> 6;
    #pragma unroll
    for (int i = 0; i < 4; ++i) {
      int j = j0 + 4 * i;
      float s = b1[j];
      const float* wr = w1 + j * 64;
      #pragma unroll 16
      for (int c = 0; c < 64; ++c) s += s0s[rl * 68 + c] * wr[c];
      float sc = bn1[j] * rsqrtf(bn1[48 + j] + EPSF);
      s = (s - bn1[32 + j]) * sc + bn1[16 + j];
      s1s[rl * 20 + j] = fmaxf(s, 0.f);
    }
  }
  __syncthreads();
  if (t < 64) {
    float s = b2[0];
    #pragma unroll
    for (int o = 0; o < 16; ++o) s += s1s[t * 20 + o] * w2[o];
    float sc = bn2[0] * rsqrtf(bn2[3] + EPSF);
    s = (s - bn2[2]) * sc + bn2[1];
    scores[row0 + t] = fmaxf(s, 0.f);
  }
}

// ---- top-k (k=16) ----
__global__ void k_topk2(const float* __restrict__ scores, int* __restrict__ idx,
                        float* __restrict__ out_idx) {
  int b = blockIdx.x, t = threadIdx.x;
  float v[8];
  int base = b * NN;
  #pragma unroll
  for (int u = 0; u < 8; ++u) v[u] = scores[base + t + 256 * u];
  __shared__ float wvs[4];
  __shared__ int wis[4];
  __shared__ int winner;
  unsigned taken = 0;
  for (int r = 0; r < TOPK; ++r) {
    float best = -1e30f; int bi = 1 << 30;
    #pragma unroll
    for (int u = 0; u < 8; ++u) {
      if (!((taken >> u) & 1)) {
        float vv = v[u]; int ii = t + 256 * u;
        if (vv > best || (vv == best && ii < bi)) { best = vv; bi = ii; }
      }
    }
    for (int off = 32; off; off >>= 1) {
      float ov = __shfl_xor(best, off);
      int oi = __shfl_xor(bi, off);
      if (ov > best || (ov == best && oi < bi)) { best = ov; bi = oi; }
    }
    if ((t & 63) == 0) { wvs[t >> 6] = best; wis[t >> 6] = bi; }
    __syncthreads();
    if (t == 0) {
      float B = wvs[0]; int I = wis[0];
      #pragma unroll
      for (int q = 1; q < 4; ++q)
        if (wvs[q] > B || (wvs[q] == B && wis[q] < I)) { B = wvs[q]; I = wis[q]; }
      winner = I;
      idx[b * TOPK + r] = I;
      out_idx[b * TOPK + r] = (float)I;
    }
    __syncthreads();
    int w = winner;
    if ((w & 255) == t) taken |= 1u << (w >> 8);
  }
}

// ---------------- ball query + 3 conv stages; grid z=2 splits conv2. ----
__global__ void __launch_bounds__(512)
k_group(const float* __restrict__ inp, const int* __restrict__ idx,
        const float* __restrict__ w0, const float* __restrict__ b0, const float* __restrict__ bn0,
        const float* __restrict__ w1, const float* __restrict__ b1, const float* __restrict__ bn1,
        const float* __restrict__ w2, const float* __restrict__ b2, const float* __restrict__ bn2,
        float* __restrict__ r2g) {
  __shared__ int swave[8 * 64];
  __shared__ int scnt[8];
  __shared__ int gidx[NSAMP];
  __shared__ __attribute__((aligned(16))) float gsh[65 * DD];
  __shared__ __attribute__((aligned(16))) float r0[128];
  __shared__ __attribute__((aligned(16))) float r1[256];
  int k = blockIdx.x, b = blockIdx.y, z = blockIdx.z;
  int t = threadIdx.x;
  int lane = t & 63, w = t >> 6;
  int qn = idx[b * TOPK + k];
  const float* px = inp + (size_t)b * DD * NN;
  float qx = px[qn], qy = px[NN + qn], qz = px[2 * NN + qn];
  {
    int cnt = 0;
    #pragma unroll
    for (int i = 0; i < 4; ++i) {
      int n = w * 256 + i * 64 + lane;
      float dx = px[n] - qx, dy = px[NN + n] - qy, dz = px[2 * NN + n] - qz;
      bool flag = (dx * dx + dy * dy + dz * dz <= R2);
      unsigned long long m = __ballot(flag);
      int pos = cnt + __popcll(m & ((1ull << lane) - 1ull));
      if (flag && pos < NSAMP) swave[w * 64 + pos] = n;
      cnt += (int)__popcll(m);
    }
    if (lane == 0) scnt[w] = cnt < NSAMP ? cnt : NSAMP;
  }
  __syncthreads();
  if (t < NSAMP) {
    int run = 0, val = -1;
    #pragma unroll
    for (int ww = 0; ww < 8; ++ww) {
      int c = scnt[ww];
      int loc = t - run;
      if (loc >= 0 && loc < c) val = swave[ww * 64 + loc];
      run += c;
    }
    gidx[t] = val;
  }
  __syncthreads();
  if (t < NSAMP) {
    int g0 = gidx[0];
    int gt = gidx[t];
    gidx[t] = (gt < 0) ? g0 : gt;
  }
  __syncthreads();
  if (t < 65 * DD) {
    int p = t / DD, d = t - p * DD;
    int n = (p == 0) ? qn : gidx[p - 1];
    gsh[t] = px[d * NN + n];
  }
  __syncthreads();
  {
    int c = t >> 2, part = t & 3;
    const float2* wr = (const float2*)(w0 + c * 390 + part * 98);
    const float2* gr = (const float2*)(gsh + part * 98);
    int n2 = (part == 3) ? 48 : 49;
    float s = 0.f;
    #pragma unroll 7
    for (int i = 0; i < n2; ++i) {
      float2 a = gr[i], ww = wr[i];
      s += a.x * ww.x + a.y * ww.y;
    }
    s += __shfl_xor(s, 1);
    s += __shfl_xor(s, 2);
    if (part == 0) {
      s += b0[c];
      float sc = bn0[c] * rsqrtf(bn0[384 + c] + EPSF);
      s = (s - bn0[256 + c]) * sc + bn0[128 + c];
      r0[c] = fmaxf(s, 0.f);
    }
  }
  __syncthreads();
  {
    int c = t >> 1, part = t & 1;
    const float4* wr = (const float4*)(w1 + c * 128 + part * 64);
    const float4* rr = (const float4*)(r0 + part * 64);
    float s0 = 0.f, s1 = 0.f, s2 = 0.f, s3 = 0.f;
    #pragma unroll 8
    for (int o = 0; o < 16; ++o) {
      float4 a = rr[o], ww = wr[o];
      s0 += a.x * ww.x; s1 += a.y * ww.y; s2 += a.z * ww.z; s3 += a.w * ww.w;
    }
    float s = (s0 + s1) + (s2 + s3);
    s += __shfl_xor(s, 1);
    if (part == 0) {
      s += b1[c];
      float sc = bn1[c] * rsqrtf(bn1[768 + c] + EPSF);
      s = (s - bn1[512 + c]) * sc + bn1[256 + c];
      r1[c] = fmaxf(s, 0.f);
    }
  }
  __syncthreads();
  {
    int c = z * 256 + (t >> 1), part = t & 1;
    const float4* wr = (const float4*)(w2 + c * 256 + part * 128);
    const float4* rr = (const float4*)(r1 + part * 128);
    float s0 = 0.f, s1 = 0.f, s2 = 0.f, s3 = 0.f;
    #pragma unroll 8
    for (int o = 0; o < 32; ++o) {
      float4 a = rr[o], ww = wr[o];
      s0 += a.x * ww.x; s1 += a.y * ww.y; s2 += a.z * ww.z; s3 += a.w * ww.w;
    }
    float s = (s0 + s1) + (s2 + s3);
    s += __shfl_xor(s, 1);
    if (part == 0) {
      s += b2[c];
      float sc = bn2[c] * rsqrtf(bn2[1536 + c] + EPSF);
      s = (s - bn2[1024 + c]) * sc + bn2[512 + c];
      r2g[b * 8192 + c * TOPK + k] = fmaxf(s, 0.f);
    }
  }
}

// ------- FC layer 1: batched GEMV, split-K 8 ----
__global__ void __launch_bounds__(256)
k_fl2(const float* __restrict__ hin, const float* __restrict__ w,
      float* __restrict__ part) {
  __shared__ float hs[8 * 1032];
  int j0 = blockIdx.x * 16;
  int kc = blockIdx.y * 1024;
  int t = threadIdx.x;
  int jj = t >> 4, l = t & 15;
  #pragma unroll
  for (int i = 0; i < 8; ++i) {
    int idx = t + i * 256;
    int b = idx >> 8, off = (idx & 255) * 4;
    *(float4*)(hs + b * 1032 + off) = *(const float4*)(hin + (size_t)b * 8192 + kc + off);
  }
  __syncthreads();
  const float* wr = w + (size_t)(j0 + jj) * 8192 + kc;
  float acc[8] = {};
  #pragma unroll
  for (int k = 0; k < 16; ++k) {
    float4 wv = *(const float4*)(wr + l * 4 + k * 64);
    #pragma unroll
    for (int b = 0; b < 8; ++b) {
      float4 hv = *(const float4*)(hs + b * 1032 + l * 4 + k * 64);
      acc[b] += wv.x * hv.x + wv.y * hv.y + wv.z * hv.z + wv.w * hv.w;
    }
  }
  #pragma unroll
  for (int b = 0; b < 8; ++b) {
    #pragma unroll
    for (int off = 1; off < 16; off <<= 1) acc[b] += __shfl_xor(acc[b], off);
  }
  if (l == 0) {
    #pragma unroll
    for (int b = 0; b < 8; ++b)
      part[((size_t)blockIdx.y * 8 + b) * 1024 + j0 + jj] = acc[b];
  }
}

// ------- combine 8 split-K partials + bias + BN + ReLU -> h1g ----
__global__ void k_flc(const float* __restrict__ part, const float* __restrict__ bias,
                      const float* __restrict__ bn, float* __restrict__ hout) {
  int i = blockIdx.x * 256 + threadIdx.x;  // 0..8191
  int b = i >> 10, j = i & 1023;
  float s = bias[j];
  #pragma unroll
  for (int ks = 0; ks < 8; ++ks) s += part[((size_t)ks * 8 + b) * 1024 + j];
  float sc = bn[j] * rsqrtf(bn[3 * 1024 + j] + EPSF);
  s = (s - bn[2 * 1024 + j]) * sc + bn[1024 + j];
  hout[i] = fmaxf(s, 0.f);
}

// ------- FC layer 2: batched GEMV, split-K 4 ----
__global__ void __launch_bounds__(256)
k_fl3(const float* __restrict__ hin, const float* __restrict__ w,
      float* __restrict__ part) {
  __shared__ float hs[8 * 264];
  int j0 = blockIdx.x * 16;
  int kc = blockIdx.y * 256;
  int t = threadIdx.x;
  int jj = t >> 4, l = t & 15;
  #pragma unroll
  for (int i = 0; i < 2; ++i) {
    int idx = t + i * 256;
    int b = idx >> 6, off = (idx & 63) * 4;
    *(float4*)(hs + b * 264 + off) = *(const float4*)(hin + (size_t)b * 1024 + kc + off);
  }
  __syncthreads();
  const float* wr = w + (size_t)(j0 + jj) * 1024 + kc;
  float acc[8] = {};
  #pragma unroll
  for (int k = 0; k < 4; ++k) {
    float4 wv = *(const float4*)(wr + l * 4 + k * 64);
    #pragma unroll
    for (int b = 0; b < 8; ++b) {
      float4 hv = *(const float4*)(hs + b * 264 + l * 4 + k * 64);
      acc[b] += wv.x * hv.x + wv.y * hv.y + wv.z * hv.z + wv.w * hv.w;
    }
  }
  #pragma unroll
  for (int b = 0; b < 8; ++b) {
    #pragma unroll
    for (int off = 1; off < 16; off <<= 1) acc[b] += __shfl_xor(acc[b], off);
  }
  if (l == 0) {
    #pragma unroll
    for (int b = 0; b < 8; ++b)
      part[((size_t)blockIdx.y * 8 + b) * 512 + j0 + jj] = acc[b];
  }
}

// ------- combine 4 split-K partials + bias + BN + ReLU -> out ----
__global__ void k_flc2(const float* __restrict__ part, const float* __restrict__ bias,
                       const float* __restrict__ bn, float* __restrict__ hout) {
  int i = blockIdx.x * 256 + threadIdx.x;  // 0..4095
  int b = i >> 9, j = i & 511;
  float s = bias[j];
  #pragma unroll
  for (int ks = 0; ks < 4; ++ks) s += part[((size_t)ks * 8 + b) * 512 + j];
  float sc = bn[j] * rsqrtf(bn[3 * 512 + j] + EPSF);
  s = (s - bn[2 * 512 + j]) * sc + bn[512 + j];
  hout[i] = fmaxf(s, 0.f);
}

extern "C" void kernel_launch(void* const* d_in, const int* in_sizes, int n_in,
                              void* d_out, int out_size, void* d_ws, size_t ws_size,
                              hipStream_t stream) {
  const float* sv      = (const float*)d_in[0];
  const float* inp     = (const float*)d_in[1];
  const float* tl_win  = (const float*)d_in[2];
  const float* tl_bin  = (const float*)d_in[3];
  const float* tl_wout = (const float*)d_in[4];
  const float* tl_bout = (const float*)d_in[5];
  const float* tl_w1   = (const float*)d_in[6];
  const float* tl_b1   = (const float*)d_in[7];
  const float* tl_w2   = (const float*)d_in[8];
  const float* tl_b2   = (const float*)d_in[9];
  const float* tl_ln1g = (const float*)d_in[10];
  const float* tl_ln1b = (const float*)d_in[11];
  const float* tl_ln2g = (const float*)d_in[12];
  const float* tl_ln2b = (const float*)d_in[13];
  const float* fg_w0   = (const float*)d_in[14];
  const float* fg_b0   = (const float*)d_in[15];
  const float* fg_w1   = (const float*)d_in[16];
  const float* fg_b1   = (const float*)d_in[17];
  const float* fg_w2   = (const float*)d_in[18];
  const float* fg_b2   = (const float*)d_in[19];
  const float* fbn0    = (const float*)d_in[20];
  const float* fbn1    = (const float*)d_in[21];
  const float* fbn2    = (const float*)d_in[22];
  const float* rc_w0   = (const float*)d_in[23];
  const float* rc_b0   = (const float*)d_in[24];
  const float* rc_w1   = (const float*)d_in[25];
  const float* rc_b1   = (const float*)d_in[26];
  const float* rc_w2   = (const float*)d_in[27];
  const float* rc_b2   = (const float*)d_in[28];
  const float* rbn0    = (const float*)d_in[29];
  const float* rbn1    = (const float*)d_in[30];
  const float* rbn2    = (const float*)d_in[31];
  const float* fl_w0   = (const float*)d_in[32];
  const float* fl_b0   = (const float*)d_in[33];
  const float* fl_w1   = (const float*)d_in[34];
  const float* fl_b1   = (const float*)d_in[35];
  const float* lbn0    = (const float*)d_in[36];
  const float* lbn1    = (const float*)d_in[37];
  (void)in_sizes; (void)n_in; (void)out_size; (void)ws_size;

  float* wsp = (float*)d_ws;
  float* x      = wsp;                        // B*N*F      = 1048576
  float* qkv    = x + BB * NN * FF;           // 3145728-float region
  float* a      = qkv + BB * NN * 192;        // B*N*F      = 1048576
  float* scores = a + BB * NN * FF;           // B*N        = 16384
  int*   idxb   = (int*)(scores + BB * NN);   // B*TOPK     = 128
  float* r2g    = (float*)(idxb + BB * TOPK); // B*8192     = 65536
  float* h1g    = r2g + BB * 8192;            // B*1024     = 8192
  // FFN weight image: [l][chg][4 planes][4096 u16] = 1M u16 = 2MB
  unsigned short* img = (unsigned short*)(h1g + BB * 1024);
  // qkv/proj weight hi/lo planes (after img)
  unsigned short* wqh = img + (size_t)NLAYER * 32 * 4 * 4096;
  unsigned short* wql = wqh + NLAYER * 192 * 64;
  unsigned short* woh = wql + NLAYER * 192 * 64;
  unsigned short* wol = woh + NLAYER * 64 * 64;
  // qkv region carve-out: Q fp32 (1M floats) | kp bf16 (1M u16) | vp bf16 (1M u16)
  float* qbuf = qkv;
  unsigned short* kp = (unsigned short*)(qkv + BB * NN * FF);
  unsigned short* vp = kp + (size_t)BB * NHEAD * NN * HD;
  float* part = qkv;        // FFN & FC-1 split-K partials reuse qkv region
  float* part2 = qkv + 65536;  // FC-2 partials (4*8*512 floats)

  float* out = (float*)d_out;  // fp32: h at [0,4096), idx-as-float at [4096,4224)

  k_transpose<<<(BB * NN * FF) / 256, 256, 0, stream>>>(sv, x);
  k_wimg<<<(NLAYER * 32 * 4 * 4096) / 256, 256, 0, stream>>>(tl_w1, tl_w2, img);
  k_wpack16<<<(NLAYER * 192 * 64) / 256, 256, 0, stream>>>(tl_win, wqh, wql, NLAYER * 192 * 64);
  k_wpack16<<<(NLAYER * 64 * 64) / 256, 256, 0, stream>>>(tl_wout, woh, wol, NLAYER * 64 * 64);

  for (int l = 0; l < NLAYER; ++l) {
    k_qkv4<<<dim3(BB * NN / 64, 3), 256, 0, stream>>>(x, wqh + l * 192 * 64,
                                                      wql + l * 192 * 64, tl_bin + l * 192,
                                                      qbuf, (uint4*)kp, (uint4*)vp);
    k_attn11<<<dim3(NN / 64, NHEAD, BB), 256, 0, stream>>>(qbuf, (const uint4*)kp,
                                                           (const unsigned*)vp, a);
    k_proj3<<<BB * NN / 64, 256, 0, stream>>>(a, woh + l * 64 * 64, wol + l * 64 * 64,
                                              tl_bout + l * FF,
                                              tl_ln1g + l * FF, tl_ln1b + l * FF, x);
    k_ffn7<<<dim3(BB * NN / 128, 4), 256, 0, stream>>>(x, (const char*)(img + (size_t)l * 524288),
                                                       tl_b1 + l * 2048, part);
    k_ffn_ln<<<BB * NN / 4, 256, 0, stream>>>(part, tl_b2 + l * FF,
                                              tl_ln2g + l * FF, tl_ln2b + l * FF, x);
  }

  k_fg2<<<BB * NN / 64, 256, 0, stream>>>(x, fg_w0, fg_b0, fbn0, fg_w1, fg_b1, fbn1,
                                          fg_w2, fg_b2, fbn2, scores);
  k_topk2<<<BB, 256, 0, stream>>>(scores, idxb, out + BB * 512);
  k_group<<<dim3(TOPK, BB, 2), 512, 0, stream>>>(inp, idxb, rc_w0, rc_b0, rbn0,
                                                 rc_w1, rc_b1, rbn1, rc_w2, rc_b2, rbn2, r2g);
  k_fl2<<<dim3(64, 8), 256, 0, stream>>>(r2g, fl_w0, part);
  k_flc<<<32, 256, 0, stream>>>(part, fl_b0, lbn0, h1g);
  k_fl3<<<dim3(32, 4), 256, 0, stream>>>(h1g, fl_w1, part2);
  k_flc2<<<16, 256, 0, stream>>>(part2, fl_b1, lbn1, out);
}